// Round 7
// baseline (611.808 us; speedup 1.0000x reference)
//
#include <hip/hip_runtime.h>
#include <cmath>

// ---------------- problem constants ----------------
// B=8, M=1024, D=768, N=32, P=32, K=8, H=2048
#define NB    8
#define MTOK  1024
#define BMT   8192      // B*M
#define DD    768
#define NEXP  32
#define PSLOT 32
#define NP    1024      // N*P
#define KTOP  8
#define HH    2048

#define SLICES 128      // partial-sum slices for cluster stats
#define TPS    64       // tokens per slice (SLICES*TPS == BMT)

typedef unsigned short ushort;
typedef __attribute__((ext_vector_type(8))) short short8v;   // 8 bf16 = 4 VGPR
typedef __attribute__((ext_vector_type(4))) short short4v;   // 8 bytes
typedef __attribute__((ext_vector_type(4))) float f32x4;

__device__ __forceinline__ ushort bf16_rne(float x) {
    unsigned u = __float_as_uint(x);
    unsigned r = (u + 0x7FFFu + ((u >> 16) & 1u)) >> 16;
    return (ushort)r;
}
__device__ __forceinline__ float bf16_to_f(ushort h) {
    return __uint_as_float(((unsigned)h) << 16);
}
__device__ __forceinline__ void split2(float x, ushort& hi, ushort& lo) {
    hi = bf16_rne(x);
    lo = bf16_rne(x - bf16_to_f(hi));
}

// async global->LDS, 16B per lane; lds dest is wave-uniform base + lane*16
__device__ __forceinline__ void gl_lds16(const ushort* g, ushort* l) {
    __builtin_amdgcn_global_load_lds(
        (const __attribute__((address_space(1))) void*)g,
        (__attribute__((address_space(3))) void*)l, 16, 0, 0);
}

// ---------------- K1: token L2 normalize ----------------
__global__ __launch_bounds__(256) void norm_x(const float* __restrict__ x, float* __restrict__ xn) {
    int tok = blockIdx.x;
    int t = threadIdx.x;
    const float* p = x + (long)tok * DD;
    float v0 = p[t], v1 = p[t + 256], v2 = p[t + 512];
    float ss = v0 * v0 + v1 * v1 + v2 * v2;
#pragma unroll
    for (int o = 32; o; o >>= 1) ss += __shfl_xor(ss, o);
    __shared__ float sred[4];
    if ((t & 63) == 0) sred[t >> 6] = ss;
    __syncthreads();
    ss = sred[0] + sred[1] + sred[2] + sred[3];
    float inv = 1.0f / fmaxf(sqrtf(ss), 1e-12f);
    float* q = xn + (long)tok * DD;
    q[t] = v0 * inv; q[t + 256] = v1 * inv; q[t + 512] = v2 * inv;
}

// ---------------- K2: phi normalize -> transposed split pair [np][d] ----------------
__global__ __launch_bounds__(256) void norm_phi_T(const float* __restrict__ phi, const float* __restrict__ scale,
                                                  ushort* __restrict__ phT_hi, ushort* __restrict__ phT_lo) {
    int np = blockIdx.x;           // 1024 blocks
    int t = threadIdx.x;
    float ss = 0.f;
    for (int d = t; d < DD; d += 256) {
        float v = phi[(long)d * NP + np];
        ss += v * v;
    }
#pragma unroll
    for (int o = 32; o; o >>= 1) ss += __shfl_xor(ss, o);
    __shared__ float sred[4];
    if ((t & 63) == 0) sred[t >> 6] = ss;
    __syncthreads();
    ss = sred[0] + sred[1] + sred[2] + sred[3];
    float sc = scale[0] / fmaxf(sqrtf(ss), 1e-12f);
    for (int d = t; d < DD; d += 256) {
        float v = phi[(long)d * NP + np] * sc;
        ushort h, l; split2(v, h, l);
        phT_hi[(long)np * DD + d] = h;
        phT_lo[(long)np * DD + d] = l;
    }
}

// ---------------- K3: per-cluster sums (deterministic partials, 128 slices) ----------------
__global__ __launch_bounds__(256) void cluster_sum(const float* __restrict__ xn, const int* __restrict__ ca,
                                                   float* __restrict__ spart, float* __restrict__ cntpart) {
    __shared__ float s[NEXP][256];
    __shared__ float cnt[NEXP];
    int chunk = blockIdx.x, slice = blockIdx.y, t = threadIdx.x;
#pragma unroll
    for (int n = 0; n < NEXP; ++n) s[n][t] = 0.f;
    if (t < NEXP) cnt[t] = 0.f;
    __syncthreads();
    int tok0 = slice * TPS;
    for (int i = 0; i < TPS; ++i) {
        int tok = tok0 + i;
        int a = ca[tok * KTOP];
        float v = xn[(long)tok * DD + chunk * 256 + t];
        s[a][t] += v;
        if (chunk == 0 && t == 0) cnt[a] += 1.f;
    }
    __syncthreads();
    for (int n = 0; n < NEXP; ++n)
        spart[(long)slice * (NEXP * DD) + n * DD + chunk * 256 + t] = s[n][t];
    if (chunk == 0 && t < NEXP) cntpart[slice * NEXP + t] = cnt[t];
}

__global__ __launch_bounds__(256) void reduce_parts(const float* __restrict__ part, float* __restrict__ outv,
                                                    const float* __restrict__ cntpart, float* __restrict__ ccnt,
                                                    int doCnt) {
    int i = blockIdx.x * 256 + threadIdx.x;
    float s = 0.f;
#pragma unroll 8
    for (int sl = 0; sl < SLICES; ++sl) s += part[(long)sl * (NEXP * DD) + i];
    outv[i] = s;
    if (doCnt && i < NEXP) {
        float c = 0.f;
#pragma unroll 8
        for (int sl = 0; sl < SLICES; ++sl) c += cntpart[sl * NEXP + i];
        ccnt[i] = c;
    }
}

// ---------------- K4: per-cluster MAD partials ----------------
__global__ __launch_bounds__(256) void cluster_mad(const float* __restrict__ xn, const int* __restrict__ ca,
                                                   const float* __restrict__ csum, const float* __restrict__ ccnt,
                                                   float* __restrict__ mpart) {
    __shared__ float md[NEXP][256];
    __shared__ float mean[NEXP][256];
    int chunk = blockIdx.x, slice = blockIdx.y, t = threadIdx.x;
#pragma unroll
    for (int n = 0; n < NEXP; ++n) {
        float c = ccnt[n];
        mean[n][t] = (c > 0.f) ? csum[n * DD + chunk * 256 + t] / c : 0.f;
        md[n][t] = 0.f;
    }
    __syncthreads();
    int tok0 = slice * TPS;
    for (int i = 0; i < TPS; ++i) {
        int tok = tok0 + i;
        int a = ca[tok * KTOP];
        float v = xn[(long)tok * DD + chunk * 256 + t];
        md[a][t] += fabsf(v - mean[a][t]);
    }
    __syncthreads();
    for (int n = 0; n < NEXP; ++n)
        mpart[(long)slice * (NEXP * DD) + n * DD + chunk * 256 + t] = md[n][t];
}

// ---------------- K5: W = normalize(clamp(1/(mad+0.35))) ----------------
__global__ __launch_bounds__(1024) void compute_W(const float* __restrict__ cmad, const float* __restrict__ ccnt,
                                                  float* __restrict__ W) {
    __shared__ float s[16];
    int t = threadIdx.x;
    auto block_sum = [&](float v) -> float {
#pragma unroll
        for (int o = 32; o; o >>= 1) v += __shfl_xor(v, o);
        if ((t & 63) == 0) s[t >> 6] = v;
        __syncthreads();
        float tot = 0.f;
#pragma unroll
        for (int i = 0; i < 16; ++i) tot += s[i];
        __syncthreads();
        return tot;
    };
    const int TOT = NEXP * DD;
    float p = 0.f;
    for (int i = t; i < TOT; i += 1024) {
        int n = i / DD;
        float c = ccnt[n];
        float wm = (c > 0.f) ? cmad[i] / c : 0.f;
        p += 1.f / (wm + 0.35f);
    }
    float mean1 = block_sum(p) / (float)TOT;
    float clamp = 5.f * mean1;
    p = 0.f;
    for (int i = t; i < TOT; i += 1024) {
        int n = i / DD;
        float c = ccnt[n];
        float wm = (c > 0.f) ? cmad[i] / c : 0.f;
        p += fminf(1.f / (wm + 0.35f), clamp);
    }
    float mean2 = block_sum(p) / (float)TOT;
    float inv2 = 1.f / mean2;
    for (int i = t; i < TOT; i += 1024) {
        int n = i / DD;
        float c = ccnt[n];
        float wm = (c > 0.f) ? cmad[i] / c : 0.f;
        W[i] = fminf(1.f / (wm + 0.35f), clamp) * inv2;
    }
}

// ---------------- K6: xn *= W[assign]; also emit bf16 hi/lo pair ----------------
__global__ __launch_bounds__(192) void apply_W(float* __restrict__ xn, const int* __restrict__ ca,
                                               const float* __restrict__ W,
                                               ushort* __restrict__ hi, ushort* __restrict__ lo) {
    int tok = blockIdx.x;
    long d4 = (long)tok * DD + threadIdx.x * 4;
    int a = ca[tok * KTOP];
    float4 v = *reinterpret_cast<float4*>(xn + d4);
    float4 w = *reinterpret_cast<const float4*>(W + a * DD + threadIdx.x * 4);
    v.x *= w.x; v.y *= w.y; v.z *= w.z; v.w *= w.w;
    *reinterpret_cast<float4*>(xn + d4) = v;
    ushort h0,h1,h2,h3,l0,l1,l2,l3;
    split2(v.x,h0,l0); split2(v.y,h1,l1); split2(v.z,h2,l2); split2(v.w,h3,l3);
    *reinterpret_cast<short4v*>(hi + d4) = short4v{(short)h0,(short)h1,(short)h2,(short)h3};
    *reinterpret_cast<short4v*>(lo + d4) = short4v{(short)l0,(short)l1,(short)l2,(short)l3};
}

// ---------------- MFMA GEMM: BM=64, BN=128, BK=32, 256 thr, dbuf, 1 barrier/K-step ----
// A (bf16, pre-rounded) staged via global_load_lds with pre-swizzled source.
// PAIR (logits): A and B are hi/lo pairs, all gload_lds, 3-MFMA split accumulate.
// !PAIR: B from f32 [k][n] source: reg-prefetch (4x float4) + round + swizzled ds_write,
//        placed BEFORE the single barrier (writes the opposite buffer).
// Swizzle: 16B slot s of row r stored at s ^ ((r>>1)&3)  -> 2-way reads (free).
// AMAP: 0 linear z-strided, 1 token remap (row -> (r>>5)*1024 + z*32 + (r&31)).
// EPI: 0 none, 1 +bias, 2 +bias+gelu.  CBF16: round C to bf16.  CMAP: 0 lin, 1 token remap.
template <bool PAIR, int AMAP, int EPI, bool CBF16, int CMAP>
__global__ __launch_bounds__(256) void gemm2(
    const ushort* __restrict__ Ah_g, const ushort* __restrict__ Al_g,
    const float*  __restrict__ Bf_g,
    const ushort* __restrict__ Bh_g, const ushort* __restrict__ Bl_g,
    float* __restrict__ Cf, ushort* __restrict__ Cb,
    int K, int lda, int ldb, int ldc,
    long sA, long sB, long sC,
    const float* __restrict__ bias, int biasStride) {
    // PAIR buf: Ah 2048 | Al 2048 | Bh 4096 | Bl 4096  (12288 sh, x2 = 48KB)
    // !PAIR buf: A 2048 | B 4096                       (6144 sh, x2 = 24KB)
    __shared__ __attribute__((aligned(16))) ushort lds[PAIR ? 24576 : 12288];
    const int BUFS = PAIR ? 12288 : 6144;

    // XCD-aware bijective remap (all grids multiples of 8)
    int orig = blockIdx.x + gridDim.x * (blockIdx.y + gridDim.y * blockIdx.z);
    int nwg = gridDim.x * gridDim.y * gridDim.z;
    int wg = (orig & 7) * (nwg >> 3) + (orig >> 3);
    int bx = wg % gridDim.x;
    int rest = wg / gridDim.x;
    int by = rest % gridDim.y;
    int z  = rest / gridDim.y;
    const int m0 = by * 64;
    const int n0 = bx * 128;

    const int tid = threadIdx.x, lane = tid & 63, w = tid >> 6;
    const int wr = w >> 1, wc = w & 1;          // 2x2 waves of 32x64
    const int lr = lane & 15, kh = lane >> 4;

    // ---- A staging coords: 64 rows x 4 slots = 256 chunks = 1/thread
    const int rA = tid >> 2, spA = tid & 3;
    const int kOffA = (spA ^ ((rA >> 1) & 3)) << 3;
    long arowA;
    {
        int rg = m0 + rA;
        if constexpr (AMAP == 0) arowA = (long)z * sA + (long)rg * lda;
        else arowA = ((long)(rg >> 5) * 1024 + (long)z * 32 + (rg & 31)) * (long)lda;
    }
    // ---- B staging coords (PAIR gl_lds): 128 rows x 4 slots = 512 chunks = 2/thread
    long browB[2]; int kOffB[2];
#pragma unroll
    for (int i = 0; i < 2; ++i) {
        int c = i * 256 + tid;
        int r = c >> 2, sp = c & 3;
        kOffB[i] = (sp ^ ((r >> 1) & 3)) << 3;
        browB[i] = (long)(n0 + r) * ldb;
    }
    // ---- !PAIR B staging coords (reg + ds_write)
    const int kq = tid & 7, nq = tid >> 3;      // kq: 4 k-rows each, nq: 4 n-cols each
    float4 rB[4];

    f32x4 acc[2][4];
#pragma unroll
    for (int i = 0; i < 2; ++i)
#pragma unroll
        for (int j = 0; j < 4; ++j) acc[i][j] = (f32x4)(0.f);

    auto stage = [&](int buf, int kk0) {
        const int bb = buf * BUFS;
        // A (1 chunk/thread; wave-uniform dest + lane*16)
        gl_lds16(Ah_g + arowA + kk0 + kOffA, &lds[bb + (w * 64) * 8]);
        if constexpr (PAIR) {
            gl_lds16(Al_g + arowA + kk0 + kOffA, &lds[bb + 2048 + (w * 64) * 8]);
#pragma unroll
            for (int i = 0; i < 2; ++i) {
                int base = bb + 4096 + (i * 256 + w * 64) * 8;
                gl_lds16(Bh_g + browB[i] + kk0 + kOffB[i], &lds[base]);
                gl_lds16(Bl_g + browB[i] + kk0 + kOffB[i], &lds[base + 4096]);
            }
        } else {
#pragma unroll
            for (int dk = 0; dk < 4; ++dk)
                rB[dk] = *reinterpret_cast<const float4*>(
                    Bf_g + (long)z * sB + (long)(kk0 + kq * 4 + dk) * ldb + n0 + nq * 4);
        }
    };

    auto bwrite = [&](int buf) {
        if constexpr (!PAIR) {
            ushort hv[4][4];
#pragma unroll
            for (int dk = 0; dk < 4; ++dk) {
                hv[dk][0] = bf16_rne(rB[dk].x); hv[dk][1] = bf16_rne(rB[dk].y);
                hv[dk][2] = bf16_rne(rB[dk].z); hv[dk][3] = bf16_rne(rB[dk].w);
            }
#pragma unroll
            for (int dn = 0; dn < 4; ++dn) {
                int n = nq * 4 + dn;
                int phys = (kq >> 1) ^ ((n >> 1) & 3);
                int off = buf * BUFS + 2048 + n * 32 + phys * 8 + (kq & 1) * 4;
                *reinterpret_cast<short4v*>(&lds[off]) =
                    short4v{(short)hv[0][dn], (short)hv[1][dn], (short)hv[2][dn], (short)hv[3][dn]};
            }
        }
    };

    auto compute = [&](int buf) {
        const int aB = buf * BUFS;
        const int bB = buf * BUFS + (PAIR ? 4096 : 2048);
        short8v bh[4], bl[4];
#pragma unroll
        for (int nj = 0; nj < 4; ++nj) {
            int rb = wc * 64 + nj * 16 + lr;
            int off = bB + rb * 32 + ((kh ^ ((rb >> 1) & 3)) << 3);
            bh[nj] = *reinterpret_cast<const short8v*>(&lds[off]);
            if constexpr (PAIR) bl[nj] = *reinterpret_cast<const short8v*>(&lds[off + 4096]);
        }
#pragma unroll
        for (int mi = 0; mi < 2; ++mi) {
            int ra = wr * 32 + mi * 16 + lr;
            int off = aB + ra * 32 + ((kh ^ ((ra >> 1) & 3)) << 3);
            short8v ah = *reinterpret_cast<const short8v*>(&lds[off]);
            if constexpr (PAIR) {
                short8v al = *reinterpret_cast<const short8v*>(&lds[off + 2048]);
#pragma unroll
                for (int nj = 0; nj < 4; ++nj) {
                    acc[mi][nj] = __builtin_amdgcn_mfma_f32_16x16x32_bf16(ah, bh[nj], acc[mi][nj], 0, 0, 0);
                    acc[mi][nj] = __builtin_amdgcn_mfma_f32_16x16x32_bf16(ah, bl[nj], acc[mi][nj], 0, 0, 0);
                    acc[mi][nj] = __builtin_amdgcn_mfma_f32_16x16x32_bf16(al, bh[nj], acc[mi][nj], 0, 0, 0);
                }
            } else {
#pragma unroll
                for (int nj = 0; nj < 4; ++nj)
                    acc[mi][nj] = __builtin_amdgcn_mfma_f32_16x16x32_bf16(ah, bh[nj], acc[mi][nj], 0, 0, 0);
            }
        }
    };

    // ---- double-buffered K-loop, ONE barrier per K-step
    const int nt = K >> 5;
    stage(0, 0);
    bwrite(0);                       // !PAIR: rB(0) -> LDS (waits own vmcnt only)
    __syncthreads();                 // drains A gl_lds + ds_writes
    for (int t = 0; t < nt; ++t) {
        int cur = t & 1;
        if (t + 1 < nt) stage(1 - cur, (t + 1) << 5);
        compute(cur);
        if (t + 1 < nt) bwrite(1 - cur);   // opposite buffer: no hazard with compute(cur)
        __syncthreads();
    }

    // ---- epilogue
#pragma unroll
    for (int mi = 0; mi < 2; ++mi)
#pragma unroll
        for (int j = 0; j < 4; ++j) {
            int rg = m0 + wr * 32 + mi * 16 + kh * 4 + j;
            long roff;
            if constexpr (CMAP == 1) roff = ((long)(rg >> 5) * 1024 + (long)z * 32 + (rg & 31)) * (long)ldc;
            else                     roff = (long)z * sC + (long)rg * ldc;
#pragma unroll
            for (int nj = 0; nj < 4; ++nj) {
                int col = n0 + wc * 64 + nj * 16 + lr;
                float v = acc[mi][nj][j];
                if constexpr (EPI >= 1) v += bias[(long)z * biasStride + col];
                if constexpr (EPI == 2) v = 0.5f * v * (1.0f + erff(v * 0.70710678118654752f));
                if constexpr (CBF16) Cb[roff + col] = bf16_rne(v);
                else                 Cf[roff + col] = v;
            }
        }
}

// ---------------- K8: per-row top-8 + row softmax stats ----------------
__global__ __launch_bounds__(64) void row_topk(const float* __restrict__ logits,
                                               float* __restrict__ mix_out, float* __restrict__ clus_out,
                                               float* __restrict__ rowmax, float* __restrict__ rowsumInv) {
    int row = blockIdx.x;
    int lane = threadIdx.x;
    const float* p = logits + (long)row * NP;
    float v[16];
#pragma unroll
    for (int i = 0; i < 16; ++i) v[i] = p[lane + i * 64];
    float mx = v[0];
#pragma unroll
    for (int i = 1; i < 16; ++i) mx = fmaxf(mx, v[i]);
#pragma unroll
    for (int o = 32; o; o >>= 1) mx = fmaxf(mx, __shfl_xor(mx, o));
    float s = 0.f;
#pragma unroll
    for (int i = 0; i < 16; ++i) s += __expf(v[i] - mx);
#pragma unroll
    for (int o = 32; o; o >>= 1) s += __shfl_xor(s, o);
    if (lane == 0) { rowmax[row] = mx; rowsumInv[row] = 1.0f / s; }
#pragma unroll
    for (int k = 0; k < KTOP; ++k) {
        float bv = -INFINITY; int bi = 1 << 30;
#pragma unroll
        for (int i = 0; i < 16; ++i) {
            if (v[i] > bv) { bv = v[i]; bi = lane + i * 64; }
        }
#pragma unroll
        for (int o = 32; o; o >>= 1) {
            float ov = __shfl_xor(bv, o); int oi = __shfl_xor(bi, o);
            if (ov > bv || (ov == bv && oi < bi)) { bv = ov; bi = oi; }
        }
        int owner = bi & 63, slot = bi >> 6;
        if (lane == owner) {
#pragma unroll
            for (int i = 0; i < 16; ++i) if (slot == i) v[i] = -INFINITY;
        }
        if (lane == k) {
            mix_out[(long)row * KTOP + k] = bv;
            clus_out[(long)row * KTOP + k] = (float)(bi >> 5);
        }
    }
}

// ---------------- K9: column softmax stats ----------------
__global__ __launch_bounds__(256) void col_stats_part(const float* __restrict__ logits,
                                                      float* __restrict__ pmax, float* __restrict__ psum) {
    int b = blockIdx.z, ms = blockIdx.y, npc = blockIdx.x;
    int np = npc * 256 + threadIdx.x;
    const float* p = logits + ((long)b * MTOK + ms * 128) * NP + np;
    float mx = -INFINITY, s = 0.f;
    for (int m = 0; m < 128; ++m) {
        float v = p[(long)m * NP];
        float nm = fmaxf(mx, v);
        s = s * __expf(mx - nm) + __expf(v - nm);
        mx = nm;
    }
    long o = ((long)b * 8 + ms) * NP + np;
    pmax[o] = mx; psum[o] = s;
}

__global__ __launch_bounds__(256) void col_stats_merge(const float* __restrict__ pmax, const float* __restrict__ psum,
                                                       float* __restrict__ cmax, float* __restrict__ csumInv) {
    int b = blockIdx.y;
    int np = blockIdx.x * 256 + threadIdx.x;
    float mx = -INFINITY;
#pragma unroll
    for (int ms = 0; ms < 8; ++ms) mx = fmaxf(mx, pmax[((long)b * 8 + ms) * NP + np]);
    float s = 0.f;
#pragma unroll
    for (int ms = 0; ms < 8; ++ms) {
        long o = ((long)b * 8 + ms) * NP + np;
        s += psum[o] * __expf(pmax[o] - mx);
    }
    cmax[(long)b * NP + np] = mx;
    csumInv[(long)b * NP + np] = 1.0f / s;
}

// ---------------- K10: dispT bf16 = softmax-over-m(logits)^T, tiled transpose ----------------
__global__ __launch_bounds__(256) void make_dispT(const float* __restrict__ logits,
                                                  const float* __restrict__ cmax, const float* __restrict__ cinv,
                                                  ushort* __restrict__ dispT) {
    __shared__ float tile[64][65];
    int b = blockIdx.z, np0 = blockIdx.x * 64, m0 = blockIdx.y * 64;
    int tr = threadIdx.x >> 6, tc = threadIdx.x & 63;
    const float* src = logits + ((long)b * MTOK + m0) * NP + np0;
#pragma unroll
    for (int i = 0; i < 16; ++i) {
        int m = tr * 16 + i;
        tile[m][tc] = src[(long)m * NP + tc];
    }
    __syncthreads();
#pragma unroll
    for (int i = 0; i < 16; ++i) {
        int npl = tr * 16 + i;
        int np = np0 + npl;
        float mx = cmax[(long)b * NP + np], iv = cinv[(long)b * NP + np];
        float v = __expf(tile[tc][npl] - mx) * iv;
        dispT[((long)b * NP + np) * MTOK + (m0 + tc)] = bf16_rne(v);
    }
}

// ---------------- K11: comb bf16 = softmax-over-np(logits), elementwise ----------------
__global__ __launch_bounds__(256) void make_comb(const float* __restrict__ logits,
                                                 const float* __restrict__ rmax, const float* __restrict__ rinv,
                                                 ushort* __restrict__ comb) {
    long base = ((long)blockIdx.x * 256 + threadIdx.x) * 4;
    int row = (int)(base >> 10);
    float mx = rmax[row], iv = rinv[row];
    float4 v = *reinterpret_cast<const float4*>(logits + base);
    *reinterpret_cast<short4v*>(comb + base) = short4v{
        (short)bf16_rne(__expf(v.x - mx) * iv), (short)bf16_rne(__expf(v.y - mx) * iv),
        (short)bf16_rne(__expf(v.z - mx) * iv), (short)bf16_rne(__expf(v.w - mx) * iv)};
}

// ---------------- launch ----------------
extern "C" void kernel_launch(void* const* d_in, const int* in_sizes, int n_in,
                              void* d_out, int out_size, void* d_ws, size_t ws_size,
                              hipStream_t stream) {
    const float* x    = (const float*)d_in[0];
    const int*   ca   = (const int*)d_in[1];
    const float* phi  = (const float*)d_in[2];
    const float* scale= (const float*)d_in[3];
    const float* w1   = (const float*)d_in[4];
    const float* b1   = (const float*)d_in[5];
    const float* w2   = (const float*)d_in[6];
    const float* b2   = (const float*)d_in[7];
    float* out = (float*)d_out;
    float* ws  = (float*)d_ws;

    float*  xn       = ws;                                   // 6291456 f32
    float*  logits   = xn + 6291456;                         // 8388608 f32
    ushort* xnp_hi   = (ushort*)(logits + 8388608);          // 6291456 sh
    ushort* xnp_lo   = xnp_hi + 6291456;                     // 6291456 sh
    ushort* phT_hi   = xnp_lo + 6291456;                     // 786432 sh
    ushort* phT_lo   = phT_hi + 786432;                      // 786432 sh
    ushort* dispT_bf = phT_lo + 786432;                      // 8388608 sh
    ushort* comb_bf  = dispT_bf + 8388608;                   // 8388608 sh
    ushort* xs_bf    = comb_bf + 8388608;                    // 6291456 sh
    ushort* h_bf     = xs_bf + 6291456;                      // 16777216 sh
    float*  stats    = (float*)(h_bf + 16777216);
    float* rowmax    = stats;                 // 8192
    float* rowsumInv = rowmax + 8192;
    float* colmax    = rowsumInv + 8192;
    float* colsumInv = colmax + 8192;
    float* pmax      = colsumInv + 8192;      // 65536
    float* psum      = pmax + 65536;          // 65536
    float* csum      = psum + 65536;          // 24576
    float* cmad      = csum + 24576;          // 24576
    float* Wbuf      = cmad + 24576;          // 24576
    float* ccnt      = Wbuf + 24576;          // 64
    float* cntpart   = ccnt + 64;             // SLICES*NEXP = 4096
    float* spart     = cntpart + 4096;        // SLICES*NEXP*DD = 3145728
    float* mpart     = spart + 3145728;       // 3145728
    float* ys        = xn;                    // alias: xn dead after xs GEMM

    float* out_y    = out;
    float* out_mix  = out + 6291456;
    float* out_clus = out + 6291456 + 65536;

    norm_x<<<BMT, 256, 0, stream>>>(x, xn);
    norm_phi_T<<<NP, 256, 0, stream>>>(phi, scale, phT_hi, phT_lo);

    cluster_sum<<<dim3(3, SLICES), 256, 0, stream>>>(xn, ca, spart, cntpart);
    reduce_parts<<<96, 256, 0, stream>>>(spart, csum, cntpart, ccnt, 1);
    cluster_mad<<<dim3(3, SLICES), 256, 0, stream>>>(xn, ca, csum, ccnt, mpart);
    reduce_parts<<<96, 256, 0, stream>>>(mpart, cmad, nullptr, nullptr, 0);
    compute_W<<<1, 1024, 0, stream>>>(cmad, ccnt, Wbuf);
    apply_W<<<BMT, 192, 0, stream>>>(xn, ca, Wbuf, xnp_hi, xnp_lo);

    // logits = xn . phin  (split-pair 3-MFMA, f32-accurate; A,B via global_load_lds)
    gemm2<true, 0, 0, false, 0><<<dim3(8, 128, 1), 256, 0, stream>>>(
        xnp_hi, xnp_lo, nullptr, phT_hi, phT_lo, logits, nullptr,
        DD, DD, DD, NP, 0, 0, 0, nullptr, 0);

    row_topk<<<BMT, 64, 0, stream>>>(logits, out_mix, out_clus, rowmax, rowsumInv);
    col_stats_part<<<dim3(4, 8, NB), 256, 0, stream>>>(logits, pmax, psum);
    col_stats_merge<<<dim3(4, NB), 256, 0, stream>>>(pmax, psum, colmax, colsumInv);
    make_dispT<<<dim3(16, 16, NB), 256, 0, stream>>>(logits, colmax, colsumInv, dispT_bf);
    make_comb<<<8192, 256, 0, stream>>>(logits, rowmax, rowsumInv, comb_bf);

    // xs[b] = dispT . xn[b]  -> bf16  (A=dispT_bf gload_lds, B=xn f32 reg-staged)
    gemm2<false, 0, 0, true, 0><<<dim3(6, 16, NB), 256, 0, stream>>>(
        dispT_bf, nullptr, xn, nullptr, nullptr, nullptr, xs_bf,
        MTOK, MTOK, DD, DD,
        (long)NP * MTOK, (long)MTOK * DD, (long)NP * DD, nullptr, 0);

    // h[n] = gelu(xs_rows(n) . w1[n] + b1[n]) -> bf16  (A tokens via remap)
    gemm2<false, 1, 2, true, 0><<<dim3(16, 4, NEXP), 256, 0, stream>>>(
        xs_bf, nullptr, w1, nullptr, nullptr, nullptr, h_bf,
        DD, DD, HH, HH,
        0, (long)DD * HH, (long)256 * HH, b1, HH);

    // ys = h_rows(n) . w2[n] + b2[n] -> f32 [b][np][768] (token-remapped C)
    gemm2<false, 0, 1, false, 1><<<dim3(6, 4, NEXP), 256, 0, stream>>>(
        h_bf, nullptr, w2, nullptr, nullptr, ys, nullptr,
        HH, HH, DD, DD,
        (long)256 * HH, (long)HH * DD, 0, b2, DD);

    // y[b] = comb . ys[b] -> f32 out
    gemm2<false, 0, 0, false, 0><<<dim3(6, 16, NB), 256, 0, stream>>>(
        comb_bf, nullptr, ys, nullptr, nullptr, out_y, nullptr,
        NP, NP, DD, DD,
        (long)MTOK * NP, (long)NP * DD, (long)MTOK * DD, nullptr, 0);
}

// Round 8
// 585.466 us; speedup vs baseline: 1.0450x; 1.0450x over previous
//
#include <hip/hip_runtime.h>
#include <cmath>

// ---------------- problem constants ----------------
// B=8, M=1024, D=768, N=32, P=32, K=8, H=2048
#define NB    8
#define MTOK  1024
#define BMT   8192      // B*M
#define DD    768
#define NEXP  32
#define PSLOT 32
#define NP    1024      // N*P
#define KTOP  8
#define HH    2048

#define SLICES 128      // partial-sum slices for cluster stats
#define TPS    64       // tokens per slice (SLICES*TPS == BMT)

typedef unsigned short ushort;
typedef __attribute__((ext_vector_type(8))) short short8v;   // 8 bf16 = 4 VGPR
typedef __attribute__((ext_vector_type(4))) short short4v;   // 8 bytes
typedef __attribute__((ext_vector_type(4))) float f32x4;

__device__ __forceinline__ ushort bf16_rne(float x) {
    unsigned u = __float_as_uint(x);
    unsigned r = (u + 0x7FFFu + ((u >> 16) & 1u)) >> 16;
    return (ushort)r;
}
__device__ __forceinline__ float bf16_to_f(ushort h) {
    return __uint_as_float(((unsigned)h) << 16);
}
__device__ __forceinline__ void split2(float x, ushort& hi, ushort& lo) {
    hi = bf16_rne(x);
    lo = bf16_rne(x - bf16_to_f(hi));
}

// async global->LDS, 16B per lane; lds dest is wave-uniform base + lane*16
__device__ __forceinline__ void gl_lds16(const ushort* g, ushort* l) {
    __builtin_amdgcn_global_load_lds(
        (const __attribute__((address_space(1))) void*)g,
        (__attribute__((address_space(3))) void*)l, 16, 0, 0);
}

// ---------------- K1: token L2 normalize ----------------
__global__ __launch_bounds__(256) void norm_x(const float* __restrict__ x, float* __restrict__ xn) {
    int tok = blockIdx.x;
    int t = threadIdx.x;
    const float* p = x + (long)tok * DD;
    float v0 = p[t], v1 = p[t + 256], v2 = p[t + 512];
    float ss = v0 * v0 + v1 * v1 + v2 * v2;
#pragma unroll
    for (int o = 32; o; o >>= 1) ss += __shfl_xor(ss, o);
    __shared__ float sred[4];
    if ((t & 63) == 0) sred[t >> 6] = ss;
    __syncthreads();
    ss = sred[0] + sred[1] + sred[2] + sred[3];
    float inv = 1.0f / fmaxf(sqrtf(ss), 1e-12f);
    float* q = xn + (long)tok * DD;
    q[t] = v0 * inv; q[t + 256] = v1 * inv; q[t + 512] = v2 * inv;
}

// ---------------- K2: phi normalize -> transposed split pair [np][d] ----------------
__global__ __launch_bounds__(256) void norm_phi_T(const float* __restrict__ phi, const float* __restrict__ scale,
                                                  ushort* __restrict__ phT_hi, ushort* __restrict__ phT_lo) {
    int np = blockIdx.x;           // 1024 blocks
    int t = threadIdx.x;
    float ss = 0.f;
    for (int d = t; d < DD; d += 256) {
        float v = phi[(long)d * NP + np];
        ss += v * v;
    }
#pragma unroll
    for (int o = 32; o; o >>= 1) ss += __shfl_xor(ss, o);
    __shared__ float sred[4];
    if ((t & 63) == 0) sred[t >> 6] = ss;
    __syncthreads();
    ss = sred[0] + sred[1] + sred[2] + sred[3];
    float sc = scale[0] / fmaxf(sqrtf(ss), 1e-12f);
    for (int d = t; d < DD; d += 256) {
        float v = phi[(long)d * NP + np] * sc;
        ushort h, l; split2(v, h, l);
        phT_hi[(long)np * DD + d] = h;
        phT_lo[(long)np * DD + d] = l;
    }
}

// ---------------- K3: per-cluster sums (deterministic partials, 128 slices) ----------------
__global__ __launch_bounds__(256) void cluster_sum(const float* __restrict__ xn, const int* __restrict__ ca,
                                                   float* __restrict__ spart, float* __restrict__ cntpart) {
    __shared__ float s[NEXP][256];
    __shared__ float cnt[NEXP];
    int chunk = blockIdx.x, slice = blockIdx.y, t = threadIdx.x;
#pragma unroll
    for (int n = 0; n < NEXP; ++n) s[n][t] = 0.f;
    if (t < NEXP) cnt[t] = 0.f;
    __syncthreads();
    int tok0 = slice * TPS;
    for (int i = 0; i < TPS; ++i) {
        int tok = tok0 + i;
        int a = ca[tok * KTOP];
        float v = xn[(long)tok * DD + chunk * 256 + t];
        s[a][t] += v;
        if (chunk == 0 && t == 0) cnt[a] += 1.f;
    }
    __syncthreads();
    for (int n = 0; n < NEXP; ++n)
        spart[(long)slice * (NEXP * DD) + n * DD + chunk * 256 + t] = s[n][t];
    if (chunk == 0 && t < NEXP) cntpart[slice * NEXP + t] = cnt[t];
}

__global__ __launch_bounds__(256) void reduce_parts(const float* __restrict__ part, float* __restrict__ outv,
                                                    const float* __restrict__ cntpart, float* __restrict__ ccnt,
                                                    int doCnt) {
    int i = blockIdx.x * 256 + threadIdx.x;
    float s = 0.f;
#pragma unroll 8
    for (int sl = 0; sl < SLICES; ++sl) s += part[(long)sl * (NEXP * DD) + i];
    outv[i] = s;
    if (doCnt && i < NEXP) {
        float c = 0.f;
#pragma unroll 8
        for (int sl = 0; sl < SLICES; ++sl) c += cntpart[sl * NEXP + i];
        ccnt[i] = c;
    }
}

// ---------------- K4: per-cluster MAD partials ----------------
__global__ __launch_bounds__(256) void cluster_mad(const float* __restrict__ xn, const int* __restrict__ ca,
                                                   const float* __restrict__ csum, const float* __restrict__ ccnt,
                                                   float* __restrict__ mpart) {
    __shared__ float md[NEXP][256];
    __shared__ float mean[NEXP][256];
    int chunk = blockIdx.x, slice = blockIdx.y, t = threadIdx.x;
#pragma unroll
    for (int n = 0; n < NEXP; ++n) {
        float c = ccnt[n];
        mean[n][t] = (c > 0.f) ? csum[n * DD + chunk * 256 + t] / c : 0.f;
        md[n][t] = 0.f;
    }
    __syncthreads();
    int tok0 = slice * TPS;
    for (int i = 0; i < TPS; ++i) {
        int tok = tok0 + i;
        int a = ca[tok * KTOP];
        float v = xn[(long)tok * DD + chunk * 256 + t];
        md[a][t] += fabsf(v - mean[a][t]);
    }
    __syncthreads();
    for (int n = 0; n < NEXP; ++n)
        mpart[(long)slice * (NEXP * DD) + n * DD + chunk * 256 + t] = md[n][t];
}

// ---------------- K5: W = normalize(clamp(1/(mad+0.35))) ----------------
__global__ __launch_bounds__(1024) void compute_W(const float* __restrict__ cmad, const float* __restrict__ ccnt,
                                                  float* __restrict__ W) {
    __shared__ float s[16];
    int t = threadIdx.x;
    auto block_sum = [&](float v) -> float {
#pragma unroll
        for (int o = 32; o; o >>= 1) v += __shfl_xor(v, o);
        if ((t & 63) == 0) s[t >> 6] = v;
        __syncthreads();
        float tot = 0.f;
#pragma unroll
        for (int i = 0; i < 16; ++i) tot += s[i];
        __syncthreads();
        return tot;
    };
    const int TOT = NEXP * DD;
    float p = 0.f;
    for (int i = t; i < TOT; i += 1024) {
        int n = i / DD;
        float c = ccnt[n];
        float wm = (c > 0.f) ? cmad[i] / c : 0.f;
        p += 1.f / (wm + 0.35f);
    }
    float mean1 = block_sum(p) / (float)TOT;
    float clamp = 5.f * mean1;
    p = 0.f;
    for (int i = t; i < TOT; i += 1024) {
        int n = i / DD;
        float c = ccnt[n];
        float wm = (c > 0.f) ? cmad[i] / c : 0.f;
        p += fminf(1.f / (wm + 0.35f), clamp);
    }
    float mean2 = block_sum(p) / (float)TOT;
    float inv2 = 1.f / mean2;
    for (int i = t; i < TOT; i += 1024) {
        int n = i / DD;
        float c = ccnt[n];
        float wm = (c > 0.f) ? cmad[i] / c : 0.f;
        W[i] = fminf(1.f / (wm + 0.35f), clamp) * inv2;
    }
}

// ---------------- K6: xn *= W[assign]; also emit bf16 hi/lo pair ----------------
__global__ __launch_bounds__(192) void apply_W(float* __restrict__ xn, const int* __restrict__ ca,
                                               const float* __restrict__ W,
                                               ushort* __restrict__ hi, ushort* __restrict__ lo) {
    int tok = blockIdx.x;
    long d4 = (long)tok * DD + threadIdx.x * 4;
    int a = ca[tok * KTOP];
    float4 v = *reinterpret_cast<float4*>(xn + d4);
    float4 w = *reinterpret_cast<const float4*>(W + a * DD + threadIdx.x * 4);
    v.x *= w.x; v.y *= w.y; v.z *= w.z; v.w *= w.w;
    *reinterpret_cast<float4*>(xn + d4) = v;
    ushort h0,h1,h2,h3,l0,l1,l2,l3;
    split2(v.x,h0,l0); split2(v.y,h1,l1); split2(v.z,h2,l2); split2(v.w,h3,l3);
    *reinterpret_cast<short4v*>(hi + d4) = short4v{(short)h0,(short)h1,(short)h2,(short)h3};
    *reinterpret_cast<short4v*>(lo + d4) = short4v{(short)l0,(short)l1,(short)l2,(short)l3};
}

// ---------------- MFMA GEMM: BM=64, BN=128, BK=32, 256 thr ----------------
// A (bf16, pre-rounded) staged via global_load_lds with pre-swizzled source.
// PAIR (logits): A and B hi/lo pairs all gload_lds, 3-MFMA split, __syncthreads loop.
// !PAIR: B f32 [k][n]: 2-AHEAD reg prefetch (rBa/rBb) + round + swizzled ds_write;
//        counted s_waitcnt vmcnt(4) + raw s_barrier -> B loads stay in flight.
// Swizzle: 16B slot s of row r stored at s ^ ((r>>1)&3)  -> 2-way reads (free).
// AMAP: 0 linear z-strided, 1 token remap.  EPI: 0/1 bias/2 bias+gelu.
// CBF16: round C to bf16.  CMAP: 0 lin, 1 token remap.
template <bool PAIR, int AMAP, int EPI, bool CBF16, int CMAP>
__global__ __launch_bounds__(256) void gemm2(
    const ushort* __restrict__ Ah_g, const ushort* __restrict__ Al_g,
    const float*  __restrict__ Bf_g,
    const ushort* __restrict__ Bh_g, const ushort* __restrict__ Bl_g,
    float* __restrict__ Cf, ushort* __restrict__ Cb,
    int K, int lda, int ldb, int ldc,
    long sA, long sB, long sC,
    const float* __restrict__ bias, int biasStride) {
    // PAIR buf: Ah 2048 | Al 2048 | Bh 4096 | Bl 4096  (12288 sh, x2 = 48KB)
    // !PAIR buf: A 2048 | B 4096                       (6144 sh, x2 = 24KB)
    __shared__ __attribute__((aligned(16))) ushort lds[PAIR ? 24576 : 12288];
    const int BUFS = PAIR ? 12288 : 6144;

    // XCD-aware bijective remap (all grids multiples of 8)
    int orig = blockIdx.x + gridDim.x * (blockIdx.y + gridDim.y * blockIdx.z);
    int nwg = gridDim.x * gridDim.y * gridDim.z;
    int wg = (orig & 7) * (nwg >> 3) + (orig >> 3);
    int bx = wg % gridDim.x;
    int rest = wg / gridDim.x;
    int by = rest % gridDim.y;
    int z  = rest / gridDim.y;
    const int m0 = by * 64;
    const int n0 = bx * 128;

    const int tid = threadIdx.x, lane = tid & 63, w = tid >> 6;
    const int wr = w >> 1, wc = w & 1;          // 2x2 waves of 32x64
    const int lr = lane & 15, kh = lane >> 4;

    // ---- A staging coords: 64 rows x 4 slots = 256 chunks = 1/thread
    const int rA = tid >> 2, spA = tid & 3;
    const int kOffA = (spA ^ ((rA >> 1) & 3)) << 3;
    long arowA;
    {
        int rg = m0 + rA;
        if constexpr (AMAP == 0) arowA = (long)z * sA + (long)rg * lda;
        else arowA = ((long)(rg >> 5) * 1024 + (long)z * 32 + (rg & 31)) * (long)lda;
    }
    // ---- B staging coords (PAIR gl_lds): 128 rows x 4 slots = 512 chunks = 2/thread
    long browB[2]; int kOffB[2];
#pragma unroll
    for (int i = 0; i < 2; ++i) {
        int c = i * 256 + tid;
        int r = c >> 2, sp = c & 3;
        kOffB[i] = (sp ^ ((r >> 1) & 3)) << 3;
        browB[i] = (long)(n0 + r) * ldb;
    }
    // ---- !PAIR B staging coords (reg + ds_write)
    const int kq = tid & 7, nq = tid >> 3;      // kq: 4 k-rows each, nq: 4 n-cols each

    f32x4 acc[2][4];
#pragma unroll
    for (int i = 0; i < 2; ++i)
#pragma unroll
        for (int j = 0; j < 4; ++j) acc[i][j] = (f32x4)(0.f);

    auto stageA = [&](int buf, int kk0) {
        const int bb = buf * BUFS;
        gl_lds16(Ah_g + arowA + kk0 + kOffA, &lds[bb + (w * 64) * 8]);
        if constexpr (PAIR) {
            gl_lds16(Al_g + arowA + kk0 + kOffA, &lds[bb + 2048 + (w * 64) * 8]);
#pragma unroll
            for (int i = 0; i < 2; ++i) {
                int base = bb + 4096 + (i * 256 + w * 64) * 8;
                gl_lds16(Bh_g + browB[i] + kk0 + kOffB[i], &lds[base]);
                gl_lds16(Bl_g + browB[i] + kk0 + kOffB[i], &lds[base + 4096]);
            }
        }
    };

    auto loadB = [&](float4 (&rB)[4], int kk0) {
#pragma unroll
        for (int dk = 0; dk < 4; ++dk)
            rB[dk] = *reinterpret_cast<const float4*>(
                Bf_g + (long)z * sB + (long)(kk0 + kq * 4 + dk) * ldb + n0 + nq * 4);
    };

    auto bwrite = [&](int buf, float4 (&rB)[4]) {
        ushort hv[4][4];
#pragma unroll
        for (int dk = 0; dk < 4; ++dk) {
            hv[dk][0] = bf16_rne(rB[dk].x); hv[dk][1] = bf16_rne(rB[dk].y);
            hv[dk][2] = bf16_rne(rB[dk].z); hv[dk][3] = bf16_rne(rB[dk].w);
        }
#pragma unroll
        for (int dn = 0; dn < 4; ++dn) {
            int n = nq * 4 + dn;
            int phys = (kq >> 1) ^ ((n >> 1) & 3);
            int off = buf * BUFS + 2048 + n * 32 + phys * 8 + (kq & 1) * 4;
            *reinterpret_cast<short4v*>(&lds[off]) =
                short4v{(short)hv[0][dn], (short)hv[1][dn], (short)hv[2][dn], (short)hv[3][dn]};
        }
    };

    auto compute = [&](int buf) {
        const int aB = buf * BUFS;
        const int bB = buf * BUFS + (PAIR ? 4096 : 2048);
        short8v bh[4], bl[4];
#pragma unroll
        for (int nj = 0; nj < 4; ++nj) {
            int rb = wc * 64 + nj * 16 + lr;
            int off = bB + rb * 32 + ((kh ^ ((rb >> 1) & 3)) << 3);
            bh[nj] = *reinterpret_cast<const short8v*>(&lds[off]);
            if constexpr (PAIR) bl[nj] = *reinterpret_cast<const short8v*>(&lds[off + 4096]);
        }
#pragma unroll
        for (int mi = 0; mi < 2; ++mi) {
            int ra = wr * 32 + mi * 16 + lr;
            int off = aB + ra * 32 + ((kh ^ ((ra >> 1) & 3)) << 3);
            short8v ah = *reinterpret_cast<const short8v*>(&lds[off]);
            if constexpr (PAIR) {
                short8v al = *reinterpret_cast<const short8v*>(&lds[off + 2048]);
#pragma unroll
                for (int nj = 0; nj < 4; ++nj) {
                    acc[mi][nj] = __builtin_amdgcn_mfma_f32_16x16x32_bf16(ah, bh[nj], acc[mi][nj], 0, 0, 0);
                    acc[mi][nj] = __builtin_amdgcn_mfma_f32_16x16x32_bf16(ah, bl[nj], acc[mi][nj], 0, 0, 0);
                    acc[mi][nj] = __builtin_amdgcn_mfma_f32_16x16x32_bf16(al, bh[nj], acc[mi][nj], 0, 0, 0);
                }
            } else {
#pragma unroll
                for (int nj = 0; nj < 4; ++nj)
                    acc[mi][nj] = __builtin_amdgcn_mfma_f32_16x16x32_bf16(ah, bh[nj], acc[mi][nj], 0, 0, 0);
            }
        }
    };

    const int nt = K >> 5;
    if constexpr (PAIR) {
        // pure-gl_lds double buffer, classic 2-phase
        stageA(0, 0);
        __syncthreads();
        for (int t = 0; t < nt; ++t) {
            int cur = t & 1;
            if (t + 1 < nt) stageA(1 - cur, (t + 1) << 5);
            compute(cur);
            __syncthreads();
        }
    } else {
        float4 rBa[4], rBb[4];
        // prologue: B(0)->rBa->LDS buf0; A(0)->buf0; B(1)->rBb
        loadB(rBa, 0);
        stageA(0, 0);
        bwrite(0, rBa);                      // waits rBa only (A still in flight)
        loadB(rBb, 32);
        asm volatile("s_waitcnt vmcnt(4) lgkmcnt(0)" ::: "memory");   // drain A(0), keep rBb
        __builtin_amdgcn_s_barrier();
        __builtin_amdgcn_sched_barrier(0);
        // steady state: at iter t, load B(t+2) into ld, write B(t+1) from wr
        auto iter = [&](int t, float4 (&ld)[4], float4 (&wr)[4]) {
            int cur = t & 1;
            if (t + 1 < nt) stageA(1 - cur, (t + 1) << 5);
            bool deep = (t + 2 < nt);
            if (deep) loadB(ld, (t + 2) << 5);
            compute(cur);
            if (t + 1 < nt) bwrite(1 - cur, wr);
            if (deep) { asm volatile("s_waitcnt vmcnt(4) lgkmcnt(0)" ::: "memory"); }
            else      { asm volatile("s_waitcnt vmcnt(0) lgkmcnt(0)" ::: "memory"); }
            __builtin_amdgcn_s_barrier();
            __builtin_amdgcn_sched_barrier(0);
        };
        for (int t = 0; t < nt; t += 2) {
            iter(t, rBa, rBb);
            if (t + 1 < nt) iter(t + 1, rBb, rBa);
        }
    }

    // ---- epilogue
#pragma unroll
    for (int mi = 0; mi < 2; ++mi)
#pragma unroll
        for (int j = 0; j < 4; ++j) {
            int rg = m0 + wr * 32 + mi * 16 + kh * 4 + j;
            long roff;
            if constexpr (CMAP == 1) roff = ((long)(rg >> 5) * 1024 + (long)z * 32 + (rg & 31)) * (long)ldc;
            else                     roff = (long)z * sC + (long)rg * ldc;
#pragma unroll
            for (int nj = 0; nj < 4; ++nj) {
                int col = n0 + wc * 64 + nj * 16 + lr;
                float v = acc[mi][nj][j];
                if constexpr (EPI >= 1) v += bias[(long)z * biasStride + col];
                if constexpr (EPI == 2) v = 0.5f * v * (1.0f + erff(v * 0.70710678118654752f));
                if constexpr (CBF16) Cb[roff + col] = bf16_rne(v);
                else                 Cf[roff + col] = v;
            }
        }
}

// ---------------- K8: per-row top-8 + row softmax stats ----------------
__global__ __launch_bounds__(64) void row_topk(const float* __restrict__ logits,
                                               float* __restrict__ mix_out, float* __restrict__ clus_out,
                                               float* __restrict__ rowmax, float* __restrict__ rowsumInv) {
    int row = blockIdx.x;
    int lane = threadIdx.x;
    const float* p = logits + (long)row * NP;
    float v[16];
#pragma unroll
    for (int i = 0; i < 16; ++i) v[i] = p[lane + i * 64];
    float mx = v[0];
#pragma unroll
    for (int i = 1; i < 16; ++i) mx = fmaxf(mx, v[i]);
#pragma unroll
    for (int o = 32; o; o >>= 1) mx = fmaxf(mx, __shfl_xor(mx, o));
    float s = 0.f;
#pragma unroll
    for (int i = 0; i < 16; ++i) s += __expf(v[i] - mx);
#pragma unroll
    for (int o = 32; o; o >>= 1) s += __shfl_xor(s, o);
    if (lane == 0) { rowmax[row] = mx; rowsumInv[row] = 1.0f / s; }
#pragma unroll
    for (int k = 0; k < KTOP; ++k) {
        float bv = -INFINITY; int bi = 1 << 30;
#pragma unroll
        for (int i = 0; i < 16; ++i) {
            if (v[i] > bv) { bv = v[i]; bi = lane + i * 64; }
        }
#pragma unroll
        for (int o = 32; o; o >>= 1) {
            float ov = __shfl_xor(bv, o); int oi = __shfl_xor(bi, o);
            if (ov > bv || (ov == bv && oi < bi)) { bv = ov; bi = oi; }
        }
        int owner = bi & 63, slot = bi >> 6;
        if (lane == owner) {
#pragma unroll
            for (int i = 0; i < 16; ++i) if (slot == i) v[i] = -INFINITY;
        }
        if (lane == k) {
            mix_out[(long)row * KTOP + k] = bv;
            clus_out[(long)row * KTOP + k] = (float)(bi >> 5);
        }
    }
}

// ---------------- K9: column softmax stats ----------------
__global__ __launch_bounds__(256) void col_stats_part(const float* __restrict__ logits,
                                                      float* __restrict__ pmax, float* __restrict__ psum) {
    int b = blockIdx.z, ms = blockIdx.y, npc = blockIdx.x;
    int np = npc * 256 + threadIdx.x;
    const float* p = logits + ((long)b * MTOK + ms * 128) * NP + np;
    float mx = -INFINITY, s = 0.f;
    for (int m = 0; m < 128; ++m) {
        float v = p[(long)m * NP];
        float nm = fmaxf(mx, v);
        s = s * __expf(mx - nm) + __expf(v - nm);
        mx = nm;
    }
    long o = ((long)b * 8 + ms) * NP + np;
    pmax[o] = mx; psum[o] = s;
}

__global__ __launch_bounds__(256) void col_stats_merge(const float* __restrict__ pmax, const float* __restrict__ psum,
                                                       float* __restrict__ cmax, float* __restrict__ csumInv) {
    int b = blockIdx.y;
    int np = blockIdx.x * 256 + threadIdx.x;
    float mx = -INFINITY;
#pragma unroll
    for (int ms = 0; ms < 8; ++ms) mx = fmaxf(mx, pmax[((long)b * 8 + ms) * NP + np]);
    float s = 0.f;
#pragma unroll
    for (int ms = 0; ms < 8; ++ms) {
        long o = ((long)b * 8 + ms) * NP + np;
        s += psum[o] * __expf(pmax[o] - mx);
    }
    cmax[(long)b * NP + np] = mx;
    csumInv[(long)b * NP + np] = 1.0f / s;
}

// ---------------- K10: dispT bf16 = softmax-over-m(logits)^T, tiled transpose ----------------
__global__ __launch_bounds__(256) void make_dispT(const float* __restrict__ logits,
                                                  const float* __restrict__ cmax, const float* __restrict__ cinv,
                                                  ushort* __restrict__ dispT) {
    __shared__ float tile[64][65];
    int b = blockIdx.z, np0 = blockIdx.x * 64, m0 = blockIdx.y * 64;
    int tr = threadIdx.x >> 6, tc = threadIdx.x & 63;
    const float* src = logits + ((long)b * MTOK + m0) * NP + np0;
#pragma unroll
    for (int i = 0; i < 16; ++i) {
        int m = tr * 16 + i;
        tile[m][tc] = src[(long)m * NP + tc];
    }
    __syncthreads();
#pragma unroll
    for (int i = 0; i < 16; ++i) {
        int npl = tr * 16 + i;
        int np = np0 + npl;
        float mx = cmax[(long)b * NP + np], iv = cinv[(long)b * NP + np];
        float v = __expf(tile[tc][npl] - mx) * iv;
        dispT[((long)b * NP + np) * MTOK + (m0 + tc)] = bf16_rne(v);
    }
}

// ---------------- K11: comb bf16 = softmax-over-np(logits), elementwise ----------------
__global__ __launch_bounds__(256) void make_comb(const float* __restrict__ logits,
                                                 const float* __restrict__ rmax, const float* __restrict__ rinv,
                                                 ushort* __restrict__ comb) {
    long base = ((long)blockIdx.x * 256 + threadIdx.x) * 4;
    int row = (int)(base >> 10);
    float mx = rmax[row], iv = rinv[row];
    float4 v = *reinterpret_cast<const float4*>(logits + base);
    *reinterpret_cast<short4v*>(comb + base) = short4v{
        (short)bf16_rne(__expf(v.x - mx) * iv), (short)bf16_rne(__expf(v.y - mx) * iv),
        (short)bf16_rne(__expf(v.z - mx) * iv), (short)bf16_rne(__expf(v.w - mx) * iv)};
}

// ---------------- launch ----------------
extern "C" void kernel_launch(void* const* d_in, const int* in_sizes, int n_in,
                              void* d_out, int out_size, void* d_ws, size_t ws_size,
                              hipStream_t stream) {
    const float* x    = (const float*)d_in[0];
    const int*   ca   = (const int*)d_in[1];
    const float* phi  = (const float*)d_in[2];
    const float* scale= (const float*)d_in[3];
    const float* w1   = (const float*)d_in[4];
    const float* b1   = (const float*)d_in[5];
    const float* w2   = (const float*)d_in[6];
    const float* b2   = (const float*)d_in[7];
    float* out = (float*)d_out;
    float* ws  = (float*)d_ws;

    float*  xn       = ws;                                   // 6291456 f32
    float*  logits   = xn + 6291456;                         // 8388608 f32
    ushort* xnp_hi   = (ushort*)(logits + 8388608);          // 6291456 sh
    ushort* xnp_lo   = xnp_hi + 6291456;                     // 6291456 sh
    ushort* phT_hi   = xnp_lo + 6291456;                     // 786432 sh
    ushort* phT_lo   = phT_hi + 786432;                      // 786432 sh
    ushort* dispT_bf = phT_lo + 786432;                      // 8388608 sh
    ushort* comb_bf  = dispT_bf + 8388608;                   // 8388608 sh
    ushort* xs_bf    = comb_bf + 8388608;                    // 6291456 sh
    ushort* h_bf     = xs_bf + 6291456;                      // 16777216 sh
    float*  stats    = (float*)(h_bf + 16777216);
    float* rowmax    = stats;                 // 8192
    float* rowsumInv = rowmax + 8192;
    float* colmax    = rowsumInv + 8192;
    float* colsumInv = colmax + 8192;
    float* pmax      = colsumInv + 8192;      // 65536
    float* psum      = pmax + 65536;          // 65536
    float* csum      = psum + 65536;          // 24576
    float* cmad      = csum + 24576;          // 24576
    float* Wbuf      = cmad + 24576;          // 24576
    float* ccnt      = Wbuf + 24576;          // 64
    float* cntpart   = ccnt + 64;             // SLICES*NEXP = 4096
    float* spart     = cntpart + 4096;        // SLICES*NEXP*DD = 3145728
    float* mpart     = spart + 3145728;       // 3145728
    float* ys        = xn;                    // alias: xn dead after xs GEMM

    float* out_y    = out;
    float* out_mix  = out + 6291456;
    float* out_clus = out + 6291456 + 65536;

    norm_x<<<BMT, 256, 0, stream>>>(x, xn);
    norm_phi_T<<<NP, 256, 0, stream>>>(phi, scale, phT_hi, phT_lo);

    cluster_sum<<<dim3(3, SLICES), 256, 0, stream>>>(xn, ca, spart, cntpart);
    reduce_parts<<<96, 256, 0, stream>>>(spart, csum, cntpart, ccnt, 1);
    cluster_mad<<<dim3(3, SLICES), 256, 0, stream>>>(xn, ca, csum, ccnt, mpart);
    reduce_parts<<<96, 256, 0, stream>>>(mpart, cmad, nullptr, nullptr, 0);
    compute_W<<<1, 1024, 0, stream>>>(cmad, ccnt, Wbuf);
    apply_W<<<BMT, 192, 0, stream>>>(xn, ca, Wbuf, xnp_hi, xnp_lo);

    // logits = xn . phin  (split-pair 3-MFMA, f32-accurate; A,B via global_load_lds)
    gemm2<true, 0, 0, false, 0><<<dim3(8, 128, 1), 256, 0, stream>>>(
        xnp_hi, xnp_lo, nullptr, phT_hi, phT_lo, logits, nullptr,
        DD, DD, DD, NP, 0, 0, 0, nullptr, 0);

    row_topk<<<BMT, 64, 0, stream>>>(logits, out_mix, out_clus, rowmax, rowsumInv);
    col_stats_part<<<dim3(4, 8, NB), 256, 0, stream>>>(logits, pmax, psum);
    col_stats_merge<<<dim3(4, NB), 256, 0, stream>>>(pmax, psum, colmax, colsumInv);
    make_dispT<<<dim3(16, 16, NB), 256, 0, stream>>>(logits, colmax, colsumInv, dispT_bf);
    make_comb<<<8192, 256, 0, stream>>>(logits, rowmax, rowsumInv, comb_bf);

    // xs[b] = dispT . xn[b]  -> bf16  (A=dispT_bf gload_lds, B=xn f32 2-ahead)
    gemm2<false, 0, 0, true, 0><<<dim3(6, 16, NB), 256, 0, stream>>>(
        dispT_bf, nullptr, xn, nullptr, nullptr, nullptr, xs_bf,
        MTOK, MTOK, DD, DD,
        (long)NP * MTOK, (long)MTOK * DD, (long)NP * DD, nullptr, 0);

    // h[n] = gelu(xs_rows(n) . w1[n] + b1[n]) -> bf16  (A tokens via remap)
    gemm2<false, 1, 2, true, 0><<<dim3(16, 4, NEXP), 256, 0, stream>>>(
        xs_bf, nullptr, w1, nullptr, nullptr, nullptr, h_bf,
        DD, DD, HH, HH,
        0, (long)DD * HH, (long)256 * HH, b1, HH);

    // ys = h_rows(n) . w2[n] + b2[n] -> f32 [b][np][768] (token-remapped C)
    gemm2<false, 0, 1, false, 1><<<dim3(6, 4, NEXP), 256, 0, stream>>>(
        h_bf, nullptr, w2, nullptr, nullptr, ys, nullptr,
        HH, HH, DD, DD,
        (long)256 * HH, (long)HH * DD, 0, b2, DD);

    // y[b] = comb . ys[b] -> f32 out
    gemm2<false, 0, 0, false, 0><<<dim3(6, 16, NB), 256, 0, stream>>>(
        comb_bf, nullptr, ys, nullptr, nullptr, out_y, nullptr,
        NP, NP, DD, DD,
        (long)MTOK * NP, (long)NP * DD, (long)MTOK * DD, nullptr, 0);
}

// Round 9
// 515.673 us; speedup vs baseline: 1.1864x; 1.1353x over previous
//
#include <hip/hip_runtime.h>
#include <cmath>

// ---------------- problem constants ----------------
// B=8, M=1024, D=768, N=32, P=32, K=8, H=2048
#define NB    8
#define MTOK  1024
#define BMT   8192      // B*M
#define DD    768
#define NEXP  32
#define PSLOT 32
#define NP    1024      // N*P
#define KTOP  8
#define HH    2048

#define SLICES 128      // partial-sum slices for cluster stats
#define TPS    64       // tokens per slice (SLICES*TPS == BMT)

typedef unsigned short ushort;
typedef __attribute__((ext_vector_type(8))) short short8v;   // 8 bf16 = 4 VGPR
typedef __attribute__((ext_vector_type(4))) short short4v;   // 8 bytes
typedef __attribute__((ext_vector_type(4))) float f32x4;

__device__ __forceinline__ ushort bf16_rne(float x) {
    unsigned u = __float_as_uint(x);
    unsigned r = (u + 0x7FFFu + ((u >> 16) & 1u)) >> 16;
    return (ushort)r;
}
__device__ __forceinline__ float bf16_to_f(ushort h) {
    return __uint_as_float(((unsigned)h) << 16);
}
__device__ __forceinline__ void split2(float x, ushort& hi, ushort& lo) {
    hi = bf16_rne(x);
    lo = bf16_rne(x - bf16_to_f(hi));
}

// async global->LDS, 16B per lane; lds dest is wave-uniform base + lane*16
__device__ __forceinline__ void gl_lds16(const ushort* g, ushort* l) {
    __builtin_amdgcn_global_load_lds(
        (const __attribute__((address_space(1))) void*)g,
        (__attribute__((address_space(3))) void*)l, 16, 0, 0);
}

// ---------------- K1: token L2 normalize ----------------
__global__ __launch_bounds__(256) void norm_x(const float* __restrict__ x, float* __restrict__ xn) {
    int tok = blockIdx.x;
    int t = threadIdx.x;
    const float* p = x + (long)tok * DD;
    float v0 = p[t], v1 = p[t + 256], v2 = p[t + 512];
    float ss = v0 * v0 + v1 * v1 + v2 * v2;
#pragma unroll
    for (int o = 32; o; o >>= 1) ss += __shfl_xor(ss, o);
    __shared__ float sred[4];
    if ((t & 63) == 0) sred[t >> 6] = ss;
    __syncthreads();
    ss = sred[0] + sred[1] + sred[2] + sred[3];
    float inv = 1.0f / fmaxf(sqrtf(ss), 1e-12f);
    float* q = xn + (long)tok * DD;
    q[t] = v0 * inv; q[t + 256] = v1 * inv; q[t + 512] = v2 * inv;
}

// ---------------- K2: phi normalize -> transposed split pair [np][d] ----------------
__global__ __launch_bounds__(256) void norm_phi_T(const float* __restrict__ phi, const float* __restrict__ scale,
                                                  ushort* __restrict__ phT_hi, ushort* __restrict__ phT_lo) {
    int np = blockIdx.x;           // 1024 blocks
    int t = threadIdx.x;
    float ss = 0.f;
    for (int d = t; d < DD; d += 256) {
        float v = phi[(long)d * NP + np];
        ss += v * v;
    }
#pragma unroll
    for (int o = 32; o; o >>= 1) ss += __shfl_xor(ss, o);
    __shared__ float sred[4];
    if ((t & 63) == 0) sred[t >> 6] = ss;
    __syncthreads();
    ss = sred[0] + sred[1] + sred[2] + sred[3];
    float sc = scale[0] / fmaxf(sqrtf(ss), 1e-12f);
    for (int d = t; d < DD; d += 256) {
        float v = phi[(long)d * NP + np] * sc;
        ushort h, l; split2(v, h, l);
        phT_hi[(long)np * DD + d] = h;
        phT_lo[(long)np * DD + d] = l;
    }
}

// ---------------- K3: per-cluster sums (deterministic partials, 128 slices) ----------------
__global__ __launch_bounds__(256) void cluster_sum(const float* __restrict__ xn, const int* __restrict__ ca,
                                                   float* __restrict__ spart, float* __restrict__ cntpart) {
    __shared__ float s[NEXP][256];
    __shared__ float cnt[NEXP];
    int chunk = blockIdx.x, slice = blockIdx.y, t = threadIdx.x;
#pragma unroll
    for (int n = 0; n < NEXP; ++n) s[n][t] = 0.f;
    if (t < NEXP) cnt[t] = 0.f;
    __syncthreads();
    int tok0 = slice * TPS;
    for (int i = 0; i < TPS; ++i) {
        int tok = tok0 + i;
        int a = ca[tok * KTOP];
        float v = xn[(long)tok * DD + chunk * 256 + t];
        s[a][t] += v;
        if (chunk == 0 && t == 0) cnt[a] += 1.f;
    }
    __syncthreads();
    for (int n = 0; n < NEXP; ++n)
        spart[(long)slice * (NEXP * DD) + n * DD + chunk * 256 + t] = s[n][t];
    if (chunk == 0 && t < NEXP) cntpart[slice * NEXP + t] = cnt[t];
}

__global__ __launch_bounds__(256) void reduce_parts(const float* __restrict__ part, float* __restrict__ outv,
                                                    const float* __restrict__ cntpart, float* __restrict__ ccnt,
                                                    int doCnt) {
    int i = blockIdx.x * 256 + threadIdx.x;
    float s = 0.f;
#pragma unroll 8
    for (int sl = 0; sl < SLICES; ++sl) s += part[(long)sl * (NEXP * DD) + i];
    outv[i] = s;
    if (doCnt && i < NEXP) {
        float c = 0.f;
#pragma unroll 8
        for (int sl = 0; sl < SLICES; ++sl) c += cntpart[sl * NEXP + i];
        ccnt[i] = c;
    }
}

// ---------------- K4: per-cluster MAD partials ----------------
__global__ __launch_bounds__(256) void cluster_mad(const float* __restrict__ xn, const int* __restrict__ ca,
                                                   const float* __restrict__ csum, const float* __restrict__ ccnt,
                                                   float* __restrict__ mpart) {
    __shared__ float md[NEXP][256];
    __shared__ float mean[NEXP][256];
    int chunk = blockIdx.x, slice = blockIdx.y, t = threadIdx.x;
#pragma unroll
    for (int n = 0; n < NEXP; ++n) {
        float c = ccnt[n];
        mean[n][t] = (c > 0.f) ? csum[n * DD + chunk * 256 + t] / c : 0.f;
        md[n][t] = 0.f;
    }
    __syncthreads();
    int tok0 = slice * TPS;
    for (int i = 0; i < TPS; ++i) {
        int tok = tok0 + i;
        int a = ca[tok * KTOP];
        float v = xn[(long)tok * DD + chunk * 256 + t];
        md[a][t] += fabsf(v - mean[a][t]);
    }
    __syncthreads();
    for (int n = 0; n < NEXP; ++n)
        mpart[(long)slice * (NEXP * DD) + n * DD + chunk * 256 + t] = md[n][t];
}

// ---------------- K5: W = normalize(clamp(1/(mad+0.35))) ----------------
__global__ __launch_bounds__(1024) void compute_W(const float* __restrict__ cmad, const float* __restrict__ ccnt,
                                                  float* __restrict__ W) {
    __shared__ float s[16];
    int t = threadIdx.x;
    auto block_sum = [&](float v) -> float {
#pragma unroll
        for (int o = 32; o; o >>= 1) v += __shfl_xor(v, o);
        if ((t & 63) == 0) s[t >> 6] = v;
        __syncthreads();
        float tot = 0.f;
#pragma unroll
        for (int i = 0; i < 16; ++i) tot += s[i];
        __syncthreads();
        return tot;
    };
    const int TOT = NEXP * DD;
    float p = 0.f;
    for (int i = t; i < TOT; i += 1024) {
        int n = i / DD;
        float c = ccnt[n];
        float wm = (c > 0.f) ? cmad[i] / c : 0.f;
        p += 1.f / (wm + 0.35f);
    }
    float mean1 = block_sum(p) / (float)TOT;
    float clamp = 5.f * mean1;
    p = 0.f;
    for (int i = t; i < TOT; i += 1024) {
        int n = i / DD;
        float c = ccnt[n];
        float wm = (c > 0.f) ? cmad[i] / c : 0.f;
        p += fminf(1.f / (wm + 0.35f), clamp);
    }
    float mean2 = block_sum(p) / (float)TOT;
    float inv2 = 1.f / mean2;
    for (int i = t; i < TOT; i += 1024) {
        int n = i / DD;
        float c = ccnt[n];
        float wm = (c > 0.f) ? cmad[i] / c : 0.f;
        W[i] = fminf(1.f / (wm + 0.35f), clamp) * inv2;
    }
}

// ---------------- K6: xn *= W[assign]; also emit bf16 hi/lo pair ----------------
__global__ __launch_bounds__(192) void apply_W(float* __restrict__ xn, const int* __restrict__ ca,
                                               const float* __restrict__ W,
                                               ushort* __restrict__ hi, ushort* __restrict__ lo) {
    int tok = blockIdx.x;
    long d4 = (long)tok * DD + threadIdx.x * 4;
    int a = ca[tok * KTOP];
    float4 v = *reinterpret_cast<float4*>(xn + d4);
    float4 w = *reinterpret_cast<const float4*>(W + a * DD + threadIdx.x * 4);
    v.x *= w.x; v.y *= w.y; v.z *= w.z; v.w *= w.w;
    *reinterpret_cast<float4*>(xn + d4) = v;
    ushort h0,h1,h2,h3,l0,l1,l2,l3;
    split2(v.x,h0,l0); split2(v.y,h1,l1); split2(v.z,h2,l2); split2(v.w,h3,l3);
    *reinterpret_cast<short4v*>(hi + d4) = short4v{(short)h0,(short)h1,(short)h2,(short)h3};
    *reinterpret_cast<short4v*>(lo + d4) = short4v{(short)l0,(short)l1,(short)l2,(short)l3};
}

// ---------------- MFMA GEMM, 3-buffer LDS ring, 2-iter prefetch depth ----------------
// PAIR (logits): BM=64, A/B bf16 hi/lo pairs all via global_load_lds (6 ops/thr/step).
// !PAIR: BM=128, A bf16 via gl_lds (2 ops), B f32 [k][n] via 2-iter-ahead reg prefetch
//        (4 loads) + round + swizzled ds_write. Barrier keeps the 6 newest VMEM ops
//        in flight: s_waitcnt vmcnt(6) + raw s_barrier (never vmcnt(0) in steady state).
// Swizzle: 16B slot sp of row r stored at sp ^ ((r>>1)&3) -> 2-way reads (free).
// AMAP: 0 linear z-strided, 1 token remap.  EPI: 0/1 bias/2 bias+gelu.
// CBF16: round C to bf16.  CMAP: 0 lin, 1 token remap.
template <bool PAIR, int AMAP, int EPI, bool CBF16, int CMAP>
__global__ __launch_bounds__(256) void gemm2(
    const ushort* __restrict__ Ah_g, const ushort* __restrict__ Al_g,
    const float*  __restrict__ Bf_g,
    const ushort* __restrict__ Bh_g, const ushort* __restrict__ Bl_g,
    float* __restrict__ Cf, ushort* __restrict__ Cb,
    int K, int lda, int ldb, int ldc,
    long sA, long sB, long sC,
    const float* __restrict__ bias, int biasStride) {
    // PAIR buf (12288 sh): Ah 2048 | Al 2048 | Bh 4096 | Bl 4096.   x3 = 72 KB
    // !PAIR buf (8192 sh): A 4096 | B 4096.                         x3 = 48 KB
    constexpr int BUFS = PAIR ? 12288 : 8192;
    constexpr int BM   = PAIR ? 64 : 128;
    constexpr int MI   = PAIR ? 2 : 4;
    __shared__ __attribute__((aligned(16))) ushort lds[3 * BUFS];

    // XCD-aware bijective remap (all grids multiples of 8)
    int orig = blockIdx.x + gridDim.x * (blockIdx.y + gridDim.y * blockIdx.z);
    int nwg = gridDim.x * gridDim.y * gridDim.z;
    int wg = (orig & 7) * (nwg >> 3) + (orig >> 3);
    int bx = wg % gridDim.x;
    int rest = wg / gridDim.x;
    int by = rest % gridDim.y;
    int z  = rest / gridDim.y;
    const int m0 = by * BM;
    const int n0 = bx * 128;

    const int tid = threadIdx.x, lane = tid & 63, w = tid >> 6;
    const int wr = w >> 1, wc = w & 1;
    const int lr = lane & 15, kh = lane >> 4;

    // ---- A staging coords (per 256-chunk: r=c>>2 row, sp=c&3 16B slot)
    const int NCA = PAIR ? 1 : 2;
    long arowA[2]; int kOffA[2];
#pragma unroll
    for (int i = 0; i < NCA; ++i) {
        int c = i * 256 + tid;
        int r = c >> 2, sp = c & 3;
        kOffA[i] = (sp ^ ((r >> 1) & 3)) << 3;
        int rg = m0 + r;
        if constexpr (AMAP == 0) arowA[i] = (long)z * sA + (long)rg * lda;
        else arowA[i] = ((long)(rg >> 5) * 1024 + (long)z * 32 + (rg & 31)) * (long)lda;
    }
    // ---- B staging coords (PAIR gl_lds): 128 rows x 4 slots = 2 chunks/thread
    long browB[2]; int kOffB[2];
#pragma unroll
    for (int i = 0; i < 2; ++i) {
        int c = i * 256 + tid;
        int r = c >> 2, sp = c & 3;
        kOffB[i] = (sp ^ ((r >> 1) & 3)) << 3;
        browB[i] = (long)(n0 + r) * ldb;
    }
    // ---- !PAIR B reg-staging coords
    const int kq = tid & 7, nq = tid >> 3;

    f32x4 acc[MI][4];
#pragma unroll
    for (int i = 0; i < MI; ++i)
#pragma unroll
        for (int j = 0; j < 4; ++j) acc[i][j] = (f32x4)(0.f);

    auto stageA = [&](int buf, int kk0) {
        const int bb = buf * BUFS;
        if constexpr (PAIR) {
            gl_lds16(Ah_g + arowA[0] + kk0 + kOffA[0], &lds[bb + (w * 64) * 8]);
            gl_lds16(Al_g + arowA[0] + kk0 + kOffA[0], &lds[bb + 2048 + (w * 64) * 8]);
#pragma unroll
            for (int i = 0; i < 2; ++i) {
                int base = bb + 4096 + (i * 256 + w * 64) * 8;
                gl_lds16(Bh_g + browB[i] + kk0 + kOffB[i], &lds[base]);
                gl_lds16(Bl_g + browB[i] + kk0 + kOffB[i], &lds[base + 4096]);
            }
        } else {
#pragma unroll
            for (int i = 0; i < 2; ++i)
                gl_lds16(Ah_g + arowA[i] + kk0 + kOffA[i], &lds[bb + (i * 256 + w * 64) * 8]);
        }
    };

    auto loadB = [&](float4 (&rB)[4], int kk0) {
#pragma unroll
        for (int dk = 0; dk < 4; ++dk)
            rB[dk] = *reinterpret_cast<const float4*>(
                Bf_g + (long)z * sB + (long)(kk0 + kq * 4 + dk) * ldb + n0 + nq * 4);
    };

    auto bwrite = [&](int buf, float4 (&rB)[4]) {
        ushort hv[4][4];
#pragma unroll
        for (int dk = 0; dk < 4; ++dk) {
            hv[dk][0] = bf16_rne(rB[dk].x); hv[dk][1] = bf16_rne(rB[dk].y);
            hv[dk][2] = bf16_rne(rB[dk].z); hv[dk][3] = bf16_rne(rB[dk].w);
        }
#pragma unroll
        for (int dn = 0; dn < 4; ++dn) {
            int n = nq * 4 + dn;
            int phys = (kq >> 1) ^ ((n >> 1) & 3);
            int off = buf * BUFS + 4096 + n * 32 + phys * 8 + (kq & 1) * 4;
            *reinterpret_cast<short4v*>(&lds[off]) =
                short4v{(short)hv[0][dn], (short)hv[1][dn], (short)hv[2][dn], (short)hv[3][dn]};
        }
    };

    auto compute = [&](int buf) {
        const int aB = buf * BUFS;
        const int bB = buf * BUFS + 4096;
        short8v bh[4], bl[4];
#pragma unroll
        for (int nj = 0; nj < 4; ++nj) {
            int rb = wc * 64 + nj * 16 + lr;
            int off = bB + rb * 32 + ((kh ^ ((rb >> 1) & 3)) << 3);
            bh[nj] = *reinterpret_cast<const short8v*>(&lds[off]);
            if constexpr (PAIR) bl[nj] = *reinterpret_cast<const short8v*>(&lds[off + 4096]);
        }
#pragma unroll
        for (int mi = 0; mi < MI; ++mi) {
            int ra = wr * (PAIR ? 32 : 64) + mi * 16 + lr;
            int off = aB + ra * 32 + ((kh ^ ((ra >> 1) & 3)) << 3);
            short8v ah = *reinterpret_cast<const short8v*>(&lds[off]);
            if constexpr (PAIR) {
                short8v al = *reinterpret_cast<const short8v*>(&lds[off + 2048]);
#pragma unroll
                for (int nj = 0; nj < 4; ++nj) {
                    acc[mi][nj] = __builtin_amdgcn_mfma_f32_16x16x32_bf16(ah, bh[nj], acc[mi][nj], 0, 0, 0);
                    acc[mi][nj] = __builtin_amdgcn_mfma_f32_16x16x32_bf16(ah, bl[nj], acc[mi][nj], 0, 0, 0);
                    acc[mi][nj] = __builtin_amdgcn_mfma_f32_16x16x32_bf16(al, bh[nj], acc[mi][nj], 0, 0, 0);
                }
            } else {
#pragma unroll
                for (int nj = 0; nj < 4; ++nj)
                    acc[mi][nj] = __builtin_amdgcn_mfma_f32_16x16x32_bf16(ah, bh[nj], acc[mi][nj], 0, 0, 0);
            }
        }
    };

    const int nt = K >> 5;     // >= 24 for all call sites
    if constexpr (PAIR) {
        // 3-buf ring, 2-ahead gl_lds; barrier keeps newest 6 in flight
        stageA(0, 0);
        stageA(1, 32);
        asm volatile("s_waitcnt vmcnt(6)" ::: "memory");
        __builtin_amdgcn_s_barrier();
        __builtin_amdgcn_sched_barrier(0);
        int cc = 0, cn2 = 2;
        for (int t = 0; t < nt; ++t) {
            bool deep = (t + 2 < nt);
            if (deep) stageA(cn2, (t + 2) << 5);
            compute(cc);
            if (deep) { asm volatile("s_waitcnt vmcnt(6)" ::: "memory"); }
            else      { asm volatile("s_waitcnt vmcnt(0)" ::: "memory"); }
            if (t + 1 < nt) {
                __builtin_amdgcn_s_barrier();
                __builtin_amdgcn_sched_barrier(0);
            }
            cc = (cc == 2) ? 0 : cc + 1;
            cn2 = (cn2 == 2) ? 0 : cn2 + 1;
        }
    } else {
        float4 rBa[4], rBb[4];
        // prologue: B(0)->rBa->buf0; A(0)->buf0; A(1)->buf1; B(1)->rBb
        loadB(rBa, 0);
        bwrite(0, rBa);                      // waits rBa only
        stageA(0, 0);
        stageA(1, 32);
        loadB(rBb, 32);
        asm volatile("s_waitcnt vmcnt(6) lgkmcnt(0)" ::: "memory");   // drain A(0), keep A(1)+B(1)
        __builtin_amdgcn_s_barrier();
        __builtin_amdgcn_sched_barrier(0);
        int cc = 0, cn1 = 1, cn2 = 2;
        auto iter = [&](int t, float4 (&ld)[4], float4 (&wr_)[4]) {
            bool deep = (t + 2 < nt);
            if (deep) { stageA(cn2, (t + 2) << 5); loadB(ld, (t + 2) << 5); }
            compute(cc);
            if (t + 1 < nt) bwrite(cn1, wr_);       // implicit wait drains B(t+1) and A(t+1)
            if (deep) { asm volatile("s_waitcnt vmcnt(6) lgkmcnt(0)" ::: "memory"); }
            else      { asm volatile("s_waitcnt vmcnt(0) lgkmcnt(0)" ::: "memory"); }
            if (t + 1 < nt) {
                __builtin_amdgcn_s_barrier();
                __builtin_amdgcn_sched_barrier(0);
            }
            cc = (cc == 2) ? 0 : cc + 1;
            cn1 = (cn1 == 2) ? 0 : cn1 + 1;
            cn2 = (cn2 == 2) ? 0 : cn2 + 1;
        };
        for (int t = 0; t < nt; t += 2) {    // nt is even at every call site
            iter(t, rBa, rBb);
            iter(t + 1, rBb, rBa);
        }
    }

    // ---- epilogue
#pragma unroll
    for (int mi = 0; mi < MI; ++mi)
#pragma unroll
        for (int j = 0; j < 4; ++j) {
            int rg = m0 + wr * (PAIR ? 32 : 64) + mi * 16 + kh * 4 + j;
            long roff;
            if constexpr (CMAP == 1) roff = ((long)(rg >> 5) * 1024 + (long)z * 32 + (rg & 31)) * (long)ldc;
            else                     roff = (long)z * sC + (long)rg * ldc;
#pragma unroll
            for (int nj = 0; nj < 4; ++nj) {
                int col = n0 + wc * 64 + nj * 16 + lr;
                float v = acc[mi][nj][j];
                if constexpr (EPI >= 1) v += bias[(long)z * biasStride + col];
                if constexpr (EPI == 2) v = 0.5f * v * (1.0f + erff(v * 0.70710678118654752f));
                if constexpr (CBF16) Cb[roff + col] = bf16_rne(v);
                else                 Cf[roff + col] = v;
            }
        }
}

// ---------------- K8: per-row top-8 + row softmax stats ----------------
__global__ __launch_bounds__(64) void row_topk(const float* __restrict__ logits,
                                               float* __restrict__ mix_out, float* __restrict__ clus_out,
                                               float* __restrict__ rowmax, float* __restrict__ rowsumInv) {
    int row = blockIdx.x;
    int lane = threadIdx.x;
    const float* p = logits + (long)row * NP;
    float v[16];
#pragma unroll
    for (int i = 0; i < 16; ++i) v[i] = p[lane + i * 64];
    float mx = v[0];
#pragma unroll
    for (int i = 1; i < 16; ++i) mx = fmaxf(mx, v[i]);
#pragma unroll
    for (int o = 32; o; o >>= 1) mx = fmaxf(mx, __shfl_xor(mx, o));
    float s = 0.f;
#pragma unroll
    for (int i = 0; i < 16; ++i) s += __expf(v[i] - mx);
#pragma unroll
    for (int o = 32; o; o >>= 1) s += __shfl_xor(s, o);
    if (lane == 0) { rowmax[row] = mx; rowsumInv[row] = 1.0f / s; }
#pragma unroll
    for (int k = 0; k < KTOP; ++k) {
        float bv = -INFINITY; int bi = 1 << 30;
#pragma unroll
        for (int i = 0; i < 16; ++i) {
            if (v[i] > bv) { bv = v[i]; bi = lane + i * 64; }
        }
#pragma unroll
        for (int o = 32; o; o >>= 1) {
            float ov = __shfl_xor(bv, o); int oi = __shfl_xor(bi, o);
            if (ov > bv || (ov == bv && oi < bi)) { bv = ov; bi = oi; }
        }
        int owner = bi & 63, slot = bi >> 6;
        if (lane == owner) {
#pragma unroll
            for (int i = 0; i < 16; ++i) if (slot == i) v[i] = -INFINITY;
        }
        if (lane == k) {
            mix_out[(long)row * KTOP + k] = bv;
            clus_out[(long)row * KTOP + k] = (float)(bi >> 5);
        }
    }
}

// ---------------- K9: column softmax stats ----------------
__global__ __launch_bounds__(256) void col_stats_part(const float* __restrict__ logits,
                                                      float* __restrict__ pmax, float* __restrict__ psum) {
    int b = blockIdx.z, ms = blockIdx.y, npc = blockIdx.x;
    int np = npc * 256 + threadIdx.x;
    const float* p = logits + ((long)b * MTOK + ms * 128) * NP + np;
    float mx = -INFINITY, s = 0.f;
    for (int m = 0; m < 128; ++m) {
        float v = p[(long)m * NP];
        float nm = fmaxf(mx, v);
        s = s * __expf(mx - nm) + __expf(v - nm);
        mx = nm;
    }
    long o = ((long)b * 8 + ms) * NP + np;
    pmax[o] = mx; psum[o] = s;
}

__global__ __launch_bounds__(256) void col_stats_merge(const float* __restrict__ pmax, const float* __restrict__ psum,
                                                       float* __restrict__ cmax, float* __restrict__ csumInv) {
    int b = blockIdx.y;
    int np = blockIdx.x * 256 + threadIdx.x;
    float mx = -INFINITY;
#pragma unroll
    for (int ms = 0; ms < 8; ++ms) mx = fmaxf(mx, pmax[((long)b * 8 + ms) * NP + np]);
    float s = 0.f;
#pragma unroll
    for (int ms = 0; ms < 8; ++ms) {
        long o = ((long)b * 8 + ms) * NP + np;
        s += psum[o] * __expf(pmax[o] - mx);
    }
    cmax[(long)b * NP + np] = mx;
    csumInv[(long)b * NP + np] = 1.0f / s;
}

// ---------------- K10: dispT bf16 = softmax-over-m(logits)^T, tiled transpose ----------------
__global__ __launch_bounds__(256) void make_dispT(const float* __restrict__ logits,
                                                  const float* __restrict__ cmax, const float* __restrict__ cinv,
                                                  ushort* __restrict__ dispT) {
    __shared__ float tile[64][65];
    int b = blockIdx.z, np0 = blockIdx.x * 64, m0 = blockIdx.y * 64;
    int tr = threadIdx.x >> 6, tc = threadIdx.x & 63;
    const float* src = logits + ((long)b * MTOK + m0) * NP + np0;
#pragma unroll
    for (int i = 0; i < 16; ++i) {
        int m = tr * 16 + i;
        tile[m][tc] = src[(long)m * NP + tc];
    }
    __syncthreads();
#pragma unroll
    for (int i = 0; i < 16; ++i) {
        int npl = tr * 16 + i;
        int np = np0 + npl;
        float mx = cmax[(long)b * NP + np], iv = cinv[(long)b * NP + np];
        float v = __expf(tile[tc][npl] - mx) * iv;
        dispT[((long)b * NP + np) * MTOK + (m0 + tc)] = bf16_rne(v);
    }
}

// ---------------- K11: comb bf16 = softmax-over-np(logits), elementwise ----------------
__global__ __launch_bounds__(256) void make_comb(const float* __restrict__ logits,
                                                 const float* __restrict__ rmax, const float* __restrict__ rinv,
                                                 ushort* __restrict__ comb) {
    long base = ((long)blockIdx.x * 256 + threadIdx.x) * 4;
    int row = (int)(base >> 10);
    float mx = rmax[row], iv = rinv[row];
    float4 v = *reinterpret_cast<const float4*>(logits + base);
    *reinterpret_cast<short4v*>(comb + base) = short4v{
        (short)bf16_rne(__expf(v.x - mx) * iv), (short)bf16_rne(__expf(v.y - mx) * iv),
        (short)bf16_rne(__expf(v.z - mx) * iv), (short)bf16_rne(__expf(v.w - mx) * iv)};
}

// ---------------- launch ----------------
extern "C" void kernel_launch(void* const* d_in, const int* in_sizes, int n_in,
                              void* d_out, int out_size, void* d_ws, size_t ws_size,
                              hipStream_t stream) {
    const float* x    = (const float*)d_in[0];
    const int*   ca   = (const int*)d_in[1];
    const float* phi  = (const float*)d_in[2];
    const float* scale= (const float*)d_in[3];
    const float* w1   = (const float*)d_in[4];
    const float* b1   = (const float*)d_in[5];
    const float* w2   = (const float*)d_in[6];
    const float* b2   = (const float*)d_in[7];
    float* out = (float*)d_out;
    float* ws  = (float*)d_ws;

    float*  xn       = ws;                                   // 6291456 f32
    float*  logits   = xn + 6291456;                         // 8388608 f32
    ushort* xnp_hi   = (ushort*)(logits + 8388608);          // 6291456 sh
    ushort* xnp_lo   = xnp_hi + 6291456;                     // 6291456 sh
    ushort* phT_hi   = xnp_lo + 6291456;                     // 786432 sh
    ushort* phT_lo   = phT_hi + 786432;                      // 786432 sh
    ushort* dispT_bf = phT_lo + 786432;                      // 8388608 sh
    ushort* comb_bf  = dispT_bf + 8388608;                   // 8388608 sh
    ushort* xs_bf    = comb_bf + 8388608;                    // 6291456 sh
    ushort* h_bf     = xs_bf + 6291456;                      // 16777216 sh
    float*  stats    = (float*)(h_bf + 16777216);
    float* rowmax    = stats;                 // 8192
    float* rowsumInv = rowmax + 8192;
    float* colmax    = rowsumInv + 8192;
    float* colsumInv = colmax + 8192;
    float* pmax      = colsumInv + 8192;      // 65536
    float* psum      = pmax + 65536;          // 65536
    float* csum      = psum + 65536;          // 24576
    float* cmad      = csum + 24576;          // 24576
    float* Wbuf      = cmad + 24576;          // 24576
    float* ccnt      = Wbuf + 24576;          // 64
    float* cntpart   = ccnt + 64;             // SLICES*NEXP = 4096
    float* spart     = cntpart + 4096;        // SLICES*NEXP*DD = 3145728
    float* mpart     = spart + 3145728;       // 3145728
    float* ys        = xn;                    // alias: xn dead after xs GEMM

    float* out_y    = out;
    float* out_mix  = out + 6291456;
    float* out_clus = out + 6291456 + 65536;

    norm_x<<<BMT, 256, 0, stream>>>(x, xn);
    norm_phi_T<<<NP, 256, 0, stream>>>(phi, scale, phT_hi, phT_lo);

    cluster_sum<<<dim3(3, SLICES), 256, 0, stream>>>(xn, ca, spart, cntpart);
    reduce_parts<<<96, 256, 0, stream>>>(spart, csum, cntpart, ccnt, 1);
    cluster_mad<<<dim3(3, SLICES), 256, 0, stream>>>(xn, ca, csum, ccnt, mpart);
    reduce_parts<<<96, 256, 0, stream>>>(mpart, cmad, nullptr, nullptr, 0);
    compute_W<<<1, 1024, 0, stream>>>(cmad, ccnt, Wbuf);
    apply_W<<<BMT, 192, 0, stream>>>(xn, ca, Wbuf, xnp_hi, xnp_lo);

    // logits = xn . phin  (split-pair 3-MFMA, f32-accurate; 3-deep gl_lds ring)
    gemm2<true, 0, 0, false, 0><<<dim3(8, 128, 1), 256, 0, stream>>>(
        xnp_hi, xnp_lo, nullptr, phT_hi, phT_lo, logits, nullptr,
        DD, DD, DD, NP, 0, 0, 0, nullptr, 0);

    row_topk<<<BMT, 64, 0, stream>>>(logits, out_mix, out_clus, rowmax, rowsumInv);
    col_stats_part<<<dim3(4, 8, NB), 256, 0, stream>>>(logits, pmax, psum);
    col_stats_merge<<<dim3(4, NB), 256, 0, stream>>>(pmax, psum, colmax, colsumInv);
    make_dispT<<<dim3(16, 16, NB), 256, 0, stream>>>(logits, colmax, colsumInv, dispT_bf);
    make_comb<<<8192, 256, 0, stream>>>(logits, rowmax, rowsumInv, comb_bf);

    // xs[b] = dispT . xn[b]  -> bf16  (BM=128; A gl_lds, B 2-ahead f32)
    gemm2<false, 0, 0, true, 0><<<dim3(6, 8, NB), 256, 0, stream>>>(
        dispT_bf, nullptr, xn, nullptr, nullptr, nullptr, xs_bf,
        MTOK, MTOK, DD, DD,
        (long)NP * MTOK, (long)MTOK * DD, (long)NP * DD, nullptr, 0);

    // h[n] = gelu(xs_rows(n) . w1[n] + b1[n]) -> bf16  (A tokens via remap)
    gemm2<false, 1, 2, true, 0><<<dim3(16, 2, NEXP), 256, 0, stream>>>(
        xs_bf, nullptr, w1, nullptr, nullptr, nullptr, h_bf,
        DD, DD, HH, HH,
        0, (long)DD * HH, (long)256 * HH, b1, HH);

    // ys = h_rows(n) . w2[n] + b2[n] -> f32 [b][np][768] (token-remapped C)
    gemm2<false, 0, 1, false, 1><<<dim3(6, 2, NEXP), 256, 0, stream>>>(
        h_bf, nullptr, w2, nullptr, nullptr, ys, nullptr,
        HH, HH, DD, DD,
        (long)256 * HH, (long)HH * DD, 0, b2, DD);

    // y[b] = comb . ys[b] -> f32 out
    gemm2<false, 0, 0, false, 0><<<dim3(6, 8, NB), 256, 0, stream>>>(
        comb_bf, nullptr, ys, nullptr, nullptr, out_y, nullptr,
        NP, NP, DD, DD,
        (long)MTOK * NP, (long)NP * DD, (long)MTOK * DD, nullptr, 0);
}

// Round 10
// 490.027 us; speedup vs baseline: 1.2485x; 1.0523x over previous
//
#include <hip/hip_runtime.h>
#include <cmath>

// ---------------- problem constants ----------------
// B=8, M=1024, D=768, N=32, P=32, K=8, H=2048
#define NB    8
#define MTOK  1024
#define BMT   8192      // B*M
#define DD    768
#define NEXP  32
#define PSLOT 32
#define NP    1024      // N*P
#define KTOP  8
#define HH    2048

#define SLICES 128      // partial-sum slices for cluster stats
#define TPS    64       // tokens per slice (SLICES*TPS == BMT)

typedef unsigned short ushort;
typedef __attribute__((ext_vector_type(8))) short short8v;   // 8 bf16 = 4 VGPR
typedef __attribute__((ext_vector_type(4))) short short4v;   // 8 bytes
typedef __attribute__((ext_vector_type(4))) float f32x4;

__device__ __forceinline__ ushort bf16_rne(float x) {
    unsigned u = __float_as_uint(x);
    unsigned r = (u + 0x7FFFu + ((u >> 16) & 1u)) >> 16;
    return (ushort)r;
}
__device__ __forceinline__ float bf16_to_f(ushort h) {
    return __uint_as_float(((unsigned)h) << 16);
}
__device__ __forceinline__ void split2(float x, ushort& hi, ushort& lo) {
    hi = bf16_rne(x);
    lo = bf16_rne(x - bf16_to_f(hi));
}

// async global->LDS, 16B per lane; lds dest is wave-uniform base + lane*16
__device__ __forceinline__ void gl_lds16(const ushort* g, ushort* l) {
    __builtin_amdgcn_global_load_lds(
        (const __attribute__((address_space(1))) void*)g,
        (__attribute__((address_space(3))) void*)l, 16, 0, 0);
}

// ---------------- K1: token L2 normalize ----------------
__global__ __launch_bounds__(256) void norm_x(const float* __restrict__ x, float* __restrict__ xn) {
    int tok = blockIdx.x;
    int t = threadIdx.x;
    const float* p = x + (long)tok * DD;
    float v0 = p[t], v1 = p[t + 256], v2 = p[t + 512];
    float ss = v0 * v0 + v1 * v1 + v2 * v2;
#pragma unroll
    for (int o = 32; o; o >>= 1) ss += __shfl_xor(ss, o);
    __shared__ float sred[4];
    if ((t & 63) == 0) sred[t >> 6] = ss;
    __syncthreads();
    ss = sred[0] + sred[1] + sred[2] + sred[3];
    float inv = 1.0f / fmaxf(sqrtf(ss), 1e-12f);
    float* q = xn + (long)tok * DD;
    q[t] = v0 * inv; q[t + 256] = v1 * inv; q[t + 512] = v2 * inv;
}

// ---------------- K2: phi normalize -> transposed split pair [np][d] ----------------
__global__ __launch_bounds__(256) void norm_phi_T(const float* __restrict__ phi, const float* __restrict__ scale,
                                                  ushort* __restrict__ phT_hi, ushort* __restrict__ phT_lo) {
    int np = blockIdx.x;           // 1024 blocks
    int t = threadIdx.x;
    float ss = 0.f;
    for (int d = t; d < DD; d += 256) {
        float v = phi[(long)d * NP + np];
        ss += v * v;
    }
#pragma unroll
    for (int o = 32; o; o >>= 1) ss += __shfl_xor(ss, o);
    __shared__ float sred[4];
    if ((t & 63) == 0) sred[t >> 6] = ss;
    __syncthreads();
    ss = sred[0] + sred[1] + sred[2] + sred[3];
    float sc = scale[0] / fmaxf(sqrtf(ss), 1e-12f);
    for (int d = t; d < DD; d += 256) {
        float v = phi[(long)d * NP + np] * sc;
        ushort h, l; split2(v, h, l);
        phT_hi[(long)np * DD + d] = h;
        phT_lo[(long)np * DD + d] = l;
    }
}

// ---------------- K3: per-cluster sums (deterministic partials, 128 slices) ----------------
__global__ __launch_bounds__(256) void cluster_sum(const float* __restrict__ xn, const int* __restrict__ ca,
                                                   float* __restrict__ spart, float* __restrict__ cntpart) {
    __shared__ float s[NEXP][256];
    __shared__ float cnt[NEXP];
    int chunk = blockIdx.x, slice = blockIdx.y, t = threadIdx.x;
#pragma unroll
    for (int n = 0; n < NEXP; ++n) s[n][t] = 0.f;
    if (t < NEXP) cnt[t] = 0.f;
    __syncthreads();
    int tok0 = slice * TPS;
    for (int i = 0; i < TPS; ++i) {
        int tok = tok0 + i;
        int a = ca[tok * KTOP];
        float v = xn[(long)tok * DD + chunk * 256 + t];
        s[a][t] += v;
        if (chunk == 0 && t == 0) cnt[a] += 1.f;
    }
    __syncthreads();
    for (int n = 0; n < NEXP; ++n)
        spart[(long)slice * (NEXP * DD) + n * DD + chunk * 256 + t] = s[n][t];
    if (chunk == 0 && t < NEXP) cntpart[slice * NEXP + t] = cnt[t];
}

__global__ __launch_bounds__(256) void reduce_parts(const float* __restrict__ part, float* __restrict__ outv,
                                                    const float* __restrict__ cntpart, float* __restrict__ ccnt,
                                                    int doCnt) {
    int i = blockIdx.x * 256 + threadIdx.x;
    float s = 0.f;
#pragma unroll 8
    for (int sl = 0; sl < SLICES; ++sl) s += part[(long)sl * (NEXP * DD) + i];
    outv[i] = s;
    if (doCnt && i < NEXP) {
        float c = 0.f;
#pragma unroll 8
        for (int sl = 0; sl < SLICES; ++sl) c += cntpart[sl * NEXP + i];
        ccnt[i] = c;
    }
}

// ---------------- K4: per-cluster MAD partials ----------------
__global__ __launch_bounds__(256) void cluster_mad(const float* __restrict__ xn, const int* __restrict__ ca,
                                                   const float* __restrict__ csum, const float* __restrict__ ccnt,
                                                   float* __restrict__ mpart) {
    __shared__ float md[NEXP][256];
    __shared__ float mean[NEXP][256];
    int chunk = blockIdx.x, slice = blockIdx.y, t = threadIdx.x;
#pragma unroll
    for (int n = 0; n < NEXP; ++n) {
        float c = ccnt[n];
        mean[n][t] = (c > 0.f) ? csum[n * DD + chunk * 256 + t] / c : 0.f;
        md[n][t] = 0.f;
    }
    __syncthreads();
    int tok0 = slice * TPS;
    for (int i = 0; i < TPS; ++i) {
        int tok = tok0 + i;
        int a = ca[tok * KTOP];
        float v = xn[(long)tok * DD + chunk * 256 + t];
        md[a][t] += fabsf(v - mean[a][t]);
    }
    __syncthreads();
    for (int n = 0; n < NEXP; ++n)
        mpart[(long)slice * (NEXP * DD) + n * DD + chunk * 256 + t] = md[n][t];
}

// ---------------- K5: W = normalize(clamp(1/(mad+0.35))) ----------------
__global__ __launch_bounds__(1024) void compute_W(const float* __restrict__ cmad, const float* __restrict__ ccnt,
                                                  float* __restrict__ W) {
    __shared__ float s[16];
    int t = threadIdx.x;
    auto block_sum = [&](float v) -> float {
#pragma unroll
        for (int o = 32; o; o >>= 1) v += __shfl_xor(v, o);
        if ((t & 63) == 0) s[t >> 6] = v;
        __syncthreads();
        float tot = 0.f;
#pragma unroll
        for (int i = 0; i < 16; ++i) tot += s[i];
        __syncthreads();
        return tot;
    };
    const int TOT = NEXP * DD;
    float p = 0.f;
    for (int i = t; i < TOT; i += 1024) {
        int n = i / DD;
        float c = ccnt[n];
        float wm = (c > 0.f) ? cmad[i] / c : 0.f;
        p += 1.f / (wm + 0.35f);
    }
    float mean1 = block_sum(p) / (float)TOT;
    float clamp = 5.f * mean1;
    p = 0.f;
    for (int i = t; i < TOT; i += 1024) {
        int n = i / DD;
        float c = ccnt[n];
        float wm = (c > 0.f) ? cmad[i] / c : 0.f;
        p += fminf(1.f / (wm + 0.35f), clamp);
    }
    float mean2 = block_sum(p) / (float)TOT;
    float inv2 = 1.f / mean2;
    for (int i = t; i < TOT; i += 1024) {
        int n = i / DD;
        float c = ccnt[n];
        float wm = (c > 0.f) ? cmad[i] / c : 0.f;
        W[i] = fminf(1.f / (wm + 0.35f), clamp) * inv2;
    }
}

// ---------------- K6: xn *= W[assign]; also emit bf16 hi/lo pair ----------------
__global__ __launch_bounds__(192) void apply_W(float* __restrict__ xn, const int* __restrict__ ca,
                                               const float* __restrict__ W,
                                               ushort* __restrict__ hi, ushort* __restrict__ lo) {
    int tok = blockIdx.x;
    long d4 = (long)tok * DD + threadIdx.x * 4;
    int a = ca[tok * KTOP];
    float4 v = *reinterpret_cast<float4*>(xn + d4);
    float4 w = *reinterpret_cast<const float4*>(W + a * DD + threadIdx.x * 4);
    v.x *= w.x; v.y *= w.y; v.z *= w.z; v.w *= w.w;
    *reinterpret_cast<float4*>(xn + d4) = v;
    ushort h0,h1,h2,h3,l0,l1,l2,l3;
    split2(v.x,h0,l0); split2(v.y,h1,l1); split2(v.z,h2,l2); split2(v.w,h3,l3);
    *reinterpret_cast<short4v*>(hi + d4) = short4v{(short)h0,(short)h1,(short)h2,(short)h3};
    *reinterpret_cast<short4v*>(lo + d4) = short4v{(short)l0,(short)l1,(short)l2,(short)l3};
}

// ---------------- K7: 64x64 tiled transpose -> bf16 [z][C][R] from [z][R][C] ----------------
template <bool F32>
__global__ __launch_bounds__(256) void make_T(const void* __restrict__ srcv, ushort* __restrict__ dst,
                                              int R, int C) {
    __shared__ ushort tile[64][65];
    int z = blockIdx.z;
    int c0 = blockIdx.x * 64, r0 = blockIdx.y * 64;
    int tr = threadIdx.x >> 4;          // 0..15
    int tc4 = (threadIdx.x & 15) * 4;
    long base = (long)z * R * C;
#pragma unroll
    for (int i = 0; i < 4; ++i) {
        int r = tr + i * 16;
        if constexpr (F32) {
            const float* s = (const float*)srcv;
            float4 v = *reinterpret_cast<const float4*>(s + base + (long)(r0 + r) * C + c0 + tc4);
            tile[r][tc4 + 0] = bf16_rne(v.x); tile[r][tc4 + 1] = bf16_rne(v.y);
            tile[r][tc4 + 2] = bf16_rne(v.z); tile[r][tc4 + 3] = bf16_rne(v.w);
        } else {
            const ushort* s = (const ushort*)srcv;
            short4v v = *reinterpret_cast<const short4v*>(s + base + (long)(r0 + r) * C + c0 + tc4);
            tile[r][tc4 + 0] = (ushort)v.x; tile[r][tc4 + 1] = (ushort)v.y;
            tile[r][tc4 + 2] = (ushort)v.z; tile[r][tc4 + 3] = (ushort)v.w;
        }
    }
    __syncthreads();
#pragma unroll
    for (int i = 0; i < 4; ++i) {
        int oc = tr + i * 16;
        short4v o = short4v{(short)tile[tc4 + 0][oc], (short)tile[tc4 + 1][oc],
                            (short)tile[tc4 + 2][oc], (short)tile[tc4 + 3][oc]};
        *reinterpret_cast<short4v*>(dst + base + (long)(c0 + oc) * R + r0 + tc4) = o;
    }
}

// ---------------- MFMA GEMM, 3-buffer LDS ring, 2-iter prefetch depth ----------------
// MODE 0 SINGLE: BM=128, A and B bf16 via gl_lds (4 ops/thr/step), 1 MFMA.     vmcnt(4)
// MODE 1 PAIR:   BM=64,  A/B hi/lo pairs via gl_lds (6 ops/thr/step), 3 MFMA.  vmcnt(6)
// MODE 2 BF32:   BM=128, A bf16 gl_lds (2 ops) + B f32 2-ahead reg prefetch
//                (4 loads) + round + swizzled ds_write.                        vmcnt(6)
// Swizzle: 16B slot sp of row r stored at sp ^ ((r>>1)&3) -> 2-way reads (free).
// AMAP: 0 linear z-strided, 1 token remap.  EPI: 0/1 bias/2 bias+gelu.
// CBF16: round C to bf16.  CMAP: 0 lin, 1 token remap.
template <int MODE, int AMAP, int EPI, bool CBF16, int CMAP>
__global__ __launch_bounds__(256) void gemm2(
    const ushort* __restrict__ Ah_g, const ushort* __restrict__ Al_g,
    const float*  __restrict__ Bf_g,
    const ushort* __restrict__ Bh_g, const ushort* __restrict__ Bl_g,
    float* __restrict__ Cf, ushort* __restrict__ Cb,
    int K, int lda, int ldb, int ldc,
    long sA, long sB, long sC,
    const float* __restrict__ bias, int biasStride) {
    constexpr bool PAIR = (MODE == 1);
    // PAIR buf (12288 sh): Ah 2048 | Al 2048 | Bh 4096 | Bl 4096.   x3 = 72 KB
    // SINGLE/BF32 buf (8192 sh): A 4096 | B 4096.                   x3 = 48 KB
    constexpr int BUFS = PAIR ? 12288 : 8192;
    constexpr int BM   = PAIR ? 64 : 128;
    constexpr int MI   = PAIR ? 2 : 4;
    __shared__ __attribute__((aligned(16))) ushort lds[3 * BUFS];

    // XCD-aware bijective remap (all grids multiples of 8)
    int orig = blockIdx.x + gridDim.x * (blockIdx.y + gridDim.y * blockIdx.z);
    int nwg = gridDim.x * gridDim.y * gridDim.z;
    int wg = (orig & 7) * (nwg >> 3) + (orig >> 3);
    int bx = wg % gridDim.x;
    int rest = wg / gridDim.x;
    int by = rest % gridDim.y;
    int z  = rest / gridDim.y;
    const int m0 = by * BM;
    const int n0 = bx * 128;

    const int tid = threadIdx.x, lane = tid & 63, w = tid >> 6;
    const int wr = w >> 1, wc = w & 1;
    const int lr = lane & 15, kh = lane >> 4;

    // ---- A staging coords (per 256-chunk: r=c>>2 row, sp=c&3 16B slot)
    const int NCA = PAIR ? 1 : 2;
    long arowA[2]; int kOffA[2];
#pragma unroll
    for (int i = 0; i < NCA; ++i) {
        int c = i * 256 + tid;
        int r = c >> 2, sp = c & 3;
        kOffA[i] = (sp ^ ((r >> 1) & 3)) << 3;
        int rg = m0 + r;
        if constexpr (AMAP == 0) arowA[i] = (long)z * sA + (long)rg * lda;
        else arowA[i] = ((long)(rg >> 5) * 1024 + (long)z * 32 + (rg & 31)) * (long)lda;
    }
    // ---- B staging coords (gl_lds modes): 128 rows x 4 slots = 2 chunks/thread
    long browB[2]; int kOffB[2];
#pragma unroll
    for (int i = 0; i < 2; ++i) {
        int c = i * 256 + tid;
        int r = c >> 2, sp = c & 3;
        kOffB[i] = (sp ^ ((r >> 1) & 3)) << 3;
        browB[i] = (long)z * sB + (long)(n0 + r) * ldb;
    }
    // ---- BF32 B reg-staging coords
    const int kq = tid & 7, nq = tid >> 3;

    f32x4 acc[MI][4];
#pragma unroll
    for (int i = 0; i < MI; ++i)
#pragma unroll
        for (int j = 0; j < 4; ++j) acc[i][j] = (f32x4)(0.f);

    auto stageA = [&](int buf, int kk0) {
        const int bb = buf * BUFS;
        if constexpr (MODE == 1) {
            gl_lds16(Ah_g + arowA[0] + kk0 + kOffA[0], &lds[bb + (w * 64) * 8]);
            gl_lds16(Al_g + arowA[0] + kk0 + kOffA[0], &lds[bb + 2048 + (w * 64) * 8]);
#pragma unroll
            for (int i = 0; i < 2; ++i) {
                int base = bb + 4096 + (i * 256 + w * 64) * 8;
                gl_lds16(Bh_g + browB[i] + kk0 + kOffB[i], &lds[base]);
                gl_lds16(Bl_g + browB[i] + kk0 + kOffB[i], &lds[base + 4096]);
            }
        } else if constexpr (MODE == 0) {
#pragma unroll
            for (int i = 0; i < 2; ++i)
                gl_lds16(Ah_g + arowA[i] + kk0 + kOffA[i], &lds[bb + (i * 256 + w * 64) * 8]);
#pragma unroll
            for (int i = 0; i < 2; ++i)
                gl_lds16(Bh_g + browB[i] + kk0 + kOffB[i], &lds[bb + 4096 + (i * 256 + w * 64) * 8]);
        } else {
#pragma unroll
            for (int i = 0; i < 2; ++i)
                gl_lds16(Ah_g + arowA[i] + kk0 + kOffA[i], &lds[bb + (i * 256 + w * 64) * 8]);
        }
    };

    auto loadB = [&](float4 (&rB)[4], int kk0) {
#pragma unroll
        for (int dk = 0; dk < 4; ++dk)
            rB[dk] = *reinterpret_cast<const float4*>(
                Bf_g + (long)z * sB + (long)(kk0 + kq * 4 + dk) * ldb + n0 + nq * 4);
    };

    auto bwrite = [&](int buf, float4 (&rB)[4]) {
        ushort hv[4][4];
#pragma unroll
        for (int dk = 0; dk < 4; ++dk) {
            hv[dk][0] = bf16_rne(rB[dk].x); hv[dk][1] = bf16_rne(rB[dk].y);
            hv[dk][2] = bf16_rne(rB[dk].z); hv[dk][3] = bf16_rne(rB[dk].w);
        }
#pragma unroll
        for (int dn = 0; dn < 4; ++dn) {
            int n = nq * 4 + dn;
            int phys = (kq >> 1) ^ ((n >> 1) & 3);
            int off = buf * BUFS + 4096 + n * 32 + phys * 8 + (kq & 1) * 4;
            *reinterpret_cast<short4v*>(&lds[off]) =
                short4v{(short)hv[0][dn], (short)hv[1][dn], (short)hv[2][dn], (short)hv[3][dn]};
        }
    };

    auto compute = [&](int buf) {
        const int aB = buf * BUFS;
        const int bB = buf * BUFS + 4096;
        short8v bh[4], bl[4];
#pragma unroll
        for (int nj = 0; nj < 4; ++nj) {
            int rb = wc * 64 + nj * 16 + lr;
            int off = bB + rb * 32 + ((kh ^ ((rb >> 1) & 3)) << 3);
            bh[nj] = *reinterpret_cast<const short8v*>(&lds[off]);
            if constexpr (PAIR) bl[nj] = *reinterpret_cast<const short8v*>(&lds[off + 4096]);
        }
#pragma unroll
        for (int mi = 0; mi < MI; ++mi) {
            int ra = wr * (PAIR ? 32 : 64) + mi * 16 + lr;
            int off = aB + ra * 32 + ((kh ^ ((ra >> 1) & 3)) << 3);
            short8v ah = *reinterpret_cast<const short8v*>(&lds[off]);
            if constexpr (PAIR) {
                short8v al = *reinterpret_cast<const short8v*>(&lds[off + 2048]);
#pragma unroll
                for (int nj = 0; nj < 4; ++nj) {
                    acc[mi][nj] = __builtin_amdgcn_mfma_f32_16x16x32_bf16(ah, bh[nj], acc[mi][nj], 0, 0, 0);
                    acc[mi][nj] = __builtin_amdgcn_mfma_f32_16x16x32_bf16(ah, bl[nj], acc[mi][nj], 0, 0, 0);
                    acc[mi][nj] = __builtin_amdgcn_mfma_f32_16x16x32_bf16(al, bh[nj], acc[mi][nj], 0, 0, 0);
                }
            } else {
#pragma unroll
                for (int nj = 0; nj < 4; ++nj)
                    acc[mi][nj] = __builtin_amdgcn_mfma_f32_16x16x32_bf16(ah, bh[nj], acc[mi][nj], 0, 0, 0);
            }
        }
    };

    const int nt = K >> 5;
    if constexpr (MODE == 0 || MODE == 1) {
        // 3-buf ring, 2-ahead gl_lds; barrier keeps newest stage in flight
        stageA(0, 0);
        stageA(1, 32);
        if constexpr (MODE == 1) { asm volatile("s_waitcnt vmcnt(6)" ::: "memory"); }
        else                     { asm volatile("s_waitcnt vmcnt(4)" ::: "memory"); }
        __builtin_amdgcn_s_barrier();
        __builtin_amdgcn_sched_barrier(0);
        int cc = 0, cn2 = 2;
        for (int t = 0; t < nt; ++t) {
            bool deep = (t + 2 < nt);
            if (deep) stageA(cn2, (t + 2) << 5);
            compute(cc);
            if (deep) {
                if constexpr (MODE == 1) { asm volatile("s_waitcnt vmcnt(6)" ::: "memory"); }
                else                     { asm volatile("s_waitcnt vmcnt(4)" ::: "memory"); }
            } else {
                asm volatile("s_waitcnt vmcnt(0)" ::: "memory");
            }
            if (t + 1 < nt) {
                __builtin_amdgcn_s_barrier();
                __builtin_amdgcn_sched_barrier(0);
            }
            cc = (cc == 2) ? 0 : cc + 1;
            cn2 = (cn2 == 2) ? 0 : cn2 + 1;
        }
    } else {
        float4 rBa[4], rBb[4];
        // prologue: B(0)->rBa->buf0; A(0)->buf0; A(1)->buf1; B(1)->rBb
        loadB(rBa, 0);
        bwrite(0, rBa);                      // waits rBa only
        stageA(0, 0);
        stageA(1, 32);
        loadB(rBb, 32);
        asm volatile("s_waitcnt vmcnt(6) lgkmcnt(0)" ::: "memory");   // drain A(0), keep A(1)+B(1)
        __builtin_amdgcn_s_barrier();
        __builtin_amdgcn_sched_barrier(0);
        int cc = 0, cn1 = 1, cn2 = 2;
        auto iter = [&](int t, float4 (&ld)[4], float4 (&wr_)[4]) {
            bool deep = (t + 2 < nt);
            if (deep) { stageA(cn2, (t + 2) << 5); loadB(ld, (t + 2) << 5); }
            compute(cc);
            if (t + 1 < nt) bwrite(cn1, wr_);       // implicit wait drains B(t+1) and A(t+1)
            if (deep) { asm volatile("s_waitcnt vmcnt(6) lgkmcnt(0)" ::: "memory"); }
            else      { asm volatile("s_waitcnt vmcnt(0) lgkmcnt(0)" ::: "memory"); }
            if (t + 1 < nt) {
                __builtin_amdgcn_s_barrier();
                __builtin_amdgcn_sched_barrier(0);
            }
            cc = (cc == 2) ? 0 : cc + 1;
            cn1 = (cn1 == 2) ? 0 : cn1 + 1;
            cn2 = (cn2 == 2) ? 0 : cn2 + 1;
        };
        for (int t = 0; t < nt; t += 2) {    // nt is even at every call site
            iter(t, rBa, rBb);
            iter(t + 1, rBb, rBa);
        }
    }

    // ---- epilogue
#pragma unroll
    for (int mi = 0; mi < MI; ++mi)
#pragma unroll
        for (int j = 0; j < 4; ++j) {
            int rg = m0 + wr * (PAIR ? 32 : 64) + mi * 16 + kh * 4 + j;
            long roff;
            if constexpr (CMAP == 1) roff = ((long)(rg >> 5) * 1024 + (long)z * 32 + (rg & 31)) * (long)ldc;
            else                     roff = (long)z * sC + (long)rg * ldc;
#pragma unroll
            for (int nj = 0; nj < 4; ++nj) {
                int col = n0 + wc * 64 + nj * 16 + lr;
                float v = acc[mi][nj][j];
                if constexpr (EPI >= 1) v += bias[(long)z * biasStride + col];
                if constexpr (EPI == 2) v = 0.5f * v * (1.0f + erff(v * 0.70710678118654752f));
                if constexpr (CBF16) Cb[roff + col] = bf16_rne(v);
                else                 Cf[roff + col] = v;
            }
        }
}

// ---------------- K8: per-row top-8 + row softmax stats ----------------
__global__ __launch_bounds__(64) void row_topk(const float* __restrict__ logits,
                                               float* __restrict__ mix_out, float* __restrict__ clus_out,
                                               float* __restrict__ rowmax, float* __restrict__ rowsumInv) {
    int row = blockIdx.x;
    int lane = threadIdx.x;
    const float* p = logits + (long)row * NP;
    float v[16];
#pragma unroll
    for (int i = 0; i < 16; ++i) v[i] = p[lane + i * 64];
    float mx = v[0];
#pragma unroll
    for (int i = 1; i < 16; ++i) mx = fmaxf(mx, v[i]);
#pragma unroll
    for (int o = 32; o; o >>= 1) mx = fmaxf(mx, __shfl_xor(mx, o));
    float s = 0.f;
#pragma unroll
    for (int i = 0; i < 16; ++i) s += __expf(v[i] - mx);
#pragma unroll
    for (int o = 32; o; o >>= 1) s += __shfl_xor(s, o);
    if (lane == 0) { rowmax[row] = mx; rowsumInv[row] = 1.0f / s; }
#pragma unroll
    for (int k = 0; k < KTOP; ++k) {
        float bv = -INFINITY; int bi = 1 << 30;
#pragma unroll
        for (int i = 0; i < 16; ++i) {
            if (v[i] > bv) { bv = v[i]; bi = lane + i * 64; }
        }
#pragma unroll
        for (int o = 32; o; o >>= 1) {
            float ov = __shfl_xor(bv, o); int oi = __shfl_xor(bi, o);
            if (ov > bv || (ov == bv && oi < bi)) { bv = ov; bi = oi; }
        }
        int owner = bi & 63, slot = bi >> 6;
        if (lane == owner) {
#pragma unroll
            for (int i = 0; i < 16; ++i) if (slot == i) v[i] = -INFINITY;
        }
        if (lane == k) {
            mix_out[(long)row * KTOP + k] = bv;
            clus_out[(long)row * KTOP + k] = (float)(bi >> 5);
        }
    }
}

// ---------------- K9: column softmax stats ----------------
__global__ __launch_bounds__(256) void col_stats_part(const float* __restrict__ logits,
                                                      float* __restrict__ pmax, float* __restrict__ psum) {
    int b = blockIdx.z, ms = blockIdx.y, npc = blockIdx.x;
    int np = npc * 256 + threadIdx.x;
    const float* p = logits + ((long)b * MTOK + ms * 128) * NP + np;
    float mx = -INFINITY, s = 0.f;
    for (int m = 0; m < 128; ++m) {
        float v = p[(long)m * NP];
        float nm = fmaxf(mx, v);
        s = s * __expf(mx - nm) + __expf(v - nm);
        mx = nm;
    }
    long o = ((long)b * 8 + ms) * NP + np;
    pmax[o] = mx; psum[o] = s;
}

__global__ __launch_bounds__(256) void col_stats_merge(const float* __restrict__ pmax, const float* __restrict__ psum,
                                                       float* __restrict__ cmax, float* __restrict__ csumInv) {
    int b = blockIdx.y;
    int np = blockIdx.x * 256 + threadIdx.x;
    float mx = -INFINITY;
#pragma unroll
    for (int ms = 0; ms < 8; ++ms) mx = fmaxf(mx, pmax[((long)b * 8 + ms) * NP + np]);
    float s = 0.f;
#pragma unroll
    for (int ms = 0; ms < 8; ++ms) {
        long o = ((long)b * 8 + ms) * NP + np;
        s += psum[o] * __expf(pmax[o] - mx);
    }
    cmax[(long)b * NP + np] = mx;
    csumInv[(long)b * NP + np] = 1.0f / s;
}

// ---------------- K10: dispT bf16 = softmax-over-m(logits)^T, tiled transpose ----------------
__global__ __launch_bounds__(256) void make_dispT(const float* __restrict__ logits,
                                                  const float* __restrict__ cmax, const float* __restrict__ cinv,
                                                  ushort* __restrict__ dispT) {
    __shared__ float tile[64][65];
    int b = blockIdx.z, np0 = blockIdx.x * 64, m0 = blockIdx.y * 64;
    int tr = threadIdx.x >> 6, tc = threadIdx.x & 63;
    const float* src = logits + ((long)b * MTOK + m0) * NP + np0;
#pragma unroll
    for (int i = 0; i < 16; ++i) {
        int m = tr * 16 + i;
        tile[m][tc] = src[(long)m * NP + tc];
    }
    __syncthreads();
#pragma unroll
    for (int i = 0; i < 16; ++i) {
        int npl = tr * 16 + i;
        int np = np0 + npl;
        float mx = cmax[(long)b * NP + np], iv = cinv[(long)b * NP + np];
        float v = __expf(tile[tc][npl] - mx) * iv;
        dispT[((long)b * NP + np) * MTOK + (m0 + tc)] = bf16_rne(v);
    }
}

// ---------------- K11: comb bf16 = softmax-over-np(logits), elementwise ----------------
__global__ __launch_bounds__(256) void make_comb(const float* __restrict__ logits,
                                                 const float* __restrict__ rmax, const float* __restrict__ rinv,
                                                 ushort* __restrict__ comb) {
    long base = ((long)blockIdx.x * 256 + threadIdx.x) * 4;
    int row = (int)(base >> 10);
    float mx = rmax[row], iv = rinv[row];
    float4 v = *reinterpret_cast<const float4*>(logits + base);
    *reinterpret_cast<short4v*>(comb + base) = short4v{
        (short)bf16_rne(__expf(v.x - mx) * iv), (short)bf16_rne(__expf(v.y - mx) * iv),
        (short)bf16_rne(__expf(v.z - mx) * iv), (short)bf16_rne(__expf(v.w - mx) * iv)};
}

// ---------------- launch ----------------
extern "C" void kernel_launch(void* const* d_in, const int* in_sizes, int n_in,
                              void* d_out, int out_size, void* d_ws, size_t ws_size,
                              hipStream_t stream) {
    const float* x    = (const float*)d_in[0];
    const int*   ca   = (const int*)d_in[1];
    const float* phi  = (const float*)d_in[2];
    const float* scale= (const float*)d_in[3];
    const float* w1   = (const float*)d_in[4];
    const float* b1   = (const float*)d_in[5];
    const float* w2   = (const float*)d_in[6];
    const float* b2   = (const float*)d_in[7];
    float* out = (float*)d_out;
    float* ws  = (float*)d_ws;

    float*  xn       = ws;                                   // 6291456 f32
    float*  logits   = xn + 6291456;                         // 8388608 f32
    ushort* xnp_hi   = (ushort*)(logits + 8388608);          // 6291456 sh
    ushort* xnp_lo   = xnp_hi + 6291456;                     // 6291456 sh
    ushort* phT_hi   = xnp_lo + 6291456;                     // 786432 sh
    ushort* phT_lo   = phT_hi + 786432;                      // 786432 sh
    ushort* dispT_bf = phT_lo + 786432;                      // 8388608 sh
    ushort* comb_bf  = dispT_bf + 8388608;                   // 8388608 sh
    ushort* xs_bf    = comb_bf + 8388608;                    // 6291456 sh
    ushort* h_bf     = xs_bf + 6291456;                      // 16777216 sh
    ushort* xnT_bf   = h_bf + 16777216;                      // 6291456 sh
    ushort* ysT_bf   = xnT_bf + 6291456;                     // 6291456 sh
    float*  stats    = (float*)(ysT_bf + 6291456);
    float* rowmax    = stats;                 // 8192
    float* rowsumInv = rowmax + 8192;
    float* colmax    = rowsumInv + 8192;
    float* colsumInv = colmax + 8192;
    float* pmax      = colsumInv + 8192;      // 65536
    float* psum      = pmax + 65536;          // 65536
    float* csum      = psum + 65536;          // 24576
    float* cmad      = csum + 24576;          // 24576
    float* Wbuf      = cmad + 24576;          // 24576
    float* ccnt      = Wbuf + 24576;          // 64
    float* cntpart   = ccnt + 64;             // SLICES*NEXP = 4096
    float* spart     = cntpart + 4096;        // SLICES*NEXP*DD = 3145728
    float* mpart     = spart + 3145728;       // 3145728
    float* ys        = xn;                    // alias: xn f32 dead after apply_W/make_T

    float* out_y    = out;
    float* out_mix  = out + 6291456;
    float* out_clus = out + 6291456 + 65536;

    norm_x<<<BMT, 256, 0, stream>>>(x, xn);
    norm_phi_T<<<NP, 256, 0, stream>>>(phi, scale, phT_hi, phT_lo);

    cluster_sum<<<dim3(3, SLICES), 256, 0, stream>>>(xn, ca, spart, cntpart);
    reduce_parts<<<96, 256, 0, stream>>>(spart, csum, cntpart, ccnt, 1);
    cluster_mad<<<dim3(3, SLICES), 256, 0, stream>>>(xn, ca, csum, ccnt, mpart);
    reduce_parts<<<96, 256, 0, stream>>>(mpart, cmad, nullptr, nullptr, 0);
    compute_W<<<1, 1024, 0, stream>>>(cmad, ccnt, Wbuf);
    apply_W<<<BMT, 192, 0, stream>>>(xn, ca, Wbuf, xnp_hi, xnp_lo);

    // xnT_bf[b][768][1024] = transpose(bf16(xn)) — B operand for xs SINGLE GEMM
    make_T<false><<<dim3(12, 16, NB), 256, 0, stream>>>(xnp_hi, xnT_bf, MTOK, DD);

    // logits = xn . phin  (split-pair 3-MFMA, f32-accurate; 3-deep gl_lds ring)
    gemm2<1, 0, 0, false, 0><<<dim3(8, 128, 1), 256, 0, stream>>>(
        xnp_hi, xnp_lo, nullptr, phT_hi, phT_lo, logits, nullptr,
        DD, DD, DD, NP, 0, 0, 0, nullptr, 0);

    row_topk<<<BMT, 64, 0, stream>>>(logits, out_mix, out_clus, rowmax, rowsumInv);
    col_stats_part<<<dim3(4, 8, NB), 256, 0, stream>>>(logits, pmax, psum);
    col_stats_merge<<<dim3(4, NB), 256, 0, stream>>>(pmax, psum, colmax, colsumInv);
    make_dispT<<<dim3(16, 16, NB), 256, 0, stream>>>(logits, colmax, colsumInv, dispT_bf);
    make_comb<<<8192, 256, 0, stream>>>(logits, rowmax, rowsumInv, comb_bf);

    // xs[b] = dispT . xn[b] -> bf16  (SINGLE: A dispT_bf, B xnT_bf, all gl_lds)
    gemm2<0, 0, 0, true, 0><<<dim3(6, 8, NB), 256, 0, stream>>>(
        dispT_bf, nullptr, nullptr, xnT_bf, nullptr, nullptr, xs_bf,
        MTOK, MTOK, MTOK, DD,
        (long)NP * MTOK, (long)DD * MTOK, (long)NP * DD, nullptr, 0);

    // h[n] = gelu(xs_rows(n) . w1[n] + b1[n]) -> bf16  (BF32: B=w1 f32, A token remap)
    gemm2<2, 1, 2, true, 0><<<dim3(16, 2, NEXP), 256, 0, stream>>>(
        xs_bf, nullptr, w1, nullptr, nullptr, nullptr, h_bf,
        DD, DD, HH, HH,
        0, (long)DD * HH, (long)256 * HH, b1, HH);

    // ys = h_rows(n) . w2[n] + b2[n] -> f32 [b][np][768] (token-remapped C)
    gemm2<2, 0, 1, false, 1><<<dim3(6, 2, NEXP), 256, 0, stream>>>(
        h_bf, nullptr, w2, nullptr, nullptr, ys, nullptr,
        HH, HH, DD, DD,
        (long)256 * HH, (long)HH * DD, 0, b2, DD);

    // ysT_bf[b][768][1024] = transpose(bf16(ys)) — B operand for y SINGLE GEMM
    make_T<true><<<dim3(12, 16, NB), 256, 0, stream>>>(ys, ysT_bf, MTOK, DD);

    // y[b] = comb . ys[b] -> f32 out  (SINGLE: A comb_bf, B ysT_bf, all gl_lds)
    gemm2<0, 0, 0, false, 0><<<dim3(6, 8, NB), 256, 0, stream>>>(
        comb_bf, nullptr, nullptr, ysT_bf, nullptr, out_y, nullptr,
        NP, NP, NP, DD,
        (long)MTOK * NP, (long)DD * NP, (long)MTOK * DD, nullptr, 0);
}

// Round 11
// 479.214 us; speedup vs baseline: 1.2767x; 1.0226x over previous
//
#include <hip/hip_runtime.h>
#include <cmath>

// ---------------- problem constants ----------------
// B=8, M=1024, D=768, N=32, P=32, K=8, H=2048
#define NB    8
#define MTOK  1024
#define BMT   8192      // B*M
#define DD    768
#define NEXP  32
#define PSLOT 32
#define NP    1024      // N*P
#define KTOP  8
#define HH    2048

#define SLICES 128      // partial-sum slices for cluster stats
#define TPS    64       // tokens per slice (SLICES*TPS == BMT)

typedef unsigned short ushort;
typedef __attribute__((ext_vector_type(8))) short short8v;   // 8 bf16 = 4 VGPR
typedef __attribute__((ext_vector_type(4))) short short4v;   // 8 bytes
typedef __attribute__((ext_vector_type(4))) float f32x4;

__device__ __forceinline__ ushort bf16_rne(float x) {
    unsigned u = __float_as_uint(x);
    unsigned r = (u + 0x7FFFu + ((u >> 16) & 1u)) >> 16;
    return (ushort)r;
}
__device__ __forceinline__ float bf16_to_f(ushort h) {
    return __uint_as_float(((unsigned)h) << 16);
}
__device__ __forceinline__ void split2(float x, ushort& hi, ushort& lo) {
    hi = bf16_rne(x);
    lo = bf16_rne(x - bf16_to_f(hi));
}
// HW packed f32->bf16 (RNE): dst[15:0]=cvt(a), dst[31:16]=cvt(b)
__device__ __forceinline__ unsigned cvt_pk_bf16(float a, float b) {
    unsigned r;
    asm volatile("v_cvt_pk_bf16_f32 %0, %1, %2" : "=v"(r) : "v"(a), "v"(b));
    return r;
}

// async global->LDS, 16B per lane; lds dest is wave-uniform base + lane*16
__device__ __forceinline__ void gl_lds16(const ushort* g, ushort* l) {
    __builtin_amdgcn_global_load_lds(
        (const __attribute__((address_space(1))) void*)g,
        (__attribute__((address_space(3))) void*)l, 16, 0, 0);
}

// ---------------- K1: token L2 normalize ----------------
__global__ __launch_bounds__(256) void norm_x(const float* __restrict__ x, float* __restrict__ xn) {
    int tok = blockIdx.x;
    int t = threadIdx.x;
    const float* p = x + (long)tok * DD;
    float v0 = p[t], v1 = p[t + 256], v2 = p[t + 512];
    float ss = v0 * v0 + v1 * v1 + v2 * v2;
#pragma unroll
    for (int o = 32; o; o >>= 1) ss += __shfl_xor(ss, o);
    __shared__ float sred[4];
    if ((t & 63) == 0) sred[t >> 6] = ss;
    __syncthreads();
    ss = sred[0] + sred[1] + sred[2] + sred[3];
    float inv = 1.0f / fmaxf(sqrtf(ss), 1e-12f);
    float* q = xn + (long)tok * DD;
    q[t] = v0 * inv; q[t + 256] = v1 * inv; q[t + 512] = v2 * inv;
}

// ---------------- K2: phi normalize -> transposed split pair [np][d] ----------------
__global__ __launch_bounds__(256) void norm_phi_T(const float* __restrict__ phi, const float* __restrict__ scale,
                                                  ushort* __restrict__ phT_hi, ushort* __restrict__ phT_lo) {
    int np = blockIdx.x;           // 1024 blocks
    int t = threadIdx.x;
    float ss = 0.f;
    for (int d = t; d < DD; d += 256) {
        float v = phi[(long)d * NP + np];
        ss += v * v;
    }
#pragma unroll
    for (int o = 32; o; o >>= 1) ss += __shfl_xor(ss, o);
    __shared__ float sred[4];
    if ((t & 63) == 0) sred[t >> 6] = ss;
    __syncthreads();
    ss = sred[0] + sred[1] + sred[2] + sred[3];
    float sc = scale[0] / fmaxf(sqrtf(ss), 1e-12f);
    for (int d = t; d < DD; d += 256) {
        float v = phi[(long)d * NP + np] * sc;
        ushort h, l; split2(v, h, l);
        phT_hi[(long)np * DD + d] = h;
        phT_lo[(long)np * DD + d] = l;
    }
}

// ---------------- K3: per-cluster sums (deterministic partials, 128 slices) ----------------
__global__ __launch_bounds__(256) void cluster_sum(const float* __restrict__ xn, const int* __restrict__ ca,
                                                   float* __restrict__ spart, float* __restrict__ cntpart) {
    __shared__ float s[NEXP][256];
    __shared__ float cnt[NEXP];
    int chunk = blockIdx.x, slice = blockIdx.y, t = threadIdx.x;
#pragma unroll
    for (int n = 0; n < NEXP; ++n) s[n][t] = 0.f;
    if (t < NEXP) cnt[t] = 0.f;
    __syncthreads();
    int tok0 = slice * TPS;
    for (int i = 0; i < TPS; ++i) {
        int tok = tok0 + i;
        int a = ca[tok * KTOP];
        float v = xn[(long)tok * DD + chunk * 256 + t];
        s[a][t] += v;
        if (chunk == 0 && t == 0) cnt[a] += 1.f;
    }
    __syncthreads();
    for (int n = 0; n < NEXP; ++n)
        spart[(long)slice * (NEXP * DD) + n * DD + chunk * 256 + t] = s[n][t];
    if (chunk == 0 && t < NEXP) cntpart[slice * NEXP + t] = cnt[t];
}

__global__ __launch_bounds__(256) void reduce_parts(const float* __restrict__ part, float* __restrict__ outv,
                                                    const float* __restrict__ cntpart, float* __restrict__ ccnt,
                                                    int doCnt) {
    int i = blockIdx.x * 256 + threadIdx.x;
    float s = 0.f;
#pragma unroll 8
    for (int sl = 0; sl < SLICES; ++sl) s += part[(long)sl * (NEXP * DD) + i];
    outv[i] = s;
    if (doCnt && i < NEXP) {
        float c = 0.f;
#pragma unroll 8
        for (int sl = 0; sl < SLICES; ++sl) c += cntpart[sl * NEXP + i];
        ccnt[i] = c;
    }
}

// ---------------- K4: per-cluster MAD partials ----------------
__global__ __launch_bounds__(256) void cluster_mad(const float* __restrict__ xn, const int* __restrict__ ca,
                                                   const float* __restrict__ csum, const float* __restrict__ ccnt,
                                                   float* __restrict__ mpart) {
    __shared__ float md[NEXP][256];
    __shared__ float mean[NEXP][256];
    int chunk = blockIdx.x, slice = blockIdx.y, t = threadIdx.x;
#pragma unroll
    for (int n = 0; n < NEXP; ++n) {
        float c = ccnt[n];
        mean[n][t] = (c > 0.f) ? csum[n * DD + chunk * 256 + t] / c : 0.f;
        md[n][t] = 0.f;
    }
    __syncthreads();
    int tok0 = slice * TPS;
    for (int i = 0; i < TPS; ++i) {
        int tok = tok0 + i;
        int a = ca[tok * KTOP];
        float v = xn[(long)tok * DD + chunk * 256 + t];
        md[a][t] += fabsf(v - mean[a][t]);
    }
    __syncthreads();
    for (int n = 0; n < NEXP; ++n)
        mpart[(long)slice * (NEXP * DD) + n * DD + chunk * 256 + t] = md[n][t];
}

// ---------------- K5: W = normalize(clamp(1/(mad+0.35))) ----------------
__global__ __launch_bounds__(1024) void compute_W(const float* __restrict__ cmad, const float* __restrict__ ccnt,
                                                  float* __restrict__ W) {
    __shared__ float s[16];
    int t = threadIdx.x;
    auto block_sum = [&](float v) -> float {
#pragma unroll
        for (int o = 32; o; o >>= 1) v += __shfl_xor(v, o);
        if ((t & 63) == 0) s[t >> 6] = v;
        __syncthreads();
        float tot = 0.f;
#pragma unroll
        for (int i = 0; i < 16; ++i) tot += s[i];
        __syncthreads();
        return tot;
    };
    const int TOT = NEXP * DD;
    float p = 0.f;
    for (int i = t; i < TOT; i += 1024) {
        int n = i / DD;
        float c = ccnt[n];
        float wm = (c > 0.f) ? cmad[i] / c : 0.f;
        p += 1.f / (wm + 0.35f);
    }
    float mean1 = block_sum(p) / (float)TOT;
    float clamp = 5.f * mean1;
    p = 0.f;
    for (int i = t; i < TOT; i += 1024) {
        int n = i / DD;
        float c = ccnt[n];
        float wm = (c > 0.f) ? cmad[i] / c : 0.f;
        p += fminf(1.f / (wm + 0.35f), clamp);
    }
    float mean2 = block_sum(p) / (float)TOT;
    float inv2 = 1.f / mean2;
    for (int i = t; i < TOT; i += 1024) {
        int n = i / DD;
        float c = ccnt[n];
        float wm = (c > 0.f) ? cmad[i] / c : 0.f;
        W[i] = fminf(1.f / (wm + 0.35f), clamp) * inv2;
    }
}

// ---------------- K6: xn *= W[assign]; also emit bf16 hi/lo pair ----------------
__global__ __launch_bounds__(192) void apply_W(float* __restrict__ xn, const int* __restrict__ ca,
                                               const float* __restrict__ W,
                                               ushort* __restrict__ hi, ushort* __restrict__ lo) {
    int tok = blockIdx.x;
    long d4 = (long)tok * DD + threadIdx.x * 4;
    int a = ca[tok * KTOP];
    float4 v = *reinterpret_cast<float4*>(xn + d4);
    float4 w = *reinterpret_cast<const float4*>(W + a * DD + threadIdx.x * 4);
    v.x *= w.x; v.y *= w.y; v.z *= w.z; v.w *= w.w;
    *reinterpret_cast<float4*>(xn + d4) = v;
    ushort h0,h1,h2,h3,l0,l1,l2,l3;
    split2(v.x,h0,l0); split2(v.y,h1,l1); split2(v.z,h2,l2); split2(v.w,h3,l3);
    *reinterpret_cast<short4v*>(hi + d4) = short4v{(short)h0,(short)h1,(short)h2,(short)h3};
    *reinterpret_cast<short4v*>(lo + d4) = short4v{(short)l0,(short)l1,(short)l2,(short)l3};
}

// ---------------- K7: 64x64 tiled transpose -> bf16 [z][C][R] from [z][R][C] ----------------
template <bool F32>
__global__ __launch_bounds__(256) void make_T(const void* __restrict__ srcv, ushort* __restrict__ dst,
                                              int R, int C) {
    __shared__ ushort tile[64][65];
    int z = blockIdx.z;
    int c0 = blockIdx.x * 64, r0 = blockIdx.y * 64;
    int tr = threadIdx.x >> 4;          // 0..15
    int tc4 = (threadIdx.x & 15) * 4;
    long base = (long)z * R * C;
#pragma unroll
    for (int i = 0; i < 4; ++i) {
        int r = tr + i * 16;
        if constexpr (F32) {
            const float* s = (const float*)srcv;
            float4 v = *reinterpret_cast<const float4*>(s + base + (long)(r0 + r) * C + c0 + tc4);
            tile[r][tc4 + 0] = bf16_rne(v.x); tile[r][tc4 + 1] = bf16_rne(v.y);
            tile[r][tc4 + 2] = bf16_rne(v.z); tile[r][tc4 + 3] = bf16_rne(v.w);
        } else {
            const ushort* s = (const ushort*)srcv;
            short4v v = *reinterpret_cast<const short4v*>(s + base + (long)(r0 + r) * C + c0 + tc4);
            tile[r][tc4 + 0] = (ushort)v.x; tile[r][tc4 + 1] = (ushort)v.y;
            tile[r][tc4 + 2] = (ushort)v.z; tile[r][tc4 + 3] = (ushort)v.w;
        }
    }
    __syncthreads();
#pragma unroll
    for (int i = 0; i < 4; ++i) {
        int oc = tr + i * 16;
        short4v o = short4v{(short)tile[tc4 + 0][oc], (short)tile[tc4 + 1][oc],
                            (short)tile[tc4 + 2][oc], (short)tile[tc4 + 3][oc]};
        *reinterpret_cast<short4v*>(dst + base + (long)(c0 + oc) * R + r0 + tc4) = o;
    }
}

// ---------------- MFMA GEMM, 3-buffer LDS ring, 2-iter prefetch depth ----------------
// MODE 0 SINGLE: BM=128, A and B bf16 via gl_lds (4 ops/thr/step), 1 MFMA.     vmcnt(4)
// MODE 1 PAIR:   BM=64,  A/B hi/lo pairs via gl_lds (6 ops/thr/step), 3 MFMA.  vmcnt(6)
// MODE 2 BF32:   BM=128, A bf16 gl_lds (2 ops) + B f32 2-ahead reg prefetch
//                (4 loads) + v_cvt_pk_bf16 + swizzled ds_write.                vmcnt(6)
// Swizzle: 16B slot sp of row r stored at sp ^ ((r>>1)&3) -> 2-way reads (free).
// AMAP: 0 linear z-strided, 1 token remap.  EPI: 0/1 bias/2 bias+gelu.
// CBF16: round C to bf16.  CMAP: 0 lin, 1 token remap.
template <int MODE, int AMAP, int EPI, bool CBF16, int CMAP>
__global__ __launch_bounds__(256) void gemm2(
    const ushort* __restrict__ Ah_g, const ushort* __restrict__ Al_g,
    const float*  __restrict__ Bf_g,
    const ushort* __restrict__ Bh_g, const ushort* __restrict__ Bl_g,
    float* __restrict__ Cf, ushort* __restrict__ Cb,
    int K, int lda, int ldb, int ldc,
    long sA, long sB, long sC,
    const float* __restrict__ bias, int biasStride) {
    constexpr bool PAIR = (MODE == 1);
    // PAIR buf (12288 sh): Ah 2048 | Al 2048 | Bh 4096 | Bl 4096.   x3 = 72 KB
    // SINGLE/BF32 buf (8192 sh): A 4096 | B 4096.                   x3 = 48 KB
    constexpr int BUFS = PAIR ? 12288 : 8192;
    constexpr int BM   = PAIR ? 64 : 128;
    constexpr int MI   = PAIR ? 2 : 4;
    __shared__ __attribute__((aligned(16))) ushort lds[3 * BUFS];

    // XCD-aware bijective remap (all grids multiples of 8)
    int orig = blockIdx.x + gridDim.x * (blockIdx.y + gridDim.y * blockIdx.z);
    int nwg = gridDim.x * gridDim.y * gridDim.z;
    int wg = (orig & 7) * (nwg >> 3) + (orig >> 3);
    int bx = wg % gridDim.x;
    int rest = wg / gridDim.x;
    int by = rest % gridDim.y;
    int z  = rest / gridDim.y;
    const int m0 = by * BM;
    const int n0 = bx * 128;

    const int tid = threadIdx.x, lane = tid & 63, w = tid >> 6;
    const int wr = w >> 1, wc = w & 1;
    const int lr = lane & 15, kh = lane >> 4;

    // ---- A staging coords (per 256-chunk: r=c>>2 row, sp=c&3 16B slot)
    const int NCA = PAIR ? 1 : 2;
    long arowA[2]; int kOffA[2];
#pragma unroll
    for (int i = 0; i < NCA; ++i) {
        int c = i * 256 + tid;
        int r = c >> 2, sp = c & 3;
        kOffA[i] = (sp ^ ((r >> 1) & 3)) << 3;
        int rg = m0 + r;
        if constexpr (AMAP == 0) arowA[i] = (long)z * sA + (long)rg * lda;
        else arowA[i] = ((long)(rg >> 5) * 1024 + (long)z * 32 + (rg & 31)) * (long)lda;
    }
    // ---- B staging coords (gl_lds modes): 128 rows x 4 slots = 2 chunks/thread
    long browB[2]; int kOffB[2];
#pragma unroll
    for (int i = 0; i < 2; ++i) {
        int c = i * 256 + tid;
        int r = c >> 2, sp = c & 3;
        kOffB[i] = (sp ^ ((r >> 1) & 3)) << 3;
        browB[i] = (long)z * sB + (long)(n0 + r) * ldb;
    }
    // ---- BF32 B reg-staging coords
    const int kq = tid & 7, nq = tid >> 3;

    f32x4 acc[MI][4];
#pragma unroll
    for (int i = 0; i < MI; ++i)
#pragma unroll
        for (int j = 0; j < 4; ++j) acc[i][j] = (f32x4)(0.f);

    auto stageA = [&](int buf, int kk0) {
        const int bb = buf * BUFS;
        if constexpr (MODE == 1) {
            gl_lds16(Ah_g + arowA[0] + kk0 + kOffA[0], &lds[bb + (w * 64) * 8]);
            gl_lds16(Al_g + arowA[0] + kk0 + kOffA[0], &lds[bb + 2048 + (w * 64) * 8]);
#pragma unroll
            for (int i = 0; i < 2; ++i) {
                int base = bb + 4096 + (i * 256 + w * 64) * 8;
                gl_lds16(Bh_g + browB[i] + kk0 + kOffB[i], &lds[base]);
                gl_lds16(Bl_g + browB[i] + kk0 + kOffB[i], &lds[base + 4096]);
            }
        } else if constexpr (MODE == 0) {
#pragma unroll
            for (int i = 0; i < 2; ++i)
                gl_lds16(Ah_g + arowA[i] + kk0 + kOffA[i], &lds[bb + (i * 256 + w * 64) * 8]);
#pragma unroll
            for (int i = 0; i < 2; ++i)
                gl_lds16(Bh_g + browB[i] + kk0 + kOffB[i], &lds[bb + 4096 + (i * 256 + w * 64) * 8]);
        } else {
#pragma unroll
            for (int i = 0; i < 2; ++i)
                gl_lds16(Ah_g + arowA[i] + kk0 + kOffA[i], &lds[bb + (i * 256 + w * 64) * 8]);
        }
    };

    auto loadB = [&](float4 (&rB)[4], int kk0) {
#pragma unroll
        for (int dk = 0; dk < 4; ++dk)
            rB[dk] = *reinterpret_cast<const float4*>(
                Bf_g + (long)z * sB + (long)(kk0 + kq * 4 + dk) * ldb + n0 + nq * 4);
    };

    // packed HW cvt: per dn, pair (dk0,dk1) and (dk2,dk3) -> uint2 (8B swizzled store)
    auto bwrite = [&](int buf, float4 (&rB)[4]) {
        unsigned p0[4], p1[4];
        p0[0] = cvt_pk_bf16(rB[0].x, rB[1].x); p1[0] = cvt_pk_bf16(rB[2].x, rB[3].x);
        p0[1] = cvt_pk_bf16(rB[0].y, rB[1].y); p1[1] = cvt_pk_bf16(rB[2].y, rB[3].y);
        p0[2] = cvt_pk_bf16(rB[0].z, rB[1].z); p1[2] = cvt_pk_bf16(rB[2].z, rB[3].z);
        p0[3] = cvt_pk_bf16(rB[0].w, rB[1].w); p1[3] = cvt_pk_bf16(rB[2].w, rB[3].w);
#pragma unroll
        for (int dn = 0; dn < 4; ++dn) {
            int n = nq * 4 + dn;
            int phys = (kq >> 1) ^ ((n >> 1) & 3);
            int off = buf * BUFS + 4096 + n * 32 + phys * 8 + (kq & 1) * 4;
            *reinterpret_cast<uint2*>(&lds[off]) = make_uint2(p0[dn], p1[dn]);
        }
    };

    auto compute = [&](int buf) {
        const int aB = buf * BUFS;
        const int bB = buf * BUFS + 4096;
        short8v bh[4], bl[4];
#pragma unroll
        for (int nj = 0; nj < 4; ++nj) {
            int rb = wc * 64 + nj * 16 + lr;
            int off = bB + rb * 32 + ((kh ^ ((rb >> 1) & 3)) << 3);
            bh[nj] = *reinterpret_cast<const short8v*>(&lds[off]);
            if constexpr (PAIR) bl[nj] = *reinterpret_cast<const short8v*>(&lds[off + 4096]);
        }
#pragma unroll
        for (int mi = 0; mi < MI; ++mi) {
            int ra = wr * (PAIR ? 32 : 64) + mi * 16 + lr;
            int off = aB + ra * 32 + ((kh ^ ((ra >> 1) & 3)) << 3);
            short8v ah = *reinterpret_cast<const short8v*>(&lds[off]);
            if constexpr (PAIR) {
                short8v al = *reinterpret_cast<const short8v*>(&lds[off + 2048]);
#pragma unroll
                for (int nj = 0; nj < 4; ++nj) {
                    acc[mi][nj] = __builtin_amdgcn_mfma_f32_16x16x32_bf16(ah, bh[nj], acc[mi][nj], 0, 0, 0);
                    acc[mi][nj] = __builtin_amdgcn_mfma_f32_16x16x32_bf16(ah, bl[nj], acc[mi][nj], 0, 0, 0);
                    acc[mi][nj] = __builtin_amdgcn_mfma_f32_16x16x32_bf16(al, bh[nj], acc[mi][nj], 0, 0, 0);
                }
            } else {
#pragma unroll
                for (int nj = 0; nj < 4; ++nj)
                    acc[mi][nj] = __builtin_amdgcn_mfma_f32_16x16x32_bf16(ah, bh[nj], acc[mi][nj], 0, 0, 0);
            }
        }
    };

    const int nt = K >> 5;
    if constexpr (MODE == 0 || MODE == 1) {
        // 3-buf ring, 2-ahead gl_lds; barrier keeps newest stage in flight
        stageA(0, 0);
        stageA(1, 32);
        if constexpr (MODE == 1) { asm volatile("s_waitcnt vmcnt(6)" ::: "memory"); }
        else                     { asm volatile("s_waitcnt vmcnt(4)" ::: "memory"); }
        __builtin_amdgcn_s_barrier();
        __builtin_amdgcn_sched_barrier(0);
        int cc = 0, cn2 = 2;
        for (int t = 0; t < nt; ++t) {
            bool deep = (t + 2 < nt);
            if (deep) stageA(cn2, (t + 2) << 5);
            compute(cc);
            if (deep) {
                if constexpr (MODE == 1) { asm volatile("s_waitcnt vmcnt(6)" ::: "memory"); }
                else                     { asm volatile("s_waitcnt vmcnt(4)" ::: "memory"); }
            } else {
                asm volatile("s_waitcnt vmcnt(0)" ::: "memory");
            }
            if (t + 1 < nt) {
                __builtin_amdgcn_s_barrier();
                __builtin_amdgcn_sched_barrier(0);
            }
            cc = (cc == 2) ? 0 : cc + 1;
            cn2 = (cn2 == 2) ? 0 : cn2 + 1;
        }
    } else {
        float4 rBa[4], rBb[4];
        // prologue: B(0)->rBa->buf0; A(0)->buf0; A(1)->buf1; B(1)->rBb
        loadB(rBa, 0);
        bwrite(0, rBa);                      // waits rBa only
        stageA(0, 0);
        stageA(1, 32);
        loadB(rBb, 32);
        asm volatile("s_waitcnt vmcnt(6) lgkmcnt(0)" ::: "memory");   // drain A(0), keep A(1)+B(1)
        __builtin_amdgcn_s_barrier();
        __builtin_amdgcn_sched_barrier(0);
        int cc = 0, cn1 = 1, cn2 = 2;
        auto iter = [&](int t, float4 (&ld)[4], float4 (&wr_)[4]) {
            bool deep = (t + 2 < nt);
            if (deep) { stageA(cn2, (t + 2) << 5); loadB(ld, (t + 2) << 5); }
            compute(cc);
            if (t + 1 < nt) bwrite(cn1, wr_);       // implicit wait drains B(t+1) and A(t+1)
            if (deep) { asm volatile("s_waitcnt vmcnt(6) lgkmcnt(0)" ::: "memory"); }
            else      { asm volatile("s_waitcnt vmcnt(0) lgkmcnt(0)" ::: "memory"); }
            if (t + 1 < nt) {
                __builtin_amdgcn_s_barrier();
                __builtin_amdgcn_sched_barrier(0);
            }
            cc = (cc == 2) ? 0 : cc + 1;
            cn1 = (cn1 == 2) ? 0 : cn1 + 1;
            cn2 = (cn2 == 2) ? 0 : cn2 + 1;
        };
        for (int t = 0; t < nt; t += 2) {    // nt is even at every call site
            iter(t, rBa, rBb);
            iter(t + 1, rBb, rBa);
        }
    }

    // ---- epilogue
#pragma unroll
    for (int mi = 0; mi < MI; ++mi)
#pragma unroll
        for (int j = 0; j < 4; ++j) {
            int rg = m0 + wr * (PAIR ? 32 : 64) + mi * 16 + kh * 4 + j;
            long roff;
            if constexpr (CMAP == 1) roff = ((long)(rg >> 5) * 1024 + (long)z * 32 + (rg & 31)) * (long)ldc;
            else                     roff = (long)z * sC + (long)rg * ldc;
#pragma unroll
            for (int nj = 0; nj < 4; ++nj) {
                int col = n0 + wc * 64 + nj * 16 + lr;
                float v = acc[mi][nj][j];
                if constexpr (EPI >= 1) v += bias[(long)z * biasStride + col];
                if constexpr (EPI == 2) v = 0.5f * v * (1.0f + erff(v * 0.70710678118654752f));
                if constexpr (CBF16) Cb[roff + col] = bf16_rne(v);
                else                 Cf[roff + col] = v;
            }
        }
}

// ---------------- K8: per-row top-8 + comb softmax (fused) ----------------
__global__ __launch_bounds__(64) void row_topk(const float* __restrict__ logits,
                                               float* __restrict__ mix_out, float* __restrict__ clus_out,
                                               ushort* __restrict__ comb) {
    int row = blockIdx.x;
    int lane = threadIdx.x;
    const float* p = logits + (long)row * NP;
    float v[16];
#pragma unroll
    for (int i = 0; i < 16; ++i) v[i] = p[lane + i * 64];
    float mx = v[0];
#pragma unroll
    for (int i = 1; i < 16; ++i) mx = fmaxf(mx, v[i]);
#pragma unroll
    for (int o = 32; o; o >>= 1) mx = fmaxf(mx, __shfl_xor(mx, o));
    float s = 0.f;
#pragma unroll
    for (int i = 0; i < 16; ++i) s += __expf(v[i] - mx);
#pragma unroll
    for (int o = 32; o; o >>= 1) s += __shfl_xor(s, o);
    float inv = 1.0f / s;
    // comb = softmax row, written from registers (bit-identical to old make_comb)
    ushort* crow = comb + (long)row * NP;
#pragma unroll
    for (int i = 0; i < 16; ++i)
        crow[lane + i * 64] = bf16_rne(__expf(v[i] - mx) * inv);
    // iterative top-8 extraction (ties -> lowest index, matches lax.top_k)
#pragma unroll
    for (int k = 0; k < KTOP; ++k) {
        float bv = -INFINITY; int bi = 1 << 30;
#pragma unroll
        for (int i = 0; i < 16; ++i) {
            if (v[i] > bv) { bv = v[i]; bi = lane + i * 64; }
        }
#pragma unroll
        for (int o = 32; o; o >>= 1) {
            float ov = __shfl_xor(bv, o); int oi = __shfl_xor(bi, o);
            if (ov > bv || (ov == bv && oi < bi)) { bv = ov; bi = oi; }
        }
        int owner = bi & 63, slot = bi >> 6;
        if (lane == owner) {
#pragma unroll
            for (int i = 0; i < 16; ++i) if (slot == i) v[i] = -INFINITY;
        }
        if (lane == k) {
            mix_out[(long)row * KTOP + k] = bv;
            clus_out[(long)row * KTOP + k] = (float)(bi >> 5);
        }
    }
}

// ---------------- K9: column softmax stats ----------------
__global__ __launch_bounds__(256) void col_stats_part(const float* __restrict__ logits,
                                                      float* __restrict__ pmax, float* __restrict__ psum) {
    int b = blockIdx.z, ms = blockIdx.y, npc = blockIdx.x;
    int np = npc * 256 + threadIdx.x;
    const float* p = logits + ((long)b * MTOK + ms * 128) * NP + np;
    float mx = -INFINITY, s = 0.f;
    for (int m = 0; m < 128; ++m) {
        float v = p[(long)m * NP];
        float nm = fmaxf(mx, v);
        s = s * __expf(mx - nm) + __expf(v - nm);
        mx = nm;
    }
    long o = ((long)b * 8 + ms) * NP + np;
    pmax[o] = mx; psum[o] = s;
}

__global__ __launch_bounds__(256) void col_stats_merge(const float* __restrict__ pmax, const float* __restrict__ psum,
                                                       float* __restrict__ cmax, float* __restrict__ csumInv) {
    int b = blockIdx.y;
    int np = blockIdx.x * 256 + threadIdx.x;
    float mx = -INFINITY;
#pragma unroll
    for (int ms = 0; ms < 8; ++ms) mx = fmaxf(mx, pmax[((long)b * 8 + ms) * NP + np]);
    float s = 0.f;
#pragma unroll
    for (int ms = 0; ms < 8; ++ms) {
        long o = ((long)b * 8 + ms) * NP + np;
        s += psum[o] * __expf(pmax[o] - mx);
    }
    cmax[(long)b * NP + np] = mx;
    csumInv[(long)b * NP + np] = 1.0f / s;
}

// ---------------- K10: dispT bf16 = softmax-over-m(logits)^T, tiled transpose ----------------
__global__ __launch_bounds__(256) void make_dispT(const float* __restrict__ logits,
                                                  const float* __restrict__ cmax, const float* __restrict__ cinv,
                                                  ushort* __restrict__ dispT) {
    __shared__ float tile[64][65];
    int b = blockIdx.z, np0 = blockIdx.x * 64, m0 = blockIdx.y * 64;
    int tr = threadIdx.x >> 6, tc = threadIdx.x & 63;
    const float* src = logits + ((long)b * MTOK + m0) * NP + np0;
#pragma unroll
    for (int i = 0; i < 16; ++i) {
        int m = tr * 16 + i;
        tile[m][tc] = src[(long)m * NP + tc];
    }
    __syncthreads();
#pragma unroll
    for (int i = 0; i < 16; ++i) {
        int npl = tr * 16 + i;
        int np = np0 + npl;
        float mx = cmax[(long)b * NP + np], iv = cinv[(long)b * NP + np];
        float v = __expf(tile[tc][npl] - mx) * iv;
        dispT[((long)b * NP + np) * MTOK + (m0 + tc)] = bf16_rne(v);
    }
}

// ---------------- launch ----------------
extern "C" void kernel_launch(void* const* d_in, const int* in_sizes, int n_in,
                              void* d_out, int out_size, void* d_ws, size_t ws_size,
                              hipStream_t stream) {
    const float* x    = (const float*)d_in[0];
    const int*   ca   = (const int*)d_in[1];
    const float* phi  = (const float*)d_in[2];
    const float* scale= (const float*)d_in[3];
    const float* w1   = (const float*)d_in[4];
    const float* b1   = (const float*)d_in[5];
    const float* w2   = (const float*)d_in[6];
    const float* b2   = (const float*)d_in[7];
    float* out = (float*)d_out;
    float* ws  = (float*)d_ws;

    float*  xn       = ws;                                   // 6291456 f32
    float*  logits   = xn + 6291456;                         // 8388608 f32
    ushort* xnp_hi   = (ushort*)(logits + 8388608);          // 6291456 sh
    ushort* xnp_lo   = xnp_hi + 6291456;                     // 6291456 sh
    ushort* phT_hi   = xnp_lo + 6291456;                     // 786432 sh
    ushort* phT_lo   = phT_hi + 786432;                      // 786432 sh
    ushort* dispT_bf = phT_lo + 786432;                      // 8388608 sh
    ushort* comb_bf  = dispT_bf + 8388608;                   // 8388608 sh
    ushort* xs_bf    = comb_bf + 8388608;                    // 6291456 sh
    ushort* h_bf     = xs_bf + 6291456;                      // 16777216 sh
    ushort* xnT_bf   = h_bf + 16777216;                      // 6291456 sh
    ushort* ysT_bf   = xnT_bf + 6291456;                     // 6291456 sh
    float*  stats    = (float*)(ysT_bf + 6291456);
    float* colmax    = stats;                 // 8192
    float* colsumInv = colmax + 8192;
    float* pmax      = colsumInv + 8192;      // 65536
    float* psum      = pmax + 65536;          // 65536
    float* csum      = psum + 65536;          // 24576
    float* cmad      = csum + 24576;          // 24576
    float* Wbuf      = cmad + 24576;          // 24576
    float* ccnt      = Wbuf + 24576;          // 64
    float* cntpart   = ccnt + 64;             // SLICES*NEXP = 4096
    float* spart     = cntpart + 4096;        // SLICES*NEXP*DD = 3145728
    float* mpart     = spart + 3145728;       // 3145728
    float* ys        = xn;                    // alias: xn f32 dead after apply_W/make_T

    float* out_y    = out;
    float* out_mix  = out + 6291456;
    float* out_clus = out + 6291456 + 65536;

    norm_x<<<BMT, 256, 0, stream>>>(x, xn);
    norm_phi_T<<<NP, 256, 0, stream>>>(phi, scale, phT_hi, phT_lo);

    cluster_sum<<<dim3(3, SLICES), 256, 0, stream>>>(xn, ca, spart, cntpart);
    reduce_parts<<<96, 256, 0, stream>>>(spart, csum, cntpart, ccnt, 1);
    cluster_mad<<<dim3(3, SLICES), 256, 0, stream>>>(xn, ca, csum, ccnt, mpart);
    reduce_parts<<<96, 256, 0, stream>>>(mpart, cmad, nullptr, nullptr, 0);
    compute_W<<<1, 1024, 0, stream>>>(cmad, ccnt, Wbuf);
    apply_W<<<BMT, 192, 0, stream>>>(xn, ca, Wbuf, xnp_hi, xnp_lo);

    // xnT_bf[b][768][1024] = transpose(bf16(xn)) — B operand for xs SINGLE GEMM
    make_T<false><<<dim3(12, 16, NB), 256, 0, stream>>>(xnp_hi, xnT_bf, MTOK, DD);

    // logits = xn . phin  (split-pair 3-MFMA, f32-accurate; 3-deep gl_lds ring)
    gemm2<1, 0, 0, false, 0><<<dim3(8, 128, 1), 256, 0, stream>>>(
        xnp_hi, xnp_lo, nullptr, phT_hi, phT_lo, logits, nullptr,
        DD, DD, DD, NP, 0, 0, 0, nullptr, 0);

    // top-8 + mixing weights + comb softmax (fused, one logits read)
    row_topk<<<BMT, 64, 0, stream>>>(logits, out_mix, out_clus, comb_bf);
    col_stats_part<<<dim3(4, 8, NB), 256, 0, stream>>>(logits, pmax, psum);
    col_stats_merge<<<dim3(4, NB), 256, 0, stream>>>(pmax, psum, colmax, colsumInv);
    make_dispT<<<dim3(16, 16, NB), 256, 0, stream>>>(logits, colmax, colsumInv, dispT_bf);

    // xs[b] = dispT . xn[b] -> bf16  (SINGLE: A dispT_bf, B xnT_bf, all gl_lds)
    gemm2<0, 0, 0, true, 0><<<dim3(6, 8, NB), 256, 0, stream>>>(
        dispT_bf, nullptr, nullptr, xnT_bf, nullptr, nullptr, xs_bf,
        MTOK, MTOK, MTOK, DD,
        (long)NP * MTOK, (long)DD * MTOK, (long)NP * DD, nullptr, 0);

    // h[n] = gelu(xs_rows(n) . w1[n] + b1[n]) -> bf16  (BF32: B=w1 f32, A token remap)
    gemm2<2, 1, 2, true, 0><<<dim3(16, 2, NEXP), 256, 0, stream>>>(
        xs_bf, nullptr, w1, nullptr, nullptr, nullptr, h_bf,
        DD, DD, HH, HH,
        0, (long)DD * HH, (long)256 * HH, b1, HH);

    // ys = h_rows(n) . w2[n] + b2[n] -> f32 [b][np][768] (token-remapped C)
    gemm2<2, 0, 1, false, 1><<<dim3(6, 2, NEXP), 256, 0, stream>>>(
        h_bf, nullptr, w2, nullptr, nullptr, ys, nullptr,
        HH, HH, DD, DD,
        (long)256 * HH, (long)HH * DD, 0, b2, DD);

    // ysT_bf[b][768][1024] = transpose(bf16(ys)) — B operand for y SINGLE GEMM
    make_T<true><<<dim3(12, 16, NB), 256, 0, stream>>>(ys, ysT_bf, MTOK, DD);

    // y[b] = comb . ys[b] -> f32 out  (SINGLE: A comb_bf, B ysT_bf, all gl_lds)
    gemm2<0, 0, 0, false, 0><<<dim3(6, 8, NB), 256, 0, stream>>>(
        comb_bf, nullptr, nullptr, ysT_bf, nullptr, out_y, nullptr,
        NP, NP, NP, DD,
        (long)MTOK * NP, (long)DD * NP, (long)MTOK * DD, nullptr, 0);
}

// Round 12
// 478.365 us; speedup vs baseline: 1.2790x; 1.0018x over previous
//
#include <hip/hip_runtime.h>
#include <cmath>

// ---------------- problem constants ----------------
// B=8, M=1024, D=768, N=32, P=32, K=8, H=2048
#define NB    8
#define MTOK  1024
#define BMT   8192      // B*M
#define DD    768
#define NEXP  32
#define PSLOT 32
#define NP    1024      // N*P
#define KTOP  8
#define HH    2048

#define SLICES 128      // partial-sum slices for cluster stats
#define TPS    64       // tokens per slice (SLICES*TPS == BMT)

typedef unsigned short ushort;
typedef __attribute__((ext_vector_type(8))) short short8v;   // 8 bf16 = 4 VGPR
typedef __attribute__((ext_vector_type(4))) short short4v;   // 8 bytes
typedef __attribute__((ext_vector_type(4))) float f32x4;

__device__ __forceinline__ ushort bf16_rne(float x) {
    unsigned u = __float_as_uint(x);
    unsigned r = (u + 0x7FFFu + ((u >> 16) & 1u)) >> 16;
    return (ushort)r;
}
__device__ __forceinline__ float bf16_to_f(ushort h) {
    return __uint_as_float(((unsigned)h) << 16);
}
__device__ __forceinline__ void split2(float x, ushort& hi, ushort& lo) {
    hi = bf16_rne(x);
    lo = bf16_rne(x - bf16_to_f(hi));
}
// HW packed f32->bf16 (RNE): dst[15:0]=cvt(a), dst[31:16]=cvt(b)
__device__ __forceinline__ unsigned cvt_pk_bf16(float a, float b) {
    unsigned r;
    asm volatile("v_cvt_pk_bf16_f32 %0, %1, %2" : "=v"(r) : "v"(a), "v"(b));
    return r;
}

// async global->LDS, 16B per lane; lds dest is wave-uniform base + lane*16
__device__ __forceinline__ void gl_lds16(const ushort* g, ushort* l) {
    __builtin_amdgcn_global_load_lds(
        (const __attribute__((address_space(1))) void*)g,
        (__attribute__((address_space(3))) void*)l, 16, 0, 0);
}

// ---------------- K1: token L2 normalize ----------------
__global__ __launch_bounds__(256) void norm_x(const float* __restrict__ x, float* __restrict__ xn) {
    int tok = blockIdx.x;
    int t = threadIdx.x;
    const float* p = x + (long)tok * DD;
    float v0 = p[t], v1 = p[t + 256], v2 = p[t + 512];
    float ss = v0 * v0 + v1 * v1 + v2 * v2;
#pragma unroll
    for (int o = 32; o; o >>= 1) ss += __shfl_xor(ss, o);
    __shared__ float sred[4];
    if ((t & 63) == 0) sred[t >> 6] = ss;
    __syncthreads();
    ss = sred[0] + sred[1] + sred[2] + sred[3];
    float inv = 1.0f / fmaxf(sqrtf(ss), 1e-12f);
    float* q = xn + (long)tok * DD;
    q[t] = v0 * inv; q[t + 256] = v1 * inv; q[t + 512] = v2 * inv;
}

// ---------------- K2: phi normalize -> transposed split pair [np][d] ----------------
__global__ __launch_bounds__(256) void norm_phi_T(const float* __restrict__ phi, const float* __restrict__ scale,
                                                  ushort* __restrict__ phT_hi, ushort* __restrict__ phT_lo) {
    int np = blockIdx.x;           // 1024 blocks
    int t = threadIdx.x;
    float ss = 0.f;
    for (int d = t; d < DD; d += 256) {
        float v = phi[(long)d * NP + np];
        ss += v * v;
    }
#pragma unroll
    for (int o = 32; o; o >>= 1) ss += __shfl_xor(ss, o);
    __shared__ float sred[4];
    if ((t & 63) == 0) sred[t >> 6] = ss;
    __syncthreads();
    ss = sred[0] + sred[1] + sred[2] + sred[3];
    float sc = scale[0] / fmaxf(sqrtf(ss), 1e-12f);
    for (int d = t; d < DD; d += 256) {
        float v = phi[(long)d * NP + np] * sc;
        ushort h, l; split2(v, h, l);
        phT_hi[(long)np * DD + d] = h;
        phT_lo[(long)np * DD + d] = l;
    }
}

// ---------------- K3: per-cluster sums (deterministic partials, 128 slices) ----------------
__global__ __launch_bounds__(256) void cluster_sum(const float* __restrict__ xn, const int* __restrict__ ca,
                                                   float* __restrict__ spart, float* __restrict__ cntpart) {
    __shared__ float s[NEXP][256];
    __shared__ float cnt[NEXP];
    int chunk = blockIdx.x, slice = blockIdx.y, t = threadIdx.x;
#pragma unroll
    for (int n = 0; n < NEXP; ++n) s[n][t] = 0.f;
    if (t < NEXP) cnt[t] = 0.f;
    __syncthreads();
    int tok0 = slice * TPS;
    for (int i = 0; i < TPS; ++i) {
        int tok = tok0 + i;
        int a = ca[tok * KTOP];
        float v = xn[(long)tok * DD + chunk * 256 + t];
        s[a][t] += v;
        if (chunk == 0 && t == 0) cnt[a] += 1.f;
    }
    __syncthreads();
    for (int n = 0; n < NEXP; ++n)
        spart[(long)slice * (NEXP * DD) + n * DD + chunk * 256 + t] = s[n][t];
    if (chunk == 0 && t < NEXP) cntpart[slice * NEXP + t] = cnt[t];
}

__global__ __launch_bounds__(256) void reduce_parts(const float* __restrict__ part, float* __restrict__ outv,
                                                    const float* __restrict__ cntpart, float* __restrict__ ccnt,
                                                    int doCnt) {
    int i = blockIdx.x * 256 + threadIdx.x;
    float s = 0.f;
#pragma unroll 8
    for (int sl = 0; sl < SLICES; ++sl) s += part[(long)sl * (NEXP * DD) + i];
    outv[i] = s;
    if (doCnt && i < NEXP) {
        float c = 0.f;
#pragma unroll 8
        for (int sl = 0; sl < SLICES; ++sl) c += cntpart[sl * NEXP + i];
        ccnt[i] = c;
    }
}

// ---------------- K4: per-cluster MAD partials ----------------
__global__ __launch_bounds__(256) void cluster_mad(const float* __restrict__ xn, const int* __restrict__ ca,
                                                   const float* __restrict__ csum, const float* __restrict__ ccnt,
                                                   float* __restrict__ mpart) {
    __shared__ float md[NEXP][256];
    __shared__ float mean[NEXP][256];
    int chunk = blockIdx.x, slice = blockIdx.y, t = threadIdx.x;
#pragma unroll
    for (int n = 0; n < NEXP; ++n) {
        float c = ccnt[n];
        mean[n][t] = (c > 0.f) ? csum[n * DD + chunk * 256 + t] / c : 0.f;
        md[n][t] = 0.f;
    }
    __syncthreads();
    int tok0 = slice * TPS;
    for (int i = 0; i < TPS; ++i) {
        int tok = tok0 + i;
        int a = ca[tok * KTOP];
        float v = xn[(long)tok * DD + chunk * 256 + t];
        md[a][t] += fabsf(v - mean[a][t]);
    }
    __syncthreads();
    for (int n = 0; n < NEXP; ++n)
        mpart[(long)slice * (NEXP * DD) + n * DD + chunk * 256 + t] = md[n][t];
}

// ---------------- K5: W = normalize(clamp(1/(mad+0.35))) ----------------
__global__ __launch_bounds__(1024) void compute_W(const float* __restrict__ cmad, const float* __restrict__ ccnt,
                                                  float* __restrict__ W) {
    __shared__ float s[16];
    int t = threadIdx.x;
    auto block_sum = [&](float v) -> float {
#pragma unroll
        for (int o = 32; o; o >>= 1) v += __shfl_xor(v, o);
        if ((t & 63) == 0) s[t >> 6] = v;
        __syncthreads();
        float tot = 0.f;
#pragma unroll
        for (int i = 0; i < 16; ++i) tot += s[i];
        __syncthreads();
        return tot;
    };
    const int TOT = NEXP * DD;
    float p = 0.f;
    for (int i = t; i < TOT; i += 1024) {
        int n = i / DD;
        float c = ccnt[n];
        float wm = (c > 0.f) ? cmad[i] / c : 0.f;
        p += 1.f / (wm + 0.35f);
    }
    float mean1 = block_sum(p) / (float)TOT;
    float clamp = 5.f * mean1;
    p = 0.f;
    for (int i = t; i < TOT; i += 1024) {
        int n = i / DD;
        float c = ccnt[n];
        float wm = (c > 0.f) ? cmad[i] / c : 0.f;
        p += fminf(1.f / (wm + 0.35f), clamp);
    }
    float mean2 = block_sum(p) / (float)TOT;
    float inv2 = 1.f / mean2;
    for (int i = t; i < TOT; i += 1024) {
        int n = i / DD;
        float c = ccnt[n];
        float wm = (c > 0.f) ? cmad[i] / c : 0.f;
        W[i] = fminf(1.f / (wm + 0.35f), clamp) * inv2;
    }
}

// ---------------- K6: xn *= W[assign]; also emit bf16 hi/lo pair ----------------
__global__ __launch_bounds__(192) void apply_W(float* __restrict__ xn, const int* __restrict__ ca,
                                               const float* __restrict__ W,
                                               ushort* __restrict__ hi, ushort* __restrict__ lo) {
    int tok = blockIdx.x;
    long d4 = (long)tok * DD + threadIdx.x * 4;
    int a = ca[tok * KTOP];
    float4 v = *reinterpret_cast<float4*>(xn + d4);
    float4 w = *reinterpret_cast<const float4*>(W + a * DD + threadIdx.x * 4);
    v.x *= w.x; v.y *= w.y; v.z *= w.z; v.w *= w.w;
    *reinterpret_cast<float4*>(xn + d4) = v;
    ushort h0,h1,h2,h3,l0,l1,l2,l3;
    split2(v.x,h0,l0); split2(v.y,h1,l1); split2(v.z,h2,l2); split2(v.w,h3,l3);
    *reinterpret_cast<short4v*>(hi + d4) = short4v{(short)h0,(short)h1,(short)h2,(short)h3};
    *reinterpret_cast<short4v*>(lo + d4) = short4v{(short)l0,(short)l1,(short)l2,(short)l3};
}

// ---------------- K7: 64x64 tiled transpose -> bf16 [z][C][R] from [z][R][C] ----------------
template <bool F32>
__global__ __launch_bounds__(256) void make_T(const void* __restrict__ srcv, ushort* __restrict__ dst,
                                              int R, int C) {
    __shared__ ushort tile[64][65];
    int z = blockIdx.z;
    int c0 = blockIdx.x * 64, r0 = blockIdx.y * 64;
    int tr = threadIdx.x >> 4;          // 0..15
    int tc4 = (threadIdx.x & 15) * 4;
    long base = (long)z * R * C;
#pragma unroll
    for (int i = 0; i < 4; ++i) {
        int r = tr + i * 16;
        if constexpr (F32) {
            const float* s = (const float*)srcv;
            float4 v = *reinterpret_cast<const float4*>(s + base + (long)(r0 + r) * C + c0 + tc4);
            tile[r][tc4 + 0] = bf16_rne(v.x); tile[r][tc4 + 1] = bf16_rne(v.y);
            tile[r][tc4 + 2] = bf16_rne(v.z); tile[r][tc4 + 3] = bf16_rne(v.w);
        } else {
            const ushort* s = (const ushort*)srcv;
            short4v v = *reinterpret_cast<const short4v*>(s + base + (long)(r0 + r) * C + c0 + tc4);
            tile[r][tc4 + 0] = (ushort)v.x; tile[r][tc4 + 1] = (ushort)v.y;
            tile[r][tc4 + 2] = (ushort)v.z; tile[r][tc4 + 3] = (ushort)v.w;
        }
    }
    __syncthreads();
#pragma unroll
    for (int i = 0; i < 4; ++i) {
        int oc = tr + i * 16;
        short4v o = short4v{(short)tile[tc4 + 0][oc], (short)tile[tc4 + 1][oc],
                            (short)tile[tc4 + 2][oc], (short)tile[tc4 + 3][oc]};
        *reinterpret_cast<short4v*>(dst + base + (long)(c0 + oc) * R + r0 + tc4) = o;
    }
}

// ---------------- MFMA GEMM, 3-buffer LDS ring, 2-iter prefetch depth ----------------
// MODE 0 SINGLE: BM=128, A and B bf16 via gl_lds (4 ops/thr/step), 1 MFMA.     vmcnt(4)
// MODE 1 PAIR:   BM=64,  A/B hi/lo pairs via gl_lds (6 ops/thr/step), 3 MFMA.  vmcnt(6)
// MODE 2 BF32:   BM=128, A bf16 gl_lds (2 ops) + B f32 2-ahead reg prefetch
//                (4 loads) + v_cvt_pk_bf16 + swizzled ds_write.                vmcnt(6)
// s_setprio(1) wraps the MFMA cluster (T5: role-split waves across blocks/CU).
// Swizzle: 16B slot sp of row r stored at sp ^ ((r>>1)&3) -> 2-way reads (free).
// AMAP: 0 linear z-strided, 1 token remap.  EPI: 0/1 bias/2 bias+gelu.
// CBF16: round C to bf16.  CMAP: 0 lin, 1 token remap.
template <int MODE, int AMAP, int EPI, bool CBF16, int CMAP>
__global__ __launch_bounds__(256) void gemm2(
    const ushort* __restrict__ Ah_g, const ushort* __restrict__ Al_g,
    const float*  __restrict__ Bf_g,
    const ushort* __restrict__ Bh_g, const ushort* __restrict__ Bl_g,
    float* __restrict__ Cf, ushort* __restrict__ Cb,
    int K, int lda, int ldb, int ldc,
    long sA, long sB, long sC,
    const float* __restrict__ bias, int biasStride) {
    constexpr bool PAIR = (MODE == 1);
    constexpr int BUFS = PAIR ? 12288 : 8192;
    constexpr int BM   = PAIR ? 64 : 128;
    constexpr int MI   = PAIR ? 2 : 4;
    __shared__ __attribute__((aligned(16))) ushort lds[3 * BUFS];

    // XCD-aware bijective remap (all grids multiples of 8)
    int orig = blockIdx.x + gridDim.x * (blockIdx.y + gridDim.y * blockIdx.z);
    int nwg = gridDim.x * gridDim.y * gridDim.z;
    int wg = (orig & 7) * (nwg >> 3) + (orig >> 3);
    int bx = wg % gridDim.x;
    int rest = wg / gridDim.x;
    int by = rest % gridDim.y;
    int z  = rest / gridDim.y;
    const int m0 = by * BM;
    const int n0 = bx * 128;

    const int tid = threadIdx.x, lane = tid & 63, w = tid >> 6;
    const int wr = w >> 1, wc = w & 1;
    const int lr = lane & 15, kh = lane >> 4;

    // ---- A staging coords (per 256-chunk: r=c>>2 row, sp=c&3 16B slot)
    const int NCA = PAIR ? 1 : 2;
    long arowA[2]; int kOffA[2];
#pragma unroll
    for (int i = 0; i < NCA; ++i) {
        int c = i * 256 + tid;
        int r = c >> 2, sp = c & 3;
        kOffA[i] = (sp ^ ((r >> 1) & 3)) << 3;
        int rg = m0 + r;
        if constexpr (AMAP == 0) arowA[i] = (long)z * sA + (long)rg * lda;
        else arowA[i] = ((long)(rg >> 5) * 1024 + (long)z * 32 + (rg & 31)) * (long)lda;
    }
    // ---- B staging coords (gl_lds modes): 128 rows x 4 slots = 2 chunks/thread
    long browB[2]; int kOffB[2];
#pragma unroll
    for (int i = 0; i < 2; ++i) {
        int c = i * 256 + tid;
        int r = c >> 2, sp = c & 3;
        kOffB[i] = (sp ^ ((r >> 1) & 3)) << 3;
        browB[i] = (long)z * sB + (long)(n0 + r) * ldb;
    }
    // ---- BF32 B reg-staging coords
    const int kq = tid & 7, nq = tid >> 3;

    f32x4 acc[MI][4];
#pragma unroll
    for (int i = 0; i < MI; ++i)
#pragma unroll
        for (int j = 0; j < 4; ++j) acc[i][j] = (f32x4)(0.f);

    auto stageA = [&](int buf, int kk0) {
        const int bb = buf * BUFS;
        if constexpr (MODE == 1) {
            gl_lds16(Ah_g + arowA[0] + kk0 + kOffA[0], &lds[bb + (w * 64) * 8]);
            gl_lds16(Al_g + arowA[0] + kk0 + kOffA[0], &lds[bb + 2048 + (w * 64) * 8]);
#pragma unroll
            for (int i = 0; i < 2; ++i) {
                int base = bb + 4096 + (i * 256 + w * 64) * 8;
                gl_lds16(Bh_g + browB[i] + kk0 + kOffB[i], &lds[base]);
                gl_lds16(Bl_g + browB[i] + kk0 + kOffB[i], &lds[base + 4096]);
            }
        } else if constexpr (MODE == 0) {
#pragma unroll
            for (int i = 0; i < 2; ++i)
                gl_lds16(Ah_g + arowA[i] + kk0 + kOffA[i], &lds[bb + (i * 256 + w * 64) * 8]);
#pragma unroll
            for (int i = 0; i < 2; ++i)
                gl_lds16(Bh_g + browB[i] + kk0 + kOffB[i], &lds[bb + 4096 + (i * 256 + w * 64) * 8]);
        } else {
#pragma unroll
            for (int i = 0; i < 2; ++i)
                gl_lds16(Ah_g + arowA[i] + kk0 + kOffA[i], &lds[bb + (i * 256 + w * 64) * 8]);
        }
    };

    auto loadB = [&](float4 (&rB)[4], int kk0) {
#pragma unroll
        for (int dk = 0; dk < 4; ++dk)
            rB[dk] = *reinterpret_cast<const float4*>(
                Bf_g + (long)z * sB + (long)(kk0 + kq * 4 + dk) * ldb + n0 + nq * 4);
    };

    // packed HW cvt: per dn, pair (dk0,dk1) and (dk2,dk3) -> uint2 (8B swizzled store)
    auto bwrite = [&](int buf, float4 (&rB)[4]) {
        unsigned p0[4], p1[4];
        p0[0] = cvt_pk_bf16(rB[0].x, rB[1].x); p1[0] = cvt_pk_bf16(rB[2].x, rB[3].x);
        p0[1] = cvt_pk_bf16(rB[0].y, rB[1].y); p1[1] = cvt_pk_bf16(rB[2].y, rB[3].y);
        p0[2] = cvt_pk_bf16(rB[0].z, rB[1].z); p1[2] = cvt_pk_bf16(rB[2].z, rB[3].z);
        p0[3] = cvt_pk_bf16(rB[0].w, rB[1].w); p1[3] = cvt_pk_bf16(rB[2].w, rB[3].w);
#pragma unroll
        for (int dn = 0; dn < 4; ++dn) {
            int n = nq * 4 + dn;
            int phys = (kq >> 1) ^ ((n >> 1) & 3);
            int off = buf * BUFS + 4096 + n * 32 + phys * 8 + (kq & 1) * 4;
            *reinterpret_cast<uint2*>(&lds[off]) = make_uint2(p0[dn], p1[dn]);
        }
    };

    auto compute = [&](int buf) {
        const int aB = buf * BUFS;
        const int bB = buf * BUFS + 4096;
        short8v bh[4], bl[4];
#pragma unroll
        for (int nj = 0; nj < 4; ++nj) {
            int rb = wc * 64 + nj * 16 + lr;
            int off = bB + rb * 32 + ((kh ^ ((rb >> 1) & 3)) << 3);
            bh[nj] = *reinterpret_cast<const short8v*>(&lds[off]);
            if constexpr (PAIR) bl[nj] = *reinterpret_cast<const short8v*>(&lds[off + 4096]);
        }
        __builtin_amdgcn_s_setprio(1);
#pragma unroll
        for (int mi = 0; mi < MI; ++mi) {
            int ra = wr * (PAIR ? 32 : 64) + mi * 16 + lr;
            int off = aB + ra * 32 + ((kh ^ ((ra >> 1) & 3)) << 3);
            short8v ah = *reinterpret_cast<const short8v*>(&lds[off]);
            if constexpr (PAIR) {
                short8v al = *reinterpret_cast<const short8v*>(&lds[off + 2048]);
#pragma unroll
                for (int nj = 0; nj < 4; ++nj) {
                    acc[mi][nj] = __builtin_amdgcn_mfma_f32_16x16x32_bf16(ah, bh[nj], acc[mi][nj], 0, 0, 0);
                    acc[mi][nj] = __builtin_amdgcn_mfma_f32_16x16x32_bf16(ah, bl[nj], acc[mi][nj], 0, 0, 0);
                    acc[mi][nj] = __builtin_amdgcn_mfma_f32_16x16x32_bf16(al, bh[nj], acc[mi][nj], 0, 0, 0);
                }
            } else {
#pragma unroll
                for (int nj = 0; nj < 4; ++nj)
                    acc[mi][nj] = __builtin_amdgcn_mfma_f32_16x16x32_bf16(ah, bh[nj], acc[mi][nj], 0, 0, 0);
            }
        }
        __builtin_amdgcn_s_setprio(0);
    };

    const int nt = K >> 5;
    if constexpr (MODE == 0 || MODE == 1) {
        stageA(0, 0);
        stageA(1, 32);
        if constexpr (MODE == 1) { asm volatile("s_waitcnt vmcnt(6)" ::: "memory"); }
        else                     { asm volatile("s_waitcnt vmcnt(4)" ::: "memory"); }
        __builtin_amdgcn_s_barrier();
        __builtin_amdgcn_sched_barrier(0);
        int cc = 0, cn2 = 2;
        for (int t = 0; t < nt; ++t) {
            bool deep = (t + 2 < nt);
            if (deep) stageA(cn2, (t + 2) << 5);
            compute(cc);
            if (deep) {
                if constexpr (MODE == 1) { asm volatile("s_waitcnt vmcnt(6)" ::: "memory"); }
                else                     { asm volatile("s_waitcnt vmcnt(4)" ::: "memory"); }
            } else {
                asm volatile("s_waitcnt vmcnt(0)" ::: "memory");
            }
            if (t + 1 < nt) {
                __builtin_amdgcn_s_barrier();
                __builtin_amdgcn_sched_barrier(0);
            }
            cc = (cc == 2) ? 0 : cc + 1;
            cn2 = (cn2 == 2) ? 0 : cn2 + 1;
        }
    } else {
        float4 rBa[4], rBb[4];
        loadB(rBa, 0);
        bwrite(0, rBa);
        stageA(0, 0);
        stageA(1, 32);
        loadB(rBb, 32);
        asm volatile("s_waitcnt vmcnt(6) lgkmcnt(0)" ::: "memory");
        __builtin_amdgcn_s_barrier();
        __builtin_amdgcn_sched_barrier(0);
        int cc = 0, cn1 = 1, cn2 = 2;
        auto iter = [&](int t, float4 (&ld)[4], float4 (&wr_)[4]) {
            bool deep = (t + 2 < nt);
            if (deep) { stageA(cn2, (t + 2) << 5); loadB(ld, (t + 2) << 5); }
            compute(cc);
            if (t + 1 < nt) bwrite(cn1, wr_);
            if (deep) { asm volatile("s_waitcnt vmcnt(6) lgkmcnt(0)" ::: "memory"); }
            else      { asm volatile("s_waitcnt vmcnt(0) lgkmcnt(0)" ::: "memory"); }
            if (t + 1 < nt) {
                __builtin_amdgcn_s_barrier();
                __builtin_amdgcn_sched_barrier(0);
            }
            cc = (cc == 2) ? 0 : cc + 1;
            cn1 = (cn1 == 2) ? 0 : cn1 + 1;
            cn2 = (cn2 == 2) ? 0 : cn2 + 1;
        };
        for (int t = 0; t < nt; t += 2) {
            iter(t, rBa, rBb);
            iter(t + 1, rBb, rBa);
        }
    }

    // ---- epilogue
#pragma unroll
    for (int mi = 0; mi < MI; ++mi)
#pragma unroll
        for (int j = 0; j < 4; ++j) {
            int rg = m0 + wr * (PAIR ? 32 : 64) + mi * 16 + kh * 4 + j;
            long roff;
            if constexpr (CMAP == 1) roff = ((long)(rg >> 5) * 1024 + (long)z * 32 + (rg & 31)) * (long)ldc;
            else                     roff = (long)z * sC + (long)rg * ldc;
#pragma unroll
            for (int nj = 0; nj < 4; ++nj) {
                int col = n0 + wc * 64 + nj * 16 + lr;
                float v = acc[mi][nj][j];
                if constexpr (EPI >= 1) v += bias[(long)z * biasStride + col];
                if constexpr (EPI == 2) v = 0.5f * v * (1.0f + erff(v * 0.70710678118654752f));
                if constexpr (CBF16) Cb[roff + col] = bf16_rne(v);
                else                 Cf[roff + col] = v;
            }
        }
}

// ---------------- K8: per-row top-8 + comb softmax (fused) ----------------
__global__ __launch_bounds__(64) void row_topk(const float* __restrict__ logits,
                                               float* __restrict__ mix_out, float* __restrict__ clus_out,
                                               ushort* __restrict__ comb) {
    int row = blockIdx.x;
    int lane = threadIdx.x;
    const float* p = logits + (long)row * NP;
    float v[16];
#pragma unroll
    for (int i = 0; i < 16; ++i) v[i] = p[lane + i * 64];
    float mx = v[0];
#pragma unroll
    for (int i = 1; i < 16; ++i) mx = fmaxf(mx, v[i]);
#pragma unroll
    for (int o = 32; o; o >>= 1) mx = fmaxf(mx, __shfl_xor(mx, o));
    float s = 0.f;
#pragma unroll
    for (int i = 0; i < 16; ++i) s += __expf(v[i] - mx);
#pragma unroll
    for (int o = 32; o; o >>= 1) s += __shfl_xor(s, o);
    float inv = 1.0f / s;
    ushort* crow = comb + (long)row * NP;
#pragma unroll
    for (int i = 0; i < 16; ++i)
        crow[lane + i * 64] = bf16_rne(__expf(v[i] - mx) * inv);
#pragma unroll
    for (int k = 0; k < KTOP; ++k) {
        float bv = -INFINITY; int bi = 1 << 30;
#pragma unroll
        for (int i = 0; i < 16; ++i) {
            if (v[i] > bv) { bv = v[i]; bi = lane + i * 64; }
        }
#pragma unroll
        for (int o = 32; o; o >>= 1) {
            float ov = __shfl_xor(bv, o); int oi = __shfl_xor(bi, o);
            if (ov > bv || (ov == bv && oi < bi)) { bv = ov; bi = oi; }
        }
        int owner = bi & 63, slot = bi >> 6;
        if (lane == owner) {
#pragma unroll
            for (int i = 0; i < 16; ++i) if (slot == i) v[i] = -INFINITY;
        }
        if (lane == k) {
            mix_out[(long)row * KTOP + k] = bv;
            clus_out[(long)row * KTOP + k] = (float)(bi >> 5);
        }
    }
}

// ---------------- K9: column softmax stats (partials only; merge fused into dispT) ----------------
__global__ __launch_bounds__(256) void col_stats_part(const float* __restrict__ logits,
                                                      float* __restrict__ pmax, float* __restrict__ psum) {
    int b = blockIdx.z, ms = blockIdx.y, npc = blockIdx.x;
    int np = npc * 256 + threadIdx.x;
    const float* p = logits + ((long)b * MTOK + ms * 128) * NP + np;
    float mx = -INFINITY, s = 0.f;
    for (int m = 0; m < 128; ++m) {
        float v = p[(long)m * NP];
        float nm = fmaxf(mx, v);
        s = s * __expf(mx - nm) + __expf(v - nm);
        mx = nm;
    }
    long o = ((long)b * 8 + ms) * NP + np;
    pmax[o] = mx; psum[o] = s;
}

// ---------------- K10: dispT bf16 = softmax-over-m(logits)^T (merge fused in) ----------------
__global__ __launch_bounds__(256) void make_dispT(const float* __restrict__ logits,
                                                  const float* __restrict__ pmax, const float* __restrict__ psum,
                                                  ushort* __restrict__ dispT) {
    __shared__ float tile[64][65];
    __shared__ float smax[64], sinv[64];
    int b = blockIdx.z, np0 = blockIdx.x * 64, m0 = blockIdx.y * 64;
    int tr = threadIdx.x >> 6, tc = threadIdx.x & 63;
    // merge col stats for this np tile (threads 0..63)
    if (threadIdx.x < 64) {
        int np = np0 + threadIdx.x;
        float mx = -INFINITY;
#pragma unroll
        for (int ms = 0; ms < 8; ++ms) mx = fmaxf(mx, pmax[((long)b * 8 + ms) * NP + np]);
        float s = 0.f;
#pragma unroll
        for (int ms = 0; ms < 8; ++ms) {
            long o = ((long)b * 8 + ms) * NP + np;
            s += psum[o] * __expf(pmax[o] - mx);
        }
        smax[threadIdx.x] = mx;
        sinv[threadIdx.x] = 1.0f / s;
    }
    const float* src = logits + ((long)b * MTOK + m0) * NP + np0;
#pragma unroll
    for (int i = 0; i < 16; ++i) {
        int m = tr * 16 + i;
        tile[m][tc] = src[(long)m * NP + tc];
    }
    __syncthreads();
#pragma unroll
    for (int i = 0; i < 16; ++i) {
        int npl = tr * 16 + i;
        float v = __expf(tile[tc][npl] - smax[npl]) * sinv[npl];
        dispT[((long)b * NP + np0 + npl) * MTOK + (m0 + tc)] = bf16_rne(v);
    }
}

// ---------------- launch ----------------
extern "C" void kernel_launch(void* const* d_in, const int* in_sizes, int n_in,
                              void* d_out, int out_size, void* d_ws, size_t ws_size,
                              hipStream_t stream) {
    const float* x    = (const float*)d_in[0];
    const int*   ca   = (const int*)d_in[1];
    const float* phi  = (const float*)d_in[2];
    const float* scale= (const float*)d_in[3];
    const float* w1   = (const float*)d_in[4];
    const float* b1   = (const float*)d_in[5];
    const float* w2   = (const float*)d_in[6];
    const float* b2   = (const float*)d_in[7];
    float* out = (float*)d_out;
    float* ws  = (float*)d_ws;

    float*  xn       = ws;                                   // 6291456 f32
    float*  logits   = xn + 6291456;                         // 8388608 f32
    ushort* xnp_hi   = (ushort*)(logits + 8388608);          // 6291456 sh
    ushort* xnp_lo   = xnp_hi + 6291456;                     // 6291456 sh
    ushort* phT_hi   = xnp_lo + 6291456;                     // 786432 sh
    ushort* phT_lo   = phT_hi + 786432;                      // 786432 sh
    ushort* dispT_bf = phT_lo + 786432;                      // 8388608 sh
    ushort* comb_bf  = dispT_bf + 8388608;                   // 8388608 sh
    ushort* xs_bf    = comb_bf + 8388608;                    // 6291456 sh
    ushort* h_bf     = xs_bf + 6291456;                      // 16777216 sh
    ushort* xnT_bf   = h_bf + 16777216;                      // 6291456 sh
    ushort* ysT_bf   = xnT_bf + 6291456;                     // 6291456 sh
    float*  stats    = (float*)(ysT_bf + 6291456);
    float* pmax      = stats;                 // 65536
    float* psum      = pmax + 65536;          // 65536
    float* csum      = psum + 65536;          // 24576
    float* cmad      = csum + 24576;          // 24576
    float* Wbuf      = cmad + 24576;          // 24576
    float* ccnt      = Wbuf + 24576;          // 64
    float* cntpart   = ccnt + 64;             // SLICES*NEXP = 4096
    float* spart     = cntpart + 4096;        // SLICES*NEXP*DD = 3145728
    float* mpart     = spart + 3145728;       // 3145728
    float* ys        = xn;                    // alias: xn f32 dead after apply_W/make_T

    float* out_y    = out;
    float* out_mix  = out + 6291456;
    float* out_clus = out + 6291456 + 65536;

    norm_x<<<BMT, 256, 0, stream>>>(x, xn);
    norm_phi_T<<<NP, 256, 0, stream>>>(phi, scale, phT_hi, phT_lo);

    cluster_sum<<<dim3(3, SLICES), 256, 0, stream>>>(xn, ca, spart, cntpart);
    reduce_parts<<<96, 256, 0, stream>>>(spart, csum, cntpart, ccnt, 1);
    cluster_mad<<<dim3(3, SLICES), 256, 0, stream>>>(xn, ca, csum, ccnt, mpart);
    reduce_parts<<<96, 256, 0, stream>>>(mpart, cmad, nullptr, nullptr, 0);
    compute_W<<<1, 1024, 0, stream>>>(cmad, ccnt, Wbuf);
    apply_W<<<BMT, 192, 0, stream>>>(xn, ca, Wbuf, xnp_hi, xnp_lo);

    // xnT_bf[b][768][1024] = transpose(bf16(xn)) — B operand for xs SINGLE GEMM
    make_T<false><<<dim3(12, 16, NB), 256, 0, stream>>>(xnp_hi, xnT_bf, MTOK, DD);

    // logits = xn . phin  (split-pair 3-MFMA, f32-accurate; 3-deep gl_lds ring)
    gemm2<1, 0, 0, false, 0><<<dim3(8, 128, 1), 256, 0, stream>>>(
        xnp_hi, xnp_lo, nullptr, phT_hi, phT_lo, logits, nullptr,
        DD, DD, DD, NP, 0, 0, 0, nullptr, 0);

    // top-8 + mixing weights + comb softmax (fused, one logits read)
    row_topk<<<BMT, 64, 0, stream>>>(logits, out_mix, out_clus, comb_bf);
    col_stats_part<<<dim3(4, 8, NB), 256, 0, stream>>>(logits, pmax, psum);
    make_dispT<<<dim3(16, 16, NB), 256, 0, stream>>>(logits, pmax, psum, dispT_bf);

    // xs[b] = dispT . xn[b] -> bf16  (SINGLE: A dispT_bf, B xnT_bf, all gl_lds)
    gemm2<0, 0, 0, true, 0><<<dim3(6, 8, NB), 256, 0, stream>>>(
        dispT_bf, nullptr, nullptr, xnT_bf, nullptr, nullptr, xs_bf,
        MTOK, MTOK, MTOK, DD,
        (long)NP * MTOK, (long)DD * MTOK, (long)NP * DD, nullptr, 0);

    // h[n] = gelu(xs_rows(n) . w1[n] + b1[n]) -> bf16  (BF32: B=w1 f32, A token remap)
    gemm2<2, 1, 2, true, 0><<<dim3(16, 2, NEXP), 256, 0, stream>>>(
        xs_bf, nullptr, w1, nullptr, nullptr, nullptr, h_bf,
        DD, DD, HH, HH,
        0, (long)DD * HH, (long)256 * HH, b1, HH);

    // ys = h_rows(n) . w2[n] + b2[n] -> f32 [b][np][768] (token-remapped C)
    gemm2<2, 0, 1, false, 1><<<dim3(6, 2, NEXP), 256, 0, stream>>>(
        h_bf, nullptr, w2, nullptr, nullptr, ys, nullptr,
        HH, HH, DD, DD,
        (long)256 * HH, (long)HH * DD, 0, b2, DD);

    // ysT_bf[b][768][1024] = transpose(bf16(ys)) — B operand for y SINGLE GEMM
    make_T<true><<<dim3(12, 16, NB), 256, 0, stream>>>(ys, ysT_bf, MTOK, DD);

    // y[b] = comb . ys[b] -> f32 out  (SINGLE: A comb_bf, B ysT_bf, all gl_lds)
    gemm2<0, 0, 0, false, 0><<<dim3(6, 8, NB), 256, 0, stream>>>(
        comb_bf, nullptr, nullptr, ysT_bf, nullptr, out_y, nullptr,
        NP, NP, NP, DD,
        (long)MTOK * NP, (long)DD * NP, (long)MTOK * DD, nullptr, 0);
}

// Round 13
// 473.427 us; speedup vs baseline: 1.2923x; 1.0104x over previous
//
#include <hip/hip_runtime.h>
#include <cmath>

// ---------------- problem constants ----------------
// B=8, M=1024, D=768, N=32, P=32, K=8, H=2048
#define NB    8
#define MTOK  1024
#define BMT   8192      // B*M
#define DD    768
#define NEXP  32
#define PSLOT 32
#define NP    1024      // N*P
#define KTOP  8
#define HH    2048

#define SLICES 128      // partial-sum slices for cluster stats
#define TPS    64       // tokens per slice (SLICES*TPS == BMT)

typedef unsigned short ushort;
typedef __attribute__((ext_vector_type(8))) short short8v;   // 8 bf16 = 4 VGPR
typedef __attribute__((ext_vector_type(4))) short short4v;   // 8 bytes
typedef __attribute__((ext_vector_type(4))) float f32x4;

__device__ __forceinline__ ushort bf16_rne(float x) {
    unsigned u = __float_as_uint(x);
    unsigned r = (u + 0x7FFFu + ((u >> 16) & 1u)) >> 16;
    return (ushort)r;
}
__device__ __forceinline__ float bf16_to_f(ushort h) {
    return __uint_as_float(((unsigned)h) << 16);
}
__device__ __forceinline__ void split2(float x, ushort& hi, ushort& lo) {
    hi = bf16_rne(x);
    lo = bf16_rne(x - bf16_to_f(hi));
}
// HW packed f32->bf16 (RNE): dst[15:0]=cvt(a), dst[31:16]=cvt(b)
__device__ __forceinline__ unsigned cvt_pk_bf16(float a, float b) {
    unsigned r;
    asm volatile("v_cvt_pk_bf16_f32 %0, %1, %2" : "=v"(r) : "v"(a), "v"(b));
    return r;
}

// async global->LDS, 16B per lane; lds dest is wave-uniform base + lane*16
__device__ __forceinline__ void gl_lds16(const ushort* g, ushort* l) {
    __builtin_amdgcn_global_load_lds(
        (const __attribute__((address_space(1))) void*)g,
        (__attribute__((address_space(3))) void*)l, 16, 0, 0);
}

// ---------------- K1: token L2 normalize ----------------
__global__ __launch_bounds__(256) void norm_x(const float* __restrict__ x, float* __restrict__ xn) {
    int tok = blockIdx.x;
    int t = threadIdx.x;
    const float* p = x + (long)tok * DD;
    float v0 = p[t], v1 = p[t + 256], v2 = p[t + 512];
    float ss = v0 * v0 + v1 * v1 + v2 * v2;
#pragma unroll
    for (int o = 32; o; o >>= 1) ss += __shfl_xor(ss, o);
    __shared__ float sred[4];
    if ((t & 63) == 0) sred[t >> 6] = ss;
    __syncthreads();
    ss = sred[0] + sred[1] + sred[2] + sred[3];
    float inv = 1.0f / fmaxf(sqrtf(ss), 1e-12f);
    float* q = xn + (long)tok * DD;
    q[t] = v0 * inv; q[t + 256] = v1 * inv; q[t + 512] = v2 * inv;
}

// ---------------- K2: phi normalize -> transposed split pair [np][d] ----------------
__global__ __launch_bounds__(256) void norm_phi_T(const float* __restrict__ phi, const float* __restrict__ scale,
                                                  ushort* __restrict__ phT_hi, ushort* __restrict__ phT_lo) {
    int np = blockIdx.x;           // 1024 blocks
    int t = threadIdx.x;
    float ss = 0.f;
    for (int d = t; d < DD; d += 256) {
        float v = phi[(long)d * NP + np];
        ss += v * v;
    }
#pragma unroll
    for (int o = 32; o; o >>= 1) ss += __shfl_xor(ss, o);
    __shared__ float sred[4];
    if ((t & 63) == 0) sred[t >> 6] = ss;
    __syncthreads();
    ss = sred[0] + sred[1] + sred[2] + sred[3];
    float sc = scale[0] / fmaxf(sqrtf(ss), 1e-12f);
    for (int d = t; d < DD; d += 256) {
        float v = phi[(long)d * NP + np] * sc;
        ushort h, l; split2(v, h, l);
        phT_hi[(long)np * DD + d] = h;
        phT_lo[(long)np * DD + d] = l;
    }
}

// ---------------- K3: per-cluster sums (deterministic partials, 128 slices) ----------------
__global__ __launch_bounds__(256) void cluster_sum(const float* __restrict__ xn, const int* __restrict__ ca,
                                                   float* __restrict__ spart, float* __restrict__ cntpart) {
    __shared__ float s[NEXP][256];
    __shared__ float cnt[NEXP];
    int chunk = blockIdx.x, slice = blockIdx.y, t = threadIdx.x;
#pragma unroll
    for (int n = 0; n < NEXP; ++n) s[n][t] = 0.f;
    if (t < NEXP) cnt[t] = 0.f;
    __syncthreads();
    int tok0 = slice * TPS;
    for (int i = 0; i < TPS; ++i) {
        int tok = tok0 + i;
        int a = ca[tok * KTOP];
        float v = xn[(long)tok * DD + chunk * 256 + t];
        s[a][t] += v;
        if (chunk == 0 && t == 0) cnt[a] += 1.f;
    }
    __syncthreads();
    for (int n = 0; n < NEXP; ++n)
        spart[(long)slice * (NEXP * DD) + n * DD + chunk * 256 + t] = s[n][t];
    if (chunk == 0 && t < NEXP) cntpart[slice * NEXP + t] = cnt[t];
}

__global__ __launch_bounds__(256) void reduce_parts(const float* __restrict__ part, float* __restrict__ outv,
                                                    const float* __restrict__ cntpart, float* __restrict__ ccnt,
                                                    int doCnt) {
    int i = blockIdx.x * 256 + threadIdx.x;
    float s = 0.f;
#pragma unroll 8
    for (int sl = 0; sl < SLICES; ++sl) s += part[(long)sl * (NEXP * DD) + i];
    outv[i] = s;
    if (doCnt && i < NEXP) {
        float c = 0.f;
#pragma unroll 8
        for (int sl = 0; sl < SLICES; ++sl) c += cntpart[sl * NEXP + i];
        ccnt[i] = c;
    }
}

// ---------------- K4: per-cluster MAD partials ----------------
__global__ __launch_bounds__(256) void cluster_mad(const float* __restrict__ xn, const int* __restrict__ ca,
                                                   const float* __restrict__ csum, const float* __restrict__ ccnt,
                                                   float* __restrict__ mpart) {
    __shared__ float md[NEXP][256];
    __shared__ float mean[NEXP][256];
    int chunk = blockIdx.x, slice = blockIdx.y, t = threadIdx.x;
#pragma unroll
    for (int n = 0; n < NEXP; ++n) {
        float c = ccnt[n];
        mean[n][t] = (c > 0.f) ? csum[n * DD + chunk * 256 + t] / c : 0.f;
        md[n][t] = 0.f;
    }
    __syncthreads();
    int tok0 = slice * TPS;
    for (int i = 0; i < TPS; ++i) {
        int tok = tok0 + i;
        int a = ca[tok * KTOP];
        float v = xn[(long)tok * DD + chunk * 256 + t];
        md[a][t] += fabsf(v - mean[a][t]);
    }
    __syncthreads();
    for (int n = 0; n < NEXP; ++n)
        mpart[(long)slice * (NEXP * DD) + n * DD + chunk * 256 + t] = md[n][t];
}

// ---------------- K5: W = normalize(clamp(1/(mad+0.35))) ----------------
__global__ __launch_bounds__(1024) void compute_W(const float* __restrict__ cmad, const float* __restrict__ ccnt,
                                                  float* __restrict__ W) {
    __shared__ float s[16];
    int t = threadIdx.x;
    auto block_sum = [&](float v) -> float {
#pragma unroll
        for (int o = 32; o; o >>= 1) v += __shfl_xor(v, o);
        if ((t & 63) == 0) s[t >> 6] = v;
        __syncthreads();
        float tot = 0.f;
#pragma unroll
        for (int i = 0; i < 16; ++i) tot += s[i];
        __syncthreads();
        return tot;
    };
    const int TOT = NEXP * DD;
    float p = 0.f;
    for (int i = t; i < TOT; i += 1024) {
        int n = i / DD;
        float c = ccnt[n];
        float wm = (c > 0.f) ? cmad[i] / c : 0.f;
        p += 1.f / (wm + 0.35f);
    }
    float mean1 = block_sum(p) / (float)TOT;
    float clamp = 5.f * mean1;
    p = 0.f;
    for (int i = t; i < TOT; i += 1024) {
        int n = i / DD;
        float c = ccnt[n];
        float wm = (c > 0.f) ? cmad[i] / c : 0.f;
        p += fminf(1.f / (wm + 0.35f), clamp);
    }
    float mean2 = block_sum(p) / (float)TOT;
    float inv2 = 1.f / mean2;
    for (int i = t; i < TOT; i += 1024) {
        int n = i / DD;
        float c = ccnt[n];
        float wm = (c > 0.f) ? cmad[i] / c : 0.f;
        W[i] = fminf(1.f / (wm + 0.35f), clamp) * inv2;
    }
}

// ---------------- K6: xn *= W[assign]; also emit bf16 hi/lo pair ----------------
__global__ __launch_bounds__(192) void apply_W(float* __restrict__ xn, const int* __restrict__ ca,
                                               const float* __restrict__ W,
                                               ushort* __restrict__ hi, ushort* __restrict__ lo) {
    int tok = blockIdx.x;
    long d4 = (long)tok * DD + threadIdx.x * 4;
    int a = ca[tok * KTOP];
    float4 v = *reinterpret_cast<float4*>(xn + d4);
    float4 w = *reinterpret_cast<const float4*>(W + a * DD + threadIdx.x * 4);
    v.x *= w.x; v.y *= w.y; v.z *= w.z; v.w *= w.w;
    *reinterpret_cast<float4*>(xn + d4) = v;
    ushort h0,h1,h2,h3,l0,l1,l2,l3;
    split2(v.x,h0,l0); split2(v.y,h1,l1); split2(v.z,h2,l2); split2(v.w,h3,l3);
    *reinterpret_cast<short4v*>(hi + d4) = short4v{(short)h0,(short)h1,(short)h2,(short)h3};
    *reinterpret_cast<short4v*>(lo + d4) = short4v{(short)l0,(short)l1,(short)l2,(short)l3};
}

// ---------------- K7: 64x64 tiled transpose -> bf16 [z][C][R] from [z][R][C] ----------------
template <bool F32>
__global__ __launch_bounds__(256) void make_T(const void* __restrict__ srcv, ushort* __restrict__ dst,
                                              int R, int C) {
    __shared__ ushort tile[64][65];
    int z = blockIdx.z;
    int c0 = blockIdx.x * 64, r0 = blockIdx.y * 64;
    int tr = threadIdx.x >> 4;          // 0..15
    int tc4 = (threadIdx.x & 15) * 4;
    long base = (long)z * R * C;
#pragma unroll
    for (int i = 0; i < 4; ++i) {
        int r = tr + i * 16;
        if constexpr (F32) {
            const float* s = (const float*)srcv;
            float4 v = *reinterpret_cast<const float4*>(s + base + (long)(r0 + r) * C + c0 + tc4);
            tile[r][tc4 + 0] = bf16_rne(v.x); tile[r][tc4 + 1] = bf16_rne(v.y);
            tile[r][tc4 + 2] = bf16_rne(v.z); tile[r][tc4 + 3] = bf16_rne(v.w);
        } else {
            const ushort* s = (const ushort*)srcv;
            short4v v = *reinterpret_cast<const short4v*>(s + base + (long)(r0 + r) * C + c0 + tc4);
            tile[r][tc4 + 0] = (ushort)v.x; tile[r][tc4 + 1] = (ushort)v.y;
            tile[r][tc4 + 2] = (ushort)v.z; tile[r][tc4 + 3] = (ushort)v.w;
        }
    }
    __syncthreads();
#pragma unroll
    for (int i = 0; i < 4; ++i) {
        int oc = tr + i * 16;
        short4v o = short4v{(short)tile[tc4 + 0][oc], (short)tile[tc4 + 1][oc],
                            (short)tile[tc4 + 2][oc], (short)tile[tc4 + 3][oc]};
        *reinterpret_cast<short4v*>(dst + base + (long)(c0 + oc) * R + r0 + tc4) = o;
    }
}

// ---------------- MFMA GEMM ----------------
// MODE 0 SINGLE: BM=128, A/B bf16 gl_lds, 3-buf ring depth-2.                  vmcnt(4)
// MODE 1 PAIR:   BM=64,  A/B hi/lo pairs gl_lds, 3-buf ring depth-2, 3 MFMA.   vmcnt(6)
// MODE 2 BF32:   BM=128, A bf16 gl_lds + B f32 reg prefetch -> cvt_pk ->
//                swizzled ds_write; 4-buf ring, DEPTH-3 (rBa/rBb/rBc).         vmcnt(12)
// Swizzle: 16B slot sp of row r stored at sp ^ ((r>>1)&3) -> 2-way reads (free).
// AMAP: 0 linear z-strided, 1 token remap.  EPI: 0/1 bias/2 bias+gelu.
// CBF16: round C to bf16.  CMAP: 0 lin, 1 token remap.
template <int MODE, int AMAP, int EPI, bool CBF16, int CMAP>
__global__ __launch_bounds__(256) void gemm2(
    const ushort* __restrict__ Ah_g, const ushort* __restrict__ Al_g,
    const float*  __restrict__ Bf_g,
    const ushort* __restrict__ Bh_g, const ushort* __restrict__ Bl_g,
    float* __restrict__ Cf, ushort* __restrict__ Cb,
    int K, int lda, int ldb, int ldc,
    long sA, long sB, long sC,
    const float* __restrict__ bias, int biasStride) {
    constexpr bool PAIR = (MODE == 1);
    constexpr int BUFS = PAIR ? 12288 : 8192;
    constexpr int NBUF = (MODE == 2) ? 4 : 3;
    constexpr int BM   = PAIR ? 64 : 128;
    constexpr int MI   = PAIR ? 2 : 4;
    __shared__ __attribute__((aligned(16))) ushort lds[NBUF * BUFS];

    // XCD-aware bijective remap (all grids multiples of 8)
    int orig = blockIdx.x + gridDim.x * (blockIdx.y + gridDim.y * blockIdx.z);
    int nwg = gridDim.x * gridDim.y * gridDim.z;
    int wg = (orig & 7) * (nwg >> 3) + (orig >> 3);
    int bx = wg % gridDim.x;
    int rest = wg / gridDim.x;
    int by = rest % gridDim.y;
    int z  = rest / gridDim.y;
    const int m0 = by * BM;
    const int n0 = bx * 128;

    const int tid = threadIdx.x, lane = tid & 63, w = tid >> 6;
    const int wr = w >> 1, wc = w & 1;
    const int lr = lane & 15, kh = lane >> 4;

    // ---- A staging coords (per 256-chunk: r=c>>2 row, sp=c&3 16B slot)
    const int NCA = PAIR ? 1 : 2;
    long arowA[2]; int kOffA[2];
#pragma unroll
    for (int i = 0; i < NCA; ++i) {
        int c = i * 256 + tid;
        int r = c >> 2, sp = c & 3;
        kOffA[i] = (sp ^ ((r >> 1) & 3)) << 3;
        int rg = m0 + r;
        if constexpr (AMAP == 0) arowA[i] = (long)z * sA + (long)rg * lda;
        else arowA[i] = ((long)(rg >> 5) * 1024 + (long)z * 32 + (rg & 31)) * (long)lda;
    }
    // ---- B staging coords (gl_lds modes): 128 rows x 4 slots = 2 chunks/thread
    long browB[2]; int kOffB[2];
#pragma unroll
    for (int i = 0; i < 2; ++i) {
        int c = i * 256 + tid;
        int r = c >> 2, sp = c & 3;
        kOffB[i] = (sp ^ ((r >> 1) & 3)) << 3;
        browB[i] = (long)z * sB + (long)(n0 + r) * ldb;
    }
    // ---- BF32 B reg-staging coords
    const int kq = tid & 7, nq = tid >> 3;

    f32x4 acc[MI][4];
#pragma unroll
    for (int i = 0; i < MI; ++i)
#pragma unroll
        for (int j = 0; j < 4; ++j) acc[i][j] = (f32x4)(0.f);

    auto stageA = [&](int buf, int kk0) {
        const int bb = buf * BUFS;
        if constexpr (MODE == 1) {
            gl_lds16(Ah_g + arowA[0] + kk0 + kOffA[0], &lds[bb + (w * 64) * 8]);
            gl_lds16(Al_g + arowA[0] + kk0 + kOffA[0], &lds[bb + 2048 + (w * 64) * 8]);
#pragma unroll
            for (int i = 0; i < 2; ++i) {
                int base = bb + 4096 + (i * 256 + w * 64) * 8;
                gl_lds16(Bh_g + browB[i] + kk0 + kOffB[i], &lds[base]);
                gl_lds16(Bl_g + browB[i] + kk0 + kOffB[i], &lds[base + 4096]);
            }
        } else if constexpr (MODE == 0) {
#pragma unroll
            for (int i = 0; i < 2; ++i)
                gl_lds16(Ah_g + arowA[i] + kk0 + kOffA[i], &lds[bb + (i * 256 + w * 64) * 8]);
#pragma unroll
            for (int i = 0; i < 2; ++i)
                gl_lds16(Bh_g + browB[i] + kk0 + kOffB[i], &lds[bb + 4096 + (i * 256 + w * 64) * 8]);
        } else {
#pragma unroll
            for (int i = 0; i < 2; ++i)
                gl_lds16(Ah_g + arowA[i] + kk0 + kOffA[i], &lds[bb + (i * 256 + w * 64) * 8]);
        }
    };

    auto loadB = [&](float4 (&rB)[4], int kk0) {
#pragma unroll
        for (int dk = 0; dk < 4; ++dk)
            rB[dk] = *reinterpret_cast<const float4*>(
                Bf_g + (long)z * sB + (long)(kk0 + kq * 4 + dk) * ldb + n0 + nq * 4);
    };

    // packed HW cvt: per dn, pair (dk0,dk1) and (dk2,dk3) -> uint2 (8B swizzled store)
    auto bwrite = [&](int buf, float4 (&rB)[4]) {
        unsigned p0[4], p1[4];
        p0[0] = cvt_pk_bf16(rB[0].x, rB[1].x); p1[0] = cvt_pk_bf16(rB[2].x, rB[3].x);
        p0[1] = cvt_pk_bf16(rB[0].y, rB[1].y); p1[1] = cvt_pk_bf16(rB[2].y, rB[3].y);
        p0[2] = cvt_pk_bf16(rB[0].z, rB[1].z); p1[2] = cvt_pk_bf16(rB[2].z, rB[3].z);
        p0[3] = cvt_pk_bf16(rB[0].w, rB[1].w); p1[3] = cvt_pk_bf16(rB[2].w, rB[3].w);
#pragma unroll
        for (int dn = 0; dn < 4; ++dn) {
            int n = nq * 4 + dn;
            int phys = (kq >> 1) ^ ((n >> 1) & 3);
            int off = buf * BUFS + 4096 + n * 32 + phys * 8 + (kq & 1) * 4;
            *reinterpret_cast<uint2*>(&lds[off]) = make_uint2(p0[dn], p1[dn]);
        }
    };

    auto compute = [&](int buf) {
        const int aB = buf * BUFS;
        const int bB = buf * BUFS + 4096;
        short8v bh[4], bl[4];
#pragma unroll
        for (int nj = 0; nj < 4; ++nj) {
            int rb = wc * 64 + nj * 16 + lr;
            int off = bB + rb * 32 + ((kh ^ ((rb >> 1) & 3)) << 3);
            bh[nj] = *reinterpret_cast<const short8v*>(&lds[off]);
            if constexpr (PAIR) bl[nj] = *reinterpret_cast<const short8v*>(&lds[off + 4096]);
        }
#pragma unroll
        for (int mi = 0; mi < MI; ++mi) {
            int ra = wr * (PAIR ? 32 : 64) + mi * 16 + lr;
            int off = aB + ra * 32 + ((kh ^ ((ra >> 1) & 3)) << 3);
            short8v ah = *reinterpret_cast<const short8v*>(&lds[off]);
            if constexpr (PAIR) {
                short8v al = *reinterpret_cast<const short8v*>(&lds[off + 2048]);
#pragma unroll
                for (int nj = 0; nj < 4; ++nj) {
                    acc[mi][nj] = __builtin_amdgcn_mfma_f32_16x16x32_bf16(ah, bh[nj], acc[mi][nj], 0, 0, 0);
                    acc[mi][nj] = __builtin_amdgcn_mfma_f32_16x16x32_bf16(ah, bl[nj], acc[mi][nj], 0, 0, 0);
                    acc[mi][nj] = __builtin_amdgcn_mfma_f32_16x16x32_bf16(al, bh[nj], acc[mi][nj], 0, 0, 0);
                }
            } else {
#pragma unroll
                for (int nj = 0; nj < 4; ++nj)
                    acc[mi][nj] = __builtin_amdgcn_mfma_f32_16x16x32_bf16(ah, bh[nj], acc[mi][nj], 0, 0, 0);
            }
        }
    };

    const int nt = K >> 5;
    if constexpr (MODE == 0 || MODE == 1) {
        stageA(0, 0);
        stageA(1, 32);
        if constexpr (MODE == 1) { asm volatile("s_waitcnt vmcnt(6)" ::: "memory"); }
        else                     { asm volatile("s_waitcnt vmcnt(4)" ::: "memory"); }
        __builtin_amdgcn_s_barrier();
        __builtin_amdgcn_sched_barrier(0);
        int cc = 0, cn2 = 2;
        for (int t = 0; t < nt; ++t) {
            bool deep = (t + 2 < nt);
            if (deep) stageA(cn2, (t + 2) << 5);
            compute(cc);
            if (deep) {
                if constexpr (MODE == 1) { asm volatile("s_waitcnt vmcnt(6)" ::: "memory"); }
                else                     { asm volatile("s_waitcnt vmcnt(4)" ::: "memory"); }
            } else {
                asm volatile("s_waitcnt vmcnt(0)" ::: "memory");
            }
            if (t + 1 < nt) {
                __builtin_amdgcn_s_barrier();
                __builtin_amdgcn_sched_barrier(0);
            }
            cc = (cc == 2) ? 0 : cc + 1;
            cn2 = (cn2 == 2) ? 0 : cn2 + 1;
        }
    } else {
        // ---- DEPTH-3, 4-buf ring ----
        float4 rBa[4], rBb[4], rBc[4];
        // prologue: B(0)->rBa->buf0; A(0..2)->buf0..2; B(1)->rBb; B(2)->rBc
        loadB(rBa, 0);
        bwrite(0, rBa);                      // implicit wait on rBa only
        stageA(0, 0);
        stageA(1, 32);
        stageA(2, 64);
        loadB(rBb, 32);
        loadB(rBc, 64);
        // outstanding: A0(2) A1(2) A2(2) B1(4) B2(4) = 14 -> drain A0, keep 12
        asm volatile("s_waitcnt vmcnt(12) lgkmcnt(0)" ::: "memory");
        __builtin_amdgcn_s_barrier();
        __builtin_amdgcn_sched_barrier(0);
        int cc = 0, cn1 = 1, cn3 = 3;
        auto iter = [&](int t, float4 (&ld)[4], float4 (&wr_)[4]) {
            bool deep3 = (t + 3 < nt);
            if (deep3) { stageA(cn3, (t + 3) << 5); loadB(ld, (t + 3) << 5); }
            compute(cc);
            if (t + 1 < nt) bwrite(cn1, wr_);    // implicit wait drains B(t+1), A(t+1)
            if (deep3)             { asm volatile("s_waitcnt vmcnt(12) lgkmcnt(0)" ::: "memory"); }
            else if (t + 2 < nt)   { asm volatile("s_waitcnt vmcnt(6) lgkmcnt(0)" ::: "memory"); }
            else                   { asm volatile("s_waitcnt vmcnt(0) lgkmcnt(0)" ::: "memory"); }
            if (t + 1 < nt) {
                __builtin_amdgcn_s_barrier();
                __builtin_amdgcn_sched_barrier(0);
            }
            cc = (cc + 1) & 3; cn1 = (cn1 + 1) & 3; cn3 = (cn3 + 1) & 3;
        };
        for (int t = 0; t < nt; t += 3) {
            iter(t, rBa, rBb);
            if (t + 1 < nt) iter(t + 1, rBb, rBc);
            if (t + 2 < nt) iter(t + 2, rBc, rBa);
        }
    }

    // ---- epilogue
#pragma unroll
    for (int mi = 0; mi < MI; ++mi)
#pragma unroll
        for (int j = 0; j < 4; ++j) {
            int rg = m0 + wr * (PAIR ? 32 : 64) + mi * 16 + kh * 4 + j;
            long roff;
            if constexpr (CMAP == 1) roff = ((long)(rg >> 5) * 1024 + (long)z * 32 + (rg & 31)) * (long)ldc;
            else                     roff = (long)z * sC + (long)rg * ldc;
#pragma unroll
            for (int nj = 0; nj < 4; ++nj) {
                int col = n0 + wc * 64 + nj * 16 + lr;
                float v = acc[mi][nj][j];
                if constexpr (EPI >= 1) v += bias[(long)z * biasStride + col];
                if constexpr (EPI == 2) v = 0.5f * v * (1.0f + erff(v * 0.70710678118654752f));
                if constexpr (CBF16) Cb[roff + col] = bf16_rne(v);
                else                 Cf[roff + col] = v;
            }
        }
}

// ---------------- K8: per-row top-8 + comb softmax (fused) ----------------
__global__ __launch_bounds__(64) void row_topk(const float* __restrict__ logits,
                                               float* __restrict__ mix_out, float* __restrict__ clus_out,
                                               ushort* __restrict__ comb) {
    int row = blockIdx.x;
    int lane = threadIdx.x;
    const float* p = logits + (long)row * NP;
    float v[16];
#pragma unroll
    for (int i = 0; i < 16; ++i) v[i] = p[lane + i * 64];
    float mx = v[0];
#pragma unroll
    for (int i = 1; i < 16; ++i) mx = fmaxf(mx, v[i]);
#pragma unroll
    for (int o = 32; o; o >>= 1) mx = fmaxf(mx, __shfl_xor(mx, o));
    float s = 0.f;
#pragma unroll
    for (int i = 0; i < 16; ++i) s += __expf(v[i] - mx);
#pragma unroll
    for (int o = 32; o; o >>= 1) s += __shfl_xor(s, o);
    float inv = 1.0f / s;
    ushort* crow = comb + (long)row * NP;
#pragma unroll
    for (int i = 0; i < 16; ++i)
        crow[lane + i * 64] = bf16_rne(__expf(v[i] - mx) * inv);
#pragma unroll
    for (int k = 0; k < KTOP; ++k) {
        float bv = -INFINITY; int bi = 1 << 30;
#pragma unroll
        for (int i = 0; i < 16; ++i) {
            if (v[i] > bv) { bv = v[i]; bi = lane + i * 64; }
        }
#pragma unroll
        for (int o = 32; o; o >>= 1) {
            float ov = __shfl_xor(bv, o); int oi = __shfl_xor(bi, o);
            if (ov > bv || (ov == bv && oi < bi)) { bv = ov; bi = oi; }
        }
        int owner = bi & 63, slot = bi >> 6;
        if (lane == owner) {
#pragma unroll
            for (int i = 0; i < 16; ++i) if (slot == i) v[i] = -INFINITY;
        }
        if (lane == k) {
            mix_out[(long)row * KTOP + k] = bv;
            clus_out[(long)row * KTOP + k] = (float)(bi >> 5);
        }
    }
}

// ---------------- K9: column softmax stats (partials only; merge fused into dispT) ----------------
__global__ __launch_bounds__(256) void col_stats_part(const float* __restrict__ logits,
                                                      float* __restrict__ pmax, float* __restrict__ psum) {
    int b = blockIdx.z, ms = blockIdx.y, npc = blockIdx.x;
    int np = npc * 256 + threadIdx.x;
    const float* p = logits + ((long)b * MTOK + ms * 128) * NP + np;
    float mx = -INFINITY, s = 0.f;
    for (int m = 0; m < 128; ++m) {
        float v = p[(long)m * NP];
        float nm = fmaxf(mx, v);
        s = s * __expf(mx - nm) + __expf(v - nm);
        mx = nm;
    }
    long o = ((long)b * 8 + ms) * NP + np;
    pmax[o] = mx; psum[o] = s;
}

// ---------------- K10: dispT bf16 = softmax-over-m(logits)^T (merge fused in) ----------------
__global__ __launch_bounds__(256) void make_dispT(const float* __restrict__ logits,
                                                  const float* __restrict__ pmax, const float* __restrict__ psum,
                                                  ushort* __restrict__ dispT) {
    __shared__ float tile[64][65];
    __shared__ float smax[64], sinv[64];
    int b = blockIdx.z, np0 = blockIdx.x * 64, m0 = blockIdx.y * 64;
    int tr = threadIdx.x >> 6, tc = threadIdx.x & 63;
    if (threadIdx.x < 64) {
        int np = np0 + threadIdx.x;
        float mx = -INFINITY;
#pragma unroll
        for (int ms = 0; ms < 8; ++ms) mx = fmaxf(mx, pmax[((long)b * 8 + ms) * NP + np]);
        float s = 0.f;
#pragma unroll
        for (int ms = 0; ms < 8; ++ms) {
            long o = ((long)b * 8 + ms) * NP + np;
            s += psum[o] * __expf(pmax[o] - mx);
        }
        smax[threadIdx.x] = mx;
        sinv[threadIdx.x] = 1.0f / s;
    }
    const float* src = logits + ((long)b * MTOK + m0) * NP + np0;
#pragma unroll
    for (int i = 0; i < 16; ++i) {
        int m = tr * 16 + i;
        tile[m][tc] = src[(long)m * NP + tc];
    }
    __syncthreads();
#pragma unroll
    for (int i = 0; i < 16; ++i) {
        int npl = tr * 16 + i;
        float v = __expf(tile[tc][npl] - smax[npl]) * sinv[npl];
        dispT[((long)b * NP + np0 + npl) * MTOK + (m0 + tc)] = bf16_rne(v);
    }
}

// ---------------- launch ----------------
extern "C" void kernel_launch(void* const* d_in, const int* in_sizes, int n_in,
                              void* d_out, int out_size, void* d_ws, size_t ws_size,
                              hipStream_t stream) {
    const float* x    = (const float*)d_in[0];
    const int*   ca   = (const int*)d_in[1];
    const float* phi  = (const float*)d_in[2];
    const float* scale= (const float*)d_in[3];
    const float* w1   = (const float*)d_in[4];
    const float* b1   = (const float*)d_in[5];
    const float* w2   = (const float*)d_in[6];
    const float* b2   = (const float*)d_in[7];
    float* out = (float*)d_out;
    float* ws  = (float*)d_ws;

    float*  xn       = ws;                                   // 6291456 f32
    float*  logits   = xn + 6291456;                         // 8388608 f32
    ushort* xnp_hi   = (ushort*)(logits + 8388608);          // 6291456 sh
    ushort* xnp_lo   = xnp_hi + 6291456;                     // 6291456 sh
    ushort* phT_hi   = xnp_lo + 6291456;                     // 786432 sh
    ushort* phT_lo   = phT_hi + 786432;                      // 786432 sh
    ushort* dispT_bf = phT_lo + 786432;                      // 8388608 sh
    ushort* comb_bf  = dispT_bf + 8388608;                   // 8388608 sh
    ushort* xs_bf    = comb_bf + 8388608;                    // 6291456 sh
    ushort* h_bf     = xs_bf + 6291456;                      // 16777216 sh
    ushort* xnT_bf   = h_bf + 16777216;                      // 6291456 sh
    ushort* ysT_bf   = xnT_bf + 6291456;                     // 6291456 sh
    float*  stats    = (float*)(ysT_bf + 6291456);
    float* pmax      = stats;                 // 65536
    float* psum      = pmax + 65536;          // 65536
    float* csum      = psum + 65536;          // 24576
    float* cmad      = csum + 24576;          // 24576
    float* Wbuf      = cmad + 24576;          // 24576
    float* ccnt      = Wbuf + 24576;          // 64
    float* cntpart   = ccnt + 64;             // SLICES*NEXP = 4096
    float* spart     = cntpart + 4096;        // SLICES*NEXP*DD = 3145728
    float* mpart     = spart + 3145728;       // 3145728
    float* ys        = xn;                    // alias: xn f32 dead after apply_W/make_T

    float* out_y    = out;
    float* out_mix  = out + 6291456;
    float* out_clus = out + 6291456 + 65536;

    norm_x<<<BMT, 256, 0, stream>>>(x, xn);
    norm_phi_T<<<NP, 256, 0, stream>>>(phi, scale, phT_hi, phT_lo);

    cluster_sum<<<dim3(3, SLICES), 256, 0, stream>>>(xn, ca, spart, cntpart);
    reduce_parts<<<96, 256, 0, stream>>>(spart, csum, cntpart, ccnt, 1);
    cluster_mad<<<dim3(3, SLICES), 256, 0, stream>>>(xn, ca, csum, ccnt, mpart);
    reduce_parts<<<96, 256, 0, stream>>>(mpart, cmad, nullptr, nullptr, 0);
    compute_W<<<1, 1024, 0, stream>>>(cmad, ccnt, Wbuf);
    apply_W<<<BMT, 192, 0, stream>>>(xn, ca, Wbuf, xnp_hi, xnp_lo);

    // xnT_bf[b][768][1024] = transpose(bf16(xn)) — B operand for xs SINGLE GEMM
    make_T<false><<<dim3(12, 16, NB), 256, 0, stream>>>(xnp_hi, xnT_bf, MTOK, DD);

    // logits = xn . phin  (split-pair 3-MFMA, f32-accurate; 3-deep gl_lds ring)
    gemm2<1, 0, 0, false, 0><<<dim3(8, 128, 1), 256, 0, stream>>>(
        xnp_hi, xnp_lo, nullptr, phT_hi, phT_lo, logits, nullptr,
        DD, DD, DD, NP, 0, 0, 0, nullptr, 0);

    // top-8 + mixing weights + comb softmax (fused, one logits read)
    row_topk<<<BMT, 64, 0, stream>>>(logits, out_mix, out_clus, comb_bf);
    col_stats_part<<<dim3(4, 8, NB), 256, 0, stream>>>(logits, pmax, psum);
    make_dispT<<<dim3(16, 16, NB), 256, 0, stream>>>(logits, pmax, psum, dispT_bf);

    // xs[b] = dispT . xn[b] -> bf16  (SINGLE: A dispT_bf, B xnT_bf, all gl_lds)
    gemm2<0, 0, 0, true, 0><<<dim3(6, 8, NB), 256, 0, stream>>>(
        dispT_bf, nullptr, nullptr, xnT_bf, nullptr, nullptr, xs_bf,
        MTOK, MTOK, MTOK, DD,
        (long)NP * MTOK, (long)DD * MTOK, (long)NP * DD, nullptr, 0);

    // h[n] = gelu(xs_rows(n) . w1[n] + b1[n]) -> bf16  (BF32 depth-3: B=w1 f32)
    gemm2<2, 1, 2, true, 0><<<dim3(16, 2, NEXP), 256, 0, stream>>>(
        xs_bf, nullptr, w1, nullptr, nullptr, nullptr, h_bf,
        DD, DD, HH, HH,
        0, (long)DD * HH, (long)256 * HH, b1, HH);

    // ys = h_rows(n) . w2[n] + b2[n] -> f32 [b][np][768] (BF32 depth-3)
    gemm2<2, 0, 1, false, 1><<<dim3(6, 2, NEXP), 256, 0, stream>>>(
        h_bf, nullptr, w2, nullptr, nullptr, ys, nullptr,
        HH, HH, DD, DD,
        (long)256 * HH, (long)HH * DD, 0, b2, DD);

    // ysT_bf[b][768][1024] = transpose(bf16(ys)) — B operand for y SINGLE GEMM
    make_T<true><<<dim3(12, 16, NB), 256, 0, stream>>>(ys, ysT_bf, MTOK, DD);

    // y[b] = comb . ys[b] -> f32 out  (SINGLE: A comb_bf, B ysT_bf, all gl_lds)
    gemm2<0, 0, 0, false, 0><<<dim3(6, 8, NB), 256, 0, stream>>>(
        comb_bf, nullptr, nullptr, ysT_bf, nullptr, out_y, nullptr,
        NP, NP, NP, DD,
        (long)MTOK * NP, (long)DD * NP, (long)MTOK * DD, nullptr, 0);
}

// Round 14
// 466.118 us; speedup vs baseline: 1.3126x; 1.0157x over previous
//
#include <hip/hip_runtime.h>
#include <cmath>

// ---------------- problem constants ----------------
// B=8, M=1024, D=768, N=32, P=32, K=8, H=2048
#define NB    8
#define MTOK  1024
#define BMT   8192      // B*M
#define DD    768
#define NEXP  32
#define PSLOT 32
#define NP    1024      // N*P
#define KTOP  8
#define HH    2048

#define SLICES 128      // partial-sum slices for cluster stats
#define TPS    64       // tokens per slice (SLICES*TPS == BMT)

typedef unsigned short ushort;
typedef __attribute__((ext_vector_type(8))) short short8v;   // 8 bf16 = 4 VGPR
typedef __attribute__((ext_vector_type(4))) short short4v;   // 8 bytes
typedef __attribute__((ext_vector_type(4))) float f32x4;

__device__ __forceinline__ ushort bf16_rne(float x) {
    unsigned u = __float_as_uint(x);
    unsigned r = (u + 0x7FFFu + ((u >> 16) & 1u)) >> 16;
    return (ushort)r;
}
__device__ __forceinline__ float bf16_to_f(ushort h) {
    return __uint_as_float(((unsigned)h) << 16);
}
__device__ __forceinline__ void split2(float x, ushort& hi, ushort& lo) {
    hi = bf16_rne(x);
    lo = bf16_rne(x - bf16_to_f(hi));
}
// HW packed f32->bf16 (RNE): dst[15:0]=cvt(a), dst[31:16]=cvt(b)
__device__ __forceinline__ unsigned cvt_pk_bf16(float a, float b) {
    unsigned r;
    asm volatile("v_cvt_pk_bf16_f32 %0, %1, %2" : "=v"(r) : "v"(a), "v"(b));
    return r;
}

// async global->LDS, 16B per lane; lds dest is wave-uniform base + lane*16
__device__ __forceinline__ void gl_lds16(const ushort* g, ushort* l) {
    __builtin_amdgcn_global_load_lds(
        (const __attribute__((address_space(1))) void*)g,
        (__attribute__((address_space(3))) void*)l, 16, 0, 0);
}

// ---------------- K1: token L2 normalize ----------------
__global__ __launch_bounds__(256) void norm_x(const float* __restrict__ x, float* __restrict__ xn) {
    int tok = blockIdx.x;
    int t = threadIdx.x;
    const float* p = x + (long)tok * DD;
    float v0 = p[t], v1 = p[t + 256], v2 = p[t + 512];
    float ss = v0 * v0 + v1 * v1 + v2 * v2;
#pragma unroll
    for (int o = 32; o; o >>= 1) ss += __shfl_xor(ss, o);
    __shared__ float sred[4];
    if ((t & 63) == 0) sred[t >> 6] = ss;
    __syncthreads();
    ss = sred[0] + sred[1] + sred[2] + sred[3];
    float inv = 1.0f / fmaxf(sqrtf(ss), 1e-12f);
    float* q = xn + (long)tok * DD;
    q[t] = v0 * inv; q[t + 256] = v1 * inv; q[t + 512] = v2 * inv;
}

// ---------------- K2: phi normalize -> transposed split pair [np][d] ----------------
__global__ __launch_bounds__(256) void norm_phi_T(const float* __restrict__ phi, const float* __restrict__ scale,
                                                  ushort* __restrict__ phT_hi, ushort* __restrict__ phT_lo) {
    int np = blockIdx.x;           // 1024 blocks
    int t = threadIdx.x;
    float ss = 0.f;
    for (int d = t; d < DD; d += 256) {
        float v = phi[(long)d * NP + np];
        ss += v * v;
    }
#pragma unroll
    for (int o = 32; o; o >>= 1) ss += __shfl_xor(ss, o);
    __shared__ float sred[4];
    if ((t & 63) == 0) sred[t >> 6] = ss;
    __syncthreads();
    ss = sred[0] + sred[1] + sred[2] + sred[3];
    float sc = scale[0] / fmaxf(sqrtf(ss), 1e-12f);
    for (int d = t; d < DD; d += 256) {
        float v = phi[(long)d * NP + np] * sc;
        ushort h, l; split2(v, h, l);
        phT_hi[(long)np * DD + d] = h;
        phT_lo[(long)np * DD + d] = l;
    }
}

// ---------------- K3: per-cluster sums (deterministic partials, 128 slices) ----------------
__global__ __launch_bounds__(256) void cluster_sum(const float* __restrict__ xn, const int* __restrict__ ca,
                                                   float* __restrict__ spart, float* __restrict__ cntpart) {
    __shared__ float s[NEXP][256];
    __shared__ float cnt[NEXP];
    int chunk = blockIdx.x, slice = blockIdx.y, t = threadIdx.x;
#pragma unroll
    for (int n = 0; n < NEXP; ++n) s[n][t] = 0.f;
    if (t < NEXP) cnt[t] = 0.f;
    __syncthreads();
    int tok0 = slice * TPS;
    for (int i = 0; i < TPS; ++i) {
        int tok = tok0 + i;
        int a = ca[tok * KTOP];
        float v = xn[(long)tok * DD + chunk * 256 + t];
        s[a][t] += v;
        if (chunk == 0 && t == 0) cnt[a] += 1.f;
    }
    __syncthreads();
    for (int n = 0; n < NEXP; ++n)
        spart[(long)slice * (NEXP * DD) + n * DD + chunk * 256 + t] = s[n][t];
    if (chunk == 0 && t < NEXP) cntpart[slice * NEXP + t] = cnt[t];
}

__global__ __launch_bounds__(256) void reduce_parts(const float* __restrict__ part, float* __restrict__ outv,
                                                    const float* __restrict__ cntpart, float* __restrict__ ccnt,
                                                    int doCnt) {
    int i = blockIdx.x * 256 + threadIdx.x;
    float s = 0.f;
#pragma unroll 8
    for (int sl = 0; sl < SLICES; ++sl) s += part[(long)sl * (NEXP * DD) + i];
    outv[i] = s;
    if (doCnt && i < NEXP) {
        float c = 0.f;
#pragma unroll 8
        for (int sl = 0; sl < SLICES; ++sl) c += cntpart[sl * NEXP + i];
        ccnt[i] = c;
    }
}

// ---------------- K4: per-cluster MAD partials ----------------
__global__ __launch_bounds__(256) void cluster_mad(const float* __restrict__ xn, const int* __restrict__ ca,
                                                   const float* __restrict__ csum, const float* __restrict__ ccnt,
                                                   float* __restrict__ mpart) {
    __shared__ float md[NEXP][256];
    __shared__ float mean[NEXP][256];
    int chunk = blockIdx.x, slice = blockIdx.y, t = threadIdx.x;
#pragma unroll
    for (int n = 0; n < NEXP; ++n) {
        float c = ccnt[n];
        mean[n][t] = (c > 0.f) ? csum[n * DD + chunk * 256 + t] / c : 0.f;
        md[n][t] = 0.f;
    }
    __syncthreads();
    int tok0 = slice * TPS;
    for (int i = 0; i < TPS; ++i) {
        int tok = tok0 + i;
        int a = ca[tok * KTOP];
        float v = xn[(long)tok * DD + chunk * 256 + t];
        md[a][t] += fabsf(v - mean[a][t]);
    }
    __syncthreads();
    for (int n = 0; n < NEXP; ++n)
        mpart[(long)slice * (NEXP * DD) + n * DD + chunk * 256 + t] = md[n][t];
}

// ---------------- K5: W = normalize(clamp(1/(mad+0.35))) ----------------
__global__ __launch_bounds__(1024) void compute_W(const float* __restrict__ cmad, const float* __restrict__ ccnt,
                                                  float* __restrict__ W) {
    __shared__ float s[16];
    int t = threadIdx.x;
    auto block_sum = [&](float v) -> float {
#pragma unroll
        for (int o = 32; o; o >>= 1) v += __shfl_xor(v, o);
        if ((t & 63) == 0) s[t >> 6] = v;
        __syncthreads();
        float tot = 0.f;
#pragma unroll
        for (int i = 0; i < 16; ++i) tot += s[i];
        __syncthreads();
        return tot;
    };
    const int TOT = NEXP * DD;
    float p = 0.f;
    for (int i = t; i < TOT; i += 1024) {
        int n = i / DD;
        float c = ccnt[n];
        float wm = (c > 0.f) ? cmad[i] / c : 0.f;
        p += 1.f / (wm + 0.35f);
    }
    float mean1 = block_sum(p) / (float)TOT;
    float clamp = 5.f * mean1;
    p = 0.f;
    for (int i = t; i < TOT; i += 1024) {
        int n = i / DD;
        float c = ccnt[n];
        float wm = (c > 0.f) ? cmad[i] / c : 0.f;
        p += fminf(1.f / (wm + 0.35f), clamp);
    }
    float mean2 = block_sum(p) / (float)TOT;
    float inv2 = 1.f / mean2;
    for (int i = t; i < TOT; i += 1024) {
        int n = i / DD;
        float c = ccnt[n];
        float wm = (c > 0.f) ? cmad[i] / c : 0.f;
        W[i] = fminf(1.f / (wm + 0.35f), clamp) * inv2;
    }
}

// ---------------- K6: xn *= W[assign]; also emit bf16 hi/lo pair ----------------
__global__ __launch_bounds__(192) void apply_W(float* __restrict__ xn, const int* __restrict__ ca,
                                               const float* __restrict__ W,
                                               ushort* __restrict__ hi, ushort* __restrict__ lo) {
    int tok = blockIdx.x;
    long d4 = (long)tok * DD + threadIdx.x * 4;
    int a = ca[tok * KTOP];
    float4 v = *reinterpret_cast<float4*>(xn + d4);
    float4 w = *reinterpret_cast<const float4*>(W + a * DD + threadIdx.x * 4);
    v.x *= w.x; v.y *= w.y; v.z *= w.z; v.w *= w.w;
    *reinterpret_cast<float4*>(xn + d4) = v;
    ushort h0,h1,h2,h3,l0,l1,l2,l3;
    split2(v.x,h0,l0); split2(v.y,h1,l1); split2(v.z,h2,l2); split2(v.w,h3,l3);
    *reinterpret_cast<short4v*>(hi + d4) = short4v{(short)h0,(short)h1,(short)h2,(short)h3};
    *reinterpret_cast<short4v*>(lo + d4) = short4v{(short)l0,(short)l1,(short)l2,(short)l3};
}

// ---------------- K7: 64x64 tiled transpose -> bf16 [z][C][R] from [z][R][C] ----------------
template <bool F32>
__global__ __launch_bounds__(256) void make_T(const void* __restrict__ srcv, ushort* __restrict__ dst,
                                              int R, int C) {
    __shared__ ushort tile[64][65];
    int z = blockIdx.z;
    int c0 = blockIdx.x * 64, r0 = blockIdx.y * 64;
    int tr = threadIdx.x >> 4;          // 0..15
    int tc4 = (threadIdx.x & 15) * 4;
    long base = (long)z * R * C;
#pragma unroll
    for (int i = 0; i < 4; ++i) {
        int r = tr + i * 16;
        if constexpr (F32) {
            const float* s = (const float*)srcv;
            float4 v = *reinterpret_cast<const float4*>(s + base + (long)(r0 + r) * C + c0 + tc4);
            tile[r][tc4 + 0] = bf16_rne(v.x); tile[r][tc4 + 1] = bf16_rne(v.y);
            tile[r][tc4 + 2] = bf16_rne(v.z); tile[r][tc4 + 3] = bf16_rne(v.w);
        } else {
            const ushort* s = (const ushort*)srcv;
            short4v v = *reinterpret_cast<const short4v*>(s + base + (long)(r0 + r) * C + c0 + tc4);
            tile[r][tc4 + 0] = (ushort)v.x; tile[r][tc4 + 1] = (ushort)v.y;
            tile[r][tc4 + 2] = (ushort)v.z; tile[r][tc4 + 3] = (ushort)v.w;
        }
    }
    __syncthreads();
#pragma unroll
    for (int i = 0; i < 4; ++i) {
        int oc = tr + i * 16;
        short4v o = short4v{(short)tile[tc4 + 0][oc], (short)tile[tc4 + 1][oc],
                            (short)tile[tc4 + 2][oc], (short)tile[tc4 + 3][oc]};
        *reinterpret_cast<short4v*>(dst + base + (long)(c0 + oc) * R + r0 + tc4) = o;
    }
}

// ---------------- MFMA GEMM, 3-buffer LDS ring (72 KB all modes) ----------------
// MODE 0 SINGLE: 512 thr, BM=256, A(2)+B(1) bf16 gl_lds/thread, 1 MFMA.   vmcnt(3)
// MODE 1 PAIR:   256 thr, BM=64, A/B hi/lo pairs gl_lds, 3 MFMA.          vmcnt(6)
// MODE 2 BF32:   512 thr, BM=256, A(2) gl_lds + B f32 2 loads/thread ->
//                cvt_pk -> swizzled ds_write, depth-2.                    vmcnt(4)
// Swizzle: 16B slot sp of row r stored at sp ^ ((r>>1)&3) -> 2-way reads (free).
// AMAP: 0 linear z-strided, 1 token remap.  EPI: 0/1 bias/2 bias+gelu.
// CBF16: round C to bf16.  CMAP: 0 lin, 1 token remap.
template <int MODE, int AMAP, int EPI, bool CBF16, int CMAP>
__global__ __launch_bounds__((MODE == 1) ? 256 : 512) void gemm2(
    const ushort* __restrict__ Ah_g, const ushort* __restrict__ Al_g,
    const float*  __restrict__ Bf_g,
    const ushort* __restrict__ Bh_g, const ushort* __restrict__ Bl_g,
    float* __restrict__ Cf, ushort* __restrict__ Cb,
    int K, int lda, int ldb, int ldc,
    long sA, long sB, long sC,
    const float* __restrict__ bias, int biasStride) {
    constexpr bool PAIR = (MODE == 1);
    constexpr int THR  = PAIR ? 256 : 512;
    constexpr int BUFS = 12288;              // shorts per buffer, all modes
    constexpr int BOFF = PAIR ? 4096 : 8192; // B region offset in buffer
    constexpr int BM   = PAIR ? 64 : 256;
    constexpr int MI   = PAIR ? 2 : 4;
    __shared__ __attribute__((aligned(16))) ushort lds[3 * BUFS];

    // XCD-aware bijective remap (all grids multiples of 8)
    int orig = blockIdx.x + gridDim.x * (blockIdx.y + gridDim.y * blockIdx.z);
    int nwg = gridDim.x * gridDim.y * gridDim.z;
    int wg = (orig & 7) * (nwg >> 3) + (orig >> 3);
    int bx = wg % gridDim.x;
    int rest = wg / gridDim.x;
    int by = rest % gridDim.y;
    int z  = rest / gridDim.y;
    const int m0 = by * BM;
    const int n0 = bx * 128;

    const int tid = threadIdx.x, lane = tid & 63, w = tid >> 6;
    const int wr = w >> 1, wc = w & 1;       // PAIR: 2x2 of 32x64; else 4x2 of 64x64
    const int lr = lane & 15, kh = lane >> 4;

    // ---- A staging coords (chunk c: r=c>>2 row, sp=c&3 16B slot)
    const int NCA = PAIR ? 1 : 2;
    long arowA[2]; int kOffA[2];
#pragma unroll
    for (int i = 0; i < NCA; ++i) {
        int c = i * THR + tid;
        int r = c >> 2, sp = c & 3;
        kOffA[i] = (sp ^ ((r >> 1) & 3)) << 3;
        int rg = m0 + r;
        if constexpr (AMAP == 0) arowA[i] = (long)z * sA + (long)rg * lda;
        else arowA[i] = ((long)(rg >> 5) * 1024 + (long)z * 32 + (rg & 31)) * (long)lda;
    }
    // ---- B staging coords (gl_lds modes): 128 rows x 4 slots = 512 chunks
    long browB[2]; int kOffB[2];
#pragma unroll
    for (int i = 0; i < 2; ++i) {
        int c = i * 256 + tid;               // MODE1: 2 chunks/thr; MODE0: c=tid (i=0)
        if (c < 512) {
            int r = c >> 2, sp = c & 3;
            kOffB[i] = (sp ^ ((r >> 1) & 3)) << 3;
            browB[i] = (long)z * sB + (long)(n0 + r) * ldb;
        }
    }
    // ---- BF32 B reg-staging coords: 2 float4/thread (kqh: 2 k-rows, nq: 4 cols)
    const int kqh = tid & 15, nq = tid >> 4;

    f32x4 acc[MI][4];
#pragma unroll
    for (int i = 0; i < MI; ++i)
#pragma unroll
        for (int j = 0; j < 4; ++j) acc[i][j] = (f32x4)(0.f);

    auto stageA = [&](int buf, int kk0) {
        const int bb = buf * BUFS;
        if constexpr (MODE == 1) {
            gl_lds16(Ah_g + arowA[0] + kk0 + kOffA[0], &lds[bb + (w * 64) * 8]);
            gl_lds16(Al_g + arowA[0] + kk0 + kOffA[0], &lds[bb + 2048 + (w * 64) * 8]);
#pragma unroll
            for (int i = 0; i < 2; ++i) {
                int base = bb + 4096 + (i * 256 + w * 64) * 8;
                gl_lds16(Bh_g + browB[i] + kk0 + kOffB[i], &lds[base]);
                gl_lds16(Bl_g + browB[i] + kk0 + kOffB[i], &lds[base + 4096]);
            }
        } else if constexpr (MODE == 0) {
#pragma unroll
            for (int i = 0; i < 2; ++i)
                gl_lds16(Ah_g + arowA[i] + kk0 + kOffA[i], &lds[bb + (i * THR + w * 64) * 8]);
            gl_lds16(Bh_g + browB[0] + kk0 + kOffB[0], &lds[bb + BOFF + (w * 64) * 8]);
        } else {
#pragma unroll
            for (int i = 0; i < 2; ++i)
                gl_lds16(Ah_g + arowA[i] + kk0 + kOffA[i], &lds[bb + (i * THR + w * 64) * 8]);
        }
    };

    auto loadB = [&](float4 (&rB)[2], int kk0) {
#pragma unroll
        for (int dk = 0; dk < 2; ++dk)
            rB[dk] = *reinterpret_cast<const float4*>(
                Bf_g + (long)z * sB + (long)(kk0 + kqh * 2 + dk) * ldb + n0 + nq * 4);
    };

    // packed HW cvt: per dn, (k, k+1) -> one uint, swizzled 4B store
    auto bwrite = [&](int buf, float4 (&rB)[2]) {
        unsigned p[4];
        p[0] = cvt_pk_bf16(rB[0].x, rB[1].x);
        p[1] = cvt_pk_bf16(rB[0].y, rB[1].y);
        p[2] = cvt_pk_bf16(rB[0].z, rB[1].z);
        p[3] = cvt_pk_bf16(rB[0].w, rB[1].w);
        int k = kqh * 2;
        int s = k >> 3, kin = k & 7;
#pragma unroll
        for (int dn = 0; dn < 4; ++dn) {
            int n = nq * 4 + dn;
            int phys = s ^ ((n >> 1) & 3);
            int off = buf * BUFS + BOFF + n * 32 + phys * 8 + kin;
            *reinterpret_cast<unsigned*>(&lds[off]) = p[dn];
        }
    };

    auto compute = [&](int buf) {
        const int aB = buf * BUFS;
        const int bB = buf * BUFS + BOFF;
        short8v bh[4], bl[4];
#pragma unroll
        for (int nj = 0; nj < 4; ++nj) {
            int rb = wc * 64 + nj * 16 + lr;
            int off = bB + rb * 32 + ((kh ^ ((rb >> 1) & 3)) << 3);
            bh[nj] = *reinterpret_cast<const short8v*>(&lds[off]);
            if constexpr (PAIR) bl[nj] = *reinterpret_cast<const short8v*>(&lds[off + 4096]);
        }
#pragma unroll
        for (int mi = 0; mi < MI; ++mi) {
            int ra = wr * (PAIR ? 32 : 64) + mi * 16 + lr;
            int off = aB + ra * 32 + ((kh ^ ((ra >> 1) & 3)) << 3);
            short8v ah = *reinterpret_cast<const short8v*>(&lds[off]);
            if constexpr (PAIR) {
                short8v al = *reinterpret_cast<const short8v*>(&lds[off + 2048]);
#pragma unroll
                for (int nj = 0; nj < 4; ++nj) {
                    acc[mi][nj] = __builtin_amdgcn_mfma_f32_16x16x32_bf16(ah, bh[nj], acc[mi][nj], 0, 0, 0);
                    acc[mi][nj] = __builtin_amdgcn_mfma_f32_16x16x32_bf16(ah, bl[nj], acc[mi][nj], 0, 0, 0);
                    acc[mi][nj] = __builtin_amdgcn_mfma_f32_16x16x32_bf16(al, bh[nj], acc[mi][nj], 0, 0, 0);
                }
            } else {
#pragma unroll
                for (int nj = 0; nj < 4; ++nj)
                    acc[mi][nj] = __builtin_amdgcn_mfma_f32_16x16x32_bf16(ah, bh[nj], acc[mi][nj], 0, 0, 0);
            }
        }
    };

    const int nt = K >> 5;
    if constexpr (MODE == 0 || MODE == 1) {
        stageA(0, 0);
        stageA(1, 32);
        if constexpr (MODE == 1) { asm volatile("s_waitcnt vmcnt(6)" ::: "memory"); }
        else                     { asm volatile("s_waitcnt vmcnt(3)" ::: "memory"); }
        __builtin_amdgcn_s_barrier();
        __builtin_amdgcn_sched_barrier(0);
        int cc = 0, cn2 = 2;
        for (int t = 0; t < nt; ++t) {
            bool deep = (t + 2 < nt);
            if (deep) stageA(cn2, (t + 2) << 5);
            compute(cc);
            if (deep) {
                if constexpr (MODE == 1) { asm volatile("s_waitcnt vmcnt(6)" ::: "memory"); }
                else                     { asm volatile("s_waitcnt vmcnt(3)" ::: "memory"); }
            } else {
                asm volatile("s_waitcnt vmcnt(0)" ::: "memory");
            }
            if (t + 1 < nt) {
                __builtin_amdgcn_s_barrier();
                __builtin_amdgcn_sched_barrier(0);
            }
            cc = (cc == 2) ? 0 : cc + 1;
            cn2 = (cn2 == 2) ? 0 : cn2 + 1;
        }
    } else {
        // ---- depth-2, 3-buf ring
        float4 rBa[2], rBb[2];
        loadB(rBa, 0);
        bwrite(0, rBa);                      // implicit wait on rBa only
        stageA(0, 0);
        stageA(1, 32);
        loadB(rBb, 32);
        // outstanding: A0(2) A1(2) B1(2) -> drain A0, keep 4
        asm volatile("s_waitcnt vmcnt(4) lgkmcnt(0)" ::: "memory");
        __builtin_amdgcn_s_barrier();
        __builtin_amdgcn_sched_barrier(0);
        int cc = 0, cn1 = 1, cn2 = 2;
        auto iter = [&](int t, float4 (&ld)[2], float4 (&wr_)[2]) {
            bool deep = (t + 2 < nt);
            if (deep) { stageA(cn2, (t + 2) << 5); loadB(ld, (t + 2) << 5); }
            compute(cc);
            if (t + 1 < nt) bwrite(cn1, wr_);    // implicit wait drains B(t+1), A(t+1)
            if (deep) { asm volatile("s_waitcnt vmcnt(4) lgkmcnt(0)" ::: "memory"); }
            else      { asm volatile("s_waitcnt vmcnt(0) lgkmcnt(0)" ::: "memory"); }
            if (t + 1 < nt) {
                __builtin_amdgcn_s_barrier();
                __builtin_amdgcn_sched_barrier(0);
            }
            cc = (cc == 2) ? 0 : cc + 1;
            cn1 = (cn1 == 2) ? 0 : cn1 + 1;
            cn2 = (cn2 == 2) ? 0 : cn2 + 1;
        };
        for (int t = 0; t < nt; t += 2) {    // nt even at all call sites
            iter(t, rBa, rBb);
            iter(t + 1, rBb, rBa);
        }
    }

    // ---- epilogue
#pragma unroll
    for (int mi = 0; mi < MI; ++mi)
#pragma unroll
        for (int j = 0; j < 4; ++j) {
            int rg = m0 + wr * (PAIR ? 32 : 64) + mi * 16 + kh * 4 + j;
            long roff;
            if constexpr (CMAP == 1) roff = ((long)(rg >> 5) * 1024 + (long)z * 32 + (rg & 31)) * (long)ldc;
            else                     roff = (long)z * sC + (long)rg * ldc;
#pragma unroll
            for (int nj = 0; nj < 4; ++nj) {
                int col = n0 + wc * 64 + nj * 16 + lr;
                float v = acc[mi][nj][j];
                if constexpr (EPI >= 1) v += bias[(long)z * biasStride + col];
                if constexpr (EPI == 2) v = 0.5f * v * (1.0f + erff(v * 0.70710678118654752f));
                if constexpr (CBF16) Cb[roff + col] = bf16_rne(v);
                else                 Cf[roff + col] = v;
            }
        }
}

// ---------------- K8: per-row top-8 + comb softmax (fused) ----------------
__global__ __launch_bounds__(64) void row_topk(const float* __restrict__ logits,
                                               float* __restrict__ mix_out, float* __restrict__ clus_out,
                                               ushort* __restrict__ comb) {
    int row = blockIdx.x;
    int lane = threadIdx.x;
    const float* p = logits + (long)row * NP;
    float v[16];
#pragma unroll
    for (int i = 0; i < 16; ++i) v[i] = p[lane + i * 64];
    float mx = v[0];
#pragma unroll
    for (int i = 1; i < 16; ++i) mx = fmaxf(mx, v[i]);
#pragma unroll
    for (int o = 32; o; o >>= 1) mx = fmaxf(mx, __shfl_xor(mx, o));
    float s = 0.f;
#pragma unroll
    for (int i = 0; i < 16; ++i) s += __expf(v[i] - mx);
#pragma unroll
    for (int o = 32; o; o >>= 1) s += __shfl_xor(s, o);
    float inv = 1.0f / s;
    ushort* crow = comb + (long)row * NP;
#pragma unroll
    for (int i = 0; i < 16; ++i)
        crow[lane + i * 64] = bf16_rne(__expf(v[i] - mx) * inv);
#pragma unroll
    for (int k = 0; k < KTOP; ++k) {
        float bv = -INFINITY; int bi = 1 << 30;
#pragma unroll
        for (int i = 0; i < 16; ++i) {
            if (v[i] > bv) { bv = v[i]; bi = lane + i * 64; }
        }
#pragma unroll
        for (int o = 32; o; o >>= 1) {
            float ov = __shfl_xor(bv, o); int oi = __shfl_xor(bi, o);
            if (ov > bv || (ov == bv && oi < bi)) { bv = ov; bi = oi; }
        }
        int owner = bi & 63, slot = bi >> 6;
        if (lane == owner) {
#pragma unroll
            for (int i = 0; i < 16; ++i) if (slot == i) v[i] = -INFINITY;
        }
        if (lane == k) {
            mix_out[(long)row * KTOP + k] = bv;
            clus_out[(long)row * KTOP + k] = (float)(bi >> 5);
        }
    }
}

// ---------------- K9: column softmax stats (partials only; merge fused into dispT) ----------------
__global__ __launch_bounds__(256) void col_stats_part(const float* __restrict__ logits,
                                                      float* __restrict__ pmax, float* __restrict__ psum) {
    int b = blockIdx.z, ms = blockIdx.y, npc = blockIdx.x;
    int np = npc * 256 + threadIdx.x;
    const float* p = logits + ((long)b * MTOK + ms * 128) * NP + np;
    float mx = -INFINITY, s = 0.f;
    for (int m = 0; m < 128; ++m) {
        float v = p[(long)m * NP];
        float nm = fmaxf(mx, v);
        s = s * __expf(mx - nm) + __expf(v - nm);
        mx = nm;
    }
    long o = ((long)b * 8 + ms) * NP + np;
    pmax[o] = mx; psum[o] = s;
}

// ---------------- K10: dispT bf16 = softmax-over-m(logits)^T (merge fused in) ----------------
__global__ __launch_bounds__(256) void make_dispT(const float* __restrict__ logits,
                                                  const float* __restrict__ pmax, const float* __restrict__ psum,
                                                  ushort* __restrict__ dispT) {
    __shared__ float tile[64][65];
    __shared__ float smax[64], sinv[64];
    int b = blockIdx.z, np0 = blockIdx.x * 64, m0 = blockIdx.y * 64;
    int tr = threadIdx.x >> 6, tc = threadIdx.x & 63;
    if (threadIdx.x < 64) {
        int np = np0 + threadIdx.x;
        float mx = -INFINITY;
#pragma unroll
        for (int ms = 0; ms < 8; ++ms) mx = fmaxf(mx, pmax[((long)b * 8 + ms) * NP + np]);
        float s = 0.f;
#pragma unroll
        for (int ms = 0; ms < 8; ++ms) {
            long o = ((long)b * 8 + ms) * NP + np;
            s += psum[o] * __expf(pmax[o] - mx);
        }
        smax[threadIdx.x] = mx;
        sinv[threadIdx.x] = 1.0f / s;
    }
    const float* src = logits + ((long)b * MTOK + m0) * NP + np0;
#pragma unroll
    for (int i = 0; i < 16; ++i) {
        int m = tr * 16 + i;
        tile[m][tc] = src[(long)m * NP + tc];
    }
    __syncthreads();
#pragma unroll
    for (int i = 0; i < 16; ++i) {
        int npl = tr * 16 + i;
        float v = __expf(tile[tc][npl] - smax[npl]) * sinv[npl];
        dispT[((long)b * NP + np0 + npl) * MTOK + (m0 + tc)] = bf16_rne(v);
    }
}

// ---------------- launch ----------------
extern "C" void kernel_launch(void* const* d_in, const int* in_sizes, int n_in,
                              void* d_out, int out_size, void* d_ws, size_t ws_size,
                              hipStream_t stream) {
    const float* x    = (const float*)d_in[0];
    const int*   ca   = (const int*)d_in[1];
    const float* phi  = (const float*)d_in[2];
    const float* scale= (const float*)d_in[3];
    const float* w1   = (const float*)d_in[4];
    const float* b1   = (const float*)d_in[5];
    const float* w2   = (const float*)d_in[6];
    const float* b2   = (const float*)d_in[7];
    float* out = (float*)d_out;
    float* ws  = (float*)d_ws;

    float*  xn       = ws;                                   // 6291456 f32
    float*  logits   = xn + 6291456;                         // 8388608 f32
    ushort* xnp_hi   = (ushort*)(logits + 8388608);          // 6291456 sh
    ushort* xnp_lo   = xnp_hi + 6291456;                     // 6291456 sh
    ushort* phT_hi   = xnp_lo + 6291456;                     // 786432 sh
    ushort* phT_lo   = phT_hi + 786432;                      // 786432 sh
    ushort* dispT_bf = phT_lo + 786432;                      // 8388608 sh
    ushort* comb_bf  = dispT_bf + 8388608;                   // 8388608 sh
    ushort* xs_bf    = comb_bf + 8388608;                    // 6291456 sh
    ushort* h_bf     = xs_bf + 6291456;                      // 16777216 sh
    ushort* xnT_bf   = h_bf + 16777216;                      // 6291456 sh
    ushort* ysT_bf   = xnT_bf + 6291456;                     // 6291456 sh
    float*  stats    = (float*)(ysT_bf + 6291456);
    float* pmax      = stats;                 // 65536
    float* psum      = pmax + 65536;          // 65536
    float* csum      = psum + 65536;          // 24576
    float* cmad      = csum + 24576;          // 24576
    float* Wbuf      = cmad + 24576;          // 24576
    float* ccnt      = Wbuf + 24576;          // 64
    float* cntpart   = ccnt + 64;             // SLICES*NEXP = 4096
    float* spart     = cntpart + 4096;        // SLICES*NEXP*DD = 3145728
    float* mpart     = spart + 3145728;       // 3145728
    float* ys        = xn;                    // alias: xn f32 dead after apply_W/make_T

    float* out_y    = out;
    float* out_mix  = out + 6291456;
    float* out_clus = out + 6291456 + 65536;

    norm_x<<<BMT, 256, 0, stream>>>(x, xn);
    norm_phi_T<<<NP, 256, 0, stream>>>(phi, scale, phT_hi, phT_lo);

    cluster_sum<<<dim3(3, SLICES), 256, 0, stream>>>(xn, ca, spart, cntpart);
    reduce_parts<<<96, 256, 0, stream>>>(spart, csum, cntpart, ccnt, 1);
    cluster_mad<<<dim3(3, SLICES), 256, 0, stream>>>(xn, ca, csum, ccnt, mpart);
    reduce_parts<<<96, 256, 0, stream>>>(mpart, cmad, nullptr, nullptr, 0);
    compute_W<<<1, 1024, 0, stream>>>(cmad, ccnt, Wbuf);
    apply_W<<<BMT, 192, 0, stream>>>(xn, ca, Wbuf, xnp_hi, xnp_lo);

    // xnT_bf[b][768][1024] = transpose(bf16(xn)) — B operand for xs SINGLE GEMM
    make_T<false><<<dim3(12, 16, NB), 256, 0, stream>>>(xnp_hi, xnT_bf, MTOK, DD);

    // logits = xn . phin  (split-pair 3-MFMA, f32-accurate; 3-deep gl_lds ring)
    gemm2<1, 0, 0, false, 0><<<dim3(8, 128, 1), 256, 0, stream>>>(
        xnp_hi, xnp_lo, nullptr, phT_hi, phT_lo, logits, nullptr,
        DD, DD, DD, NP, 0, 0, 0, nullptr, 0);

    // top-8 + mixing weights + comb softmax (fused, one logits read)
    row_topk<<<BMT, 64, 0, stream>>>(logits, out_mix, out_clus, comb_bf);
    col_stats_part<<<dim3(4, 8, NB), 256, 0, stream>>>(logits, pmax, psum);
    make_dispT<<<dim3(16, 16, NB), 256, 0, stream>>>(logits, pmax, psum, dispT_bf);

    // xs[b] = dispT . xn[b] -> bf16  (SINGLE 512thr BM=256)
    gemm2<0, 0, 0, true, 0><<<dim3(6, 4, NB), 512, 0, stream>>>(
        dispT_bf, nullptr, nullptr, xnT_bf, nullptr, nullptr, xs_bf,
        MTOK, MTOK, MTOK, DD,
        (long)NP * MTOK, (long)DD * MTOK, (long)NP * DD, nullptr, 0);

    // h[n] = gelu(xs_rows(n) . w1[n] + b1[n]) -> bf16  (BF32 512thr BM=256)
    gemm2<2, 1, 2, true, 0><<<dim3(16, 1, NEXP), 512, 0, stream>>>(
        xs_bf, nullptr, w1, nullptr, nullptr, nullptr, h_bf,
        DD, DD, HH, HH,
        0, (long)DD * HH, (long)256 * HH, b1, HH);

    // ys = h_rows(n) . w2[n] + b2[n] -> f32 [b][np][768] (BF32 512thr BM=256)
    gemm2<2, 0, 1, false, 1><<<dim3(6, 1, NEXP), 512, 0, stream>>>(
        h_bf, nullptr, w2, nullptr, nullptr, ys, nullptr,
        HH, HH, DD, DD,
        (long)256 * HH, (long)HH * DD, 0, b2, DD);

    // ysT_bf[b][768][1024] = transpose(bf16(ys)) — B operand for y SINGLE GEMM
    make_T<true><<<dim3(12, 16, NB), 256, 0, stream>>>(ys, ysT_bf, MTOK, DD);

    // y[b] = comb . ys[b] -> f32 out  (SINGLE 512thr BM=256)
    gemm2<0, 0, 0, false, 0><<<dim3(6, 4, NB), 512, 0, stream>>>(
        comb_bf, nullptr, nullptr, ysT_bf, nullptr, out_y, nullptr,
        NP, NP, NP, DD,
        (long)MTOK * NP, (long)DD * NP, (long)MTOK * DD, nullptr, 0);
}

// Round 15
// 457.515 us; speedup vs baseline: 1.3372x; 1.0188x over previous
//
#include <hip/hip_runtime.h>
#include <cmath>

// ---------------- problem constants ----------------
// B=8, M=1024, D=768, N=32, P=32, K=8, H=2048
#define NB    8
#define MTOK  1024
#define BMT   8192      // B*M
#define DD    768
#define NEXP  32
#define PSLOT 32
#define NP    1024      // N*P
#define KTOP  8
#define HH    2048

#define SLICES 128      // partial-sum slices for cluster stats
#define TPS    64       // tokens per slice (SLICES*TPS == BMT)

typedef unsigned short ushort;
typedef __attribute__((ext_vector_type(8))) short short8v;   // 8 bf16 = 4 VGPR
typedef __attribute__((ext_vector_type(4))) short short4v;   // 8 bytes
typedef __attribute__((ext_vector_type(4))) float f32x4;

__device__ __forceinline__ ushort bf16_rne(float x) {
    unsigned u = __float_as_uint(x);
    unsigned r = (u + 0x7FFFu + ((u >> 16) & 1u)) >> 16;
    return (ushort)r;
}
__device__ __forceinline__ float bf16_to_f(ushort h) {
    return __uint_as_float(((unsigned)h) << 16);
}
__device__ __forceinline__ void split2(float x, ushort& hi, ushort& lo) {
    hi = bf16_rne(x);
    lo = bf16_rne(x - bf16_to_f(hi));
}
// HW packed f32->bf16 (RNE): dst[15:0]=cvt(a), dst[31:16]=cvt(b)
__device__ __forceinline__ unsigned cvt_pk_bf16(float a, float b) {
    unsigned r;
    asm volatile("v_cvt_pk_bf16_f32 %0, %1, %2" : "=v"(r) : "v"(a), "v"(b));
    return r;
}

// async global->LDS, 16B per lane; lds dest is wave-uniform base + lane*16
__device__ __forceinline__ void gl_lds16(const ushort* g, ushort* l) {
    __builtin_amdgcn_global_load_lds(
        (const __attribute__((address_space(1))) void*)g,
        (__attribute__((address_space(3))) void*)l, 16, 0, 0);
}

// ---------------- K1: token L2 normalize ----------------
__global__ __launch_bounds__(256) void norm_x(const float* __restrict__ x, float* __restrict__ xn) {
    int tok = blockIdx.x;
    int t = threadIdx.x;
    const float* p = x + (long)tok * DD;
    float v0 = p[t], v1 = p[t + 256], v2 = p[t + 512];
    float ss = v0 * v0 + v1 * v1 + v2 * v2;
#pragma unroll
    for (int o = 32; o; o >>= 1) ss += __shfl_xor(ss, o);
    __shared__ float sred[4];
    if ((t & 63) == 0) sred[t >> 6] = ss;
    __syncthreads();
    ss = sred[0] + sred[1] + sred[2] + sred[3];
    float inv = 1.0f / fmaxf(sqrtf(ss), 1e-12f);
    float* q = xn + (long)tok * DD;
    q[t] = v0 * inv; q[t + 256] = v1 * inv; q[t + 512] = v2 * inv;
}

// ---------------- K2: phi normalize -> transposed split pair [np][d] ----------------
__global__ __launch_bounds__(256) void norm_phi_T(const float* __restrict__ phi, const float* __restrict__ scale,
                                                  ushort* __restrict__ phT_hi, ushort* __restrict__ phT_lo) {
    int np = blockIdx.x;           // 1024 blocks
    int t = threadIdx.x;
    float ss = 0.f;
    for (int d = t; d < DD; d += 256) {
        float v = phi[(long)d * NP + np];
        ss += v * v;
    }
#pragma unroll
    for (int o = 32; o; o >>= 1) ss += __shfl_xor(ss, o);
    __shared__ float sred[4];
    if ((t & 63) == 0) sred[t >> 6] = ss;
    __syncthreads();
    ss = sred[0] + sred[1] + sred[2] + sred[3];
    float sc = scale[0] / fmaxf(sqrtf(ss), 1e-12f);
    for (int d = t; d < DD; d += 256) {
        float v = phi[(long)d * NP + np] * sc;
        ushort h, l; split2(v, h, l);
        phT_hi[(long)np * DD + d] = h;
        phT_lo[(long)np * DD + d] = l;
    }
}

// ---------------- K3: per-cluster sums (deterministic partials, 128 slices) ----------------
__global__ __launch_bounds__(256) void cluster_sum(const float* __restrict__ xn, const int* __restrict__ ca,
                                                   float* __restrict__ spart, float* __restrict__ cntpart) {
    __shared__ float s[NEXP][256];
    __shared__ float cnt[NEXP];
    int chunk = blockIdx.x, slice = blockIdx.y, t = threadIdx.x;
#pragma unroll
    for (int n = 0; n < NEXP; ++n) s[n][t] = 0.f;
    if (t < NEXP) cnt[t] = 0.f;
    __syncthreads();
    int tok0 = slice * TPS;
    for (int i = 0; i < TPS; ++i) {
        int tok = tok0 + i;
        int a = ca[tok * KTOP];
        float v = xn[(long)tok * DD + chunk * 256 + t];
        s[a][t] += v;
        if (chunk == 0 && t == 0) cnt[a] += 1.f;
    }
    __syncthreads();
    for (int n = 0; n < NEXP; ++n)
        spart[(long)slice * (NEXP * DD) + n * DD + chunk * 256 + t] = s[n][t];
    if (chunk == 0 && t < NEXP) cntpart[slice * NEXP + t] = cnt[t];
}

__global__ __launch_bounds__(256) void reduce_parts(const float* __restrict__ part, float* __restrict__ outv,
                                                    const float* __restrict__ cntpart, float* __restrict__ ccnt,
                                                    int doCnt) {
    int i = blockIdx.x * 256 + threadIdx.x;
    float s = 0.f;
#pragma unroll 8
    for (int sl = 0; sl < SLICES; ++sl) s += part[(long)sl * (NEXP * DD) + i];
    outv[i] = s;
    if (doCnt && i < NEXP) {
        float c = 0.f;
#pragma unroll 8
        for (int sl = 0; sl < SLICES; ++sl) c += cntpart[sl * NEXP + i];
        ccnt[i] = c;
    }
}

// ---------------- K4: per-cluster MAD partials ----------------
__global__ __launch_bounds__(256) void cluster_mad(const float* __restrict__ xn, const int* __restrict__ ca,
                                                   const float* __restrict__ csum, const float* __restrict__ ccnt,
                                                   float* __restrict__ mpart) {
    __shared__ float md[NEXP][256];
    __shared__ float mean[NEXP][256];
    int chunk = blockIdx.x, slice = blockIdx.y, t = threadIdx.x;
#pragma unroll
    for (int n = 0; n < NEXP; ++n) {
        float c = ccnt[n];
        mean[n][t] = (c > 0.f) ? csum[n * DD + chunk * 256 + t] / c : 0.f;
        md[n][t] = 0.f;
    }
    __syncthreads();
    int tok0 = slice * TPS;
    for (int i = 0; i < TPS; ++i) {
        int tok = tok0 + i;
        int a = ca[tok * KTOP];
        float v = xn[(long)tok * DD + chunk * 256 + t];
        md[a][t] += fabsf(v - mean[a][t]);
    }
    __syncthreads();
    for (int n = 0; n < NEXP; ++n)
        mpart[(long)slice * (NEXP * DD) + n * DD + chunk * 256 + t] = md[n][t];
}

// ---------------- K5: W = normalize(clamp(1/(mad+0.35))) ----------------
__global__ __launch_bounds__(1024) void compute_W(const float* __restrict__ cmad, const float* __restrict__ ccnt,
                                                  float* __restrict__ W) {
    __shared__ float s[16];
    int t = threadIdx.x;
    auto block_sum = [&](float v) -> float {
#pragma unroll
        for (int o = 32; o; o >>= 1) v += __shfl_xor(v, o);
        if ((t & 63) == 0) s[t >> 6] = v;
        __syncthreads();
        float tot = 0.f;
#pragma unroll
        for (int i = 0; i < 16; ++i) tot += s[i];
        __syncthreads();
        return tot;
    };
    const int TOT = NEXP * DD;
    float p = 0.f;
    for (int i = t; i < TOT; i += 1024) {
        int n = i / DD;
        float c = ccnt[n];
        float wm = (c > 0.f) ? cmad[i] / c : 0.f;
        p += 1.f / (wm + 0.35f);
    }
    float mean1 = block_sum(p) / (float)TOT;
    float clamp = 5.f * mean1;
    p = 0.f;
    for (int i = t; i < TOT; i += 1024) {
        int n = i / DD;
        float c = ccnt[n];
        float wm = (c > 0.f) ? cmad[i] / c : 0.f;
        p += fminf(1.f / (wm + 0.35f), clamp);
    }
    float mean2 = block_sum(p) / (float)TOT;
    float inv2 = 1.f / mean2;
    for (int i = t; i < TOT; i += 1024) {
        int n = i / DD;
        float c = ccnt[n];
        float wm = (c > 0.f) ? cmad[i] / c : 0.f;
        W[i] = fminf(1.f / (wm + 0.35f), clamp) * inv2;
    }
}

// ---------------- K6: emit bf16 hi/lo pair of xn*W (xn f32 store is dead -> removed) ----------------
__global__ __launch_bounds__(192) void apply_W(const float* __restrict__ xn, const int* __restrict__ ca,
                                               const float* __restrict__ W,
                                               ushort* __restrict__ hi, ushort* __restrict__ lo) {
    int tok = blockIdx.x;
    long d4 = (long)tok * DD + threadIdx.x * 4;
    int a = ca[tok * KTOP];
    float4 v = *reinterpret_cast<const float4*>(xn + d4);
    float4 w = *reinterpret_cast<const float4*>(W + a * DD + threadIdx.x * 4);
    v.x *= w.x; v.y *= w.y; v.z *= w.z; v.w *= w.w;
    ushort h0,h1,h2,h3,l0,l1,l2,l3;
    split2(v.x,h0,l0); split2(v.y,h1,l1); split2(v.z,h2,l2); split2(v.w,h3,l3);
    *reinterpret_cast<short4v*>(hi + d4) = short4v{(short)h0,(short)h1,(short)h2,(short)h3};
    *reinterpret_cast<short4v*>(lo + d4) = short4v{(short)l0,(short)l1,(short)l2,(short)l3};
}

// ---------------- K7: 64x64 tiled transpose -> bf16 [z][C][R] from [z][R][C] ----------------
template <bool F32>
__global__ __launch_bounds__(256) void make_T(const void* __restrict__ srcv, ushort* __restrict__ dst,
                                              int R, int C) {
    __shared__ ushort tile[64][65];
    int z = blockIdx.z;
    int c0 = blockIdx.x * 64, r0 = blockIdx.y * 64;
    int tr = threadIdx.x >> 4;          // 0..15
    int tc4 = (threadIdx.x & 15) * 4;
    long base = (long)z * R * C;
#pragma unroll
    for (int i = 0; i < 4; ++i) {
        int r = tr + i * 16;
        if constexpr (F32) {
            const float* s = (const float*)srcv;
            float4 v = *reinterpret_cast<const float4*>(s + base + (long)(r0 + r) * C + c0 + tc4);
            tile[r][tc4 + 0] = bf16_rne(v.x); tile[r][tc4 + 1] = bf16_rne(v.y);
            tile[r][tc4 + 2] = bf16_rne(v.z); tile[r][tc4 + 3] = bf16_rne(v.w);
        } else {
            const ushort* s = (const ushort*)srcv;
            short4v v = *reinterpret_cast<const short4v*>(s + base + (long)(r0 + r) * C + c0 + tc4);
            tile[r][tc4 + 0] = (ushort)v.x; tile[r][tc4 + 1] = (ushort)v.y;
            tile[r][tc4 + 2] = (ushort)v.z; tile[r][tc4 + 3] = (ushort)v.w;
        }
    }
    __syncthreads();
#pragma unroll
    for (int i = 0; i < 4; ++i) {
        int oc = tr + i * 16;
        short4v o = short4v{(short)tile[tc4 + 0][oc], (short)tile[tc4 + 1][oc],
                            (short)tile[tc4 + 2][oc], (short)tile[tc4 + 3][oc]};
        *reinterpret_cast<short4v*>(dst + base + (long)(c0 + oc) * R + r0 + tc4) = o;
    }
}

// ---------------- MFMA GEMM, 3-buffer LDS ring (72 KB all modes) ----------------
// MODE 0 SINGLE: 512 thr, BM=256, A(2)+B(1) bf16 gl_lds/thread, 1 MFMA.   vmcnt(3)
// MODE 1 PAIR:   256 thr, BM=64, A/B hi/lo pairs gl_lds, 3 MFMA.          vmcnt(6)
// MODE 2 BF32:   512 thr, BM=256, A(2) gl_lds + B f32 2 loads/thread ->
//                cvt_pk -> swizzled ds_write, depth-2.                    vmcnt(4)
// CSTAT (PAIR logits): epilogue column max/exp-sum partials per 64-row tile.
// Swizzle: 16B slot sp of row r stored at sp ^ ((r>>1)&3) -> 2-way reads (free).
// AMAP: 0 linear z-strided, 1 token remap.  EPI: 0/1 bias/2 bias+gelu.
// CBF16: round C to bf16.  CMAP: 0 lin, 1 token remap.
template <int MODE, int AMAP, int EPI, bool CBF16, int CMAP, bool CSTAT>
__global__ __launch_bounds__((MODE == 1) ? 256 : 512) void gemm2(
    const ushort* __restrict__ Ah_g, const ushort* __restrict__ Al_g,
    const float*  __restrict__ Bf_g,
    const ushort* __restrict__ Bh_g, const ushort* __restrict__ Bl_g,
    float* __restrict__ Cf, ushort* __restrict__ Cb,
    int K, int lda, int ldb, int ldc,
    long sA, long sB, long sC,
    const float* __restrict__ bias, int biasStride,
    float* __restrict__ pmaxO, float* __restrict__ psumO) {
    constexpr bool PAIR = (MODE == 1);
    constexpr int THR  = PAIR ? 256 : 512;
    constexpr int BUFS = 12288;              // shorts per buffer, all modes
    constexpr int BOFF = PAIR ? 4096 : 8192; // B region offset in buffer
    constexpr int BM   = PAIR ? 64 : 256;
    constexpr int MI   = PAIR ? 2 : 4;
    __shared__ __attribute__((aligned(16))) ushort lds[3 * BUFS];

    // XCD-aware bijective remap (all grids multiples of 8)
    int orig = blockIdx.x + gridDim.x * (blockIdx.y + gridDim.y * blockIdx.z);
    int nwg = gridDim.x * gridDim.y * gridDim.z;
    int wg = (orig & 7) * (nwg >> 3) + (orig >> 3);
    int bx = wg % gridDim.x;
    int rest = wg / gridDim.x;
    int by = rest % gridDim.y;
    int z  = rest / gridDim.y;
    const int m0 = by * BM;
    const int n0 = bx * 128;

    const int tid = threadIdx.x, lane = tid & 63, w = tid >> 6;
    const int wr = w >> 1, wc = w & 1;       // PAIR: 2x2 of 32x64; else 4x2 of 64x64
    const int lr = lane & 15, kh = lane >> 4;

    // ---- A staging coords (chunk c: r=c>>2 row, sp=c&3 16B slot)
    const int NCA = PAIR ? 1 : 2;
    long arowA[2]; int kOffA[2];
#pragma unroll
    for (int i = 0; i < NCA; ++i) {
        int c = i * THR + tid;
        int r = c >> 2, sp = c & 3;
        kOffA[i] = (sp ^ ((r >> 1) & 3)) << 3;
        int rg = m0 + r;
        if constexpr (AMAP == 0) arowA[i] = (long)z * sA + (long)rg * lda;
        else arowA[i] = ((long)(rg >> 5) * 1024 + (long)z * 32 + (rg & 31)) * (long)lda;
    }
    // ---- B staging coords (gl_lds modes): 128 rows x 4 slots = 512 chunks
    long browB[2]; int kOffB[2];
#pragma unroll
    for (int i = 0; i < 2; ++i) {
        int c = i * 256 + tid;               // MODE1: 2 chunks/thr; MODE0: c=tid (i=0)
        if (c < 512) {
            int r = c >> 2, sp = c & 3;
            kOffB[i] = (sp ^ ((r >> 1) & 3)) << 3;
            browB[i] = (long)z * sB + (long)(n0 + r) * ldb;
        }
    }
    // ---- BF32 B reg-staging coords: 2 float4/thread (kqh: 2 k-rows, nq: 4 cols)
    const int kqh = tid & 15, nq = tid >> 4;

    f32x4 acc[MI][4];
#pragma unroll
    for (int i = 0; i < MI; ++i)
#pragma unroll
        for (int j = 0; j < 4; ++j) acc[i][j] = (f32x4)(0.f);

    auto stageA = [&](int buf, int kk0) {
        const int bb = buf * BUFS;
        if constexpr (MODE == 1) {
            gl_lds16(Ah_g + arowA[0] + kk0 + kOffA[0], &lds[bb + (w * 64) * 8]);
            gl_lds16(Al_g + arowA[0] + kk0 + kOffA[0], &lds[bb + 2048 + (w * 64) * 8]);
#pragma unroll
            for (int i = 0; i < 2; ++i) {
                int base = bb + 4096 + (i * 256 + w * 64) * 8;
                gl_lds16(Bh_g + browB[i] + kk0 + kOffB[i], &lds[base]);
                gl_lds16(Bl_g + browB[i] + kk0 + kOffB[i], &lds[base + 4096]);
            }
        } else if constexpr (MODE == 0) {
#pragma unroll
            for (int i = 0; i < 2; ++i)
                gl_lds16(Ah_g + arowA[i] + kk0 + kOffA[i], &lds[bb + (i * THR + w * 64) * 8]);
            gl_lds16(Bh_g + browB[0] + kk0 + kOffB[0], &lds[bb + BOFF + (w * 64) * 8]);
        } else {
#pragma unroll
            for (int i = 0; i < 2; ++i)
                gl_lds16(Ah_g + arowA[i] + kk0 + kOffA[i], &lds[bb + (i * THR + w * 64) * 8]);
        }
    };

    auto loadB = [&](float4 (&rB)[2], int kk0) {
#pragma unroll
        for (int dk = 0; dk < 2; ++dk)
            rB[dk] = *reinterpret_cast<const float4*>(
                Bf_g + (long)z * sB + (long)(kk0 + kqh * 2 + dk) * ldb + n0 + nq * 4);
    };

    // packed HW cvt: per dn, (k, k+1) -> one uint, swizzled 4B store
    auto bwrite = [&](int buf, float4 (&rB)[2]) {
        unsigned p[4];
        p[0] = cvt_pk_bf16(rB[0].x, rB[1].x);
        p[1] = cvt_pk_bf16(rB[0].y, rB[1].y);
        p[2] = cvt_pk_bf16(rB[0].z, rB[1].z);
        p[3] = cvt_pk_bf16(rB[0].w, rB[1].w);
        int k = kqh * 2;
        int s = k >> 3, kin = k & 7;
#pragma unroll
        for (int dn = 0; dn < 4; ++dn) {
            int n = nq * 4 + dn;
            int phys = s ^ ((n >> 1) & 3);
            int off = buf * BUFS + BOFF + n * 32 + phys * 8 + kin;
            *reinterpret_cast<unsigned*>(&lds[off]) = p[dn];
        }
    };

    auto compute = [&](int buf) {
        const int aB = buf * BUFS;
        const int bB = buf * BUFS + BOFF;
        short8v bh[4], bl[4];
#pragma unroll
        for (int nj = 0; nj < 4; ++nj) {
            int rb = wc * 64 + nj * 16 + lr;
            int off = bB + rb * 32 + ((kh ^ ((rb >> 1) & 3)) << 3);
            bh[nj] = *reinterpret_cast<const short8v*>(&lds[off]);
            if constexpr (PAIR) bl[nj] = *reinterpret_cast<const short8v*>(&lds[off + 4096]);
        }
#pragma unroll
        for (int mi = 0; mi < MI; ++mi) {
            int ra = wr * (PAIR ? 32 : 64) + mi * 16 + lr;
            int off = aB + ra * 32 + ((kh ^ ((ra >> 1) & 3)) << 3);
            short8v ah = *reinterpret_cast<const short8v*>(&lds[off]);
            if constexpr (PAIR) {
                short8v al = *reinterpret_cast<const short8v*>(&lds[off + 2048]);
#pragma unroll
                for (int nj = 0; nj < 4; ++nj) {
                    acc[mi][nj] = __builtin_amdgcn_mfma_f32_16x16x32_bf16(ah, bh[nj], acc[mi][nj], 0, 0, 0);
                    acc[mi][nj] = __builtin_amdgcn_mfma_f32_16x16x32_bf16(ah, bl[nj], acc[mi][nj], 0, 0, 0);
                    acc[mi][nj] = __builtin_amdgcn_mfma_f32_16x16x32_bf16(al, bh[nj], acc[mi][nj], 0, 0, 0);
                }
            } else {
#pragma unroll
                for (int nj = 0; nj < 4; ++nj)
                    acc[mi][nj] = __builtin_amdgcn_mfma_f32_16x16x32_bf16(ah, bh[nj], acc[mi][nj], 0, 0, 0);
            }
        }
    };

    const int nt = K >> 5;
    if constexpr (MODE == 0 || MODE == 1) {
        stageA(0, 0);
        stageA(1, 32);
        if constexpr (MODE == 1) { asm volatile("s_waitcnt vmcnt(6)" ::: "memory"); }
        else                     { asm volatile("s_waitcnt vmcnt(3)" ::: "memory"); }
        __builtin_amdgcn_s_barrier();
        __builtin_amdgcn_sched_barrier(0);
        int cc = 0, cn2 = 2;
        for (int t = 0; t < nt; ++t) {
            bool deep = (t + 2 < nt);
            if (deep) stageA(cn2, (t + 2) << 5);
            compute(cc);
            if (deep) {
                if constexpr (MODE == 1) { asm volatile("s_waitcnt vmcnt(6)" ::: "memory"); }
                else                     { asm volatile("s_waitcnt vmcnt(3)" ::: "memory"); }
            } else {
                asm volatile("s_waitcnt vmcnt(0)" ::: "memory");
            }
            if (t + 1 < nt) {
                __builtin_amdgcn_s_barrier();
                __builtin_amdgcn_sched_barrier(0);
            }
            cc = (cc == 2) ? 0 : cc + 1;
            cn2 = (cn2 == 2) ? 0 : cn2 + 1;
        }
    } else {
        // ---- depth-2, 3-buf ring
        float4 rBa[2], rBb[2];
        loadB(rBa, 0);
        bwrite(0, rBa);                      // implicit wait on rBa only
        stageA(0, 0);
        stageA(1, 32);
        loadB(rBb, 32);
        asm volatile("s_waitcnt vmcnt(4) lgkmcnt(0)" ::: "memory");
        __builtin_amdgcn_s_barrier();
        __builtin_amdgcn_sched_barrier(0);
        int cc = 0, cn1 = 1, cn2 = 2;
        auto iter = [&](int t, float4 (&ld)[2], float4 (&wr_)[2]) {
            bool deep = (t + 2 < nt);
            if (deep) { stageA(cn2, (t + 2) << 5); loadB(ld, (t + 2) << 5); }
            compute(cc);
            if (t + 1 < nt) bwrite(cn1, wr_);    // implicit wait drains B(t+1), A(t+1)
            if (deep) { asm volatile("s_waitcnt vmcnt(4) lgkmcnt(0)" ::: "memory"); }
            else      { asm volatile("s_waitcnt vmcnt(0) lgkmcnt(0)" ::: "memory"); }
            if (t + 1 < nt) {
                __builtin_amdgcn_s_barrier();
                __builtin_amdgcn_sched_barrier(0);
            }
            cc = (cc == 2) ? 0 : cc + 1;
            cn1 = (cn1 == 2) ? 0 : cn1 + 1;
            cn2 = (cn2 == 2) ? 0 : cn2 + 1;
        };
        for (int t = 0; t < nt; t += 2) {    // nt even at all call sites
            iter(t, rBa, rBb);
            iter(t + 1, rBb, rBa);
        }
    }

    // ---- epilogue: C write
#pragma unroll
    for (int mi = 0; mi < MI; ++mi)
#pragma unroll
        for (int j = 0; j < 4; ++j) {
            int rg = m0 + wr * (PAIR ? 32 : 64) + mi * 16 + kh * 4 + j;
            long roff;
            if constexpr (CMAP == 1) roff = ((long)(rg >> 5) * 1024 + (long)z * 32 + (rg & 31)) * (long)ldc;
            else                     roff = (long)z * sC + (long)rg * ldc;
#pragma unroll
            for (int nj = 0; nj < 4; ++nj) {
                int col = n0 + wc * 64 + nj * 16 + lr;
                float v = acc[mi][nj][j];
                if constexpr (EPI >= 1) v += bias[(long)z * biasStride + col];
                if constexpr (EPI == 2) v = 0.5f * v * (1.0f + erff(v * 0.70710678118654752f));
                if constexpr (CBF16) Cb[roff + col] = bf16_rne(v);
                else                 Cf[roff + col] = v;
            }
        }

    // ---- epilogue: fused column stats over this 64-row tile (PAIR/logits only)
    if constexpr (CSTAT) {
        float* red = (float*)lds;            // [2 wr][2 wc][16 lr][4 nj]
        __syncthreads();                     // K-loop LDS dead; all waves done
        float tmax[4];
#pragma unroll
        for (int nj = 0; nj < 4; ++nj) {
            float m = acc[0][nj][0];
#pragma unroll
            for (int mi = 0; mi < MI; ++mi)
#pragma unroll
                for (int j = 0; j < 4; ++j) m = fmaxf(m, acc[mi][nj][j]);
            m = fmaxf(m, __shfl_xor(m, 16));     // reduce over kh bit0
            m = fmaxf(m, __shfl_xor(m, 32));     // reduce over kh bit1
            tmax[nj] = m;
        }
        if (kh == 0) {
#pragma unroll
            for (int nj = 0; nj < 4; ++nj)
                red[((wr * 2 + wc) * 16 + lr) * 4 + nj] = tmax[nj];
        }
        __syncthreads();
        float tsum[4];
#pragma unroll
        for (int nj = 0; nj < 4; ++nj) {
            float m = fmaxf(red[((0 * 2 + wc) * 16 + lr) * 4 + nj],
                            red[((1 * 2 + wc) * 16 + lr) * 4 + nj]);
            tmax[nj] = m;
            float s = 0.f;
#pragma unroll
            for (int mi = 0; mi < MI; ++mi)
#pragma unroll
                for (int j = 0; j < 4; ++j) s += __expf(acc[mi][nj][j] - m);
            s += __shfl_xor(s, 16);
            s += __shfl_xor(s, 32);
            tsum[nj] = s;
        }
        __syncthreads();
        if (kh == 0) {
#pragma unroll
            for (int nj = 0; nj < 4; ++nj)
                red[((wr * 2 + wc) * 16 + lr) * 4 + nj] = tsum[nj];
        }
        __syncthreads();
        if (w < 2 && kh == 0) {              // wr==0 waves write 128 cols total
#pragma unroll
            for (int nj = 0; nj < 4; ++nj) {
                int col = n0 + wc * 64 + nj * 16 + lr;
                float stot = red[((0 * 2 + wc) * 16 + lr) * 4 + nj] +
                             red[((1 * 2 + wc) * 16 + lr) * 4 + nj];
                pmaxO[(long)by * NP + col] = tmax[nj];
                psumO[(long)by * NP + col] = stot;
            }
        }
    }
}

// ---------------- K8: per-row top-8 + comb softmax (fused) ----------------
__global__ __launch_bounds__(64) void row_topk(const float* __restrict__ logits,
                                               float* __restrict__ mix_out, float* __restrict__ clus_out,
                                               ushort* __restrict__ comb) {
    int row = blockIdx.x;
    int lane = threadIdx.x;
    const float* p = logits + (long)row * NP;
    float v[16];
#pragma unroll
    for (int i = 0; i < 16; ++i) v[i] = p[lane + i * 64];
    float mx = v[0];
#pragma unroll
    for (int i = 1; i < 16; ++i) mx = fmaxf(mx, v[i]);
#pragma unroll
    for (int o = 32; o; o >>= 1) mx = fmaxf(mx, __shfl_xor(mx, o));
    float s = 0.f;
#pragma unroll
    for (int i = 0; i < 16; ++i) s += __expf(v[i] - mx);
#pragma unroll
    for (int o = 32; o; o >>= 1) s += __shfl_xor(s, o);
    float inv = 1.0f / s;
    ushort* crow = comb + (long)row * NP;
#pragma unroll
    for (int i = 0; i < 16; ++i)
        crow[lane + i * 64] = bf16_rne(__expf(v[i] - mx) * inv);
#pragma unroll
    for (int k = 0; k < KTOP; ++k) {
        float bv = -INFINITY; int bi = 1 << 30;
#pragma unroll
        for (int i = 0; i < 16; ++i) {
            if (v[i] > bv) { bv = v[i]; bi = lane + i * 64; }
        }
#pragma unroll
        for (int o = 32; o; o >>= 1) {
            float ov = __shfl_xor(bv, o); int oi = __shfl_xor(bi, o);
            if (ov > bv || (ov == bv && oi < bi)) { bv = ov; bi = oi; }
        }
        int owner = bi & 63, slot = bi >> 6;
        if (lane == owner) {
#pragma unroll
            for (int i = 0; i < 16; ++i) if (slot == i) v[i] = -INFINITY;
        }
        if (lane == k) {
            mix_out[(long)row * KTOP + k] = bv;
            clus_out[(long)row * KTOP + k] = (float)(bi >> 5);
        }
    }
}

// ---------------- K10: dispT bf16 = softmax-over-m(logits)^T (merges 16 tile partials) ----------------
__global__ __launch_bounds__(256) void make_dispT(const float* __restrict__ logits,
                                                  const float* __restrict__ pmax, const float* __restrict__ psum,
                                                  ushort* __restrict__ dispT) {
    __shared__ float tile[64][65];
    __shared__ float smax[64], sinv[64];
    int b = blockIdx.z, np0 = blockIdx.x * 64, m0 = blockIdx.y * 64;
    int tr = threadIdx.x >> 6, tc = threadIdx.x & 63;
    if (threadIdx.x < 64) {
        int np = np0 + threadIdx.x;
        float mx = -INFINITY;
#pragma unroll
        for (int ms = 0; ms < 16; ++ms) mx = fmaxf(mx, pmax[((long)(b * 16 + ms)) * NP + np]);
        float s = 0.f;
#pragma unroll
        for (int ms = 0; ms < 16; ++ms) {
            long o = ((long)(b * 16 + ms)) * NP + np;
            s += psum[o] * __expf(pmax[o] - mx);
        }
        smax[threadIdx.x] = mx;
        sinv[threadIdx.x] = 1.0f / s;
    }
    const float* src = logits + ((long)b * MTOK + m0) * NP + np0;
#pragma unroll
    for (int i = 0; i < 16; ++i) {
        int m = tr * 16 + i;
        tile[m][tc] = src[(long)m * NP + tc];
    }
    __syncthreads();
#pragma unroll
    for (int i = 0; i < 16; ++i) {
        int npl = tr * 16 + i;
        float v = __expf(tile[tc][npl] - smax[npl]) * sinv[npl];
        dispT[((long)b * NP + np0 + npl) * MTOK + (m0 + tc)] = bf16_rne(v);
    }
}

// ---------------- launch ----------------
extern "C" void kernel_launch(void* const* d_in, const int* in_sizes, int n_in,
                              void* d_out, int out_size, void* d_ws, size_t ws_size,
                              hipStream_t stream) {
    const float* x    = (const float*)d_in[0];
    const int*   ca   = (const int*)d_in[1];
    const float* phi  = (const float*)d_in[2];
    const float* scale= (const float*)d_in[3];
    const float* w1   = (const float*)d_in[4];
    const float* b1   = (const float*)d_in[5];
    const float* w2   = (const float*)d_in[6];
    const float* b2   = (const float*)d_in[7];
    float* out = (float*)d_out;
    float* ws  = (float*)d_ws;

    float*  xn       = ws;                                   // 6291456 f32
    float*  logits   = xn + 6291456;                         // 8388608 f32
    ushort* xnp_hi   = (ushort*)(logits + 8388608);          // 6291456 sh
    ushort* xnp_lo   = xnp_hi + 6291456;                     // 6291456 sh
    ushort* phT_hi   = xnp_lo + 6291456;                     // 786432 sh
    ushort* phT_lo   = phT_hi + 786432;                      // 786432 sh
    ushort* dispT_bf = phT_lo + 786432;                      // 8388608 sh
    ushort* comb_bf  = dispT_bf + 8388608;                   // 8388608 sh
    ushort* xs_bf    = comb_bf + 8388608;                    // 6291456 sh
    ushort* h_bf     = xs_bf + 6291456;                      // 16777216 sh
    ushort* xnT_bf   = h_bf + 16777216;                      // 6291456 sh
    ushort* ysT_bf   = xnT_bf + 6291456;                     // 6291456 sh
    float*  stats    = (float*)(ysT_bf + 6291456);
    float* pmax      = stats;                 // 128*1024 = 131072
    float* psum      = pmax + 131072;         // 131072
    float* csum      = psum + 131072;         // 24576
    float* cmad      = csum + 24576;          // 24576
    float* Wbuf      = cmad + 24576;          // 24576
    float* ccnt      = Wbuf + 24576;          // 64
    float* cntpart   = ccnt + 64;             // SLICES*NEXP = 4096
    float* spart     = cntpart + 4096;        // SLICES*NEXP*DD = 3145728
    float* mpart     = spart + 3145728;       // 3145728
    float* ys        = xn;                    // alias: xn f32 dead after apply_W

    float* out_y    = out;
    float* out_mix  = out + 6291456;
    float* out_clus = out + 6291456 + 65536;

    norm_x<<<BMT, 256, 0, stream>>>(x, xn);
    norm_phi_T<<<NP, 256, 0, stream>>>(phi, scale, phT_hi, phT_lo);

    cluster_sum<<<dim3(3, SLICES), 256, 0, stream>>>(xn, ca, spart, cntpart);
    reduce_parts<<<96, 256, 0, stream>>>(spart, csum, cntpart, ccnt, 1);
    cluster_mad<<<dim3(3, SLICES), 256, 0, stream>>>(xn, ca, csum, ccnt, mpart);
    reduce_parts<<<96, 256, 0, stream>>>(mpart, cmad, nullptr, nullptr, 0);
    compute_W<<<1, 1024, 0, stream>>>(cmad, ccnt, Wbuf);
    apply_W<<<BMT, 192, 0, stream>>>(xn, ca, Wbuf, xnp_hi, xnp_lo);

    // xnT_bf[b][768][1024] = transpose(bf16(xn)) — B operand for xs SINGLE GEMM
    make_T<false><<<dim3(12, 16, NB), 256, 0, stream>>>(xnp_hi, xnT_bf, MTOK, DD);

    // logits = xn . phin  (split-pair 3-MFMA; fused per-tile column stats)
    gemm2<1, 0, 0, false, 0, true><<<dim3(8, 128, 1), 256, 0, stream>>>(
        xnp_hi, xnp_lo, nullptr, phT_hi, phT_lo, logits, nullptr,
        DD, DD, DD, NP, 0, 0, 0, nullptr, 0, pmax, psum);

    // top-8 + mixing weights + comb softmax (fused, one logits read)
    row_topk<<<BMT, 64, 0, stream>>>(logits, out_mix, out_clus, comb_bf);
    make_dispT<<<dim3(16, 16, NB), 256, 0, stream>>>(logits, pmax, psum, dispT_bf);

    // xs[b] = dispT . xn[b] -> bf16  (SINGLE 512thr BM=256)
    gemm2<0, 0, 0, true, 0, false><<<dim3(6, 4, NB), 512, 0, stream>>>(
        dispT_bf, nullptr, nullptr, xnT_bf, nullptr, nullptr, xs_bf,
        MTOK, MTOK, MTOK, DD,
        (long)NP * MTOK, (long)DD * MTOK, (long)NP * DD, nullptr, 0, nullptr, nullptr);

    // h[n] = gelu(xs_rows(n) . w1[n] + b1[n]) -> bf16  (BF32 512thr BM=256)
    gemm2<2, 1, 2, true, 0, false><<<dim3(16, 1, NEXP), 512, 0, stream>>>(
        xs_bf, nullptr, w1, nullptr, nullptr, nullptr, h_bf,
        DD, DD, HH, HH,
        0, (long)DD * HH, (long)256 * HH, b1, HH, nullptr, nullptr);

    // ys = h_rows(n) . w2[n] + b2[n] -> f32 [b][np][768] (BF32 512thr BM=256)
    gemm2<2, 0, 1, false, 1, false><<<dim3(6, 1, NEXP), 512, 0, stream>>>(
        h_bf, nullptr, w2, nullptr, nullptr, ys, nullptr,
        HH, HH, DD, DD,
        (long)256 * HH, (long)HH * DD, 0, b2, DD, nullptr, nullptr);

    // ysT_bf[b][768][1024] = transpose(bf16(ys)) — B operand for y SINGLE GEMM
    make_T<true><<<dim3(12, 16, NB), 256, 0, stream>>>(ys, ysT_bf, MTOK, DD);

    // y[b] = comb . ys[b] -> f32 out  (SINGLE 512thr BM=256)
    gemm2<0, 0, 0, false, 0, false><<<dim3(6, 4, NB), 512, 0, stream>>>(
        comb_bf, nullptr, nullptr, ysT_bf, nullptr, out_y, nullptr,
        NP, NP, NP, DD,
        (long)MTOK * NP, (long)DD * NP, (long)MTOK * DD, nullptr, 0, nullptr, nullptr);
}

// Round 17
// 455.839 us; speedup vs baseline: 1.3422x; 1.0037x over previous
//
#include <hip/hip_runtime.h>
#include <cmath>

// ---------------- problem constants ----------------
// B=8, M=1024, D=768, N=32, P=32, K=8, H=2048
#define NB    8
#define MTOK  1024
#define BMT   8192      // B*M
#define DD    768
#define NEXP  32
#define PSLOT 32
#define NP    1024      // N*P
#define KTOP  8
#define HH    2048

#define SLICES 128      // partial-sum slices for cluster stats
#define TPS    64       // tokens per slice (SLICES*TPS == BMT)

typedef unsigned short ushort;
typedef __attribute__((ext_vector_type(8))) short short8v;   // 8 bf16 = 4 VGPR
typedef __attribute__((ext_vector_type(4))) short short4v;   // 8 bytes
typedef __attribute__((ext_vector_type(4))) float f32x4;

__device__ __forceinline__ ushort bf16_rne(float x) {
    unsigned u = __float_as_uint(x);
    unsigned r = (u + 0x7FFFu + ((u >> 16) & 1u)) >> 16;
    return (ushort)r;
}
__device__ __forceinline__ float bf16_to_f(ushort h) {
    return __uint_as_float(((unsigned)h) << 16);
}
__device__ __forceinline__ void split2(float x, ushort& hi, ushort& lo) {
    hi = bf16_rne(x);
    lo = bf16_rne(x - bf16_to_f(hi));
}
// HW packed f32->bf16 (RNE): dst[15:0]=cvt(a), dst[31:16]=cvt(b)
__device__ __forceinline__ unsigned cvt_pk_bf16(float a, float b) {
    unsigned r;
    asm volatile("v_cvt_pk_bf16_f32 %0, %1, %2" : "=v"(r) : "v"(a), "v"(b));
    return r;
}

// async global->LDS, 16B per lane; lds dest is wave-uniform base + lane*16
__device__ __forceinline__ void gl_lds16(const ushort* g, ushort* l) {
    __builtin_amdgcn_global_load_lds(
        (const __attribute__((address_space(1))) void*)g,
        (__attribute__((address_space(3))) void*)l, 16, 0, 0);
}

// ---------------- K1: token L2 normalize ----------------
__global__ __launch_bounds__(256) void norm_x(const float* __restrict__ x, float* __restrict__ xn) {
    int tok = blockIdx.x;
    int t = threadIdx.x;
    const float* p = x + (long)tok * DD;
    float v0 = p[t], v1 = p[t + 256], v2 = p[t + 512];
    float ss = v0 * v0 + v1 * v1 + v2 * v2;
#pragma unroll
    for (int o = 32; o; o >>= 1) ss += __shfl_xor(ss, o);
    __shared__ float sred[4];
    if ((t & 63) == 0) sred[t >> 6] = ss;
    __syncthreads();
    ss = sred[0] + sred[1] + sred[2] + sred[3];
    float inv = 1.0f / fmaxf(sqrtf(ss), 1e-12f);
    float* q = xn + (long)tok * DD;
    q[t] = v0 * inv; q[t + 256] = v1 * inv; q[t + 512] = v2 * inv;
}

// ---------------- K2: phi normalize -> transposed split pair [np][d] ----------------
__global__ __launch_bounds__(256) void norm_phi_T(const float* __restrict__ phi, const float* __restrict__ scale,
                                                  ushort* __restrict__ phT_hi, ushort* __restrict__ phT_lo) {
    int np = blockIdx.x;           // 1024 blocks
    int t = threadIdx.x;
    float ss = 0.f;
    for (int d = t; d < DD; d += 256) {
        float v = phi[(long)d * NP + np];
        ss += v * v;
    }
#pragma unroll
    for (int o = 32; o; o >>= 1) ss += __shfl_xor(ss, o);
    __shared__ float sred[4];
    if ((t & 63) == 0) sred[t >> 6] = ss;
    __syncthreads();
    ss = sred[0] + sred[1] + sred[2] + sred[3];
    float sc = scale[0] / fmaxf(sqrtf(ss), 1e-12f);
    for (int d = t; d < DD; d += 256) {
        float v = phi[(long)d * NP + np] * sc;
        ushort h, l; split2(v, h, l);
        phT_hi[(long)np * DD + d] = h;
        phT_lo[(long)np * DD + d] = l;
    }
}

// ---------------- K3: per-cluster sums (deterministic partials, 128 slices) ----------------
__global__ __launch_bounds__(256) void cluster_sum(const float* __restrict__ xn, const int* __restrict__ ca,
                                                   float* __restrict__ spart, float* __restrict__ cntpart) {
    __shared__ float s[NEXP][256];
    __shared__ float cnt[NEXP];
    int chunk = blockIdx.x, slice = blockIdx.y, t = threadIdx.x;
#pragma unroll
    for (int n = 0; n < NEXP; ++n) s[n][t] = 0.f;
    if (t < NEXP) cnt[t] = 0.f;
    __syncthreads();
    int tok0 = slice * TPS;
    for (int i = 0; i < TPS; ++i) {
        int tok = tok0 + i;
        int a = ca[tok * KTOP];
        float v = xn[(long)tok * DD + chunk * 256 + t];
        s[a][t] += v;
        if (chunk == 0 && t == 0) cnt[a] += 1.f;
    }
    __syncthreads();
    for (int n = 0; n < NEXP; ++n)
        spart[(long)slice * (NEXP * DD) + n * DD + chunk * 256 + t] = s[n][t];
    if (chunk == 0 && t < NEXP) cntpart[slice * NEXP + t] = cnt[t];
}

__global__ __launch_bounds__(256) void reduce_parts(const float* __restrict__ part, float* __restrict__ outv,
                                                    const float* __restrict__ cntpart, float* __restrict__ ccnt,
                                                    int doCnt) {
    int i = blockIdx.x * 256 + threadIdx.x;
    float s = 0.f;
#pragma unroll 8
    for (int sl = 0; sl < SLICES; ++sl) s += part[(long)sl * (NEXP * DD) + i];
    outv[i] = s;
    if (doCnt && i < NEXP) {
        float c = 0.f;
#pragma unroll 8
        for (int sl = 0; sl < SLICES; ++sl) c += cntpart[sl * NEXP + i];
        ccnt[i] = c;
    }
}

// ---------------- K4: per-cluster MAD partials ----------------
__global__ __launch_bounds__(256) void cluster_mad(const float* __restrict__ xn, const int* __restrict__ ca,
                                                   const float* __restrict__ csum, const float* __restrict__ ccnt,
                                                   float* __restrict__ mpart) {
    __shared__ float md[NEXP][256];
    __shared__ float mean[NEXP][256];
    int chunk = blockIdx.x, slice = blockIdx.y, t = threadIdx.x;
#pragma unroll
    for (int n = 0; n < NEXP; ++n) {
        float c = ccnt[n];
        mean[n][t] = (c > 0.f) ? csum[n * DD + chunk * 256 + t] / c : 0.f;
        md[n][t] = 0.f;
    }
    __syncthreads();
    int tok0 = slice * TPS;
    for (int i = 0; i < TPS; ++i) {
        int tok = tok0 + i;
        int a = ca[tok * KTOP];
        float v = xn[(long)tok * DD + chunk * 256 + t];
        md[a][t] += fabsf(v - mean[a][t]);
    }
    __syncthreads();
    for (int n = 0; n < NEXP; ++n)
        mpart[(long)slice * (NEXP * DD) + n * DD + chunk * 256 + t] = md[n][t];
}

// ---------------- K5: W = normalize(clamp(1/(mad+0.35))) ----------------
__global__ __launch_bounds__(1024) void compute_W(const float* __restrict__ cmad, const float* __restrict__ ccnt,
                                                  float* __restrict__ W) {
    __shared__ float s[16];
    int t = threadIdx.x;
    auto block_sum = [&](float v) -> float {
#pragma unroll
        for (int o = 32; o; o >>= 1) v += __shfl_xor(v, o);
        if ((t & 63) == 0) s[t >> 6] = v;
        __syncthreads();
        float tot = 0.f;
#pragma unroll
        for (int i = 0; i < 16; ++i) tot += s[i];
        __syncthreads();
        return tot;
    };
    const int TOT = NEXP * DD;
    float p = 0.f;
    for (int i = t; i < TOT; i += 1024) {
        int n = i / DD;
        float c = ccnt[n];
        float wm = (c > 0.f) ? cmad[i] / c : 0.f;
        p += 1.f / (wm + 0.35f);
    }
    float mean1 = block_sum(p) / (float)TOT;
    float clamp = 5.f * mean1;
    p = 0.f;
    for (int i = t; i < TOT; i += 1024) {
        int n = i / DD;
        float c = ccnt[n];
        float wm = (c > 0.f) ? cmad[i] / c : 0.f;
        p += fminf(1.f / (wm + 0.35f), clamp);
    }
    float mean2 = block_sum(p) / (float)TOT;
    float inv2 = 1.f / mean2;
    for (int i = t; i < TOT; i += 1024) {
        int n = i / DD;
        float c = ccnt[n];
        float wm = (c > 0.f) ? cmad[i] / c : 0.f;
        W[i] = fminf(1.f / (wm + 0.35f), clamp) * inv2;
    }
}

// ---------------- K6: emit bf16 hi/lo pair of xn*W (xn f32 store is dead -> removed) ----------------
__global__ __launch_bounds__(192) void apply_W(const float* __restrict__ xn, const int* __restrict__ ca,
                                               const float* __restrict__ W,
                                               ushort* __restrict__ hi, ushort* __restrict__ lo) {
    int tok = blockIdx.x;
    long d4 = (long)tok * DD + threadIdx.x * 4;
    int a = ca[tok * KTOP];
    float4 v = *reinterpret_cast<const float4*>(xn + d4);
    float4 w = *reinterpret_cast<const float4*>(W + a * DD + threadIdx.x * 4);
    v.x *= w.x; v.y *= w.y; v.z *= w.z; v.w *= w.w;
    ushort h0,h1,h2,h3,l0,l1,l2,l3;
    split2(v.x,h0,l0); split2(v.y,h1,l1); split2(v.z,h2,l2); split2(v.w,h3,l3);
    *reinterpret_cast<short4v*>(hi + d4) = short4v{(short)h0,(short)h1,(short)h2,(short)h3};
    *reinterpret_cast<short4v*>(lo + d4) = short4v{(short)l0,(short)l1,(short)l2,(short)l3};
}

// ---------------- K7: 64x64 tiled transpose -> bf16 [z][C][R] from [z][R][C] ----------------
template <bool F32>
__global__ __launch_bounds__(256) void make_T(const void* __restrict__ srcv, ushort* __restrict__ dst,
                                              int R, int C) {
    __shared__ ushort tile[64][65];
    int z = blockIdx.z;
    int c0 = blockIdx.x * 64, r0 = blockIdx.y * 64;
    int tr = threadIdx.x >> 4;          // 0..15
    int tc4 = (threadIdx.x & 15) * 4;
    long base = (long)z * R * C;
#pragma unroll
    for (int i = 0; i < 4; ++i) {
        int r = tr + i * 16;
        if constexpr (F32) {
            const float* s = (const float*)srcv;
            float4 v = *reinterpret_cast<const float4*>(s + base + (long)(r0 + r) * C + c0 + tc4);
            tile[r][tc4 + 0] = bf16_rne(v.x); tile[r][tc4 + 1] = bf16_rne(v.y);
            tile[r][tc4 + 2] = bf16_rne(v.z); tile[r][tc4 + 3] = bf16_rne(v.w);
        } else {
            const ushort* s = (const ushort*)srcv;
            short4v v = *reinterpret_cast<const short4v*>(s + base + (long)(r0 + r) * C + c0 + tc4);
            tile[r][tc4 + 0] = (ushort)v.x; tile[r][tc4 + 1] = (ushort)v.y;
            tile[r][tc4 + 2] = (ushort)v.z; tile[r][tc4 + 3] = (ushort)v.w;
        }
    }
    __syncthreads();
#pragma unroll
    for (int i = 0; i < 4; ++i) {
        int oc = tr + i * 16;
        short4v o = short4v{(short)tile[tc4 + 0][oc], (short)tile[tc4 + 1][oc],
                            (short)tile[tc4 + 2][oc], (short)tile[tc4 + 3][oc]};
        *reinterpret_cast<short4v*>(dst + base + (long)(c0 + oc) * R + r0 + tc4) = o;
    }
}

// ---------------- MFMA GEMM, 3-buffer LDS ring (72 KB all modes) ----------------
// MODE 0 SINGLE: 512 thr, BM=256, A(2)+B(1) bf16 gl_lds/thread, 1 MFMA.   vmcnt(3)
// MODE 1 PAIR:   256 thr, BM=64, A/B hi/lo pairs gl_lds, 3 MFMA.          vmcnt(6)
// MODE 2 BF32:   512 thr, BM=256, A(2) gl_lds + B f32 2 loads/thread ->
//                cvt_pk -> swizzled ds_write, depth-2.                    vmcnt(4)
// CSTAT (PAIR logits): epilogue column max/exp-sum partials per 64-row tile.
// Swizzle: 16B slot sp of row r stored at sp ^ ((r>>1)&3) -> 2-way reads (free).
// AMAP: 0 linear z-strided, 1 token remap.  EPI: 0/1 bias/2 bias+gelu.
// CBF16: round C to bf16.  CMAP: 0 lin, 1 token remap.
template <int MODE, int AMAP, int EPI, bool CBF16, int CMAP, bool CSTAT>
__global__ __launch_bounds__((MODE == 1) ? 256 : 512) void gemm2(
    const ushort* __restrict__ Ah_g, const ushort* __restrict__ Al_g,
    const float*  __restrict__ Bf_g,
    const ushort* __restrict__ Bh_g, const ushort* __restrict__ Bl_g,
    float* __restrict__ Cf, ushort* __restrict__ Cb,
    int K, int lda, int ldb, int ldc,
    long sA, long sB, long sC,
    const float* __restrict__ bias, int biasStride,
    float* __restrict__ pmaxO, float* __restrict__ psumO) {
    constexpr bool PAIR = (MODE == 1);
    constexpr int THR  = PAIR ? 256 : 512;
    constexpr int BUFS = 12288;              // shorts per buffer, all modes
    constexpr int BOFF = PAIR ? 4096 : 8192; // B region offset in buffer
    constexpr int BM   = PAIR ? 64 : 256;
    constexpr int MI   = PAIR ? 2 : 4;
    __shared__ __attribute__((aligned(16))) ushort lds[3 * BUFS];

    // XCD-aware bijective remap (all grids multiples of 8)
    int orig = blockIdx.x + gridDim.x * (blockIdx.y + gridDim.y * blockIdx.z);
    int nwg = gridDim.x * gridDim.y * gridDim.z;
    int wg = (orig & 7) * (nwg >> 3) + (orig >> 3);
    int bx = wg % gridDim.x;
    int rest = wg / gridDim.x;
    int by = rest % gridDim.y;
    int z  = rest / gridDim.y;
    const int m0 = by * BM;
    const int n0 = bx * 128;

    const int tid = threadIdx.x, lane = tid & 63, w = tid >> 6;
    const int wr = w >> 1, wc = w & 1;       // PAIR: 2x2 of 32x64; else 4x2 of 64x64
    const int lr = lane & 15, kh = lane >> 4;

    // ---- A staging coords (chunk c: r=c>>2 row, sp=c&3 16B slot)
    const int NCA = PAIR ? 1 : 2;
    long arowA[2]; int kOffA[2];
#pragma unroll
    for (int i = 0; i < NCA; ++i) {
        int c = i * THR + tid;
        int r = c >> 2, sp = c & 3;
        kOffA[i] = (sp ^ ((r >> 1) & 3)) << 3;
        int rg = m0 + r;
        if constexpr (AMAP == 0) arowA[i] = (long)z * sA + (long)rg * lda;
        else arowA[i] = ((long)(rg >> 5) * 1024 + (long)z * 32 + (rg & 31)) * (long)lda;
    }
    // ---- B staging coords (gl_lds modes): 128 rows x 4 slots = 512 chunks
    long browB[2]; int kOffB[2];
#pragma unroll
    for (int i = 0; i < 2; ++i) {
        int c = i * 256 + tid;               // MODE1: 2 chunks/thr; MODE0: c=tid (i=0)
        if (c < 512) {
            int r = c >> 2, sp = c & 3;
            kOffB[i] = (sp ^ ((r >> 1) & 3)) << 3;
            browB[i] = (long)z * sB + (long)(n0 + r) * ldb;
        }
    }
    // ---- BF32 B reg-staging coords: 2 float4/thread (kqh: 2 k-rows, nq: 4 cols)
    const int kqh = tid & 15, nq = tid >> 4;

    f32x4 acc[MI][4];
#pragma unroll
    for (int i = 0; i < MI; ++i)
#pragma unroll
        for (int j = 0; j < 4; ++j) acc[i][j] = (f32x4)(0.f);

    auto stageA = [&](int buf, int kk0) {
        const int bb = buf * BUFS;
        if constexpr (MODE == 1) {
            gl_lds16(Ah_g + arowA[0] + kk0 + kOffA[0], &lds[bb + (w * 64) * 8]);
            gl_lds16(Al_g + arowA[0] + kk0 + kOffA[0], &lds[bb + 2048 + (w * 64) * 8]);
#pragma unroll
            for (int i = 0; i < 2; ++i) {
                int base = bb + 4096 + (i * 256 + w * 64) * 8;
                gl_lds16(Bh_g + browB[i] + kk0 + kOffB[i], &lds[base]);
                gl_lds16(Bl_g + browB[i] + kk0 + kOffB[i], &lds[base + 4096]);
            }
        } else if constexpr (MODE == 0) {
#pragma unroll
            for (int i = 0; i < 2; ++i)
                gl_lds16(Ah_g + arowA[i] + kk0 + kOffA[i], &lds[bb + (i * THR + w * 64) * 8]);
            gl_lds16(Bh_g + browB[0] + kk0 + kOffB[0], &lds[bb + BOFF + (w * 64) * 8]);
        } else {
#pragma unroll
            for (int i = 0; i < 2; ++i)
                gl_lds16(Ah_g + arowA[i] + kk0 + kOffA[i], &lds[bb + (i * THR + w * 64) * 8]);
        }
    };

    auto loadB = [&](float4 (&rB)[2], int kk0) {
#pragma unroll
        for (int dk = 0; dk < 2; ++dk)
            rB[dk] = *reinterpret_cast<const float4*>(
                Bf_g + (long)z * sB + (long)(kk0 + kqh * 2 + dk) * ldb + n0 + nq * 4);
    };

    // packed HW cvt: per dn, (k, k+1) -> one uint, swizzled 4B store
    auto bwrite = [&](int buf, float4 (&rB)[2]) {
        unsigned p[4];
        p[0] = cvt_pk_bf16(rB[0].x, rB[1].x);
        p[1] = cvt_pk_bf16(rB[0].y, rB[1].y);
        p[2] = cvt_pk_bf16(rB[0].z, rB[1].z);
        p[3] = cvt_pk_bf16(rB[0].w, rB[1].w);
        int k = kqh * 2;
        int s = k >> 3, kin = k & 7;
#pragma unroll
        for (int dn = 0; dn < 4; ++dn) {
            int n = nq * 4 + dn;
            int phys = s ^ ((n >> 1) & 3);
            int off = buf * BUFS + BOFF + n * 32 + phys * 8 + kin;
            *reinterpret_cast<unsigned*>(&lds[off]) = p[dn];
        }
    };

    auto compute = [&](int buf) {
        const int aB = buf * BUFS;
        const int bB = buf * BUFS + BOFF;
        short8v bh[4], bl[4];
#pragma unroll
        for (int nj = 0; nj < 4; ++nj) {
            int rb = wc * 64 + nj * 16 + lr;
            int off = bB + rb * 32 + ((kh ^ ((rb >> 1) & 3)) << 3);
            bh[nj] = *reinterpret_cast<const short8v*>(&lds[off]);
            if constexpr (PAIR) bl[nj] = *reinterpret_cast<const short8v*>(&lds[off + 4096]);
        }
#pragma unroll
        for (int mi = 0; mi < MI; ++mi) {
            int ra = wr * (PAIR ? 32 : 64) + mi * 16 + lr;
            int off = aB + ra * 32 + ((kh ^ ((ra >> 1) & 3)) << 3);
            short8v ah = *reinterpret_cast<const short8v*>(&lds[off]);
            if constexpr (PAIR) {
                short8v al = *reinterpret_cast<const short8v*>(&lds[off + 2048]);
#pragma unroll
                for (int nj = 0; nj < 4; ++nj) {
                    acc[mi][nj] = __builtin_amdgcn_mfma_f32_16x16x32_bf16(ah, bh[nj], acc[mi][nj], 0, 0, 0);
                    acc[mi][nj] = __builtin_amdgcn_mfma_f32_16x16x32_bf16(ah, bl[nj], acc[mi][nj], 0, 0, 0);
                    acc[mi][nj] = __builtin_amdgcn_mfma_f32_16x16x32_bf16(al, bh[nj], acc[mi][nj], 0, 0, 0);
                }
            } else {
#pragma unroll
                for (int nj = 0; nj < 4; ++nj)
                    acc[mi][nj] = __builtin_amdgcn_mfma_f32_16x16x32_bf16(ah, bh[nj], acc[mi][nj], 0, 0, 0);
            }
        }
    };

    const int nt = K >> 5;
    if constexpr (MODE == 0 || MODE == 1) {
        stageA(0, 0);
        stageA(1, 32);
        if constexpr (MODE == 1) { asm volatile("s_waitcnt vmcnt(6)" ::: "memory"); }
        else                     { asm volatile("s_waitcnt vmcnt(3)" ::: "memory"); }
        __builtin_amdgcn_s_barrier();
        __builtin_amdgcn_sched_barrier(0);
        int cc = 0, cn2 = 2;
        for (int t = 0; t < nt; ++t) {
            bool deep = (t + 2 < nt);
            if (deep) stageA(cn2, (t + 2) << 5);
            compute(cc);
            if (deep) {
                if constexpr (MODE == 1) { asm volatile("s_waitcnt vmcnt(6)" ::: "memory"); }
                else                     { asm volatile("s_waitcnt vmcnt(3)" ::: "memory"); }
            } else {
                asm volatile("s_waitcnt vmcnt(0)" ::: "memory");
            }
            if (t + 1 < nt) {
                __builtin_amdgcn_s_barrier();
                __builtin_amdgcn_sched_barrier(0);
            }
            cc = (cc == 2) ? 0 : cc + 1;
            cn2 = (cn2 == 2) ? 0 : cn2 + 1;
        }
    } else {
        // ---- depth-2, 3-buf ring
        float4 rBa[2], rBb[2];
        loadB(rBa, 0);
        bwrite(0, rBa);                      // implicit wait on rBa only
        stageA(0, 0);
        stageA(1, 32);
        loadB(rBb, 32);
        asm volatile("s_waitcnt vmcnt(4) lgkmcnt(0)" ::: "memory");
        __builtin_amdgcn_s_barrier();
        __builtin_amdgcn_sched_barrier(0);
        int cc = 0, cn1 = 1, cn2 = 2;
        auto iter = [&](int t, float4 (&ld)[2], float4 (&wr_)[2]) {
            bool deep = (t + 2 < nt);
            if (deep) { stageA(cn2, (t + 2) << 5); loadB(ld, (t + 2) << 5); }
            compute(cc);
            if (t + 1 < nt) bwrite(cn1, wr_);    // implicit wait drains B(t+1), A(t+1)
            if (deep) { asm volatile("s_waitcnt vmcnt(4) lgkmcnt(0)" ::: "memory"); }
            else      { asm volatile("s_waitcnt vmcnt(0) lgkmcnt(0)" ::: "memory"); }
            if (t + 1 < nt) {
                __builtin_amdgcn_s_barrier();
                __builtin_amdgcn_sched_barrier(0);
            }
            cc = (cc == 2) ? 0 : cc + 1;
            cn1 = (cn1 == 2) ? 0 : cn1 + 1;
            cn2 = (cn2 == 2) ? 0 : cn2 + 1;
        };
        for (int t = 0; t < nt; t += 2) {    // nt even at all call sites
            iter(t, rBa, rBb);
            iter(t + 1, rBb, rBa);
        }
    }

    // ---- epilogue: C write
#pragma unroll
    for (int mi = 0; mi < MI; ++mi)
#pragma unroll
        for (int j = 0; j < 4; ++j) {
            int rg = m0 + wr * (PAIR ? 32 : 64) + mi * 16 + kh * 4 + j;
            long roff;
            if constexpr (CMAP == 1) roff = ((long)(rg >> 5) * 1024 + (long)z * 32 + (rg & 31)) * (long)ldc;
            else                     roff = (long)z * sC + (long)rg * ldc;
#pragma unroll
            for (int nj = 0; nj < 4; ++nj) {
                int col = n0 + wc * 64 + nj * 16 + lr;
                float v = acc[mi][nj][j];
                if constexpr (EPI >= 1) v += bias[(long)z * biasStride + col];
                if constexpr (EPI == 2) v = 0.5f * v * (1.0f + erff(v * 0.70710678118654752f));
                if constexpr (CBF16) Cb[roff + col] = bf16_rne(v);
                else                 Cf[roff + col] = v;
            }
        }

    // ---- epilogue: fused column stats over this 64-row tile (PAIR/logits only)
    if constexpr (CSTAT) {
        float* red = (float*)lds;            // [2 wr][2 wc][16 lr][4 nj]
        __syncthreads();                     // K-loop LDS dead; all waves done
        float tmax[4];
#pragma unroll
        for (int nj = 0; nj < 4; ++nj) {
            float m = acc[0][nj][0];
#pragma unroll
            for (int mi = 0; mi < MI; ++mi)
#pragma unroll
                for (int j = 0; j < 4; ++j) m = fmaxf(m, acc[mi][nj][j]);
            m = fmaxf(m, __shfl_xor(m, 16));     // reduce over kh bit0
            m = fmaxf(m, __shfl_xor(m, 32));     // reduce over kh bit1
            tmax[nj] = m;
        }
        if (kh == 0) {
#pragma unroll
            for (int nj = 0; nj < 4; ++nj)
                red[((wr * 2 + wc) * 16 + lr) * 4 + nj] = tmax[nj];
        }
        __syncthreads();
        float tsum[4];
#pragma unroll
        for (int nj = 0; nj < 4; ++nj) {
            float m = fmaxf(red[((0 * 2 + wc) * 16 + lr) * 4 + nj],
                            red[((1 * 2 + wc) * 16 + lr) * 4 + nj]);
            tmax[nj] = m;
            float s = 0.f;
#pragma unroll
            for (int mi = 0; mi < MI; ++mi)
#pragma unroll
                for (int j = 0; j < 4; ++j) s += __expf(acc[mi][nj][j] - m);
            s += __shfl_xor(s, 16);
            s += __shfl_xor(s, 32);
            tsum[nj] = s;
        }
        __syncthreads();
        if (kh == 0) {
#pragma unroll
            for (int nj = 0; nj < 4; ++nj)
                red[((wr * 2 + wc) * 16 + lr) * 4 + nj] = tsum[nj];
        }
        __syncthreads();
        if (w < 2 && kh == 0) {              // wr==0 waves write 128 cols total
#pragma unroll
            for (int nj = 0; nj < 4; ++nj) {
                int col = n0 + wc * 64 + nj * 16 + lr;
                float stot = red[((0 * 2 + wc) * 16 + lr) * 4 + nj] +
                             red[((1 * 2 + wc) * 16 + lr) * 4 + nj];
                pmaxO[(long)by * NP + col] = tmax[nj];
                psumO[(long)by * NP + col] = stot;
            }
        }
    }
}

// ---------------- K8: per-row top-8 + comb softmax (fused) ----------------
__global__ __launch_bounds__(64) void row_topk(const float* __restrict__ logits,
                                               float* __restrict__ mix_out, float* __restrict__ clus_out,
                                               ushort* __restrict__ comb) {
    int row = blockIdx.x;
    int lane = threadIdx.x;
    const float* p = logits + (long)row * NP;
    float v[16];
#pragma unroll
    for (int i = 0; i < 16; ++i) v[i] = p[lane + i * 64];
    float mx = v[0];
#pragma unroll
    for (int i = 1; i < 16; ++i) mx = fmaxf(mx, v[i]);
#pragma unroll
    for (int o = 32; o; o >>= 1) mx = fmaxf(mx, __shfl_xor(mx, o));
    float s = 0.f;
#pragma unroll
    for (int i = 0; i < 16; ++i) s += __expf(v[i] - mx);
#pragma unroll
    for (int o = 32; o; o >>= 1) s += __shfl_xor(s, o);
    float inv = 1.0f / s;
    ushort* crow = comb + (long)row * NP;
#pragma unroll
    for (int i = 0; i < 16; ++i)
        crow[lane + i * 64] = bf16_rne(__expf(v[i] - mx) * inv);
#pragma unroll
    for (int k = 0; k < KTOP; ++k) {
        float bv = -INFINITY; int bi = 1 << 30;
#pragma unroll
        for (int i = 0; i < 16; ++i) {
            if (v[i] > bv) { bv = v[i]; bi = lane + i * 64; }
        }
#pragma unroll
        for (int o = 32; o; o >>= 1) {
            float ov = __shfl_xor(bv, o); int oi = __shfl_xor(bi, o);
            if (ov > bv || (ov == bv && oi < bi)) { bv = ov; bi = oi; }
        }
        int owner = bi & 63, slot = bi >> 6;
        if (lane == owner) {
#pragma unroll
            for (int i = 0; i < 16; ++i) if (slot == i) v[i] = -INFINITY;
        }
        if (lane == k) {
            mix_out[(long)row * KTOP + k] = bv;
            clus_out[(long)row * KTOP + k] = (float)(bi >> 5);
        }
    }
}

// ---------------- K10: dispT bf16 = softmax-over-m(logits)^T (merges 16 tile partials) ----------------
__global__ __launch_bounds__(256) void make_dispT(const float* __restrict__ logits,
                                                  const float* __restrict__ pmax, const float* __restrict__ psum,
                                                  ushort* __restrict__ dispT) {
    __shared__ float tile[64][65];
    __shared__ float smax[64], sinv[64];
    int b = blockIdx.z, np0 = blockIdx.x * 64, m0 = blockIdx.y * 64;
    int tr = threadIdx.x >> 6, tc = threadIdx.x & 63;
    if (threadIdx.x < 64) {
        int np = np0 + threadIdx.x;
        float mx = -INFINITY;
#pragma unroll
        for (int ms = 0; ms < 16; ++ms) mx = fmaxf(mx, pmax[((long)(b * 16 + ms)) * NP + np]);
        float s = 0.f;
#pragma unroll
        for (int ms = 0; ms < 16; ++ms) {
            long o = ((long)(b * 16 + ms)) * NP + np;
            s += psum[o] * __expf(pmax[o] - mx);
        }
        smax[threadIdx.x] = mx;
        sinv[threadIdx.x] = 1.0f / s;
    }
    const float* src = logits + ((long)b * MTOK + m0) * NP + np0;
#pragma unroll
    for (int i = 0; i < 16; ++i) {
        int m = tr * 16 + i;
        tile[m][tc] = src[(long)m * NP + tc];
    }
    __syncthreads();
#pragma unroll
    for (int i = 0; i < 16; ++i) {
        int npl = tr * 16 + i;
        float v = __expf(tile[tc][npl] - smax[npl]) * sinv[npl];
        dispT[((long)b * NP + np0 + npl) * MTOK + (m0 + tc)] = bf16_rne(v);
    }
}

// ---------------- launch ----------------
extern "C" void kernel_launch(void* const* d_in, const int* in_sizes, int n_in,
                              void* d_out, int out_size, void* d_ws, size_t ws_size,
                              hipStream_t stream) {
    const float* x    = (const float*)d_in[0];
    const int*   ca   = (const int*)d_in[1];
    const float* phi  = (const float*)d_in[2];
    const float* scale= (const float*)d_in[3];
    const float* w1   = (const float*)d_in[4];
    const float* b1   = (const float*)d_in[5];
    const float* w2   = (const float*)d_in[6];
    const float* b2   = (const float*)d_in[7];
    float* out = (float*)d_out;
    float* ws  = (float*)d_ws;

    float*  xn       = ws;                                   // 6291456 f32
    float*  logits   = xn + 6291456;                         // 8388608 f32
    ushort* xnp_hi   = (ushort*)(logits + 8388608);          // 6291456 sh
    ushort* xnp_lo   = xnp_hi + 6291456;                     // 6291456 sh
    ushort* phT_hi   = xnp_lo + 6291456;                     // 786432 sh
    ushort* phT_lo   = phT_hi + 786432;                      // 786432 sh
    ushort* dispT_bf = phT_lo + 786432;                      // 8388608 sh
    ushort* comb_bf  = dispT_bf + 8388608;                   // 8388608 sh
    ushort* xs_bf    = comb_bf + 8388608;                    // 6291456 sh
    ushort* h_bf     = xs_bf + 6291456;                      // 16777216 sh
    ushort* xnT_bf   = h_bf + 16777216;                      // 6291456 sh
    ushort* ysT_bf   = xnT_bf + 6291456;                     // 6291456 sh
    float*  stats    = (float*)(ysT_bf + 6291456);
    float* pmax      = stats;                 // 128*1024 = 131072
    float* psum      = pmax + 131072;         // 131072
    float* csum      = psum + 131072;         // 24576
    float* cmad      = csum + 24576;          // 24576
    float* Wbuf      = cmad + 24576;          // 24576
    float* ccnt      = Wbuf + 24576;          // 64
    float* cntpart   = ccnt + 64;             // SLICES*NEXP = 4096
    float* spart     = cntpart + 4096;        // SLICES*NEXP*DD = 3145728
    float* mpart     = spart + 3145728;       // 3145728
    float* ys        = xn;                    // alias: xn f32 dead after apply_W

    float* out_y    = out;
    float* out_mix  = out + 6291456;
    float* out_clus = out + 6291456 + 65536;

    norm_x<<<BMT, 256, 0, stream>>>(x, xn);
    norm_phi_T<<<NP, 256, 0, stream>>>(phi, scale, phT_hi, phT_lo);

    cluster_sum<<<dim3(3, SLICES), 256, 0, stream>>>(xn, ca, spart, cntpart);
    reduce_parts<<<96, 256, 0, stream>>>(spart, csum, cntpart, ccnt, 1);
    cluster_mad<<<dim3(3, SLICES), 256, 0, stream>>>(xn, ca, csum, ccnt, mpart);
    reduce_parts<<<96, 256, 0, stream>>>(mpart, cmad, nullptr, nullptr, 0);
    compute_W<<<1, 1024, 0, stream>>>(cmad, ccnt, Wbuf);
    apply_W<<<BMT, 192, 0, stream>>>(xn, ca, Wbuf, xnp_hi, xnp_lo);

    // xnT_bf[b][768][1024] = transpose(bf16(xn)) — B operand for xs SINGLE GEMM
    make_T<false><<<dim3(12, 16, NB), 256, 0, stream>>>(xnp_hi, xnT_bf, MTOK, DD);

    // logits = xn . phin  (split-pair 3-MFMA; fused per-tile column stats)
    gemm2<1, 0, 0, false, 0, true><<<dim3(8, 128, 1), 256, 0, stream>>>(
        xnp_hi, xnp_lo, nullptr, phT_hi, phT_lo, logits, nullptr,
        DD, DD, DD, NP, 0, 0, 0, nullptr, 0, pmax, psum);

    // top-8 + mixing weights + comb softmax (fused, one logits read)
    row_topk<<<BMT, 64, 0, stream>>>(logits, out_mix, out_clus, comb_bf);
    make_dispT<<<dim3(16, 16, NB), 256, 0, stream>>>(logits, pmax, psum, dispT_bf);

    // xs[b] = dispT . xn[b] -> bf16  (SINGLE 512thr BM=256)
    gemm2<0, 0, 0, true, 0, false><<<dim3(6, 4, NB), 512, 0, stream>>>(
        dispT_bf, nullptr, nullptr, xnT_bf, nullptr, nullptr, xs_bf,
        MTOK, MTOK, MTOK, DD,
        (long)NP * MTOK, (long)DD * MTOK, (long)NP * DD, nullptr, 0, nullptr, nullptr);

    // h[n] = gelu(xs_rows(n) . w1[n] + b1[n]) -> bf16  (BF32 512thr BM=256)
    gemm2<2, 1, 2, true, 0, false><<<dim3(16, 1, NEXP), 512, 0, stream>>>(
        xs_bf, nullptr, w1, nullptr, nullptr, nullptr, h_bf,
        DD, DD, HH, HH,
        0, (long)DD * HH, (long)256 * HH, b1, HH, nullptr, nullptr);

    // ys = h_rows(n) . w2[n] + b2[n] -> f32 [b][np][768] (BF32 512thr BM=256)
    gemm2<2, 0, 1, false, 1, false><<<dim3(6, 1, NEXP), 512, 0, stream>>>(
        h_bf, nullptr, w2, nullptr, nullptr, ys, nullptr,
        HH, HH, DD, DD,
        (long)256 * HH, (long)HH * DD, 0, b2, DD, nullptr, nullptr);

    // ysT_bf[b][768][1024] = transpose(bf16(ys)) — B operand for y SINGLE GEMM
    make_T<true><<<dim3(12, 16, NB), 256, 0, stream>>>(ys, ysT_bf, MTOK, DD);

    // y[b] = comb . ys[b] -> f32 out  (SINGLE 512thr BM=256)
    gemm2<0, 0, 0, false, 0, false><<<dim3(6, 4, NB), 512, 0, stream>>>(
        comb_bf, nullptr, nullptr, ysT_bf, nullptr, out_y, nullptr,
        NP, NP, NP, DD,
        (long)MTOK * NP, (long)DD * NP, (long)MTOK * DD, nullptr, 0, nullptr, nullptr);
}

// Round 18
// 447.280 us; speedup vs baseline: 1.3678x; 1.0191x over previous
//
#include <hip/hip_runtime.h>
#include <cmath>

// ---------------- problem constants ----------------
// B=8, M=1024, D=768, N=32, P=32, K=8, H=2048
#define NB    8
#define MTOK  1024
#define BMT   8192      // B*M
#define DD    768
#define NEXP  32
#define PSLOT 32
#define NP    1024      // N*P
#define KTOP  8
#define HH    2048

#define SLICES 128      // partial-sum slices for cluster stats
#define TPS    64       // tokens per slice (SLICES*TPS == BMT)

typedef unsigned short ushort;
typedef __attribute__((ext_vector_type(8))) short short8v;   // 8 bf16 = 4 VGPR
typedef __attribute__((ext_vector_type(4))) short short4v;   // 8 bytes
typedef __attribute__((ext_vector_type(4))) float f32x4;

__device__ __forceinline__ ushort bf16_rne(float x) {
    unsigned u = __float_as_uint(x);
    unsigned r = (u + 0x7FFFu + ((u >> 16) & 1u)) >> 16;
    return (ushort)r;
}
__device__ __forceinline__ float bf16_to_f(ushort h) {
    return __uint_as_float(((unsigned)h) << 16);
}
__device__ __forceinline__ void split2(float x, ushort& hi, ushort& lo) {
    hi = bf16_rne(x);
    lo = bf16_rne(x - bf16_to_f(hi));
}
// HW packed f32->bf16 (RNE): dst[15:0]=cvt(a), dst[31:16]=cvt(b)
__device__ __forceinline__ unsigned cvt_pk_bf16(float a, float b) {
    unsigned r;
    asm volatile("v_cvt_pk_bf16_f32 %0, %1, %2" : "=v"(r) : "v"(a), "v"(b));
    return r;
}

// async global->LDS, 16B per lane; lds dest is wave-uniform base + lane*16
__device__ __forceinline__ void gl_lds16(const ushort* g, ushort* l) {
    __builtin_amdgcn_global_load_lds(
        (const __attribute__((address_space(1))) void*)g,
        (__attribute__((address_space(3))) void*)l, 16, 0, 0);
}

// ---------------- K1: token L2 normalize ----------------
__global__ __launch_bounds__(256) void norm_x(const float* __restrict__ x, float* __restrict__ xn) {
    int tok = blockIdx.x;
    int t = threadIdx.x;
    const float* p = x + (long)tok * DD;
    float v0 = p[t], v1 = p[t + 256], v2 = p[t + 512];
    float ss = v0 * v0 + v1 * v1 + v2 * v2;
#pragma unroll
    for (int o = 32; o; o >>= 1) ss += __shfl_xor(ss, o);
    __shared__ float sred[4];
    if ((t & 63) == 0) sred[t >> 6] = ss;
    __syncthreads();
    ss = sred[0] + sred[1] + sred[2] + sred[3];
    float inv = 1.0f / fmaxf(sqrtf(ss), 1e-12f);
    float* q = xn + (long)tok * DD;
    q[t] = v0 * inv; q[t + 256] = v1 * inv; q[t + 512] = v2 * inv;
}

// ---------------- K2: phi normalize -> transposed split pair [np][d] ----------------
__global__ __launch_bounds__(256) void norm_phi_T(const float* __restrict__ phi, const float* __restrict__ scale,
                                                  ushort* __restrict__ phT_hi, ushort* __restrict__ phT_lo) {
    int np = blockIdx.x;           // 1024 blocks
    int t = threadIdx.x;
    float ss = 0.f;
    for (int d = t; d < DD; d += 256) {
        float v = phi[(long)d * NP + np];
        ss += v * v;
    }
#pragma unroll
    for (int o = 32; o; o >>= 1) ss += __shfl_xor(ss, o);
    __shared__ float sred[4];
    if ((t & 63) == 0) sred[t >> 6] = ss;
    __syncthreads();
    ss = sred[0] + sred[1] + sred[2] + sred[3];
    float sc = scale[0] / fmaxf(sqrtf(ss), 1e-12f);
    for (int d = t; d < DD; d += 256) {
        float v = phi[(long)d * NP + np] * sc;
        ushort h, l; split2(v, h, l);
        phT_hi[(long)np * DD + d] = h;
        phT_lo[(long)np * DD + d] = l;
    }
}

// ---------------- K3: per-cluster sums (deterministic partials, 128 slices) ----------------
__global__ __launch_bounds__(256) void cluster_sum(const float* __restrict__ xn, const int* __restrict__ ca,
                                                   float* __restrict__ spart, float* __restrict__ cntpart) {
    __shared__ float s[NEXP][256];
    __shared__ float cnt[NEXP];
    int chunk = blockIdx.x, slice = blockIdx.y, t = threadIdx.x;
#pragma unroll
    for (int n = 0; n < NEXP; ++n) s[n][t] = 0.f;
    if (t < NEXP) cnt[t] = 0.f;
    __syncthreads();
    int tok0 = slice * TPS;
    for (int i = 0; i < TPS; ++i) {
        int tok = tok0 + i;
        int a = ca[tok * KTOP];
        float v = xn[(long)tok * DD + chunk * 256 + t];
        s[a][t] += v;
        if (chunk == 0 && t == 0) cnt[a] += 1.f;
    }
    __syncthreads();
    for (int n = 0; n < NEXP; ++n)
        spart[(long)slice * (NEXP * DD) + n * DD + chunk * 256 + t] = s[n][t];
    if (chunk == 0 && t < NEXP) cntpart[slice * NEXP + t] = cnt[t];
}

__global__ __launch_bounds__(256) void reduce_parts(const float* __restrict__ part, float* __restrict__ outv,
                                                    const float* __restrict__ cntpart, float* __restrict__ ccnt,
                                                    int doCnt) {
    int i = blockIdx.x * 256 + threadIdx.x;
    float s = 0.f;
#pragma unroll 8
    for (int sl = 0; sl < SLICES; ++sl) s += part[(long)sl * (NEXP * DD) + i];
    outv[i] = s;
    if (doCnt && i < NEXP) {
        float c = 0.f;
#pragma unroll 8
        for (int sl = 0; sl < SLICES; ++sl) c += cntpart[sl * NEXP + i];
        ccnt[i] = c;
    }
}

// ---------------- K4: per-cluster MAD partials ----------------
__global__ __launch_bounds__(256) void cluster_mad(const float* __restrict__ xn, const int* __restrict__ ca,
                                                   const float* __restrict__ csum, const float* __restrict__ ccnt,
                                                   float* __restrict__ mpart) {
    __shared__ float md[NEXP][256];
    __shared__ float mean[NEXP][256];
    int chunk = blockIdx.x, slice = blockIdx.y, t = threadIdx.x;
#pragma unroll
    for (int n = 0; n < NEXP; ++n) {
        float c = ccnt[n];
        mean[n][t] = (c > 0.f) ? csum[n * DD + chunk * 256 + t] / c : 0.f;
        md[n][t] = 0.f;
    }
    __syncthreads();
    int tok0 = slice * TPS;
    for (int i = 0; i < TPS; ++i) {
        int tok = tok0 + i;
        int a = ca[tok * KTOP];
        float v = xn[(long)tok * DD + chunk * 256 + t];
        md[a][t] += fabsf(v - mean[a][t]);
    }
    __syncthreads();
    for (int n = 0; n < NEXP; ++n)
        mpart[(long)slice * (NEXP * DD) + n * DD + chunk * 256 + t] = md[n][t];
}

// ---------------- K5: W = normalize(clamp(1/(mad+0.35))) ----------------
__global__ __launch_bounds__(1024) void compute_W(const float* __restrict__ cmad, const float* __restrict__ ccnt,
                                                  float* __restrict__ W) {
    __shared__ float s[16];
    int t = threadIdx.x;
    auto block_sum = [&](float v) -> float {
#pragma unroll
        for (int o = 32; o; o >>= 1) v += __shfl_xor(v, o);
        if ((t & 63) == 0) s[t >> 6] = v;
        __syncthreads();
        float tot = 0.f;
#pragma unroll
        for (int i = 0; i < 16; ++i) tot += s[i];
        __syncthreads();
        return tot;
    };
    const int TOT = NEXP * DD;
    float p = 0.f;
    for (int i = t; i < TOT; i += 1024) {
        int n = i / DD;
        float c = ccnt[n];
        float wm = (c > 0.f) ? cmad[i] / c : 0.f;
        p += 1.f / (wm + 0.35f);
    }
    float mean1 = block_sum(p) / (float)TOT;
    float clamp = 5.f * mean1;
    p = 0.f;
    for (int i = t; i < TOT; i += 1024) {
        int n = i / DD;
        float c = ccnt[n];
        float wm = (c > 0.f) ? cmad[i] / c : 0.f;
        p += fminf(1.f / (wm + 0.35f), clamp);
    }
    float mean2 = block_sum(p) / (float)TOT;
    float inv2 = 1.f / mean2;
    for (int i = t; i < TOT; i += 1024) {
        int n = i / DD;
        float c = ccnt[n];
        float wm = (c > 0.f) ? cmad[i] / c : 0.f;
        W[i] = fminf(1.f / (wm + 0.35f), clamp) * inv2;
    }
}

// ---------------- K6: emit bf16 hi/lo pair of xn*W ----------------
__global__ __launch_bounds__(192) void apply_W(const float* __restrict__ xn, const int* __restrict__ ca,
                                               const float* __restrict__ W,
                                               ushort* __restrict__ hi, ushort* __restrict__ lo) {
    int tok = blockIdx.x;
    long d4 = (long)tok * DD + threadIdx.x * 4;
    int a = ca[tok * KTOP];
    float4 v = *reinterpret_cast<const float4*>(xn + d4);
    float4 w = *reinterpret_cast<const float4*>(W + a * DD + threadIdx.x * 4);
    v.x *= w.x; v.y *= w.y; v.z *= w.z; v.w *= w.w;
    ushort h0,h1,h2,h3,l0,l1,l2,l3;
    split2(v.x,h0,l0); split2(v.y,h1,l1); split2(v.z,h2,l2); split2(v.w,h3,l3);
    *reinterpret_cast<short4v*>(hi + d4) = short4v{(short)h0,(short)h1,(short)h2,(short)h3};
    *reinterpret_cast<short4v*>(lo + d4) = short4v{(short)l0,(short)l1,(short)l2,(short)l3};
}

// ---------------- K7: 64x64 tiled transpose -> bf16 [z][C][R] from [z][R][C] ----------------
template <bool F32>
__global__ __launch_bounds__(256) void make_T(const void* __restrict__ srcv, ushort* __restrict__ dst,
                                              int R, int C) {
    __shared__ ushort tile[64][65];
    int z = blockIdx.z;
    int c0 = blockIdx.x * 64, r0 = blockIdx.y * 64;
    int tr = threadIdx.x >> 4;          // 0..15
    int tc4 = (threadIdx.x & 15) * 4;
    long base = (long)z * R * C;
#pragma unroll
    for (int i = 0; i < 4; ++i) {
        int r = tr + i * 16;
        if constexpr (F32) {
            const float* s = (const float*)srcv;
            float4 v = *reinterpret_cast<const float4*>(s + base + (long)(r0 + r) * C + c0 + tc4);
            tile[r][tc4 + 0] = bf16_rne(v.x); tile[r][tc4 + 1] = bf16_rne(v.y);
            tile[r][tc4 + 2] = bf16_rne(v.z); tile[r][tc4 + 3] = bf16_rne(v.w);
        } else {
            const ushort* s = (const ushort*)srcv;
            short4v v = *reinterpret_cast<const short4v*>(s + base + (long)(r0 + r) * C + c0 + tc4);
            tile[r][tc4 + 0] = (ushort)v.x; tile[r][tc4 + 1] = (ushort)v.y;
            tile[r][tc4 + 2] = (ushort)v.z; tile[r][tc4 + 3] = (ushort)v.w;
        }
    }
    __syncthreads();
#pragma unroll
    for (int i = 0; i < 4; ++i) {
        int oc = tr + i * 16;
        short4v o = short4v{(short)tile[tc4 + 0][oc], (short)tile[tc4 + 1][oc],
                            (short)tile[tc4 + 2][oc], (short)tile[tc4 + 3][oc]};
        *reinterpret_cast<short4v*>(dst + base + (long)(c0 + oc) * R + r0 + tc4) = o;
    }
}

// ---------------- MFMA GEMM, 3-buffer LDS ring (72 KB all modes) ----------------
// MODE 0 SINGLE: 512 thr, BM=256, A(2)+B(1) bf16 gl_lds/thread, 1 MFMA.   vmcnt(3)
// MODE 1 PAIR:   256 thr, BM=64, A/B hi/lo pairs gl_lds, 3 MFMA.          vmcnt(6)
// MODE 2 BF32:   512 thr, BM=256, A(2) gl_lds + B f32 2 loads/thread ->
//                cvt_pk -> swizzled ds_write, depth-2.                    vmcnt(4)
// CSTAT (PAIR logits): epilogue column max/exp-sum partials per 64-row tile.
// CT (ys GEMM): transposed bf16 C write ysT[b][col][z*32+slot] (+bias).
// Swizzle: 16B slot sp of row r stored at sp ^ ((r>>1)&3) -> 2-way reads (free).
// AMAP: 0 linear z-strided, 1 token remap.  EPI: 0/1 bias/2 bias+gelu.
// CBF16: round C to bf16.  CMAP: 0 lin, 1 token remap.
template <int MODE, int AMAP, int EPI, bool CBF16, int CMAP, bool CSTAT, bool CT = false>
__global__ __launch_bounds__((MODE == 1) ? 256 : 512) void gemm2(
    const ushort* __restrict__ Ah_g, const ushort* __restrict__ Al_g,
    const float*  __restrict__ Bf_g,
    const ushort* __restrict__ Bh_g, const ushort* __restrict__ Bl_g,
    float* __restrict__ Cf, ushort* __restrict__ Cb,
    int K, int lda, int ldb, int ldc,
    long sA, long sB, long sC,
    const float* __restrict__ bias, int biasStride,
    float* __restrict__ pmaxO, float* __restrict__ psumO) {
    constexpr bool PAIR = (MODE == 1);
    constexpr int THR  = PAIR ? 256 : 512;
    constexpr int BUFS = 12288;              // shorts per buffer, all modes
    constexpr int BOFF = PAIR ? 4096 : 8192; // B region offset in buffer
    constexpr int BM   = PAIR ? 64 : 256;
    constexpr int MI   = PAIR ? 2 : 4;
    __shared__ __attribute__((aligned(16))) ushort lds[3 * BUFS];

    // XCD-aware bijective remap (all grids multiples of 8)
    int orig = blockIdx.x + gridDim.x * (blockIdx.y + gridDim.y * blockIdx.z);
    int nwg = gridDim.x * gridDim.y * gridDim.z;
    int wg = (orig & 7) * (nwg >> 3) + (orig >> 3);
    int bx = wg % gridDim.x;
    int rest = wg / gridDim.x;
    int by = rest % gridDim.y;
    int z  = rest / gridDim.y;
    const int m0 = by * BM;
    const int n0 = bx * 128;

    const int tid = threadIdx.x, lane = tid & 63, w = tid >> 6;
    const int wr = w >> 1, wc = w & 1;       // PAIR: 2x2 of 32x64; else 4x2 of 64x64
    const int lr = lane & 15, kh = lane >> 4;

    // ---- A staging coords (chunk c: r=c>>2 row, sp=c&3 16B slot)
    const int NCA = PAIR ? 1 : 2;
    long arowA[2]; int kOffA[2];
#pragma unroll
    for (int i = 0; i < NCA; ++i) {
        int c = i * THR + tid;
        int r = c >> 2, sp = c & 3;
        kOffA[i] = (sp ^ ((r >> 1) & 3)) << 3;
        int rg = m0 + r;
        if constexpr (AMAP == 0) arowA[i] = (long)z * sA + (long)rg * lda;
        else arowA[i] = ((long)(rg >> 5) * 1024 + (long)z * 32 + (rg & 31)) * (long)lda;
    }
    // ---- B staging coords (gl_lds modes): 128 rows x 4 slots = 512 chunks
    long browB[2]; int kOffB[2];
#pragma unroll
    for (int i = 0; i < 2; ++i) {
        int c = i * 256 + tid;               // MODE1: 2 chunks/thr; MODE0: c=tid (i=0)
        if (c < 512) {
            int r = c >> 2, sp = c & 3;
            kOffB[i] = (sp ^ ((r >> 1) & 3)) << 3;
            browB[i] = (long)z * sB + (long)(n0 + r) * ldb;
        }
    }
    // ---- BF32 B reg-staging coords: 2 float4/thread (kqh: 2 k-rows, nq: 4 cols)
    const int kqh = tid & 15, nq = tid >> 4;

    f32x4 acc[MI][4];
#pragma unroll
    for (int i = 0; i < MI; ++i)
#pragma unroll
        for (int j = 0; j < 4; ++j) acc[i][j] = (f32x4)(0.f);

    auto stageA = [&](int buf, int kk0) {
        const int bb = buf * BUFS;
        if constexpr (MODE == 1) {
            gl_lds16(Ah_g + arowA[0] + kk0 + kOffA[0], &lds[bb + (w * 64) * 8]);
            gl_lds16(Al_g + arowA[0] + kk0 + kOffA[0], &lds[bb + 2048 + (w * 64) * 8]);
#pragma unroll
            for (int i = 0; i < 2; ++i) {
                int base = bb + 4096 + (i * 256 + w * 64) * 8;
                gl_lds16(Bh_g + browB[i] + kk0 + kOffB[i], &lds[base]);
                gl_lds16(Bl_g + browB[i] + kk0 + kOffB[i], &lds[base + 4096]);
            }
        } else if constexpr (MODE == 0) {
#pragma unroll
            for (int i = 0; i < 2; ++i)
                gl_lds16(Ah_g + arowA[i] + kk0 + kOffA[i], &lds[bb + (i * THR + w * 64) * 8]);
            gl_lds16(Bh_g + browB[0] + kk0 + kOffB[0], &lds[bb + BOFF + (w * 64) * 8]);
        } else {
#pragma unroll
            for (int i = 0; i < 2; ++i)
                gl_lds16(Ah_g + arowA[i] + kk0 + kOffA[i], &lds[bb + (i * THR + w * 64) * 8]);
        }
    };

    auto loadB = [&](float4 (&rB)[2], int kk0) {
#pragma unroll
        for (int dk = 0; dk < 2; ++dk)
            rB[dk] = *reinterpret_cast<const float4*>(
                Bf_g + (long)z * sB + (long)(kk0 + kqh * 2 + dk) * ldb + n0 + nq * 4);
    };

    // packed HW cvt: per dn, (k, k+1) -> one uint, swizzled 4B store
    auto bwrite = [&](int buf, float4 (&rB)[2]) {
        unsigned p[4];
        p[0] = cvt_pk_bf16(rB[0].x, rB[1].x);
        p[1] = cvt_pk_bf16(rB[0].y, rB[1].y);
        p[2] = cvt_pk_bf16(rB[0].z, rB[1].z);
        p[3] = cvt_pk_bf16(rB[0].w, rB[1].w);
        int k = kqh * 2;
        int s = k >> 3, kin = k & 7;
#pragma unroll
        for (int dn = 0; dn < 4; ++dn) {
            int n = nq * 4 + dn;
            int phys = s ^ ((n >> 1) & 3);
            int off = buf * BUFS + BOFF + n * 32 + phys * 8 + kin;
            *reinterpret_cast<unsigned*>(&lds[off]) = p[dn];
        }
    };

    auto compute = [&](int buf) {
        const int aB = buf * BUFS;
        const int bB = buf * BUFS + BOFF;
        short8v bh[4], bl[4];
#pragma unroll
        for (int nj = 0; nj < 4; ++nj) {
            int rb = wc * 64 + nj * 16 + lr;
            int off = bB + rb * 32 + ((kh ^ ((rb >> 1) & 3)) << 3);
            bh[nj] = *reinterpret_cast<const short8v*>(&lds[off]);
            if constexpr (PAIR) bl[nj] = *reinterpret_cast<const short8v*>(&lds[off + 4096]);
        }
#pragma unroll
        for (int mi = 0; mi < MI; ++mi) {
            int ra = wr * (PAIR ? 32 : 64) + mi * 16 + lr;
            int off = aB + ra * 32 + ((kh ^ ((ra >> 1) & 3)) << 3);
            short8v ah = *reinterpret_cast<const short8v*>(&lds[off]);
            if constexpr (PAIR) {
                short8v al = *reinterpret_cast<const short8v*>(&lds[off + 2048]);
#pragma unroll
                for (int nj = 0; nj < 4; ++nj) {
                    acc[mi][nj] = __builtin_amdgcn_mfma_f32_16x16x32_bf16(ah, bh[nj], acc[mi][nj], 0, 0, 0);
                    acc[mi][nj] = __builtin_amdgcn_mfma_f32_16x16x32_bf16(ah, bl[nj], acc[mi][nj], 0, 0, 0);
                    acc[mi][nj] = __builtin_amdgcn_mfma_f32_16x16x32_bf16(al, bh[nj], acc[mi][nj], 0, 0, 0);
                }
            } else {
#pragma unroll
                for (int nj = 0; nj < 4; ++nj)
                    acc[mi][nj] = __builtin_amdgcn_mfma_f32_16x16x32_bf16(ah, bh[nj], acc[mi][nj], 0, 0, 0);
            }
        }
    };

    const int nt = K >> 5;
    if constexpr (MODE == 0 || MODE == 1) {
        stageA(0, 0);
        stageA(1, 32);
        if constexpr (MODE == 1) { asm volatile("s_waitcnt vmcnt(6)" ::: "memory"); }
        else                     { asm volatile("s_waitcnt vmcnt(3)" ::: "memory"); }
        __builtin_amdgcn_s_barrier();
        __builtin_amdgcn_sched_barrier(0);
        int cc = 0, cn2 = 2;
        for (int t = 0; t < nt; ++t) {
            bool deep = (t + 2 < nt);
            if (deep) stageA(cn2, (t + 2) << 5);
            compute(cc);
            if (deep) {
                if constexpr (MODE == 1) { asm volatile("s_waitcnt vmcnt(6)" ::: "memory"); }
                else                     { asm volatile("s_waitcnt vmcnt(3)" ::: "memory"); }
            } else {
                asm volatile("s_waitcnt vmcnt(0)" ::: "memory");
            }
            if (t + 1 < nt) {
                __builtin_amdgcn_s_barrier();
                __builtin_amdgcn_sched_barrier(0);
            }
            cc = (cc == 2) ? 0 : cc + 1;
            cn2 = (cn2 == 2) ? 0 : cn2 + 1;
        }
    } else {
        // ---- depth-2, 3-buf ring
        float4 rBa[2], rBb[2];
        loadB(rBa, 0);
        bwrite(0, rBa);                      // implicit wait on rBa only
        stageA(0, 0);
        stageA(1, 32);
        loadB(rBb, 32);
        asm volatile("s_waitcnt vmcnt(4) lgkmcnt(0)" ::: "memory");
        __builtin_amdgcn_s_barrier();
        __builtin_amdgcn_sched_barrier(0);
        int cc = 0, cn1 = 1, cn2 = 2;
        auto iter = [&](int t, float4 (&ld)[2], float4 (&wr_)[2]) {
            bool deep = (t + 2 < nt);
            if (deep) { stageA(cn2, (t + 2) << 5); loadB(ld, (t + 2) << 5); }
            compute(cc);
            if (t + 1 < nt) bwrite(cn1, wr_);    // implicit wait drains B(t+1), A(t+1)
            if (deep) { asm volatile("s_waitcnt vmcnt(4) lgkmcnt(0)" ::: "memory"); }
            else      { asm volatile("s_waitcnt vmcnt(0) lgkmcnt(0)" ::: "memory"); }
            if (t + 1 < nt) {
                __builtin_amdgcn_s_barrier();
                __builtin_amdgcn_sched_barrier(0);
            }
            cc = (cc == 2) ? 0 : cc + 1;
            cn1 = (cn1 == 2) ? 0 : cn1 + 1;
            cn2 = (cn2 == 2) ? 0 : cn2 + 1;
        };
        for (int t = 0; t < nt; t += 2) {    // nt even at all call sites
            iter(t, rBa, rBb);
            iter(t + 1, rBb, rBa);
        }
    }

    // ---- epilogue: C write
    if constexpr (CT) {
        // transposed bf16 write: ysT[b][col][z*32 + slot] ; slot=(mi&1)*16+kh*4+j
#pragma unroll
        for (int mi = 0; mi < MI; ++mi) {
            int bb = wr * 2 + (mi >> 1);
            int slot0 = (mi & 1) * 16 + kh * 4;
#pragma unroll
            for (int nj = 0; nj < 4; ++nj) {
                int col = n0 + wc * 64 + nj * 16 + lr;
                float bv = bias[(long)z * biasStride + col];
                ushort o0 = bf16_rne(acc[mi][nj][0] + bv);
                ushort o1 = bf16_rne(acc[mi][nj][1] + bv);
                ushort o2 = bf16_rne(acc[mi][nj][2] + bv);
                ushort o3 = bf16_rne(acc[mi][nj][3] + bv);
                long addr = (long)bb * (DD * MTOK) + (long)col * MTOK + z * 32 + slot0;
                *reinterpret_cast<short4v*>(Cb + addr) =
                    short4v{(short)o0, (short)o1, (short)o2, (short)o3};
            }
        }
    } else {
#pragma unroll
        for (int mi = 0; mi < MI; ++mi)
#pragma unroll
            for (int j = 0; j < 4; ++j) {
                int rg = m0 + wr * (PAIR ? 32 : 64) + mi * 16 + kh * 4 + j;
                long roff;
                if constexpr (CMAP == 1) roff = ((long)(rg >> 5) * 1024 + (long)z * 32 + (rg & 31)) * (long)ldc;
                else                     roff = (long)z * sC + (long)rg * ldc;
#pragma unroll
                for (int nj = 0; nj < 4; ++nj) {
                    int col = n0 + wc * 64 + nj * 16 + lr;
                    float v = acc[mi][nj][j];
                    if constexpr (EPI >= 1) v += bias[(long)z * biasStride + col];
                    if constexpr (EPI == 2) v = 0.5f * v * (1.0f + erff(v * 0.70710678118654752f));
                    if constexpr (CBF16) Cb[roff + col] = bf16_rne(v);
                    else                 Cf[roff + col] = v;
                }
            }
    }

    // ---- epilogue: fused column stats over this 64-row tile (PAIR/logits only)
    if constexpr (CSTAT) {
        float* red = (float*)lds;            // [2 wr][2 wc][16 lr][4 nj]
        __syncthreads();                     // K-loop LDS dead; all waves done
        float tmax[4];
#pragma unroll
        for (int nj = 0; nj < 4; ++nj) {
            float m = acc[0][nj][0];
#pragma unroll
            for (int mi = 0; mi < MI; ++mi)
#pragma unroll
                for (int j = 0; j < 4; ++j) m = fmaxf(m, acc[mi][nj][j]);
            m = fmaxf(m, __shfl_xor(m, 16));     // reduce over kh bit0
            m = fmaxf(m, __shfl_xor(m, 32));     // reduce over kh bit1
            tmax[nj] = m;
        }
        if (kh == 0) {
#pragma unroll
            for (int nj = 0; nj < 4; ++nj)
                red[((wr * 2 + wc) * 16 + lr) * 4 + nj] = tmax[nj];
        }
        __syncthreads();
        float tsum[4];
#pragma unroll
        for (int nj = 0; nj < 4; ++nj) {
            float m = fmaxf(red[((0 * 2 + wc) * 16 + lr) * 4 + nj],
                            red[((1 * 2 + wc) * 16 + lr) * 4 + nj]);
            tmax[nj] = m;
            float s = 0.f;
#pragma unroll
            for (int mi = 0; mi < MI; ++mi)
#pragma unroll
                for (int j = 0; j < 4; ++j) s += __expf(acc[mi][nj][j] - m);
            s += __shfl_xor(s, 16);
            s += __shfl_xor(s, 32);
            tsum[nj] = s;
        }
        __syncthreads();
        if (kh == 0) {
#pragma unroll
            for (int nj = 0; nj < 4; ++nj)
                red[((wr * 2 + wc) * 16 + lr) * 4 + nj] = tsum[nj];
        }
        __syncthreads();
        if (w < 2 && kh == 0) {              // wr==0 waves write 128 cols total
#pragma unroll
            for (int nj = 0; nj < 4; ++nj) {
                int col = n0 + wc * 64 + nj * 16 + lr;
                float stot = red[((0 * 2 + wc) * 16 + lr) * 4 + nj] +
                             red[((1 * 2 + wc) * 16 + lr) * 4 + nj];
                pmaxO[(long)by * NP + col] = tmax[nj];
                psumO[(long)by * NP + col] = stot;
            }
        }
    }
}

// ---------------- K8: per-row top-8 + comb softmax (fused) ----------------
__global__ __launch_bounds__(64) void row_topk(const float* __restrict__ logits,
                                               float* __restrict__ mix_out, float* __restrict__ clus_out,
                                               ushort* __restrict__ comb) {
    int row = blockIdx.x;
    int lane = threadIdx.x;
    const float* p = logits + (long)row * NP;
    float v[16];
#pragma unroll
    for (int i = 0; i < 16; ++i) v[i] = p[lane + i * 64];
    float mx = v[0];
#pragma unroll
    for (int i = 1; i < 16; ++i) mx = fmaxf(mx, v[i]);
#pragma unroll
    for (int o = 32; o; o >>= 1) mx = fmaxf(mx, __shfl_xor(mx, o));
    float s = 0.f;
#pragma unroll
    for (int i = 0; i < 16; ++i) s += __expf(v[i] - mx);
#pragma unroll
    for (int o = 32; o; o >>= 1) s += __shfl_xor(s, o);
    float inv = 1.0f / s;
    ushort* crow = comb + (long)row * NP;
#pragma unroll
    for (int i = 0; i < 16; ++i)
        crow[lane + i * 64] = bf16_rne(__expf(v[i] - mx) * inv);
#pragma unroll
    for (int k = 0; k < KTOP; ++k) {
        float bv = -INFINITY; int bi = 1 << 30;
#pragma unroll
        for (int i = 0; i < 16; ++i) {
            if (v[i] > bv) { bv = v[i]; bi = lane + i * 64; }
        }
#pragma unroll
        for (int o = 32; o; o >>= 1) {
            float ov = __shfl_xor(bv, o); int oi = __shfl_xor(bi, o);
            if (ov > bv || (ov == bv && oi < bi)) { bv = ov; bi = oi; }
        }
        int owner = bi & 63, slot = bi >> 6;
        if (lane == owner) {
#pragma unroll
            for (int i = 0; i < 16; ++i) if (slot == i) v[i] = -INFINITY;
        }
        if (lane == k) {
            mix_out[(long)row * KTOP + k] = bv;
            clus_out[(long)row * KTOP + k] = (float)(bi >> 5);
        }
    }
}

// ---------------- K10: dispT bf16 = softmax-over-m(logits)^T (merges 16 tile partials) ----------------
__global__ __launch_bounds__(256) void make_dispT(const float* __restrict__ logits,
                                                  const float* __restrict__ pmax, const float* __restrict__ psum,
                                                  ushort* __restrict__ dispT) {
    __shared__ float tile[64][65];
    __shared__ float smax[64], sinv[64];
    int b = blockIdx.z, np0 = blockIdx.x * 64, m0 = blockIdx.y * 64;
    int tr = threadIdx.x >> 6, tc = threadIdx.x & 63;
    if (threadIdx.x < 64) {
        int np = np0 + threadIdx.x;
        float mx = -INFINITY;
#pragma unroll
        for (int ms = 0; ms < 16; ++ms) mx = fmaxf(mx, pmax[((long)(b * 16 + ms)) * NP + np]);
        float s = 0.f;
#pragma unroll
        for (int ms = 0; ms < 16; ++ms) {
            long o = ((long)(b * 16 + ms)) * NP + np;
            s += psum[o] * __expf(pmax[o] - mx);
        }
        smax[threadIdx.x] = mx;
        sinv[threadIdx.x] = 1.0f / s;
    }
    const float* src = logits + ((long)b * MTOK + m0) * NP + np0;
#pragma unroll
    for (int i = 0; i < 16; ++i) {
        int m = tr * 16 + i;
        tile[m][tc] = src[(long)m * NP + tc];
    }
    __syncthreads();
#pragma unroll
    for (int i = 0; i < 16; ++i) {
        int npl = tr * 16 + i;
        float v = __expf(tile[tc][npl] - smax[npl]) * sinv[npl];
        dispT[((long)b * NP + np0 + npl) * MTOK + (m0 + tc)] = bf16_rne(v);
    }
}

// ---------------- launch ----------------
extern "C" void kernel_launch(void* const* d_in, const int* in_sizes, int n_in,
                              void* d_out, int out_size, void* d_ws, size_t ws_size,
                              hipStream_t stream) {
    const float* x    = (const float*)d_in[0];
    const int*   ca   = (const int*)d_in[1];
    const float* phi  = (const float*)d_in[2];
    const float* scale= (const float*)d_in[3];
    const float* w1   = (const float*)d_in[4];
    const float* b1   = (const float*)d_in[5];
    const float* w2   = (const float*)d_in[6];
    const float* b2   = (const float*)d_in[7];
    float* out = (float*)d_out;
    float* ws  = (float*)d_ws;

    float*  xn       = ws;                                   // 6291456 f32
    float*  logits   = xn + 6291456;                         // 8388608 f32
    ushort* xnp_hi   = (ushort*)(logits + 8388608);          // 6291456 sh
    ushort* xnp_lo   = xnp_hi + 6291456;                     // 6291456 sh
    ushort* phT_hi   = xnp_lo + 6291456;                     // 786432 sh
    ushort* phT_lo   = phT_hi + 786432;                      // 786432 sh
    ushort* dispT_bf = phT_lo + 786432;                      // 8388608 sh
    ushort* comb_bf  = dispT_bf + 8388608;                   // 8388608 sh
    ushort* xs_bf    = comb_bf + 8388608;                    // 6291456 sh
    ushort* h_bf     = xs_bf + 6291456;                      // 16777216 sh
    ushort* xnT_bf   = h_bf + 16777216;                      // 6291456 sh
    ushort* ysT_bf   = xnT_bf + 6291456;                     // 6291456 sh
    float*  stats    = (float*)(ysT_bf + 6291456);
    float* pmax      = stats;                 // 128*1024 = 131072
    float* psum      = pmax + 131072;         // 131072
    float* csum      = psum + 131072;         // 24576
    float* cmad      = csum + 24576;          // 24576
    float* Wbuf      = cmad + 24576;          // 24576
    float* ccnt      = Wbuf + 24576;          // 64
    float* cntpart   = ccnt + 64;             // SLICES*NEXP = 4096
    float* spart     = cntpart + 4096;        // SLICES*NEXP*DD = 3145728
    float* mpart     = spart + 3145728;       // 3145728

    float* out_y    = out;
    float* out_mix  = out + 6291456;
    float* out_clus = out + 6291456 + 65536;

    norm_x<<<BMT, 256, 0, stream>>>(x, xn);
    norm_phi_T<<<NP, 256, 0, stream>>>(phi, scale, phT_hi, phT_lo);

    cluster_sum<<<dim3(3, SLICES), 256, 0, stream>>>(xn, ca, spart, cntpart);
    reduce_parts<<<96, 256, 0, stream>>>(spart, csum, cntpart, ccnt, 1);
    cluster_mad<<<dim3(3, SLICES), 256, 0, stream>>>(xn, ca, csum, ccnt, mpart);
    reduce_parts<<<96, 256, 0, stream>>>(mpart, cmad, nullptr, nullptr, 0);
    compute_W<<<1, 1024, 0, stream>>>(cmad, ccnt, Wbuf);
    apply_W<<<BMT, 192, 0, stream>>>(xn, ca, Wbuf, xnp_hi, xnp_lo);

    // xnT_bf[b][768][1024] = transpose(bf16(xn)) — B operand for xs SINGLE GEMM
    make_T<false><<<dim3(12, 16, NB), 256, 0, stream>>>(xnp_hi, xnT_bf, MTOK, DD);

    // logits = xn . phin  (split-pair 3-MFMA; fused per-tile column stats)
    gemm2<1, 0, 0, false, 0, true><<<dim3(8, 128, 1), 256, 0, stream>>>(
        xnp_hi, xnp_lo, nullptr, phT_hi, phT_lo, logits, nullptr,
        DD, DD, DD, NP, 0, 0, 0, nullptr, 0, pmax, psum);

    // top-8 + mixing weights + comb softmax (fused, one logits read)
    row_topk<<<BMT, 64, 0, stream>>>(logits, out_mix, out_clus, comb_bf);
    make_dispT<<<dim3(16, 16, NB), 256, 0, stream>>>(logits, pmax, psum, dispT_bf);

    // xs[b] = dispT . xn[b] -> bf16  (SINGLE 512thr BM=256)
    gemm2<0, 0, 0, true, 0, false><<<dim3(6, 4, NB), 512, 0, stream>>>(
        dispT_bf, nullptr, nullptr, xnT_bf, nullptr, nullptr, xs_bf,
        MTOK, MTOK, MTOK, DD,
        (long)NP * MTOK, (long)DD * MTOK, (long)NP * DD, nullptr, 0, nullptr, nullptr);

    // h[n] = gelu(xs_rows(n) . w1[n] + b1[n]) -> bf16  (BF32 512thr BM=256)
    gemm2<2, 1, 2, true, 0, false><<<dim3(16, 1, NEXP), 512, 0, stream>>>(
        xs_bf, nullptr, w1, nullptr, nullptr, nullptr, h_bf,
        DD, DD, HH, HH,
        0, (long)DD * HH, (long)256 * HH, b1, HH, nullptr, nullptr);

    // ysT_bf[b][768][1024] = (h_rows(n) . w2[n] + b2[n])^T, fused transposed bf16 write
    gemm2<2, 0, 1, true, 0, false, true><<<dim3(6, 1, NEXP), 512, 0, stream>>>(
        h_bf, nullptr, w2, nullptr, nullptr, nullptr, ysT_bf,
        HH, HH, DD, DD,
        (long)256 * HH, (long)HH * DD, 0, b2, DD, nullptr, nullptr);

    // y[b] = comb . ys[b] -> f32 out  (SINGLE 512thr BM=256)
    gemm2<0, 0, 0, false, 0, false><<<dim3(6, 4, NB), 512, 0, stream>>>(
        comb_bf, nullptr, nullptr, ysT_bf, nullptr, out_y, nullptr,
        NP, NP, NP, DD,
        (long)MTOK * NP, (long)DD * NP, (long)MTOK * DD, nullptr, 0, nullptr, nullptr);
}

// Round 19
// 439.902 us; speedup vs baseline: 1.3908x; 1.0168x over previous
//
#include <hip/hip_runtime.h>
#include <cmath>

// ---------------- problem constants ----------------
// B=8, M=1024, D=768, N=32, P=32, K=8, H=2048
#define NB    8
#define MTOK  1024
#define BMT   8192      // B*M
#define DD    768
#define NEXP  32
#define PSLOT 32
#define NP    1024      // N*P
#define KTOP  8
#define HH    2048

#define SLICES 128      // partial-sum slices for cluster stats
#define TPS    64       // tokens per slice (SLICES*TPS == BMT)

typedef unsigned short ushort;
typedef __attribute__((ext_vector_type(8))) short short8v;   // 8 bf16 = 4 VGPR
typedef __attribute__((ext_vector_type(4))) short short4v;   // 8 bytes
typedef __attribute__((ext_vector_type(4))) float f32x4;

__device__ __forceinline__ ushort bf16_rne(float x) {
    unsigned u = __float_as_uint(x);
    unsigned r = (u + 0x7FFFu + ((u >> 16) & 1u)) >> 16;
    return (ushort)r;
}
__device__ __forceinline__ float bf16_to_f(ushort h) {
    return __uint_as_float(((unsigned)h) << 16);
}
__device__ __forceinline__ void split2(float x, ushort& hi, ushort& lo) {
    hi = bf16_rne(x);
    lo = bf16_rne(x - bf16_to_f(hi));
}
// HW packed f32->bf16 (RNE): dst[15:0]=cvt(a), dst[31:16]=cvt(b)
__device__ __forceinline__ unsigned cvt_pk_bf16(float a, float b) {
    unsigned r;
    asm volatile("v_cvt_pk_bf16_f32 %0, %1, %2" : "=v"(r) : "v"(a), "v"(b));
    return r;
}

// async global->LDS, 16B per lane; lds dest is wave-uniform base + lane*16
__device__ __forceinline__ void gl_lds16(const ushort* g, ushort* l) {
    __builtin_amdgcn_global_load_lds(
        (const __attribute__((address_space(1))) void*)g,
        (__attribute__((address_space(3))) void*)l, 16, 0, 0);
}

// ---------------- K1: token L2 normalize ----------------
__global__ __launch_bounds__(256) void norm_x(const float* __restrict__ x, float* __restrict__ xn) {
    int tok = blockIdx.x;
    int t = threadIdx.x;
    const float* p = x + (long)tok * DD;
    float v0 = p[t], v1 = p[t + 256], v2 = p[t + 512];
    float ss = v0 * v0 + v1 * v1 + v2 * v2;
#pragma unroll
    for (int o = 32; o; o >>= 1) ss += __shfl_xor(ss, o);
    __shared__ float sred[4];
    if ((t & 63) == 0) sred[t >> 6] = ss;
    __syncthreads();
    ss = sred[0] + sred[1] + sred[2] + sred[3];
    float inv = 1.0f / fmaxf(sqrtf(ss), 1e-12f);
    float* q = xn + (long)tok * DD;
    q[t] = v0 * inv; q[t + 256] = v1 * inv; q[t + 512] = v2 * inv;
}

// ---------------- K2: phi normalize -> transposed split pair [np][d] ----------------
__global__ __launch_bounds__(256) void norm_phi_T(const float* __restrict__ phi, const float* __restrict__ scale,
                                                  ushort* __restrict__ phT_hi, ushort* __restrict__ phT_lo) {
    int np = blockIdx.x;           // 1024 blocks
    int t = threadIdx.x;
    float ss = 0.f;
    for (int d = t; d < DD; d += 256) {
        float v = phi[(long)d * NP + np];
        ss += v * v;
    }
#pragma unroll
    for (int o = 32; o; o >>= 1) ss += __shfl_xor(ss, o);
    __shared__ float sred[4];
    if ((t & 63) == 0) sred[t >> 6] = ss;
    __syncthreads();
    ss = sred[0] + sred[1] + sred[2] + sred[3];
    float sc = scale[0] / fmaxf(sqrtf(ss), 1e-12f);
    for (int d = t; d < DD; d += 256) {
        float v = phi[(long)d * NP + np] * sc;
        ushort h, l; split2(v, h, l);
        phT_hi[(long)np * DD + d] = h;
        phT_lo[(long)np * DD + d] = l;
    }
}

// ---------------- K3: per-cluster sums (deterministic partials, 128 slices) ----------------
__global__ __launch_bounds__(256) void cluster_sum(const float* __restrict__ xn, const int* __restrict__ ca,
                                                   float* __restrict__ spart, float* __restrict__ cntpart) {
    __shared__ float s[NEXP][256];
    __shared__ float cnt[NEXP];
    int chunk = blockIdx.x, slice = blockIdx.y, t = threadIdx.x;
#pragma unroll
    for (int n = 0; n < NEXP; ++n) s[n][t] = 0.f;
    if (t < NEXP) cnt[t] = 0.f;
    __syncthreads();
    int tok0 = slice * TPS;
    for (int i = 0; i < TPS; ++i) {
        int tok = tok0 + i;
        int a = ca[tok * KTOP];
        float v = xn[(long)tok * DD + chunk * 256 + t];
        s[a][t] += v;
        if (chunk == 0 && t == 0) cnt[a] += 1.f;
    }
    __syncthreads();
    for (int n = 0; n < NEXP; ++n)
        spart[(long)slice * (NEXP * DD) + n * DD + chunk * 256 + t] = s[n][t];
    if (chunk == 0 && t < NEXP) cntpart[slice * NEXP + t] = cnt[t];
}

__global__ __launch_bounds__(256) void reduce_parts(const float* __restrict__ part, float* __restrict__ outv,
                                                    const float* __restrict__ cntpart, float* __restrict__ ccnt,
                                                    int doCnt) {
    int i = blockIdx.x * 256 + threadIdx.x;
    float s = 0.f;
#pragma unroll 8
    for (int sl = 0; sl < SLICES; ++sl) s += part[(long)sl * (NEXP * DD) + i];
    outv[i] = s;
    if (doCnt && i < NEXP) {
        float c = 0.f;
#pragma unroll 8
        for (int sl = 0; sl < SLICES; ++sl) c += cntpart[sl * NEXP + i];
        ccnt[i] = c;
    }
}

// ---------------- K4: per-cluster MAD partials ----------------
__global__ __launch_bounds__(256) void cluster_mad(const float* __restrict__ xn, const int* __restrict__ ca,
                                                   const float* __restrict__ csum, const float* __restrict__ ccnt,
                                                   float* __restrict__ mpart) {
    __shared__ float md[NEXP][256];
    __shared__ float mean[NEXP][256];
    int chunk = blockIdx.x, slice = blockIdx.y, t = threadIdx.x;
#pragma unroll
    for (int n = 0; n < NEXP; ++n) {
        float c = ccnt[n];
        mean[n][t] = (c > 0.f) ? csum[n * DD + chunk * 256 + t] / c : 0.f;
        md[n][t] = 0.f;
    }
    __syncthreads();
    int tok0 = slice * TPS;
    for (int i = 0; i < TPS; ++i) {
        int tok = tok0 + i;
        int a = ca[tok * KTOP];
        float v = xn[(long)tok * DD + chunk * 256 + t];
        md[a][t] += fabsf(v - mean[a][t]);
    }
    __syncthreads();
    for (int n = 0; n < NEXP; ++n)
        mpart[(long)slice * (NEXP * DD) + n * DD + chunk * 256 + t] = md[n][t];
}

// ---------------- K5: W = normalize(clamp(1/(mad+0.35))) ----------------
__global__ __launch_bounds__(1024) void compute_W(const float* __restrict__ cmad, const float* __restrict__ ccnt,
                                                  float* __restrict__ W) {
    __shared__ float s[16];
    int t = threadIdx.x;
    auto block_sum = [&](float v) -> float {
#pragma unroll
        for (int o = 32; o; o >>= 1) v += __shfl_xor(v, o);
        if ((t & 63) == 0) s[t >> 6] = v;
        __syncthreads();
        float tot = 0.f;
#pragma unroll
        for (int i = 0; i < 16; ++i) tot += s[i];
        __syncthreads();
        return tot;
    };
    const int TOT = NEXP * DD;
    float p = 0.f;
    for (int i = t; i < TOT; i += 1024) {
        int n = i / DD;
        float c = ccnt[n];
        float wm = (c > 0.f) ? cmad[i] / c : 0.f;
        p += 1.f / (wm + 0.35f);
    }
    float mean1 = block_sum(p) / (float)TOT;
    float clamp = 5.f * mean1;
    p = 0.f;
    for (int i = t; i < TOT; i += 1024) {
        int n = i / DD;
        float c = ccnt[n];
        float wm = (c > 0.f) ? cmad[i] / c : 0.f;
        p += fminf(1.f / (wm + 0.35f), clamp);
    }
    float mean2 = block_sum(p) / (float)TOT;
    float inv2 = 1.f / mean2;
    for (int i = t; i < TOT; i += 1024) {
        int n = i / DD;
        float c = ccnt[n];
        float wm = (c > 0.f) ? cmad[i] / c : 0.f;
        W[i] = fminf(1.f / (wm + 0.35f), clamp) * inv2;
    }
}

// ---------------- K6: fused apply_W + transpose ----------------
// block: tokens [b*1024+m0, +64) x dims [d0, +64).  Writes hi/lo row-major and
// xnT[b][d][m] (transposed hi bits) via LDS tile.  Bit-identical to old
// apply_W + make_T<false> chain.
__global__ __launch_bounds__(256) void apply_W_T(const float* __restrict__ xn, const int* __restrict__ ca,
                                                 const float* __restrict__ W,
                                                 ushort* __restrict__ hi, ushort* __restrict__ lo,
                                                 ushort* __restrict__ xnT) {
    __shared__ ushort tile[64][65];
    int b = blockIdx.z, m0 = blockIdx.y * 64, d0 = blockIdx.x * 64;
    int tr = threadIdx.x >> 4;          // 0..15
    int tc4 = (threadIdx.x & 15) * 4;
#pragma unroll
    for (int i = 0; i < 4; ++i) {
        int r = tr + i * 16;
        long tok = (long)b * MTOK + m0 + r;
        int a = ca[tok * KTOP];
        float4 v = *reinterpret_cast<const float4*>(xn + tok * DD + d0 + tc4);
        float4 w = *reinterpret_cast<const float4*>(W + (long)a * DD + d0 + tc4);
        v.x *= w.x; v.y *= w.y; v.z *= w.z; v.w *= w.w;
        ushort h0,h1,h2,h3,l0,l1,l2,l3;
        split2(v.x,h0,l0); split2(v.y,h1,l1); split2(v.z,h2,l2); split2(v.w,h3,l3);
        long o = tok * DD + d0 + tc4;
        *reinterpret_cast<short4v*>(hi + o) = short4v{(short)h0,(short)h1,(short)h2,(short)h3};
        *reinterpret_cast<short4v*>(lo + o) = short4v{(short)l0,(short)l1,(short)l2,(short)l3};
        tile[r][tc4 + 0] = h0; tile[r][tc4 + 1] = h1;
        tile[r][tc4 + 2] = h2; tile[r][tc4 + 3] = h3;
    }
    __syncthreads();
#pragma unroll
    for (int i = 0; i < 4; ++i) {
        int oc = tr + i * 16;           // dim within tile
        short4v o = short4v{(short)tile[tc4 + 0][oc], (short)tile[tc4 + 1][oc],
                            (short)tile[tc4 + 2][oc], (short)tile[tc4 + 3][oc]};
        *reinterpret_cast<short4v*>(xnT + (long)b * DD * MTOK + (long)(d0 + oc) * MTOK + m0 + tc4) = o;
    }
}

// ---------------- MFMA GEMM, 3-buffer LDS ring (72 KB all modes) ----------------
// MODE 0 SINGLE: 512 thr, BM=256, A(2)+B(1) bf16 gl_lds/thread, 1 MFMA.   vmcnt(3)
// MODE 1 PAIR:   256 thr, BM=64, A/B hi/lo pairs gl_lds, 3 MFMA.          vmcnt(6)
// MODE 2 BF32:   512 thr, BM=256, A(2) gl_lds + B f32 2 loads/thread ->
//                cvt_pk -> swizzled ds_write, depth-2.                    vmcnt(4)
// CSTAT (PAIR logits): epilogue column max/exp-sum partials per 64-row tile.
// CT (ys GEMM): transposed bf16 C write ysT[b][col][z*32+slot] (+bias).
// Swizzle: 16B slot sp of row r stored at sp ^ ((r>>1)&3) -> 2-way reads (free).
// AMAP: 0 linear z-strided, 1 token remap.  EPI: 0/1 bias/2 bias+gelu.
// CBF16: round C to bf16.  CMAP: 0 lin, 1 token remap.
template <int MODE, int AMAP, int EPI, bool CBF16, int CMAP, bool CSTAT, bool CT = false>
__global__ __launch_bounds__((MODE == 1) ? 256 : 512) void gemm2(
    const ushort* __restrict__ Ah_g, const ushort* __restrict__ Al_g,
    const float*  __restrict__ Bf_g,
    const ushort* __restrict__ Bh_g, const ushort* __restrict__ Bl_g,
    float* __restrict__ Cf, ushort* __restrict__ Cb,
    int K, int lda, int ldb, int ldc,
    long sA, long sB, long sC,
    const float* __restrict__ bias, int biasStride,
    float* __restrict__ pmaxO, float* __restrict__ psumO) {
    constexpr bool PAIR = (MODE == 1);
    constexpr int THR  = PAIR ? 256 : 512;
    constexpr int BUFS = 12288;              // shorts per buffer, all modes
    constexpr int BOFF = PAIR ? 4096 : 8192; // B region offset in buffer
    constexpr int BM   = PAIR ? 64 : 256;
    constexpr int MI   = PAIR ? 2 : 4;
    __shared__ __attribute__((aligned(16))) ushort lds[3 * BUFS];

    // XCD-aware bijective remap (all grids multiples of 8)
    int orig = blockIdx.x + gridDim.x * (blockIdx.y + gridDim.y * blockIdx.z);
    int nwg = gridDim.x * gridDim.y * gridDim.z;
    int wg = (orig & 7) * (nwg >> 3) + (orig >> 3);
    int bx = wg % gridDim.x;
    int rest = wg / gridDim.x;
    int by = rest % gridDim.y;
    int z  = rest / gridDim.y;
    const int m0 = by * BM;
    const int n0 = bx * 128;

    const int tid = threadIdx.x, lane = tid & 63, w = tid >> 6;
    const int wr = w >> 1, wc = w & 1;       // PAIR: 2x2 of 32x64; else 4x2 of 64x64
    const int lr = lane & 15, kh = lane >> 4;

    // ---- A staging coords (chunk c: r=c>>2 row, sp=c&3 16B slot)
    const int NCA = PAIR ? 1 : 2;
    long arowA[2]; int kOffA[2];
#pragma unroll
    for (int i = 0; i < NCA; ++i) {
        int c = i * THR + tid;
        int r = c >> 2, sp = c & 3;
        kOffA[i] = (sp ^ ((r >> 1) & 3)) << 3;
        int rg = m0 + r;
        if constexpr (AMAP == 0) arowA[i] = (long)z * sA + (long)rg * lda;
        else arowA[i] = ((long)(rg >> 5) * 1024 + (long)z * 32 + (rg & 31)) * (long)lda;
    }
    // ---- B staging coords (gl_lds modes): 128 rows x 4 slots = 512 chunks
    long browB[2]; int kOffB[2];
#pragma unroll
    for (int i = 0; i < 2; ++i) {
        int c = i * 256 + tid;               // MODE1: 2 chunks/thr; MODE0: c=tid (i=0)
        if (c < 512) {
            int r = c >> 2, sp = c & 3;
            kOffB[i] = (sp ^ ((r >> 1) & 3)) << 3;
            browB[i] = (long)z * sB + (long)(n0 + r) * ldb;
        }
    }
    // ---- BF32 B reg-staging coords: 2 float4/thread (kqh: 2 k-rows, nq: 4 cols)
    const int kqh = tid & 15, nq = tid >> 4;

    f32x4 acc[MI][4];
#pragma unroll
    for (int i = 0; i < MI; ++i)
#pragma unroll
        for (int j = 0; j < 4; ++j) acc[i][j] = (f32x4)(0.f);

    auto stageA = [&](int buf, int kk0) {
        const int bb = buf * BUFS;
        if constexpr (MODE == 1) {
            gl_lds16(Ah_g + arowA[0] + kk0 + kOffA[0], &lds[bb + (w * 64) * 8]);
            gl_lds16(Al_g + arowA[0] + kk0 + kOffA[0], &lds[bb + 2048 + (w * 64) * 8]);
#pragma unroll
            for (int i = 0; i < 2; ++i) {
                int base = bb + 4096 + (i * 256 + w * 64) * 8;
                gl_lds16(Bh_g + browB[i] + kk0 + kOffB[i], &lds[base]);
                gl_lds16(Bl_g + browB[i] + kk0 + kOffB[i], &lds[base + 4096]);
            }
        } else if constexpr (MODE == 0) {
#pragma unroll
            for (int i = 0; i < 2; ++i)
                gl_lds16(Ah_g + arowA[i] + kk0 + kOffA[i], &lds[bb + (i * THR + w * 64) * 8]);
            gl_lds16(Bh_g + browB[0] + kk0 + kOffB[0], &lds[bb + BOFF + (w * 64) * 8]);
        } else {
#pragma unroll
            for (int i = 0; i < 2; ++i)
                gl_lds16(Ah_g + arowA[i] + kk0 + kOffA[i], &lds[bb + (i * THR + w * 64) * 8]);
        }
    };

    auto loadB = [&](float4 (&rB)[2], int kk0) {
#pragma unroll
        for (int dk = 0; dk < 2; ++dk)
            rB[dk] = *reinterpret_cast<const float4*>(
                Bf_g + (long)z * sB + (long)(kk0 + kqh * 2 + dk) * ldb + n0 + nq * 4);
    };

    // packed HW cvt: per dn, (k, k+1) -> one uint, swizzled 4B store
    auto bwrite = [&](int buf, float4 (&rB)[2]) {
        unsigned p[4];
        p[0] = cvt_pk_bf16(rB[0].x, rB[1].x);
        p[1] = cvt_pk_bf16(rB[0].y, rB[1].y);
        p[2] = cvt_pk_bf16(rB[0].z, rB[1].z);
        p[3] = cvt_pk_bf16(rB[0].w, rB[1].w);
        int k = kqh * 2;
        int s = k >> 3, kin = k & 7;
#pragma unroll
        for (int dn = 0; dn < 4; ++dn) {
            int n = nq * 4 + dn;
            int phys = s ^ ((n >> 1) & 3);
            int off = buf * BUFS + BOFF + n * 32 + phys * 8 + kin;
            *reinterpret_cast<unsigned*>(&lds[off]) = p[dn];
        }
    };

    auto compute = [&](int buf) {
        const int aB = buf * BUFS;
        const int bB = buf * BUFS + BOFF;
        short8v bh[4], bl[4];
#pragma unroll
        for (int nj = 0; nj < 4; ++nj) {
            int rb = wc * 64 + nj * 16 + lr;
            int off = bB + rb * 32 + ((kh ^ ((rb >> 1) & 3)) << 3);
            bh[nj] = *reinterpret_cast<const short8v*>(&lds[off]);
            if constexpr (PAIR) bl[nj] = *reinterpret_cast<const short8v*>(&lds[off + 4096]);
        }
#pragma unroll
        for (int mi = 0; mi < MI; ++mi) {
            int ra = wr * (PAIR ? 32 : 64) + mi * 16 + lr;
            int off = aB + ra * 32 + ((kh ^ ((ra >> 1) & 3)) << 3);
            short8v ah = *reinterpret_cast<const short8v*>(&lds[off]);
            if constexpr (PAIR) {
                short8v al = *reinterpret_cast<const short8v*>(&lds[off + 2048]);
#pragma unroll
                for (int nj = 0; nj < 4; ++nj) {
                    acc[mi][nj] = __builtin_amdgcn_mfma_f32_16x16x32_bf16(ah, bh[nj], acc[mi][nj], 0, 0, 0);
                    acc[mi][nj] = __builtin_amdgcn_mfma_f32_16x16x32_bf16(ah, bl[nj], acc[mi][nj], 0, 0, 0);
                    acc[mi][nj] = __builtin_amdgcn_mfma_f32_16x16x32_bf16(al, bh[nj], acc[mi][nj], 0, 0, 0);
                }
            } else {
#pragma unroll
                for (int nj = 0; nj < 4; ++nj)
                    acc[mi][nj] = __builtin_amdgcn_mfma_f32_16x16x32_bf16(ah, bh[nj], acc[mi][nj], 0, 0, 0);
            }
        }
    };

    const int nt = K >> 5;
    if constexpr (MODE == 0 || MODE == 1) {
        stageA(0, 0);
        stageA(1, 32);
        if constexpr (MODE == 1) { asm volatile("s_waitcnt vmcnt(6)" ::: "memory"); }
        else                     { asm volatile("s_waitcnt vmcnt(3)" ::: "memory"); }
        __builtin_amdgcn_s_barrier();
        __builtin_amdgcn_sched_barrier(0);
        int cc = 0, cn2 = 2;
        for (int t = 0; t < nt; ++t) {
            bool deep = (t + 2 < nt);
            if (deep) stageA(cn2, (t + 2) << 5);
            compute(cc);
            if (deep) {
                if constexpr (MODE == 1) { asm volatile("s_waitcnt vmcnt(6)" ::: "memory"); }
                else                     { asm volatile("s_waitcnt vmcnt(3)" ::: "memory"); }
            } else {
                asm volatile("s_waitcnt vmcnt(0)" ::: "memory");
            }
            if (t + 1 < nt) {
                __builtin_amdgcn_s_barrier();
                __builtin_amdgcn_sched_barrier(0);
            }
            cc = (cc == 2) ? 0 : cc + 1;
            cn2 = (cn2 == 2) ? 0 : cn2 + 1;
        }
    } else {
        // ---- depth-2, 3-buf ring
        float4 rBa[2], rBb[2];
        loadB(rBa, 0);
        bwrite(0, rBa);                      // implicit wait on rBa only
        stageA(0, 0);
        stageA(1, 32);
        loadB(rBb, 32);
        asm volatile("s_waitcnt vmcnt(4) lgkmcnt(0)" ::: "memory");
        __builtin_amdgcn_s_barrier();
        __builtin_amdgcn_sched_barrier(0);
        int cc = 0, cn1 = 1, cn2 = 2;
        auto iter = [&](int t, float4 (&ld)[2], float4 (&wr_)[2]) {
            bool deep = (t + 2 < nt);
            if (deep) { stageA(cn2, (t + 2) << 5); loadB(ld, (t + 2) << 5); }
            compute(cc);
            if (t + 1 < nt) bwrite(cn1, wr_);    // implicit wait drains B(t+1), A(t+1)
            if (deep) { asm volatile("s_waitcnt vmcnt(4) lgkmcnt(0)" ::: "memory"); }
            else      { asm volatile("s_waitcnt vmcnt(0) lgkmcnt(0)" ::: "memory"); }
            if (t + 1 < nt) {
                __builtin_amdgcn_s_barrier();
                __builtin_amdgcn_sched_barrier(0);
            }
            cc = (cc == 2) ? 0 : cc + 1;
            cn1 = (cn1 == 2) ? 0 : cn1 + 1;
            cn2 = (cn2 == 2) ? 0 : cn2 + 1;
        };
        for (int t = 0; t < nt; t += 2) {    // nt even at all call sites
            iter(t, rBa, rBb);
            iter(t + 1, rBb, rBa);
        }
    }

    // ---- epilogue: C write
    if constexpr (CT) {
        // transposed bf16 write: ysT[b][col][z*32 + slot] ; slot=(mi&1)*16+kh*4+j
#pragma unroll
        for (int mi = 0; mi < MI; ++mi) {
            int bb = wr * 2 + (mi >> 1);
            int slot0 = (mi & 1) * 16 + kh * 4;
#pragma unroll
            for (int nj = 0; nj < 4; ++nj) {
                int col = n0 + wc * 64 + nj * 16 + lr;
                float bv = bias[(long)z * biasStride + col];
                ushort o0 = bf16_rne(acc[mi][nj][0] + bv);
                ushort o1 = bf16_rne(acc[mi][nj][1] + bv);
                ushort o2 = bf16_rne(acc[mi][nj][2] + bv);
                ushort o3 = bf16_rne(acc[mi][nj][3] + bv);
                long addr = (long)bb * (DD * MTOK) + (long)col * MTOK + z * 32 + slot0;
                *reinterpret_cast<short4v*>(Cb + addr) =
                    short4v{(short)o0, (short)o1, (short)o2, (short)o3};
            }
        }
    } else {
#pragma unroll
        for (int mi = 0; mi < MI; ++mi)
#pragma unroll
            for (int j = 0; j < 4; ++j) {
                int rg = m0 + wr * (PAIR ? 32 : 64) + mi * 16 + kh * 4 + j;
                long roff;
                if constexpr (CMAP == 1) roff = ((long)(rg >> 5) * 1024 + (long)z * 32 + (rg & 31)) * (long)ldc;
                else                     roff = (long)z * sC + (long)rg * ldc;
#pragma unroll
                for (int nj = 0; nj < 4; ++nj) {
                    int col = n0 + wc * 64 + nj * 16 + lr;
                    float v = acc[mi][nj][j];
                    if constexpr (EPI >= 1) v += bias[(long)z * biasStride + col];
                    if constexpr (EPI == 2) v = 0.5f * v * (1.0f + erff(v * 0.70710678118654752f));
                    if constexpr (CBF16) Cb[roff + col] = bf16_rne(v);
                    else                 Cf[roff + col] = v;
                }
            }
    }

    // ---- epilogue: fused column stats over this 64-row tile (PAIR/logits only)
    if constexpr (CSTAT) {
        float* red = (float*)lds;            // [2 wr][2 wc][16 lr][4 nj]
        __syncthreads();                     // K-loop LDS dead; all waves done
        float tmax[4];
#pragma unroll
        for (int nj = 0; nj < 4; ++nj) {
            float m = acc[0][nj][0];
#pragma unroll
            for (int mi = 0; mi < MI; ++mi)
#pragma unroll
                for (int j = 0; j < 4; ++j) m = fmaxf(m, acc[mi][nj][j]);
            m = fmaxf(m, __shfl_xor(m, 16));     // reduce over kh bit0
            m = fmaxf(m, __shfl_xor(m, 32));     // reduce over kh bit1
            tmax[nj] = m;
        }
        if (kh == 0) {
#pragma unroll
            for (int nj = 0; nj < 4; ++nj)
                red[((wr * 2 + wc) * 16 + lr) * 4 + nj] = tmax[nj];
        }
        __syncthreads();
        float tsum[4];
#pragma unroll
        for (int nj = 0; nj < 4; ++nj) {
            float m = fmaxf(red[((0 * 2 + wc) * 16 + lr) * 4 + nj],
                            red[((1 * 2 + wc) * 16 + lr) * 4 + nj]);
            tmax[nj] = m;
            float s = 0.f;
#pragma unroll
            for (int mi = 0; mi < MI; ++mi)
#pragma unroll
                for (int j = 0; j < 4; ++j) s += __expf(acc[mi][nj][j] - m);
            s += __shfl_xor(s, 16);
            s += __shfl_xor(s, 32);
            tsum[nj] = s;
        }
        __syncthreads();
        if (kh == 0) {
#pragma unroll
            for (int nj = 0; nj < 4; ++nj)
                red[((wr * 2 + wc) * 16 + lr) * 4 + nj] = tsum[nj];
        }
        __syncthreads();
        if (w < 2 && kh == 0) {              // wr==0 waves write 128 cols total
#pragma unroll
            for (int nj = 0; nj < 4; ++nj) {
                int col = n0 + wc * 64 + nj * 16 + lr;
                float stot = red[((0 * 2 + wc) * 16 + lr) * 4 + nj] +
                             red[((1 * 2 + wc) * 16 + lr) * 4 + nj];
                pmaxO[(long)by * NP + col] = tmax[nj];
                psumO[(long)by * NP + col] = stot;
            }
        }
    }
}

// ---------------- K8: per-row top-8 + comb softmax (fused) ----------------
__global__ __launch_bounds__(64) void row_topk(const float* __restrict__ logits,
                                               float* __restrict__ mix_out, float* __restrict__ clus_out,
                                               ushort* __restrict__ comb) {
    int row = blockIdx.x;
    int lane = threadIdx.x;
    const float* p = logits + (long)row * NP;
    float v[16];
#pragma unroll
    for (int i = 0; i < 16; ++i) v[i] = p[lane + i * 64];
    float mx = v[0];
#pragma unroll
    for (int i = 1; i < 16; ++i) mx = fmaxf(mx, v[i]);
#pragma unroll
    for (int o = 32; o; o >>= 1) mx = fmaxf(mx, __shfl_xor(mx, o));
    float s = 0.f;
#pragma unroll
    for (int i = 0; i < 16; ++i) s += __expf(v[i] - mx);
#pragma unroll
    for (int o = 32; o; o >>= 1) s += __shfl_xor(s, o);
    float inv = 1.0f / s;
    ushort* crow = comb + (long)row * NP;
#pragma unroll
    for (int i = 0; i < 16; ++i)
        crow[lane + i * 64] = bf16_rne(__expf(v[i] - mx) * inv);
#pragma unroll
    for (int k = 0; k < KTOP; ++k) {
        float bv = -INFINITY; int bi = 1 << 30;
#pragma unroll
        for (int i = 0; i < 16; ++i) {
            if (v[i] > bv) { bv = v[i]; bi = lane + i * 64; }
        }
#pragma unroll
        for (int o = 32; o; o >>= 1) {
            float ov = __shfl_xor(bv, o); int oi = __shfl_xor(bi, o);
            if (ov > bv || (ov == bv && oi < bi)) { bv = ov; bi = oi; }
        }
        int owner = bi & 63, slot = bi >> 6;
        if (lane == owner) {
#pragma unroll
            for (int i = 0; i < 16; ++i) if (slot == i) v[i] = -INFINITY;
        }
        if (lane == k) {
            mix_out[(long)row * KTOP + k] = bv;
            clus_out[(long)row * KTOP + k] = (float)(bi >> 5);
        }
    }
}

// ---------------- K10: dispT bf16 = softmax-over-m(logits)^T (merges 16 tile partials) ----------------
__global__ __launch_bounds__(256) void make_dispT(const float* __restrict__ logits,
                                                  const float* __restrict__ pmax, const float* __restrict__ psum,
                                                  ushort* __restrict__ dispT) {
    __shared__ float tile[64][65];
    __shared__ float smax[64], sinv[64];
    int b = blockIdx.z, np0 = blockIdx.x * 64, m0 = blockIdx.y * 64;
    int tr = threadIdx.x >> 6, tc = threadIdx.x & 63;
    if (threadIdx.x < 64) {
        int np = np0 + threadIdx.x;
        float mx = -INFINITY;
#pragma unroll
        for (int ms = 0; ms < 16; ++ms) mx = fmaxf(mx, pmax[((long)(b * 16 + ms)) * NP + np]);
        float s = 0.f;
#pragma unroll
        for (int ms = 0; ms < 16; ++ms) {
            long o = ((long)(b * 16 + ms)) * NP + np;
            s += psum[o] * __expf(pmax[o] - mx);
        }
        smax[threadIdx.x] = mx;
        sinv[threadIdx.x] = 1.0f / s;
    }
    const float* src = logits + ((long)b * MTOK + m0) * NP + np0;
#pragma unroll
    for (int i = 0; i < 16; ++i) {
        int m = tr * 16 + i;
        tile[m][tc] = src[(long)m * NP + tc];
    }
    __syncthreads();
#pragma unroll
    for (int i = 0; i < 16; ++i) {
        int npl = tr * 16 + i;
        float v = __expf(tile[tc][npl] - smax[npl]) * sinv[npl];
        dispT[((long)b * NP + np0 + npl) * MTOK + (m0 + tc)] = bf16_rne(v);
    }
}

// ---------------- launch ----------------
extern "C" void kernel_launch(void* const* d_in, const int* in_sizes, int n_in,
                              void* d_out, int out_size, void* d_ws, size_t ws_size,
                              hipStream_t stream) {
    const float* x    = (const float*)d_in[0];
    const int*   ca   = (const int*)d_in[1];
    const float* phi  = (const float*)d_in[2];
    const float* scale= (const float*)d_in[3];
    const float* w1   = (const float*)d_in[4];
    const float* b1   = (const float*)d_in[5];
    const float* w2   = (const float*)d_in[6];
    const float* b2   = (const float*)d_in[7];
    float* out = (float*)d_out;
    float* ws  = (float*)d_ws;

    float*  xn       = ws;                                   // 6291456 f32
    float*  logits   = xn + 6291456;                         // 8388608 f32
    ushort* xnp_hi   = (ushort*)(logits + 8388608);          // 6291456 sh
    ushort* xnp_lo   = xnp_hi + 6291456;                     // 6291456 sh
    ushort* phT_hi   = xnp_lo + 6291456;                     // 786432 sh
    ushort* phT_lo   = phT_hi + 786432;                      // 786432 sh
    ushort* dispT_bf = phT_lo + 786432;                      // 8388608 sh
    ushort* comb_bf  = dispT_bf + 8388608;                   // 8388608 sh
    ushort* xs_bf    = comb_bf + 8388608;                    // 6291456 sh
    ushort* h_bf     = xs_bf + 6291456;                      // 16777216 sh
    ushort* xnT_bf   = h_bf + 16777216;                      // 6291456 sh
    ushort* ysT_bf   = xnT_bf + 6291456;                     // 6291456 sh
    float*  stats    = (float*)(ysT_bf + 6291456);
    float* pmax      = stats;                 // 128*1024 = 131072
    float* psum      = pmax + 131072;         // 131072
    float* csum      = psum + 131072;         // 24576
    float* cmad      = csum + 24576;          // 24576
    float* Wbuf      = cmad + 24576;          // 24576
    float* ccnt      = Wbuf + 24576;          // 64
    float* cntpart   = ccnt + 64;             // SLICES*NEXP = 4096
    float* spart     = cntpart + 4096;        // SLICES*NEXP*DD = 3145728
    float* mpart     = spart + 3145728;       // 3145728

    float* out_y    = out;
    float* out_mix  = out + 6291456;
    float* out_clus = out + 6291456 + 65536;

    norm_x<<<BMT, 256, 0, stream>>>(x, xn);
    norm_phi_T<<<NP, 256, 0, stream>>>(phi, scale, phT_hi, phT_lo);

    cluster_sum<<<dim3(3, SLICES), 256, 0, stream>>>(xn, ca, spart, cntpart);
    reduce_parts<<<96, 256, 0, stream>>>(spart, csum, cntpart, ccnt, 1);
    cluster_mad<<<dim3(3, SLICES), 256, 0, stream>>>(xn, ca, csum, ccnt, mpart);
    reduce_parts<<<96, 256, 0, stream>>>(mpart, cmad, nullptr, nullptr, 0);
    compute_W<<<1, 1024, 0, stream>>>(cmad, ccnt, Wbuf);

    // fused: xn*W -> bf16 hi/lo pair AND xnT_bf (transposed hi), one pass
    apply_W_T<<<dim3(12, 16, NB), 256, 0, stream>>>(xn, ca, Wbuf, xnp_hi, xnp_lo, xnT_bf);

    // logits = xn . phin  (split-pair 3-MFMA; fused per-tile column stats)
    gemm2<1, 0, 0, false, 0, true><<<dim3(8, 128, 1), 256, 0, stream>>>(
        xnp_hi, xnp_lo, nullptr, phT_hi, phT_lo, logits, nullptr,
        DD, DD, DD, NP, 0, 0, 0, nullptr, 0, pmax, psum);

    // top-8 + mixing weights + comb softmax (fused, one logits read)
    row_topk<<<BMT, 64, 0, stream>>>(logits, out_mix, out_clus, comb_bf);
    make_dispT<<<dim3(16, 16, NB), 256, 0, stream>>>(logits, pmax, psum, dispT_bf);

    // xs[b] = dispT . xn[b] -> bf16  (SINGLE 512thr BM=256)
    gemm2<0, 0, 0, true, 0, false><<<dim3(6, 4, NB), 512, 0, stream>>>(
        dispT_bf, nullptr, nullptr, xnT_bf, nullptr, nullptr, xs_bf,
        MTOK, MTOK, MTOK, DD,
        (long)NP * MTOK, (long)DD * MTOK, (long)NP * DD, nullptr, 0, nullptr, nullptr);

    // h[n] = gelu(xs_rows(n) . w1[n] + b1[n]) -> bf16  (BF32 512thr BM=256)
    gemm2<2, 1, 2, true, 0, false><<<dim3(16, 1, NEXP), 512, 0, stream>>>(
        xs_bf, nullptr, w1, nullptr, nullptr, nullptr, h_bf,
        DD, DD, HH, HH,
        0, (long)DD * HH, (long)256 * HH, b1, HH, nullptr, nullptr);

    // ysT_bf[b][768][1024] = (h_rows(n) . w2[n] + b2[n])^T, fused transposed bf16 write
    gemm2<2, 0, 1, true, 0, false, true><<<dim3(6, 1, NEXP), 512, 0, stream>>>(
        h_bf, nullptr, w2, nullptr, nullptr, nullptr, ysT_bf,
        HH, HH, DD, DD,
        (long)256 * HH, (long)HH * DD, 0, b2, DD, nullptr, nullptr);

    // y[b] = comb . ys[b] -> f32 out  (SINGLE 512thr BM=256)
    gemm2<0, 0, 0, false, 0, false><<<dim3(6, 4, NB), 512, 0, stream>>>(
        comb_bf, nullptr, nullptr, ysT_bf, nullptr, out_y, nullptr,
        NP, NP, NP, DD,
        (long)MTOK * NP, (long)DD * NP, (long)MTOK * DD, nullptr, 0, nullptr, nullptr);
}